// Round 1
// baseline (518.055 us; speedup 1.0000x reference)
//
#include <hip/hip_runtime.h>

// VQ-VAE forward, MI355X round 11: R10 + convt3 moved onto matrix cores
// (per-wave parity GEMM, M=64 N=16(3 used) K=256). fp32 I/O, bf16 inters.

typedef __attribute__((ext_vector_type(8))) short     short8;
typedef __attribute__((ext_vector_type(4))) short     s16x4;
typedef __attribute__((ext_vector_type(8))) __bf16    bf16x8;
typedef __attribute__((ext_vector_type(4))) float     f32x4;

#define BATCH 32

__device__ __forceinline__ float b2f(unsigned short b) {
  union { unsigned u; float f; } v; v.u = ((unsigned)b) << 16; return v.f;
}
__device__ __forceinline__ unsigned short f2b(float f) {  // round-to-nearest-even
  union { float f; unsigned u; } v; v.f = f;
  unsigned r = v.u + 0x7FFF + ((v.u >> 16) & 1);
  return (unsigned short)(r >> 16);
}

// ---------------- weight prep: reorganize to [tap][co][ci] bf16 -------------
__global__ __launch_bounds__(256) void prep2_k(const float* __restrict__ w,
                                               unsigned short* __restrict__ wq) {
  const int i = blockIdx.x*256 + threadIdx.x;                 // 131072 exact
  const int ci = i & 63, co = (i >> 6) & 127, t = i >> 13;
  wq[i] = f2b(w[(co*64 + ci)*16 + t]);                        // ew2 OIHW(128,64,4,4)
}
__global__ __launch_bounds__(256) void prep3_k(const float* __restrict__ w,
                                               unsigned short* __restrict__ wq) {
  const int i = blockIdx.x*256 + threadIdx.x;                 // 36864 exact
  const int ci = i & 127, co = (i >> 7) & 31, t = i >> 12;
  wq[i] = f2b(w[(co*128 + ci)*9 + t]);                        // ew3 OIHW(32,128,3,3)
}
__global__ __launch_bounds__(256) void prep4_k(const float* __restrict__ w,
                                               unsigned short* __restrict__ wq) {
  const int i = blockIdx.x*256 + threadIdx.x;                 // 36864 exact
  const int ci = i & 31, co = (i >> 5) & 127, t = i >> 12;
  wq[i] = f2b(w[(ci*128 + co)*9 + (8 - t)]);                  // dw1(32,128,3,3), flipped
}
__global__ __launch_bounds__(256) void prep5_k(const float* __restrict__ w,
                                               unsigned short* __restrict__ wq) {
  const int i = blockIdx.x*256 + threadIdx.x;                 // 131072 exact
  const int ci = i & 127, co = (i >> 7) & 63, t = (i >> 13) & 3, p = i >> 15;
  const int ky = 2 - 2*(t >> 1) + (1 - (p >> 1));
  const int kx = 2 - 2*(t & 1)  + (1 - (p & 1));
  wq[i] = f2b(w[(ci*64 + co)*16 + ky*4 + kx]);                // dw2(128,64,4,4)
}
// convt3 B-frags: wq6[p][kc][lane l][j] = w[tap(a,b,p)][ci=(kc&1)*32+lk*8+j][co=lm]
__global__ __launch_bounds__(256) void prep6_k(const float* __restrict__ w,
                                               unsigned short* __restrict__ wq) {
  const int i = blockIdx.x*256 + threadIdx.x;                 // 16384 exact
  const int j = i & 7, l = (i >> 3) & 63, kc = (i >> 9) & 7, p = i >> 12;
  const int lm = l & 15, lk = l >> 4;
  const int a = kc >> 2, b = (kc >> 1) & 1, ch = kc & 1;
  const int ci = ch*32 + lk*8 + j, co = lm;
  const int py = p >> 1, px = p & 1;
  const int ky = 2 - 2*a + (1 - py), kx = 2 - 2*b + (1 - px);
  wq[i] = (co < 3) ? f2b(w[(ci*3 + co)*16 + ky*4 + kx]) : (unsigned short)0;
}

// --------- MFMA implicit-GEMM conv: NHWC in -> NHWC out (64x64 spatial) -----
template<int CIN,int COUT,int HIN,int S,int KW,int NTAPS,int OSTRIDE,int P,
         bool PARITY,bool RELU,bool INF32,bool OUTF32>
__global__ __launch_bounds__(256) void mconv_k(const void* __restrict__ in_,
    const unsigned short* __restrict__ wq_, const float* __restrict__ bias,
    void* __restrict__ out_) {
  constexpr int NF  = COUT / 16;
  constexpr int NCH = CIN / 32;
  __shared__ short Al[128*40];      // 128 rows x 32 k, stride 40 (80B, 16B-mult)
  __shared__ short Bl[COUT*40];
  int py = 0, px = 0, PY = P, PX = P;
  const unsigned short* wq = wq_;
  if (PARITY) {
    py = blockIdx.y >> 1; px = blockIdx.y & 1;
    PY = 1 - py; PX = 1 - px;
    wq += blockIdx.y * (NTAPS*COUT*CIN);
  }
  const int m0 = blockIdx.x * 128;
  const int w  = threadIdx.x >> 6, l = threadIdx.x & 63;
  const int lm = l & 15, lk = l >> 4;
  f32x4 acc[2][NF];
  #pragma unroll
  for (int mi = 0; mi < 2; ++mi)
    #pragma unroll
    for (int ni = 0; ni < NF; ++ni) acc[mi][ni] = (f32x4)0.0f;

  for (int tap = 0; tap < NTAPS; ++tap) {
    const int ky = tap / KW, kx = tap % KW;
    for (int ch = 0; ch < NCH; ++ch) {
      const int c0 = ch * 32;
      __syncthreads();                       // prev iter frag reads done
      for (int s = threadIdx.x; s < 512; s += 256) {
        const int row = s >> 2, part = s & 3;
        const int m = m0 + row;
        const int n = m >> 12, oy = (m >> 6) & 63, ox = m & 63;
        const int iy = oy*S - PY + ky, ix = ox*S - PX + kx;
        short8 v = (short8)(short)0;
        if (iy >= 0 && iy < HIN && ix >= 0 && ix < HIN) {
          const int base = ((n*HIN + iy)*HIN + ix)*CIN + c0 + part*8;
          if (INF32) {
            const float* pf = (const float*)in_ + base;
            const f32x4 f0 = *(const f32x4*)pf;
            const f32x4 f1 = *(const f32x4*)(pf + 4);
            #pragma unroll
            for (int j = 0; j < 4; ++j) {
              v[j]     = (short)f2b(f0[j]);
              v[j + 4] = (short)f2b(f1[j]);
            }
          } else {
            v = *(const short8*)((const unsigned short*)in_ + base);
          }
        }
        *(short8*)&Al[row*40 + part*8] = v;
      }
      for (int s = threadIdx.x; s < COUT*4; s += 256) {
        const int co = s >> 2, part = s & 3;
        *(short8*)&Bl[co*40 + part*8] =
            *(const short8*)(wq + (tap*COUT + co)*CIN + c0 + part*8);
      }
      __syncthreads();
      short8 av[2];
      #pragma unroll
      for (int mi = 0; mi < 2; ++mi)
        av[mi] = *(const short8*)&Al[(w*32 + mi*16 + lm)*40 + lk*8];
      #pragma unroll
      for (int ni = 0; ni < NF; ++ni) {
        const short8 bv = *(const short8*)&Bl[(ni*16 + lm)*40 + lk*8];
        #pragma unroll
        for (int mi = 0; mi < 2; ++mi)
          acc[mi][ni] = __builtin_amdgcn_mfma_f32_16x16x32_bf16(
              __builtin_bit_cast(bf16x8, av[mi]),
              __builtin_bit_cast(bf16x8, bv),
              acc[mi][ni], 0, 0, 0);
      }
    }
  }
  #pragma unroll
  for (int ni = 0; ni < NF; ++ni) {
    const int co = ni*16 + lm;
    const float bv = bias[co];
    #pragma unroll
    for (int mi = 0; mi < 2; ++mi) {
      #pragma unroll
      for (int r = 0; r < 4; ++r) {
        const int ml = w*32 + mi*16 + lk*4 + r;
        const int m  = m0 + ml;
        float vv = acc[mi][ni][r] + bv;
        if (RELU) vv = fmaxf(vv, 0.f);
        int off;
        if (OSTRIDE == 1) {
          off = m*COUT + co;
        } else {
          const int n = m >> 12, oy = (m >> 6) & 63, ox = m & 63;
          off = ((n*128 + oy*2 + py)*128 + ox*2 + px)*COUT + co;
        }
        if (OUTF32) ((float*)out_)[off] = vv;
        else ((unsigned short*)out_)[off] = f2b(vv);
      }
    }
  }
}

// ---------------- conv1: x NCHW fp32 (3ch) -> h1 NHWC bf16 [32,128,128,64] --
__global__ __launch_bounds__(256) void conv1_k(const float* __restrict__ x,
    const float* __restrict__ w, const float* __restrict__ bias,
    unsigned short* __restrict__ out) {
  __shared__ float wl[64*48];
  __shared__ float bl[64];
  for (int t = threadIdx.x; t < 3072; t += 256) wl[t] = w[t];
  if (threadIdx.x < 64) bl[threadIdx.x] = bias[threadIdx.x];
  __syncthreads();
  const int n  = blockIdx.x >> 6, oy = (blockIdx.x & 63)*2 + (threadIdx.x >> 7);
  const int ox = threadIdx.x & 127;
  float xin[48];
  #pragma unroll
  for (int ci = 0; ci < 3; ++ci)
    #pragma unroll
    for (int ky = 0; ky < 4; ++ky) {
      const int iy = oy*2 - 1 + ky;
      #pragma unroll
      for (int kx = 0; kx < 4; ++kx) {
        const int ix = ox*2 - 1 + kx;
        float v = 0.f;
        if (iy >= 0 && iy < 256 && ix >= 0 && ix < 256)
          v = x[((n*3 + ci)*256 + iy)*256 + ix];
        xin[ci*16 + ky*4 + kx] = v;
      }
    }
  const int ob = ((n*128 + oy)*128 + ox)*64;
  #pragma unroll
  for (int cb = 0; cb < 8; ++cb) {
    short8 sv;
    #pragma unroll
    for (int j = 0; j < 8; ++j) {
      const int co = cb*8 + j;
      float a = bl[co];
      #pragma unroll
      for (int q = 0; q < 12; ++q) {
        const f32x4 wv = *(const f32x4*)&wl[co*48 + q*4];
        a = fmaf(xin[q*4+0], wv[0], a);
        a = fmaf(xin[q*4+1], wv[1], a);
        a = fmaf(xin[q*4+2], wv[2], a);
        a = fmaf(xin[q*4+3], wv[3], a);
      }
      sv[j] = (short)f2b(fmaxf(a, 0.f));
    }
    *(short8*)&out[ob + cb*8] = sv;
  }
}

// ------- VQ via MFMA: z fp32 [131072,32] -> zq fp32 + loss partials ---------
__global__ __launch_bounds__(256) void vqm_k(const float* __restrict__ z,
    const float* __restrict__ embed, float* __restrict__ zq,
    float* __restrict__ partial) {
  __shared__ short Be[512*40];     // bf16 codes, pad stride 40 (40960 B)
  __shared__ float en[512];        // |e|^2 (bf16-rounded e), fp32
  __shared__ int   bidx[128];
  __shared__ float red[256];
  const int m0 = blockIdx.x * 128;
  for (int i = threadIdx.x; i < 4096; i += 256) {
    const int j = i >> 3, k0 = (i & 7) * 4;
    const f32x4 v = *(const f32x4*)&embed[j*32 + k0];
    s16x4 s;
    #pragma unroll
    for (int e = 0; e < 4; ++e) s[e] = (short)f2b(v[e]);
    *(s16x4*)&Be[j*40 + k0] = s;
  }
  __syncthreads();
  for (int j = threadIdx.x; j < 512; j += 256) {
    float s = 0.f;
    #pragma unroll
    for (int q = 0; q < 4; ++q) {
      const short8 v = *(const short8*)&Be[j*40 + q*8];
      #pragma unroll
      for (int e = 0; e < 8; ++e) {
        const float f = b2f((unsigned short)v[e]);
        s = fmaf(f, f, s);
      }
    }
    en[j] = s;
  }
  __syncthreads();
  const int w = threadIdx.x >> 6, l = threadIdx.x & 63;
  const int lm = l & 15, lk = l >> 4;
  const int rw = w * 32;
  short8 av[2];
  #pragma unroll
  for (int mi = 0; mi < 2; ++mi) {
    const float* zp = z + (long)(m0 + rw + mi*16 + lm)*32 + lk*8;
    const f32x4 f0 = *(const f32x4*)zp;
    const f32x4 f1 = *(const f32x4*)(zp + 4);
    short8 v;
    #pragma unroll
    for (int e = 0; e < 4; ++e) {
      v[e]     = (short)f2b(f0[e]);
      v[e + 4] = (short)f2b(f1[e]);
    }
    av[mi] = v;
  }
  float bd[2][4]; int bj[2][4];
  #pragma unroll
  for (int mi = 0; mi < 2; ++mi)
    #pragma unroll
    for (int r = 0; r < 4; ++r) { bd[mi][r] = 1e30f; bj[mi][r] = 0; }
  for (int nc = 0; nc < 8; ++nc) {               // N-chunks of 64 codes
    f32x4 acc[2][4];
    #pragma unroll
    for (int mi = 0; mi < 2; ++mi)
      #pragma unroll
      for (int ni = 0; ni < 4; ++ni) acc[mi][ni] = (f32x4)0.0f;
    #pragma unroll
    for (int ni = 0; ni < 4; ++ni) {
      const short8 bv = *(const short8*)&Be[(nc*64 + ni*16 + lm)*40 + lk*8];
      #pragma unroll
      for (int mi = 0; mi < 2; ++mi)
        acc[mi][ni] = __builtin_amdgcn_mfma_f32_16x16x32_bf16(
            __builtin_bit_cast(bf16x8, av[mi]),
            __builtin_bit_cast(bf16x8, bv),
            acc[mi][ni], 0, 0, 0);
    }
    #pragma unroll
    for (int ni = 0; ni < 4; ++ni) {
      const int j = nc*64 + ni*16 + lm;
      const float e_n = en[j];
      #pragma unroll
      for (int mi = 0; mi < 2; ++mi)
        #pragma unroll
        for (int r = 0; r < 4; ++r) {
          const float d = fmaf(-2.f, acc[mi][ni][r], e_n);
          if (d < bd[mi][r]) { bd[mi][r] = d; bj[mi][r] = j; }
        }
    }
  }
  #pragma unroll
  for (int mi = 0; mi < 2; ++mi)
    #pragma unroll
    for (int r = 0; r < 4; ++r) {
      float d = bd[mi][r]; int j = bj[mi][r];
      #pragma unroll
      for (int off = 1; off < 16; off <<= 1) {
        const float od = __shfl_xor(d, off);
        const int   oj = __shfl_xor(j, off);
        if (od < d || (od == d && oj < j)) { d = od; j = oj; }
      }
      if (lm == 0) bidx[rw + mi*16 + lk*4 + r] = j;
    }
  __syncthreads();
  const int pl = threadIdx.x >> 1, hf = (threadIdx.x & 1) * 16;
  const int code = bidx[pl];
  const long pb = (long)(m0 + pl)*32 + hf;
  float se = 0.f;
  #pragma unroll
  for (int q = 0; q < 4; ++q) {
    const f32x4 ev = *(const f32x4*)&embed[code*32 + hf + q*4];
    const f32x4 zv = *(const f32x4*)&z[pb + q*4];
    *(f32x4*)&zq[pb + q*4] = ev;
    const f32x4 df = ev - zv;
    #pragma unroll
    for (int e = 0; e < 4; ++e) se = fmaf(df[e], df[e], se);
  }
  red[threadIdx.x] = se; __syncthreads();
  for (int s = 128; s > 0; s >>= 1) {
    if (threadIdx.x < s) red[threadIdx.x] += red[threadIdx.x + s];
    __syncthreads();
  }
  if (threadIdx.x == 0) partial[blockIdx.x] = red[0];
}

__global__ __launch_bounds__(256) void loss_k(const float* __restrict__ part,
                                              float* __restrict__ out) {
  __shared__ float red[256];
  const int t = threadIdx.x;
  float s = 0.f;
  #pragma unroll
  for (int q = 0; q < 4; ++q) s += part[t + q*256];   // 1024 partials
  red[t] = s; __syncthreads();
  for (int st = 128; st > 0; st >>= 1) {
    if (t < st) red[t] += red[t + st];
    __syncthreads();
  }
  if (t == 0) out[0] = red[0] * (1.25f / (131072.f * 32.f));
}

// ---- convt3 via MFMA: d2 NHWC bf16 [32,128,128,64] -> x_recon NCHW fp32 ----
// Block = (n, input row q, x-half h); wave w = parity (py=w>>1, px=w&1).
// Per wave: M=64 output cols (4 m-tiles), N=16 (co, 3 used), K=256 (a,b,ci).
// IL staging identical to the proven conflict-free layout; B frags (8/wave)
// from prepped wq6, loaded once. Zero-padded halo rows give exact-0 taps.
__global__ __launch_bounds__(256) void convt3m_k(const unsigned short* __restrict__ in,
    const unsigned short* __restrict__ wq6, const float* __restrict__ bias,
    float* __restrict__ out) {
  __shared__ short8 IL[3*8*66];      // [(r*8+c8)*66 + ixl], 25344 B
  const int h = blockIdx.x & 1, q = (blockIdx.x >> 1) & 127, n = blockIdx.x >> 8;
  for (int i = threadIdx.x; i < 1584; i += 256) {   // 3*66*8
    const int c8 = i & 7, t = i >> 3, ixl = t % 66, r = t / 66;
    const int iy = q - 1 + r, ix = h*64 - 1 + ixl;
    short8 v = (short8)(short)0;
    if (iy >= 0 && iy < 128 && ix >= 0 && ix < 128)
      v = *(const short8*)(in + (((long)(n*128 + iy)*128 + ix)*64 + c8*8));
    IL[(r*8 + c8)*66 + ixl] = v;
  }
  const int w = threadIdx.x >> 6, l = threadIdx.x & 63;
  const int py = w >> 1, px = w & 1;
  const int lm = l & 15, lk = l >> 4;
  short8 bfrag[8];
  #pragma unroll
  for (int kc = 0; kc < 8; ++kc)
    bfrag[kc] = *(const short8*)(wq6 + (((w*8 + kc)*64 + l) << 3));
  __syncthreads();
  f32x4 acc[4];
  #pragma unroll
  for (int mi = 0; mi < 4; ++mi) acc[mi] = (f32x4)0.0f;
  #pragma unroll
  for (int kc = 0; kc < 8; ++kc) {
    const int a = kc >> 2, b = (kc >> 1) & 1, ch = kc & 1;
    const int base = (((py + a)*8 + ch*4 + lk)*66) + px + b;   // + ixl(xq)
    #pragma unroll
    for (int mi = 0; mi < 4; ++mi) {
      const short8 av = *(const short8*)&IL[base + mi*16 + lm];
      acc[mi] = __builtin_amdgcn_mfma_f32_16x16x32_bf16(
          __builtin_bit_cast(bf16x8, av),
          __builtin_bit_cast(bf16x8, bfrag[kc]),
          acc[mi], 0, 0, 0);
    }
  }
  // epilogue: C row = xq (lk*4+r within tile), col = co (lanes lm<3 write)
  if (lm < 3) {
    const float bv = bias[lm];
    const int oy = 2*q + py;
    const long ob = ((long)(n*3 + lm))*65536 + oy*256;
    #pragma unroll
    for (int mi = 0; mi < 4; ++mi)
      #pragma unroll
      for (int r = 0; r < 4; ++r) {
        const int xq = mi*16 + lk*4 + r;
        out[ob + h*128 + 2*xq + px] = acc[mi][r] + bv;
      }
  }
}

extern "C" void kernel_launch(void* const* d_in, const int* in_sizes, int n_in,
                              void* d_out, int out_size, void* d_ws, size_t ws_size,
                              hipStream_t stream) {
  const float* x   = (const float*)d_in[0];
  const float* ew1 = (const float*)d_in[1];  const float* eb1 = (const float*)d_in[2];
  const float* ew2 = (const float*)d_in[3];  const float* eb2 = (const float*)d_in[4];
  const float* ew3 = (const float*)d_in[5];  const float* eb3 = (const float*)d_in[6];
  const float* emb = (const float*)d_in[7];
  const float* dw1 = (const float*)d_in[8];  const float* db1 = (const float*)d_in[9];
  const float* dw2 = (const float*)d_in[10]; const float* db2 = (const float*)d_in[11];
  const float* dw3 = (const float*)d_in[12]; const float* db3 = (const float*)d_in[13];
  float* out = (float*)d_out;

  // ws layout (bytes), total 134,217,728:
  //   h1  NHWC bf16 [32,128,128,64]  @ 0          (67108864)   -> reused as d2
  //   h2  NHWC bf16 [32, 64, 64,128] @ 67108864   (33554432)   -> reused as d1
  //   z   f32  [131072,32]           @ 100663296  (16777216)
  //   zq  f32  [131072,32]           @ 117440512  (16777216)
  //   loss partials (1024 f32) @ 67108864 — h2 region, DEAD during vqm_k
  //     (R9 post-mortem: z is live inside vqm_k; h2 isn't).
  //   wq2/wq3 overlaid in zq region (dead until vqm writes zq);
  //   wq4/wq5/wq6 overlaid in z region (written after vqm, z dead then).
  uint8_t* w8 = (uint8_t*)d_ws;
  unsigned short* h1 = (unsigned short*)w8;
  unsigned short* h2 = (unsigned short*)(w8 + 67108864);
  float* z   = (float*)(w8 + 100663296);
  float* zq  = (float*)(w8 + 117440512);
  float* part = (float*)(w8 + 67108864);              // h2 region (dead @ vqm)
  unsigned short* wq2 = (unsigned short*)(w8 + 117440512);            // 262144 B
  unsigned short* wq3 = (unsigned short*)(w8 + 117440512 + 262144);   // 73728 B
  unsigned short* wq4 = (unsigned short*)(w8 + 100663296);            // 73728 B
  unsigned short* wq5 = (unsigned short*)(w8 + 100663296 + 73728);    // 262144 B
  unsigned short* wq6 = (unsigned short*)(w8 + 100663296 + 335872);   // 32768 B
  unsigned short* d1 = h2;
  unsigned short* d2 = h1;

  // encoder weight prep (into zq region, consumed before vqm writes zq)
  prep2_k<<<dim3(512),256,0,stream>>>(ew2, wq2);
  prep3_k<<<dim3(144),256,0,stream>>>(ew3, wq3);
  // encoder
  conv1_k<<<dim3(2048),256,0,stream>>>(x, ew1, eb1, h1);
  mconv_k<64,128,128,2,4,16,1,1,false,true,false,false>
      <<<dim3(1024),256,0,stream>>>(h1, wq2, eb2, h2);
  mconv_k<128,32,64,1,3,9,1,1,false,true,false,true>
      <<<dim3(1024),256,0,stream>>>(h2, wq3, eb3, z);
  // VQ (MFMA) + loss  (partials in h2 region; loss_k consumes before d1 write)
  vqm_k<<<dim3(1024),256,0,stream>>>(z, emb, zq, part);
  loss_k<<<dim3(1),256,0,stream>>>(part, out + 6291456);
  // decoder weight prep (into z region, dead after vqm)
  prep4_k<<<dim3(144),256,0,stream>>>(dw1, wq4);
  prep5_k<<<dim3(512),256,0,stream>>>(dw2, wq5);
  prep6_k<<<dim3(64),256,0,stream>>>(dw3, wq6);
  // decoder
  mconv_k<32,128,64,1,3,9,1,1,false,true,true,false>
      <<<dim3(1024),256,0,stream>>>(zq, wq4, db1, d1);
  mconv_k<128,64,64,1,2,4,2,0,true,true,false,false>
      <<<dim3(1024,4),256,0,stream>>>(d1, wq5, db2, d2);
  convt3m_k<<<dim3(8192),256,0,stream>>>(d2, wq6, db3, out);
}

// Round 2
// 480.573 us; speedup vs baseline: 1.0780x; 1.0780x over previous
//
#include <hip/hip_runtime.h>

// VQ-VAE forward, MI355X round 12: R11 + d2 convT rewritten as merged-parity
// barrier-free MFMA kernel (convt2m_k): input staged once per block, 4 waves
// = 4 parities, K=512 per wave, B-frags streamed from L2 (prep5v layout).

typedef __attribute__((ext_vector_type(8))) short     short8;
typedef __attribute__((ext_vector_type(4))) short     s16x4;
typedef __attribute__((ext_vector_type(8))) __bf16    bf16x8;
typedef __attribute__((ext_vector_type(4))) float     f32x4;

#define BATCH 32

__device__ __forceinline__ float b2f(unsigned short b) {
  union { unsigned u; float f; } v; v.u = ((unsigned)b) << 16; return v.f;
}
__device__ __forceinline__ unsigned short f2b(float f) {  // round-to-nearest-even
  union { float f; unsigned u; } v; v.f = f;
  unsigned r = v.u + 0x7FFF + ((v.u >> 16) & 1);
  return (unsigned short)(r >> 16);
}

// ---------------- weight prep: reorganize to [tap][co][ci] bf16 -------------
__global__ __launch_bounds__(256) void prep2_k(const float* __restrict__ w,
                                               unsigned short* __restrict__ wq) {
  const int i = blockIdx.x*256 + threadIdx.x;                 // 131072 exact
  const int ci = i & 63, co = (i >> 6) & 127, t = i >> 13;
  wq[i] = f2b(w[(co*64 + ci)*16 + t]);                        // ew2 OIHW(128,64,4,4)
}
__global__ __launch_bounds__(256) void prep3_k(const float* __restrict__ w,
                                               unsigned short* __restrict__ wq) {
  const int i = blockIdx.x*256 + threadIdx.x;                 // 36864 exact
  const int ci = i & 127, co = (i >> 7) & 31, t = i >> 12;
  wq[i] = f2b(w[(co*128 + ci)*9 + t]);                        // ew3 OIHW(32,128,3,3)
}
__global__ __launch_bounds__(256) void prep4_k(const float* __restrict__ w,
                                               unsigned short* __restrict__ wq) {
  const int i = blockIdx.x*256 + threadIdx.x;                 // 36864 exact
  const int ci = i & 31, co = (i >> 5) & 127, t = i >> 12;
  wq[i] = f2b(w[(ci*128 + co)*9 + (8 - t)]);                  // dw1(32,128,3,3), flipped
}
// d2 convT B-frags, frag-ordered for convt2m_k:
// wq5v[((p*16+ks)*4+ni)*64 + l][j] = w'[p][tap(a,b)][co=ni*16+lm][ci=cc*32+lk*8+j]
// where ks=(a*2+b)*4+cc, lm=l&15, lk=l>>4; w' = flipped/transposed dw2.
__global__ __launch_bounds__(256) void prep5v_k(const float* __restrict__ w,
                                                unsigned short* __restrict__ wq) {
  const int i = blockIdx.x*256 + threadIdx.x;                 // 131072 exact
  const int j = i & 7, l = (i >> 3) & 63, ni = (i >> 9) & 3;
  const int ks = (i >> 11) & 15, p = i >> 15;
  const int lm = l & 15, lk = l >> 4;
  const int py = p >> 1, px = p & 1;
  const int a = ks >> 3, b = (ks >> 2) & 1, cc = ks & 3;
  const int co = ni*16 + lm, ci = cc*32 + lk*8 + j;
  const int ky = 3 - 2*a - py, kx = 3 - 2*b - px;
  wq[i] = f2b(w[(ci*64 + co)*16 + ky*4 + kx]);                // dw2(128,64,4,4)
}
// convt3 B-frags: wq6[p][kc][lane l][j] = w[tap(a,b,p)][ci=(kc&1)*32+lk*8+j][co=lm]
__global__ __launch_bounds__(256) void prep6_k(const float* __restrict__ w,
                                               unsigned short* __restrict__ wq) {
  const int i = blockIdx.x*256 + threadIdx.x;                 // 16384 exact
  const int j = i & 7, l = (i >> 3) & 63, kc = (i >> 9) & 7, p = i >> 12;
  const int lm = l & 15, lk = l >> 4;
  const int a = kc >> 2, b = (kc >> 1) & 1, ch = kc & 1;
  const int ci = ch*32 + lk*8 + j, co = lm;
  const int py = p >> 1, px = p & 1;
  const int ky = 2 - 2*a + (1 - py), kx = 2 - 2*b + (1 - px);
  wq[i] = (co < 3) ? f2b(w[(ci*3 + co)*16 + ky*4 + kx]) : (unsigned short)0;
}

// --------- MFMA implicit-GEMM conv: NHWC in -> NHWC out (64x64 spatial) -----
template<int CIN,int COUT,int HIN,int S,int KW,int NTAPS,int OSTRIDE,int P,
         bool PARITY,bool RELU,bool INF32,bool OUTF32>
__global__ __launch_bounds__(256) void mconv_k(const void* __restrict__ in_,
    const unsigned short* __restrict__ wq_, const float* __restrict__ bias,
    void* __restrict__ out_) {
  constexpr int NF  = COUT / 16;
  constexpr int NCH = CIN / 32;
  __shared__ short Al[128*40];      // 128 rows x 32 k, stride 40 (80B, 16B-mult)
  __shared__ short Bl[COUT*40];
  int py = 0, px = 0, PY = P, PX = P;
  const unsigned short* wq = wq_;
  if (PARITY) {
    py = blockIdx.y >> 1; px = blockIdx.y & 1;
    PY = 1 - py; PX = 1 - px;
    wq += blockIdx.y * (NTAPS*COUT*CIN);
  }
  const int m0 = blockIdx.x * 128;
  const int w  = threadIdx.x >> 6, l = threadIdx.x & 63;
  const int lm = l & 15, lk = l >> 4;
  f32x4 acc[2][NF];
  #pragma unroll
  for (int mi = 0; mi < 2; ++mi)
    #pragma unroll
    for (int ni = 0; ni < NF; ++ni) acc[mi][ni] = (f32x4)0.0f;

  for (int tap = 0; tap < NTAPS; ++tap) {
    const int ky = tap / KW, kx = tap % KW;
    for (int ch = 0; ch < NCH; ++ch) {
      const int c0 = ch * 32;
      __syncthreads();                       // prev iter frag reads done
      for (int s = threadIdx.x; s < 512; s += 256) {
        const int row = s >> 2, part = s & 3;
        const int m = m0 + row;
        const int n = m >> 12, oy = (m >> 6) & 63, ox = m & 63;
        const int iy = oy*S - PY + ky, ix = ox*S - PX + kx;
        short8 v = (short8)(short)0;
        if (iy >= 0 && iy < HIN && ix >= 0 && ix < HIN) {
          const int base = ((n*HIN + iy)*HIN + ix)*CIN + c0 + part*8;
          if (INF32) {
            const float* pf = (const float*)in_ + base;
            const f32x4 f0 = *(const f32x4*)pf;
            const f32x4 f1 = *(const f32x4*)(pf + 4);
            #pragma unroll
            for (int j = 0; j < 4; ++j) {
              v[j]     = (short)f2b(f0[j]);
              v[j + 4] = (short)f2b(f1[j]);
            }
          } else {
            v = *(const short8*)((const unsigned short*)in_ + base);
          }
        }
        *(short8*)&Al[row*40 + part*8] = v;
      }
      for (int s = threadIdx.x; s < COUT*4; s += 256) {
        const int co = s >> 2, part = s & 3;
        *(short8*)&Bl[co*40 + part*8] =
            *(const short8*)(wq + (tap*COUT + co)*CIN + c0 + part*8);
      }
      __syncthreads();
      short8 av[2];
      #pragma unroll
      for (int mi = 0; mi < 2; ++mi)
        av[mi] = *(const short8*)&Al[(w*32 + mi*16 + lm)*40 + lk*8];
      #pragma unroll
      for (int ni = 0; ni < NF; ++ni) {
        const short8 bv = *(const short8*)&Bl[(ni*16 + lm)*40 + lk*8];
        #pragma unroll
        for (int mi = 0; mi < 2; ++mi)
          acc[mi][ni] = __builtin_amdgcn_mfma_f32_16x16x32_bf16(
              __builtin_bit_cast(bf16x8, av[mi]),
              __builtin_bit_cast(bf16x8, bv),
              acc[mi][ni], 0, 0, 0);
      }
    }
  }
  #pragma unroll
  for (int ni = 0; ni < NF; ++ni) {
    const int co = ni*16 + lm;
    const float bv = bias[co];
    #pragma unroll
    for (int mi = 0; mi < 2; ++mi) {
      #pragma unroll
      for (int r = 0; r < 4; ++r) {
        const int ml = w*32 + mi*16 + lk*4 + r;
        const int m  = m0 + ml;
        float vv = acc[mi][ni][r] + bv;
        if (RELU) vv = fmaxf(vv, 0.f);
        int off;
        if (OSTRIDE == 1) {
          off = m*COUT + co;
        } else {
          const int n = m >> 12, oy = (m >> 6) & 63, ox = m & 63;
          off = ((n*128 + oy*2 + py)*128 + ox*2 + px)*COUT + co;
        }
        if (OUTF32) ((float*)out_)[off] = vv;
        else ((unsigned short*)out_)[off] = f2b(vv);
      }
    }
  }
}

// ---- d2 convT via merged-parity MFMA: d1 NHWC bf16 [32,64,64,128] ->
//      d2 NHWC bf16 [32,128,128,64].  Block=(n,q): stage input rows q-1..q+1
//      (halo cols -1..64, 128ci) in LDS once; wave w = parity (py,px) runs a
//      barrier-free K=512 GEMM: M=64 (ox), N=64 (co), K=2x2 taps x 128 ci.
//      A from swizzled LDS (2-way max); B streamed coalesced from wq5v (L2).
__global__ __launch_bounds__(256) void convt2m_k(const unsigned short* __restrict__ in,
    const unsigned short* __restrict__ wv, const float* __restrict__ bias,
    unsigned short* __restrict__ out) {
  __shared__ short IL[3*66*128];       // 50688 B, byteoff ^= ((col&7)<<4)
  // XCD-chunked swizzle: 2048 blocks, 8 XCDs -> 256-block contiguous chunks
  const int wid = (blockIdx.x & 7)*256 + (blockIdx.x >> 3);
  const int q = wid & 63, n = wid >> 6;
  for (int i = threadIdx.x; i < 3168; i += 256) {   // 3 rows * 66 cols * 16 parts
    const int part = i & 15, t = i >> 4, col = t % 66, r = t / 66;
    const int iy = q - 1 + r, ix = col - 1;
    short8 v = (short8)(short)0;
    if (iy >= 0 && iy < 64 && ix >= 0 && ix < 64)
      v = *(const short8*)(in + (((n*64 + iy)*64 + ix)*128 + part*8));
    const int bo = (((r*66 + col) << 8) + (part << 4)) ^ ((col & 7) << 4);
    *(short8*)((char*)IL + bo) = v;
  }
  const int w = threadIdx.x >> 6, l = threadIdx.x & 63;
  const int py = w >> 1, px = w & 1;
  const int lm = l & 15, lk = l >> 4;
  __syncthreads();
  f32x4 acc[4][4];
  #pragma unroll
  for (int mi = 0; mi < 4; ++mi)
    #pragma unroll
    for (int ni = 0; ni < 4; ++ni) acc[mi][ni] = (f32x4)0.0f;
  for (int ks = 0; ks < 16; ++ks) {                  // (a,b,cc): K=512 total
    const int a = ks >> 3, b = (ks >> 2) & 1, cc = ks & 3;
    short8 bv[4];
    #pragma unroll
    for (int ni = 0; ni < 4; ++ni)
      bv[ni] = *(const short8*)(wv + ((((w*16 + ks)*4 + ni)*64 + l) << 3));
    const int r = py + a;
    #pragma unroll
    for (int mi = 0; mi < 4; ++mi) {
      const int col = mi*16 + lm + px + b;
      const int bo = (((r*66 + col) << 8) + (cc << 6) + (lk << 4)) ^ ((col & 7) << 4);
      const short8 av = *(const short8*)((const char*)IL + bo);
      #pragma unroll
      for (int ni = 0; ni < 4; ++ni)
        acc[mi][ni] = __builtin_amdgcn_mfma_f32_16x16x32_bf16(
            __builtin_bit_cast(bf16x8, av),
            __builtin_bit_cast(bf16x8, bv[ni]),
            acc[mi][ni], 0, 0, 0);
    }
  }
  const int oy = 2*q + py;
  #pragma unroll
  for (int mi = 0; mi < 4; ++mi)
    #pragma unroll
    for (int r = 0; r < 4; ++r) {
      const int ox = 2*(mi*16 + lk*4 + r) + px;
      const int ob = ((n*128 + oy)*128 + ox)*64;
      #pragma unroll
      for (int ni = 0; ni < 4; ++ni) {
        const int co = ni*16 + lm;
        out[ob + co] = f2b(fmaxf(acc[mi][ni][r] + bias[co], 0.f));
      }
    }
}

// ---------------- conv1: x NCHW fp32 (3ch) -> h1 NHWC bf16 [32,128,128,64] --
__global__ __launch_bounds__(256) void conv1_k(const float* __restrict__ x,
    const float* __restrict__ w, const float* __restrict__ bias,
    unsigned short* __restrict__ out) {
  __shared__ float wl[64*48];
  __shared__ float bl[64];
  for (int t = threadIdx.x; t < 3072; t += 256) wl[t] = w[t];
  if (threadIdx.x < 64) bl[threadIdx.x] = bias[threadIdx.x];
  __syncthreads();
  const int n  = blockIdx.x >> 6, oy = (blockIdx.x & 63)*2 + (threadIdx.x >> 7);
  const int ox = threadIdx.x & 127;
  float xin[48];
  #pragma unroll
  for (int ci = 0; ci < 3; ++ci)
    #pragma unroll
    for (int ky = 0; ky < 4; ++ky) {
      const int iy = oy*2 - 1 + ky;
      #pragma unroll
      for (int kx = 0; kx < 4; ++kx) {
        const int ix = ox*2 - 1 + kx;
        float v = 0.f;
        if (iy >= 0 && iy < 256 && ix >= 0 && ix < 256)
          v = x[((n*3 + ci)*256 + iy)*256 + ix];
        xin[ci*16 + ky*4 + kx] = v;
      }
    }
  const int ob = ((n*128 + oy)*128 + ox)*64;
  #pragma unroll
  for (int cb = 0; cb < 8; ++cb) {
    short8 sv;
    #pragma unroll
    for (int j = 0; j < 8; ++j) {
      const int co = cb*8 + j;
      float a = bl[co];
      #pragma unroll
      for (int q = 0; q < 12; ++q) {
        const f32x4 wv = *(const f32x4*)&wl[co*48 + q*4];
        a = fmaf(xin[q*4+0], wv[0], a);
        a = fmaf(xin[q*4+1], wv[1], a);
        a = fmaf(xin[q*4+2], wv[2], a);
        a = fmaf(xin[q*4+3], wv[3], a);
      }
      sv[j] = (short)f2b(fmaxf(a, 0.f));
    }
    *(short8*)&out[ob + cb*8] = sv;
  }
}

// ------- VQ via MFMA: z fp32 [131072,32] -> zq fp32 + loss partials ---------
__global__ __launch_bounds__(256) void vqm_k(const float* __restrict__ z,
    const float* __restrict__ embed, float* __restrict__ zq,
    float* __restrict__ partial) {
  __shared__ short Be[512*40];     // bf16 codes, pad stride 40 (40960 B)
  __shared__ float en[512];        // |e|^2 (bf16-rounded e), fp32
  __shared__ int   bidx[128];
  __shared__ float red[256];
  const int m0 = blockIdx.x * 128;
  for (int i = threadIdx.x; i < 4096; i += 256) {
    const int j = i >> 3, k0 = (i & 7) * 4;
    const f32x4 v = *(const f32x4*)&embed[j*32 + k0];
    s16x4 s;
    #pragma unroll
    for (int e = 0; e < 4; ++e) s[e] = (short)f2b(v[e]);
    *(s16x4*)&Be[j*40 + k0] = s;
  }
  __syncthreads();
  for (int j = threadIdx.x; j < 512; j += 256) {
    float s = 0.f;
    #pragma unroll
    for (int q = 0; q < 4; ++q) {
      const short8 v = *(const short8*)&Be[j*40 + q*8];
      #pragma unroll
      for (int e = 0; e < 8; ++e) {
        const float f = b2f((unsigned short)v[e]);
        s = fmaf(f, f, s);
      }
    }
    en[j] = s;
  }
  __syncthreads();
  const int w = threadIdx.x >> 6, l = threadIdx.x & 63;
  const int lm = l & 15, lk = l >> 4;
  const int rw = w * 32;
  short8 av[2];
  #pragma unroll
  for (int mi = 0; mi < 2; ++mi) {
    const float* zp = z + (long)(m0 + rw + mi*16 + lm)*32 + lk*8;
    const f32x4 f0 = *(const f32x4*)zp;
    const f32x4 f1 = *(const f32x4*)(zp + 4);
    short8 v;
    #pragma unroll
    for (int e = 0; e < 4; ++e) {
      v[e]     = (short)f2b(f0[e]);
      v[e + 4] = (short)f2b(f1[e]);
    }
    av[mi] = v;
  }
  float bd[2][4]; int bj[2][4];
  #pragma unroll
  for (int mi = 0; mi < 2; ++mi)
    #pragma unroll
    for (int r = 0; r < 4; ++r) { bd[mi][r] = 1e30f; bj[mi][r] = 0; }
  for (int nc = 0; nc < 8; ++nc) {               // N-chunks of 64 codes
    f32x4 acc[2][4];
    #pragma unroll
    for (int mi = 0; mi < 2; ++mi)
      #pragma unroll
      for (int ni = 0; ni < 4; ++ni) acc[mi][ni] = (f32x4)0.0f;
    #pragma unroll
    for (int ni = 0; ni < 4; ++ni) {
      const short8 bv = *(const short8*)&Be[(nc*64 + ni*16 + lm)*40 + lk*8];
      #pragma unroll
      for (int mi = 0; mi < 2; ++mi)
        acc[mi][ni] = __builtin_amdgcn_mfma_f32_16x16x32_bf16(
            __builtin_bit_cast(bf16x8, av[mi]),
            __builtin_bit_cast(bf16x8, bv),
            acc[mi][ni], 0, 0, 0);
    }
    #pragma unroll
    for (int ni = 0; ni < 4; ++ni) {
      const int j = nc*64 + ni*16 + lm;
      const float e_n = en[j];
      #pragma unroll
      for (int mi = 0; mi < 2; ++mi)
        #pragma unroll
        for (int r = 0; r < 4; ++r) {
          const float d = fmaf(-2.f, acc[mi][ni][r], e_n);
          if (d < bd[mi][r]) { bd[mi][r] = d; bj[mi][r] = j; }
        }
    }
  }
  #pragma unroll
  for (int mi = 0; mi < 2; ++mi)
    #pragma unroll
    for (int r = 0; r < 4; ++r) {
      float d = bd[mi][r]; int j = bj[mi][r];
      #pragma unroll
      for (int off = 1; off < 16; off <<= 1) {
        const float od = __shfl_xor(d, off);
        const int   oj = __shfl_xor(j, off);
        if (od < d || (od == d && oj < j)) { d = od; j = oj; }
      }
      if (lm == 0) bidx[rw + mi*16 + lk*4 + r] = j;
    }
  __syncthreads();
  const int pl = threadIdx.x >> 1, hf = (threadIdx.x & 1) * 16;
  const int code = bidx[pl];
  const long pb = (long)(m0 + pl)*32 + hf;
  float se = 0.f;
  #pragma unroll
  for (int q = 0; q < 4; ++q) {
    const f32x4 ev = *(const f32x4*)&embed[code*32 + hf + q*4];
    const f32x4 zv = *(const f32x4*)&z[pb + q*4];
    *(f32x4*)&zq[pb + q*4] = ev;
    const f32x4 df = ev - zv;
    #pragma unroll
    for (int e = 0; e < 4; ++e) se = fmaf(df[e], df[e], se);
  }
  red[threadIdx.x] = se; __syncthreads();
  for (int s = 128; s > 0; s >>= 1) {
    if (threadIdx.x < s) red[threadIdx.x] += red[threadIdx.x + s];
    __syncthreads();
  }
  if (threadIdx.x == 0) partial[blockIdx.x] = red[0];
}

__global__ __launch_bounds__(256) void loss_k(const float* __restrict__ part,
                                              float* __restrict__ out) {
  __shared__ float red[256];
  const int t = threadIdx.x;
  float s = 0.f;
  #pragma unroll
  for (int q = 0; q < 4; ++q) s += part[t + q*256];   // 1024 partials
  red[t] = s; __syncthreads();
  for (int st = 128; st > 0; st >>= 1) {
    if (t < st) red[t] += red[t + st];
    __syncthreads();
  }
  if (t == 0) out[0] = red[0] * (1.25f / (131072.f * 32.f));
}

// ---- convt3 via MFMA: d2 NHWC bf16 [32,128,128,64] -> x_recon NCHW fp32 ----
__global__ __launch_bounds__(256) void convt3m_k(const unsigned short* __restrict__ in,
    const unsigned short* __restrict__ wq6, const float* __restrict__ bias,
    float* __restrict__ out) {
  __shared__ short8 IL[3*8*66];      // [(r*8+c8)*66 + ixl], 25344 B
  const int h = blockIdx.x & 1, q = (blockIdx.x >> 1) & 127, n = blockIdx.x >> 8;
  for (int i = threadIdx.x; i < 1584; i += 256) {   // 3*66*8
    const int c8 = i & 7, t = i >> 3, ixl = t % 66, r = t / 66;
    const int iy = q - 1 + r, ix = h*64 - 1 + ixl;
    short8 v = (short8)(short)0;
    if (iy >= 0 && iy < 128 && ix >= 0 && ix < 128)
      v = *(const short8*)(in + (((long)(n*128 + iy)*128 + ix)*64 + c8*8));
    IL[(r*8 + c8)*66 + ixl] = v;
  }
  const int w = threadIdx.x >> 6, l = threadIdx.x & 63;
  const int py = w >> 1, px = w & 1;
  const int lm = l & 15, lk = l >> 4;
  short8 bfrag[8];
  #pragma unroll
  for (int kc = 0; kc < 8; ++kc)
    bfrag[kc] = *(const short8*)(wq6 + (((w*8 + kc)*64 + l) << 3));
  __syncthreads();
  f32x4 acc[4];
  #pragma unroll
  for (int mi = 0; mi < 4; ++mi) acc[mi] = (f32x4)0.0f;
  #pragma unroll
  for (int kc = 0; kc < 8; ++kc) {
    const int a = kc >> 2, b = (kc >> 1) & 1, ch = kc & 1;
    const int base = (((py + a)*8 + ch*4 + lk)*66) + px + b;   // + ixl(xq)
    #pragma unroll
    for (int mi = 0; mi < 4; ++mi) {
      const short8 av = *(const short8*)&IL[base + mi*16 + lm];
      acc[mi] = __builtin_amdgcn_mfma_f32_16x16x32_bf16(
          __builtin_bit_cast(bf16x8, av),
          __builtin_bit_cast(bf16x8, bfrag[kc]),
          acc[mi], 0, 0, 0);
    }
  }
  // epilogue: C row = xq (lk*4+r within tile), col = co (lanes lm<3 write)
  if (lm < 3) {
    const float bv = bias[lm];
    const int oy = 2*q + py;
    const long ob = ((long)(n*3 + lm))*65536 + oy*256;
    #pragma unroll
    for (int mi = 0; mi < 4; ++mi)
      #pragma unroll
      for (int r = 0; r < 4; ++r) {
        const int xq = mi*16 + lk*4 + r;
        out[ob + h*128 + 2*xq + px] = acc[mi][r] + bv;
      }
  }
}

extern "C" void kernel_launch(void* const* d_in, const int* in_sizes, int n_in,
                              void* d_out, int out_size, void* d_ws, size_t ws_size,
                              hipStream_t stream) {
  const float* x   = (const float*)d_in[0];
  const float* ew1 = (const float*)d_in[1];  const float* eb1 = (const float*)d_in[2];
  const float* ew2 = (const float*)d_in[3];  const float* eb2 = (const float*)d_in[4];
  const float* ew3 = (const float*)d_in[5];  const float* eb3 = (const float*)d_in[6];
  const float* emb = (const float*)d_in[7];
  const float* dw1 = (const float*)d_in[8];  const float* db1 = (const float*)d_in[9];
  const float* dw2 = (const float*)d_in[10]; const float* db2 = (const float*)d_in[11];
  const float* dw3 = (const float*)d_in[12]; const float* db3 = (const float*)d_in[13];
  float* out = (float*)d_out;

  // ws layout (bytes), total 134,217,728:
  //   h1  NHWC bf16 [32,128,128,64]  @ 0          (67108864)   -> reused as d2
  //   h2  NHWC bf16 [32, 64, 64,128] @ 67108864   (33554432)   -> reused as d1
  //   z   f32  [131072,32]           @ 100663296  (16777216)
  //   zq  f32  [131072,32]           @ 117440512  (16777216)
  //   loss partials (1024 f32) @ 67108864 — h2 region, DEAD during vqm_k
  //   wq2/wq3 overlaid in zq region (dead until vqm writes zq);
  //   wq4/wq5v/wq6 overlaid in z region (written after vqm, z dead then).
  uint8_t* w8 = (uint8_t*)d_ws;
  unsigned short* h1 = (unsigned short*)w8;
  unsigned short* h2 = (unsigned short*)(w8 + 67108864);
  float* z   = (float*)(w8 + 100663296);
  float* zq  = (float*)(w8 + 117440512);
  float* part = (float*)(w8 + 67108864);              // h2 region (dead @ vqm)
  unsigned short* wq2 = (unsigned short*)(w8 + 117440512);            // 262144 B
  unsigned short* wq3 = (unsigned short*)(w8 + 117440512 + 262144);   // 73728 B
  unsigned short* wq4 = (unsigned short*)(w8 + 100663296);            // 73728 B
  unsigned short* wq5 = (unsigned short*)(w8 + 100663296 + 73728);    // 262144 B
  unsigned short* wq6 = (unsigned short*)(w8 + 100663296 + 335872);   // 32768 B
  unsigned short* d1 = h2;
  unsigned short* d2 = h1;

  // encoder weight prep (into zq region, consumed before vqm writes zq)
  prep2_k<<<dim3(512),256,0,stream>>>(ew2, wq2);
  prep3_k<<<dim3(144),256,0,stream>>>(ew3, wq3);
  // encoder
  conv1_k<<<dim3(2048),256,0,stream>>>(x, ew1, eb1, h1);
  mconv_k<64,128,128,2,4,16,1,1,false,true,false,false>
      <<<dim3(1024),256,0,stream>>>(h1, wq2, eb2, h2);
  mconv_k<128,32,64,1,3,9,1,1,false,true,false,true>
      <<<dim3(1024),256,0,stream>>>(h2, wq3, eb3, z);
  // VQ (MFMA) + loss  (partials in h2 region; loss_k consumes before d1 write)
  vqm_k<<<dim3(1024),256,0,stream>>>(z, emb, zq, part);
  loss_k<<<dim3(1),256,0,stream>>>(part, out + 6291456);
  // decoder weight prep (into z region, dead after vqm)
  prep4_k<<<dim3(144),256,0,stream>>>(dw1, wq4);
  prep5v_k<<<dim3(512),256,0,stream>>>(dw2, wq5);
  prep6_k<<<dim3(64),256,0,stream>>>(dw3, wq6);
  // decoder
  mconv_k<32,128,64,1,3,9,1,1,false,true,true,false>
      <<<dim3(1024),256,0,stream>>>(zq, wq4, db1, d1);
  convt2m_k<<<dim3(2048),256,0,stream>>>(d1, wq5, db2, d2);
  convt3m_k<<<dim3(8192),256,0,stream>>>(d2, wq6, db3, out);
}

// Round 3
// 446.791 us; speedup vs baseline: 1.1595x; 1.0756x over previous
//
#include <hip/hip_runtime.h>

// VQ-VAE forward, MI355X round 13: R12 + conv2 rewritten as single-pass
// barrier-free MFMA kernel (conv2m_k): input rows staged once per block in
// even/odd parity planes (stride-2 conv -> stride-1 LDS reads), K=1024
// barrier-free per wave, B-frags streamed from L2 (prep2v layout).

typedef __attribute__((ext_vector_type(8))) short     short8;
typedef __attribute__((ext_vector_type(4))) short     s16x4;
typedef __attribute__((ext_vector_type(8))) __bf16    bf16x8;
typedef __attribute__((ext_vector_type(4))) float     f32x4;

#define BATCH 32

__device__ __forceinline__ float b2f(unsigned short b) {
  union { unsigned u; float f; } v; v.u = ((unsigned)b) << 16; return v.f;
}
__device__ __forceinline__ unsigned short f2b(float f) {  // round-to-nearest-even
  union { float f; unsigned u; } v; v.f = f;
  unsigned r = v.u + 0x7FFF + ((v.u >> 16) & 1);
  return (unsigned short)(r >> 16);
}

// ---------------- weight prep ------------------------------------------------
// conv2 B-frags, frag-ordered for conv2m_k:
// wq2v[((ks*8+ni)*64+l)*8+j] = ew2[co=ni*16+lm][ci=cc*32+lk*8+j][ky][kx]
// where ks = tap*2+cc, tap=ky*4+kx; lm=l&15, lk=l>>4.  ew2 OIHW (128,64,4,4).
__global__ __launch_bounds__(256) void prep2v_k(const float* __restrict__ w,
                                                unsigned short* __restrict__ wq) {
  const int i = blockIdx.x*256 + threadIdx.x;                 // 131072 exact
  const int j = i & 7, l = (i >> 3) & 63, ni = (i >> 9) & 7, ks = i >> 12;
  const int lm = l & 15, lk = l >> 4;
  const int tap = ks >> 1, cc = ks & 1;
  const int co = ni*16 + lm, ci = cc*32 + lk*8 + j;
  wq[i] = f2b(w[(co*64 + ci)*16 + tap]);
}
__global__ __launch_bounds__(256) void prep3_k(const float* __restrict__ w,
                                               unsigned short* __restrict__ wq) {
  const int i = blockIdx.x*256 + threadIdx.x;                 // 36864 exact
  const int ci = i & 127, co = (i >> 7) & 31, t = i >> 12;
  wq[i] = f2b(w[(co*128 + ci)*9 + t]);                        // ew3 OIHW(32,128,3,3)
}
__global__ __launch_bounds__(256) void prep4_k(const float* __restrict__ w,
                                               unsigned short* __restrict__ wq) {
  const int i = blockIdx.x*256 + threadIdx.x;                 // 36864 exact
  const int ci = i & 31, co = (i >> 5) & 127, t = i >> 12;
  wq[i] = f2b(w[(ci*128 + co)*9 + (8 - t)]);                  // dw1(32,128,3,3), flipped
}
// d2 convT B-frags, frag-ordered for convt2m_k:
// wq5v[((p*16+ks)*4+ni)*64 + l][j] = w'[p][tap(a,b)][co=ni*16+lm][ci=cc*32+lk*8+j]
__global__ __launch_bounds__(256) void prep5v_k(const float* __restrict__ w,
                                                unsigned short* __restrict__ wq) {
  const int i = blockIdx.x*256 + threadIdx.x;                 // 131072 exact
  const int j = i & 7, l = (i >> 3) & 63, ni = (i >> 9) & 3;
  const int ks = (i >> 11) & 15, p = i >> 15;
  const int lm = l & 15, lk = l >> 4;
  const int py = p >> 1, px = p & 1;
  const int a = ks >> 3, b = (ks >> 2) & 1, cc = ks & 3;
  const int co = ni*16 + lm, ci = cc*32 + lk*8 + j;
  const int ky = 3 - 2*a - py, kx = 3 - 2*b - px;
  wq[i] = f2b(w[(ci*64 + co)*16 + ky*4 + kx]);                // dw2(128,64,4,4)
}
// convt3 B-frags: wq6[p][kc][lane l][j] = w[tap(a,b,p)][ci=(kc&1)*32+lk*8+j][co=lm]
__global__ __launch_bounds__(256) void prep6_k(const float* __restrict__ w,
                                               unsigned short* __restrict__ wq) {
  const int i = blockIdx.x*256 + threadIdx.x;                 // 16384 exact
  const int j = i & 7, l = (i >> 3) & 63, kc = (i >> 9) & 7, p = i >> 12;
  const int lm = l & 15, lk = l >> 4;
  const int a = kc >> 2, b = (kc >> 1) & 1, ch = kc & 1;
  const int ci = ch*32 + lk*8 + j, co = lm;
  const int py = p >> 1, px = p & 1;
  const int ky = 2 - 2*a + (1 - py), kx = 2 - 2*b + (1 - px);
  wq[i] = (co < 3) ? f2b(w[(ci*3 + co)*16 + ky*4 + kx]) : (unsigned short)0;
}

// --------- MFMA implicit-GEMM conv: NHWC in -> NHWC out (64x64 spatial) -----
template<int CIN,int COUT,int HIN,int S,int KW,int NTAPS,int OSTRIDE,int P,
         bool PARITY,bool RELU,bool INF32,bool OUTF32>
__global__ __launch_bounds__(256) void mconv_k(const void* __restrict__ in_,
    const unsigned short* __restrict__ wq_, const float* __restrict__ bias,
    void* __restrict__ out_) {
  constexpr int NF  = COUT / 16;
  constexpr int NCH = CIN / 32;
  __shared__ short Al[128*40];      // 128 rows x 32 k, stride 40 (80B, 16B-mult)
  __shared__ short Bl[COUT*40];
  int py = 0, px = 0, PY = P, PX = P;
  const unsigned short* wq = wq_;
  if (PARITY) {
    py = blockIdx.y >> 1; px = blockIdx.y & 1;
    PY = 1 - py; PX = 1 - px;
    wq += blockIdx.y * (NTAPS*COUT*CIN);
  }
  const int m0 = blockIdx.x * 128;
  const int w  = threadIdx.x >> 6, l = threadIdx.x & 63;
  const int lm = l & 15, lk = l >> 4;
  f32x4 acc[2][NF];
  #pragma unroll
  for (int mi = 0; mi < 2; ++mi)
    #pragma unroll
    for (int ni = 0; ni < NF; ++ni) acc[mi][ni] = (f32x4)0.0f;

  for (int tap = 0; tap < NTAPS; ++tap) {
    const int ky = tap / KW, kx = tap % KW;
    for (int ch = 0; ch < NCH; ++ch) {
      const int c0 = ch * 32;
      __syncthreads();                       // prev iter frag reads done
      for (int s = threadIdx.x; s < 512; s += 256) {
        const int row = s >> 2, part = s & 3;
        const int m = m0 + row;
        const int n = m >> 12, oy = (m >> 6) & 63, ox = m & 63;
        const int iy = oy*S - PY + ky, ix = ox*S - PX + kx;
        short8 v = (short8)(short)0;
        if (iy >= 0 && iy < HIN && ix >= 0 && ix < HIN) {
          const int base = ((n*HIN + iy)*HIN + ix)*CIN + c0 + part*8;
          if (INF32) {
            const float* pf = (const float*)in_ + base;
            const f32x4 f0 = *(const f32x4*)pf;
            const f32x4 f1 = *(const f32x4*)(pf + 4);
            #pragma unroll
            for (int j = 0; j < 4; ++j) {
              v[j]     = (short)f2b(f0[j]);
              v[j + 4] = (short)f2b(f1[j]);
            }
          } else {
            v = *(const short8*)((const unsigned short*)in_ + base);
          }
        }
        *(short8*)&Al[row*40 + part*8] = v;
      }
      for (int s = threadIdx.x; s < COUT*4; s += 256) {
        const int co = s >> 2, part = s & 3;
        *(short8*)&Bl[co*40 + part*8] =
            *(const short8*)(wq + (tap*COUT + co)*CIN + c0 + part*8);
      }
      __syncthreads();
      short8 av[2];
      #pragma unroll
      for (int mi = 0; mi < 2; ++mi)
        av[mi] = *(const short8*)&Al[(w*32 + mi*16 + lm)*40 + lk*8];
      #pragma unroll
      for (int ni = 0; ni < NF; ++ni) {
        const short8 bv = *(const short8*)&Bl[(ni*16 + lm)*40 + lk*8];
        #pragma unroll
        for (int mi = 0; mi < 2; ++mi)
          acc[mi][ni] = __builtin_amdgcn_mfma_f32_16x16x32_bf16(
              __builtin_bit_cast(bf16x8, av[mi]),
              __builtin_bit_cast(bf16x8, bv),
              acc[mi][ni], 0, 0, 0);
      }
    }
  }
  #pragma unroll
  for (int ni = 0; ni < NF; ++ni) {
    const int co = ni*16 + lm;
    const float bv = bias[co];
    #pragma unroll
    for (int mi = 0; mi < 2; ++mi) {
      #pragma unroll
      for (int r = 0; r < 4; ++r) {
        const int ml = w*32 + mi*16 + lk*4 + r;
        const int m  = m0 + ml;
        float vv = acc[mi][ni][r] + bv;
        if (RELU) vv = fmaxf(vv, 0.f);
        int off;
        if (OSTRIDE == 1) {
          off = m*COUT + co;
        } else {
          const int n = m >> 12, oy = (m >> 6) & 63, ox = m & 63;
          off = ((n*128 + oy*2 + py)*128 + ox*2 + px)*COUT + co;
        }
        if (OUTF32) ((float*)out_)[off] = vv;
        else ((unsigned short*)out_)[off] = f2b(vv);
      }
    }
  }
}

// ---- conv2 via single-pass MFMA: h1 NHWC bf16 [32,128,128,64] ->
//      h2 NHWC bf16 [32,64,64,128].  Block=(n,oy): stage input rows
//      2oy-1..2oy+2 split into even/odd column-parity planes (stride-2 conv
//      becomes stride-1 LDS access); 4 waves x N=32 co, K=1024 barrier-free.
//      A from swizzled LDS; B streamed coalesced from wq2v (L2-resident).
__global__ __launch_bounds__(256) void conv2m_k(const unsigned short* __restrict__ in,
    const unsigned short* __restrict__ wv, const float* __restrict__ bias,
    unsigned short* __restrict__ out) {
  __shared__ short IL[8*66*64];        // [(r*2+p)*66 + idx][ci], 67584 B
  // XCD-chunked swizzle: 2048 blocks -> 8 chunks of 256
  const int wid = (blockIdx.x & 7)*256 + (blockIdx.x >> 3);
  const int q = wid & 63, n = wid >> 6;          // q = output row oy
  for (int i = threadIdx.x; i < 4160; i += 256) {  // 4 rows * 130 cols * 8 parts
    const int part = i & 7, t = i >> 3, col = t % 130, r = t / 130;
    const int iy = 2*q - 1 + r, ix = col - 1;
    short8 v = (short8)(short)0;
    if (iy >= 0 && iy < 128 && ix >= 0 && ix < 128)
      v = *(const short8*)(in + (((n*128 + iy)*128 + ix)*64 + part*8));
    const int p = 1 - (ix & 1 ? 0 : 1);            // odd ix (incl -1) -> p=1
    const int idx = (ix & 1) ? ((ix + 1) >> 1) : (ix >> 1);
    const int bo = ((((r*2 + p)*66 + idx) << 7) + (part << 4)) ^ ((idx & 7) << 4);
    *(short8*)((char*)IL + bo) = v;
  }
  const int w = threadIdx.x >> 6, l = threadIdx.x & 63;
  const int lm = l & 15, lk = l >> 4;
  __syncthreads();
  f32x4 acc[4][2];
  #pragma unroll
  for (int mi = 0; mi < 4; ++mi)
    #pragma unroll
    for (int ni = 0; ni < 2; ++ni) acc[mi][ni] = (f32x4)0.0f;
  for (int ks = 0; ks < 32; ++ks) {                // (tap, cc): K=1024 total
    const int tap = ks >> 1, cc = ks & 1;
    const int ky = tap >> 2, kx = tap & 3;
    const int p = 1 - (kx & 1), d = kx >> 1;       // plane, idx offset
    short8 bv[2];
    #pragma unroll
    for (int ni = 0; ni < 2; ++ni)
      bv[ni] = *(const short8*)(wv + (((ks*8 + w*2 + ni)*64 + l) << 3));
    #pragma unroll
    for (int mi = 0; mi < 4; ++mi) {
      const int idx = mi*16 + lm + d;
      const int bo = ((((ky*2 + p)*66 + idx) << 7) + (cc << 6) + (lk << 4))
                     ^ ((idx & 7) << 4);
      const short8 av = *(const short8*)((const char*)IL + bo);
      #pragma unroll
      for (int ni = 0; ni < 2; ++ni)
        acc[mi][ni] = __builtin_amdgcn_mfma_f32_16x16x32_bf16(
            __builtin_bit_cast(bf16x8, av),
            __builtin_bit_cast(bf16x8, bv[ni]),
            acc[mi][ni], 0, 0, 0);
    }
  }
  #pragma unroll
  for (int mi = 0; mi < 4; ++mi)
    #pragma unroll
    for (int r = 0; r < 4; ++r) {
      const int ox = mi*16 + lk*4 + r;
      const int ob = ((n*64 + q)*64 + ox)*128;
      #pragma unroll
      for (int ni = 0; ni < 2; ++ni) {
        const int co = (w*2 + ni)*16 + lm;
        out[ob + co] = f2b(fmaxf(acc[mi][ni][r] + bias[co], 0.f));
      }
    }
}

// ---- d2 convT via merged-parity MFMA: d1 NHWC bf16 [32,64,64,128] ->
//      d2 NHWC bf16 [32,128,128,64].
__global__ __launch_bounds__(256) void convt2m_k(const unsigned short* __restrict__ in,
    const unsigned short* __restrict__ wv, const float* __restrict__ bias,
    unsigned short* __restrict__ out) {
  __shared__ short IL[3*66*128];       // 50688 B, byteoff ^= ((col&7)<<4)
  const int wid = (blockIdx.x & 7)*256 + (blockIdx.x >> 3);
  const int q = wid & 63, n = wid >> 6;
  for (int i = threadIdx.x; i < 3168; i += 256) {   // 3 rows * 66 cols * 16 parts
    const int part = i & 15, t = i >> 4, col = t % 66, r = t / 66;
    const int iy = q - 1 + r, ix = col - 1;
    short8 v = (short8)(short)0;
    if (iy >= 0 && iy < 64 && ix >= 0 && ix < 64)
      v = *(const short8*)(in + (((n*64 + iy)*64 + ix)*128 + part*8));
    const int bo = (((r*66 + col) << 8) + (part << 4)) ^ ((col & 7) << 4);
    *(short8*)((char*)IL + bo) = v;
  }
  const int w = threadIdx.x >> 6, l = threadIdx.x & 63;
  const int py = w >> 1, px = w & 1;
  const int lm = l & 15, lk = l >> 4;
  __syncthreads();
  f32x4 acc[4][4];
  #pragma unroll
  for (int mi = 0; mi < 4; ++mi)
    #pragma unroll
    for (int ni = 0; ni < 4; ++ni) acc[mi][ni] = (f32x4)0.0f;
  for (int ks = 0; ks < 16; ++ks) {                  // (a,b,cc): K=512 total
    const int a = ks >> 3, b = (ks >> 2) & 1, cc = ks & 3;
    short8 bv[4];
    #pragma unroll
    for (int ni = 0; ni < 4; ++ni)
      bv[ni] = *(const short8*)(wv + ((((w*16 + ks)*4 + ni)*64 + l) << 3));
    const int r = py + a;
    #pragma unroll
    for (int mi = 0; mi < 4; ++mi) {
      const int col = mi*16 + lm + px + b;
      const int bo = (((r*66 + col) << 8) + (cc << 6) + (lk << 4)) ^ ((col & 7) << 4);
      const short8 av = *(const short8*)((const char*)IL + bo);
      #pragma unroll
      for (int ni = 0; ni < 4; ++ni)
        acc[mi][ni] = __builtin_amdgcn_mfma_f32_16x16x32_bf16(
            __builtin_bit_cast(bf16x8, av),
            __builtin_bit_cast(bf16x8, bv[ni]),
            acc[mi][ni], 0, 0, 0);
    }
  }
  const int oy = 2*q + py;
  #pragma unroll
  for (int mi = 0; mi < 4; ++mi)
    #pragma unroll
    for (int r = 0; r < 4; ++r) {
      const int ox = 2*(mi*16 + lk*4 + r) + px;
      const int ob = ((n*128 + oy)*128 + ox)*64;
      #pragma unroll
      for (int ni = 0; ni < 4; ++ni) {
        const int co = ni*16 + lm;
        out[ob + co] = f2b(fmaxf(acc[mi][ni][r] + bias[co], 0.f));
      }
    }
}

// ---------------- conv1: x NCHW fp32 (3ch) -> h1 NHWC bf16 [32,128,128,64] --
__global__ __launch_bounds__(256) void conv1_k(const float* __restrict__ x,
    const float* __restrict__ w, const float* __restrict__ bias,
    unsigned short* __restrict__ out) {
  __shared__ float wl[64*48];
  __shared__ float bl[64];
  for (int t = threadIdx.x; t < 3072; t += 256) wl[t] = w[t];
  if (threadIdx.x < 64) bl[threadIdx.x] = bias[threadIdx.x];
  __syncthreads();
  const int n  = blockIdx.x >> 6, oy = (blockIdx.x & 63)*2 + (threadIdx.x >> 7);
  const int ox = threadIdx.x & 127;
  float xin[48];
  #pragma unroll
  for (int ci = 0; ci < 3; ++ci)
    #pragma unroll
    for (int ky = 0; ky < 4; ++ky) {
      const int iy = oy*2 - 1 + ky;
      #pragma unroll
      for (int kx = 0; kx < 4; ++kx) {
        const int ix = ox*2 - 1 + kx;
        float v = 0.f;
        if (iy >= 0 && iy < 256 && ix >= 0 && ix < 256)
          v = x[((n*3 + ci)*256 + iy)*256 + ix];
        xin[ci*16 + ky*4 + kx] = v;
      }
    }
  const int ob = ((n*128 + oy)*128 + ox)*64;
  #pragma unroll
  for (int cb = 0; cb < 8; ++cb) {
    short8 sv;
    #pragma unroll
    for (int j = 0; j < 8; ++j) {
      const int co = cb*8 + j;
      float a = bl[co];
      #pragma unroll
      for (int q = 0; q < 12; ++q) {
        const f32x4 wv = *(const f32x4*)&wl[co*48 + q*4];
        a = fmaf(xin[q*4+0], wv[0], a);
        a = fmaf(xin[q*4+1], wv[1], a);
        a = fmaf(xin[q*4+2], wv[2], a);
        a = fmaf(xin[q*4+3], wv[3], a);
      }
      sv[j] = (short)f2b(fmaxf(a, 0.f));
    }
    *(short8*)&out[ob + cb*8] = sv;
  }
}

// ------- VQ via MFMA: z fp32 [131072,32] -> zq fp32 + loss partials ---------
__global__ __launch_bounds__(256) void vqm_k(const float* __restrict__ z,
    const float* __restrict__ embed, float* __restrict__ zq,
    float* __restrict__ partial) {
  __shared__ short Be[512*40];     // bf16 codes, pad stride 40 (40960 B)
  __shared__ float en[512];        // |e|^2 (bf16-rounded e), fp32
  __shared__ int   bidx[128];
  __shared__ float red[256];
  const int m0 = blockIdx.x * 128;
  for (int i = threadIdx.x; i < 4096; i += 256) {
    const int j = i >> 3, k0 = (i & 7) * 4;
    const f32x4 v = *(const f32x4*)&embed[j*32 + k0];
    s16x4 s;
    #pragma unroll
    for (int e = 0; e < 4; ++e) s[e] = (short)f2b(v[e]);
    *(s16x4*)&Be[j*40 + k0] = s;
  }
  __syncthreads();
  for (int j = threadIdx.x; j < 512; j += 256) {
    float s = 0.f;
    #pragma unroll
    for (int q = 0; q < 4; ++q) {
      const short8 v = *(const short8*)&Be[j*40 + q*8];
      #pragma unroll
      for (int e = 0; e < 8; ++e) {
        const float f = b2f((unsigned short)v[e]);
        s = fmaf(f, f, s);
      }
    }
    en[j] = s;
  }
  __syncthreads();
  const int w = threadIdx.x >> 6, l = threadIdx.x & 63;
  const int lm = l & 15, lk = l >> 4;
  const int rw = w * 32;
  short8 av[2];
  #pragma unroll
  for (int mi = 0; mi < 2; ++mi) {
    const float* zp = z + (long)(m0 + rw + mi*16 + lm)*32 + lk*8;
    const f32x4 f0 = *(const f32x4*)zp;
    const f32x4 f1 = *(const f32x4*)(zp + 4);
    short8 v;
    #pragma unroll
    for (int e = 0; e < 4; ++e) {
      v[e]     = (short)f2b(f0[e]);
      v[e + 4] = (short)f2b(f1[e]);
    }
    av[mi] = v;
  }
  float bd[2][4]; int bj[2][4];
  #pragma unroll
  for (int mi = 0; mi < 2; ++mi)
    #pragma unroll
    for (int r = 0; r < 4; ++r) { bd[mi][r] = 1e30f; bj[mi][r] = 0; }
  for (int nc = 0; nc < 8; ++nc) {               // N-chunks of 64 codes
    f32x4 acc[2][4];
    #pragma unroll
    for (int mi = 0; mi < 2; ++mi)
      #pragma unroll
      for (int ni = 0; ni < 4; ++ni) acc[mi][ni] = (f32x4)0.0f;
    #pragma unroll
    for (int ni = 0; ni < 4; ++ni) {
      const short8 bv = *(const short8*)&Be[(nc*64 + ni*16 + lm)*40 + lk*8];
      #pragma unroll
      for (int mi = 0; mi < 2; ++mi)
        acc[mi][ni] = __builtin_amdgcn_mfma_f32_16x16x32_bf16(
            __builtin_bit_cast(bf16x8, av[mi]),
            __builtin_bit_cast(bf16x8, bv),
            acc[mi][ni], 0, 0, 0);
    }
    #pragma unroll
    for (int ni = 0; ni < 4; ++ni) {
      const int j = nc*64 + ni*16 + lm;
      const float e_n = en[j];
      #pragma unroll
      for (int mi = 0; mi < 2; ++mi)
        #pragma unroll
        for (int r = 0; r < 4; ++r) {
          const float d = fmaf(-2.f, acc[mi][ni][r], e_n);
          if (d < bd[mi][r]) { bd[mi][r] = d; bj[mi][r] = j; }
        }
    }
  }
  #pragma unroll
  for (int mi = 0; mi < 2; ++mi)
    #pragma unroll
    for (int r = 0; r < 4; ++r) {
      float d = bd[mi][r]; int j = bj[mi][r];
      #pragma unroll
      for (int off = 1; off < 16; off <<= 1) {
        const float od = __shfl_xor(d, off);
        const int   oj = __shfl_xor(j, off);
        if (od < d || (od == d && oj < j)) { d = od; j = oj; }
      }
      if (lm == 0) bidx[rw + mi*16 + lk*4 + r] = j;
    }
  __syncthreads();
  const int pl = threadIdx.x >> 1, hf = (threadIdx.x & 1) * 16;
  const int code = bidx[pl];
  const long pb = (long)(m0 + pl)*32 + hf;
  float se = 0.f;
  #pragma unroll
  for (int q = 0; q < 4; ++q) {
    const f32x4 ev = *(const f32x4*)&embed[code*32 + hf + q*4];
    const f32x4 zv = *(const f32x4*)&z[pb + q*4];
    *(f32x4*)&zq[pb + q*4] = ev;
    const f32x4 df = ev - zv;
    #pragma unroll
    for (int e = 0; e < 4; ++e) se = fmaf(df[e], df[e], se);
  }
  red[threadIdx.x] = se; __syncthreads();
  for (int s = 128; s > 0; s >>= 1) {
    if (threadIdx.x < s) red[threadIdx.x] += red[threadIdx.x + s];
    __syncthreads();
  }
  if (threadIdx.x == 0) partial[blockIdx.x] = red[0];
}

__global__ __launch_bounds__(256) void loss_k(const float* __restrict__ part,
                                              float* __restrict__ out) {
  __shared__ float red[256];
  const int t = threadIdx.x;
  float s = 0.f;
  #pragma unroll
  for (int q = 0; q < 4; ++q) s += part[t + q*256];   // 1024 partials
  red[t] = s; __syncthreads();
  for (int st = 128; st > 0; st >>= 1) {
    if (t < st) red[t] += red[t + st];
    __syncthreads();
  }
  if (t == 0) out[0] = red[0] * (1.25f / (131072.f * 32.f));
}

// ---- convt3 via MFMA: d2 NHWC bf16 [32,128,128,64] -> x_recon NCHW fp32 ----
__global__ __launch_bounds__(256) void convt3m_k(const unsigned short* __restrict__ in,
    const unsigned short* __restrict__ wq6, const float* __restrict__ bias,
    float* __restrict__ out) {
  __shared__ short8 IL[3*8*66];      // [(r*8+c8)*66 + ixl], 25344 B
  const int h = blockIdx.x & 1, q = (blockIdx.x >> 1) & 127, n = blockIdx.x >> 8;
  for (int i = threadIdx.x; i < 1584; i += 256) {   // 3*66*8
    const int c8 = i & 7, t = i >> 3, ixl = t % 66, r = t / 66;
    const int iy = q - 1 + r, ix = h*64 - 1 + ixl;
    short8 v = (short8)(short)0;
    if (iy >= 0 && iy < 128 && ix >= 0 && ix < 128)
      v = *(const short8*)(in + (((long)(n*128 + iy)*128 + ix)*64 + c8*8));
    IL[(r*8 + c8)*66 + ixl] = v;
  }
  const int w = threadIdx.x >> 6, l = threadIdx.x & 63;
  const int py = w >> 1, px = w & 1;
  const int lm = l & 15, lk = l >> 4;
  short8 bfrag[8];
  #pragma unroll
  for (int kc = 0; kc < 8; ++kc)
    bfrag[kc] = *(const short8*)(wq6 + (((w*8 + kc)*64 + l) << 3));
  __syncthreads();
  f32x4 acc[4];
  #pragma unroll
  for (int mi = 0; mi < 4; ++mi) acc[mi] = (f32x4)0.0f;
  #pragma unroll
  for (int kc = 0; kc < 8; ++kc) {
    const int a = kc >> 2, b = (kc >> 1) & 1, ch = kc & 1;
    const int base = (((py + a)*8 + ch*4 + lk)*66) + px + b;   // + ixl(xq)
    #pragma unroll
    for (int mi = 0; mi < 4; ++mi) {
      const short8 av = *(const short8*)&IL[base + mi*16 + lm];
      acc[mi] = __builtin_amdgcn_mfma_f32_16x16x32_bf16(
          __builtin_bit_cast(bf16x8, av),
          __builtin_bit_cast(bf16x8, bfrag[kc]),
          acc[mi], 0, 0, 0);
    }
  }
  // epilogue: C row = xq (lk*4+r within tile), col = co (lanes lm<3 write)
  if (lm < 3) {
    const float bv = bias[lm];
    const int oy = 2*q + py;
    const long ob = ((long)(n*3 + lm))*65536 + oy*256;
    #pragma unroll
    for (int mi = 0; mi < 4; ++mi)
      #pragma unroll
      for (int r = 0; r < 4; ++r) {
        const int xq = mi*16 + lk*4 + r;
        out[ob + h*128 + 2*xq + px] = acc[mi][r] + bv;
      }
  }
}

extern "C" void kernel_launch(void* const* d_in, const int* in_sizes, int n_in,
                              void* d_out, int out_size, void* d_ws, size_t ws_size,
                              hipStream_t stream) {
  const float* x   = (const float*)d_in[0];
  const float* ew1 = (const float*)d_in[1];  const float* eb1 = (const float*)d_in[2];
  const float* ew2 = (const float*)d_in[3];  const float* eb2 = (const float*)d_in[4];
  const float* ew3 = (const float*)d_in[5];  const float* eb3 = (const float*)d_in[6];
  const float* emb = (const float*)d_in[7];
  const float* dw1 = (const float*)d_in[8];  const float* db1 = (const float*)d_in[9];
  const float* dw2 = (const float*)d_in[10]; const float* db2 = (const float*)d_in[11];
  const float* dw3 = (const float*)d_in[12]; const float* db3 = (const float*)d_in[13];
  float* out = (float*)d_out;

  // ws layout (bytes), total 134,217,728:
  //   h1  NHWC bf16 [32,128,128,64]  @ 0          (67108864)   -> reused as d2
  //   h2  NHWC bf16 [32, 64, 64,128] @ 67108864   (33554432)   -> reused as d1
  //   z   f32  [131072,32]           @ 100663296  (16777216)
  //   zq  f32  [131072,32]           @ 117440512  (16777216)
  //   loss partials (1024 f32) @ 67108864 — h2 region, DEAD during vqm_k
  //   wq2/wq3 overlaid in zq region (dead until vqm writes zq);
  //   wq4/wq5v/wq6 overlaid in z region (written after vqm, z dead then).
  uint8_t* w8 = (uint8_t*)d_ws;
  unsigned short* h1 = (unsigned short*)w8;
  unsigned short* h2 = (unsigned short*)(w8 + 67108864);
  float* z   = (float*)(w8 + 100663296);
  float* zq  = (float*)(w8 + 117440512);
  float* part = (float*)(w8 + 67108864);              // h2 region (dead @ vqm)
  unsigned short* wq2 = (unsigned short*)(w8 + 117440512);            // 262144 B
  unsigned short* wq3 = (unsigned short*)(w8 + 117440512 + 262144);   // 73728 B
  unsigned short* wq4 = (unsigned short*)(w8 + 100663296);            // 73728 B
  unsigned short* wq5 = (unsigned short*)(w8 + 100663296 + 73728);    // 262144 B
  unsigned short* wq6 = (unsigned short*)(w8 + 100663296 + 335872);   // 32768 B
  unsigned short* d1 = h2;
  unsigned short* d2 = h1;

  // encoder weight prep (into zq region, consumed before vqm writes zq)
  prep2v_k<<<dim3(512),256,0,stream>>>(ew2, wq2);
  prep3_k<<<dim3(144),256,0,stream>>>(ew3, wq3);
  // encoder
  conv1_k<<<dim3(2048),256,0,stream>>>(x, ew1, eb1, h1);
  conv2m_k<<<dim3(2048),256,0,stream>>>(h1, wq2, eb2, h2);
  mconv_k<128,32,64,1,3,9,1,1,false,true,false,true>
      <<<dim3(1024),256,0,stream>>>(h2, wq3, eb3, z);
  // VQ (MFMA) + loss  (partials in h2 region; loss_k consumes before d1 write)
  vqm_k<<<dim3(1024),256,0,stream>>>(z, emb, zq, part);
  loss_k<<<dim3(1),256,0,stream>>>(part, out + 6291456);
  // decoder weight prep (into z region, dead after vqm)
  prep4_k<<<dim3(144),256,0,stream>>>(dw1, wq4);
  prep5v_k<<<dim3(512),256,0,stream>>>(dw2, wq5);
  prep6_k<<<dim3(64),256,0,stream>>>(dw3, wq6);
  // decoder
  mconv_k<32,128,64,1,3,9,1,1,false,true,true,false>
      <<<dim3(1024),256,0,stream>>>(zq, wq4, db1, d1);
  convt2m_k<<<dim3(2048),256,0,stream>>>(d1, wq5, db2, d2);
  convt3m_k<<<dim3(8192),256,0,stream>>>(d2, wq6, db3, out);
}

// Round 4
// 408.542 us; speedup vs baseline: 1.2681x; 1.0936x over previous
//
#include <hip/hip_runtime.h>

// VQ-VAE forward, MI355X round 14: R13 + conv1 moved onto matrix cores
// (conv1m_k implicit GEMM M=128,N=64,K=48pad64; LDS im2col; coalesced writes).

typedef __attribute__((ext_vector_type(8))) short     short8;
typedef __attribute__((ext_vector_type(4))) short     s16x4;
typedef __attribute__((ext_vector_type(8))) __bf16    bf16x8;
typedef __attribute__((ext_vector_type(4))) float     f32x4;
typedef __attribute__((ext_vector_type(4))) unsigned  uint32x4;

#define BATCH 32

__device__ __forceinline__ float b2f(unsigned short b) {
  union { unsigned u; float f; } v; v.u = ((unsigned)b) << 16; return v.f;
}
__device__ __forceinline__ unsigned short f2b(float f) {  // round-to-nearest-even
  union { float f; unsigned u; } v; v.f = f;
  unsigned r = v.u + 0x7FFF + ((v.u >> 16) & 1);
  return (unsigned short)(r >> 16);
}

// ---------------- weight prep ------------------------------------------------
// conv1 B-frags: wq1[((ks*4+ni)*64+l)*8+j] = ew1[co=ni*16+lm][k], k=ks*32+lk*8+j
// k = ci*16 + ky*4 + kx (natural OIHW inner index), k>=48 -> 0.
__global__ __launch_bounds__(256) void prep1v_k(const float* __restrict__ w,
                                                unsigned short* __restrict__ wq) {
  const int i = blockIdx.x*256 + threadIdx.x;                 // 4096 exact
  const int j = i & 7, l = (i >> 3) & 63, ni = (i >> 9) & 3, ks = i >> 11;
  const int k = ks*32 + (l >> 4)*8 + j;
  const int co = ni*16 + (l & 15);
  wq[i] = (k < 48) ? f2b(w[co*48 + k]) : (unsigned short)0;
}
// conv2 B-frags, frag-ordered for conv2m_k:
__global__ __launch_bounds__(256) void prep2v_k(const float* __restrict__ w,
                                                unsigned short* __restrict__ wq) {
  const int i = blockIdx.x*256 + threadIdx.x;                 // 131072 exact
  const int j = i & 7, l = (i >> 3) & 63, ni = (i >> 9) & 7, ks = i >> 12;
  const int lm = l & 15, lk = l >> 4;
  const int tap = ks >> 1, cc = ks & 1;
  const int co = ni*16 + lm, ci = cc*32 + lk*8 + j;
  wq[i] = f2b(w[(co*64 + ci)*16 + tap]);
}
__global__ __launch_bounds__(256) void prep3_k(const float* __restrict__ w,
                                               unsigned short* __restrict__ wq) {
  const int i = blockIdx.x*256 + threadIdx.x;                 // 36864 exact
  const int ci = i & 127, co = (i >> 7) & 31, t = i >> 12;
  wq[i] = f2b(w[(co*128 + ci)*9 + t]);                        // ew3 OIHW(32,128,3,3)
}
__global__ __launch_bounds__(256) void prep4_k(const float* __restrict__ w,
                                               unsigned short* __restrict__ wq) {
  const int i = blockIdx.x*256 + threadIdx.x;                 // 36864 exact
  const int ci = i & 31, co = (i >> 5) & 127, t = i >> 12;
  wq[i] = f2b(w[(ci*128 + co)*9 + (8 - t)]);                  // dw1(32,128,3,3), flipped
}
// d2 convT B-frags, frag-ordered for convt2m_k:
__global__ __launch_bounds__(256) void prep5v_k(const float* __restrict__ w,
                                                unsigned short* __restrict__ wq) {
  const int i = blockIdx.x*256 + threadIdx.x;                 // 131072 exact
  const int j = i & 7, l = (i >> 3) & 63, ni = (i >> 9) & 3;
  const int ks = (i >> 11) & 15, p = i >> 15;
  const int lm = l & 15, lk = l >> 4;
  const int py = p >> 1, px = p & 1;
  const int a = ks >> 3, b = (ks >> 2) & 1, cc = ks & 3;
  const int co = ni*16 + lm, ci = cc*32 + lk*8 + j;
  const int ky = 3 - 2*a - py, kx = 3 - 2*b - px;
  wq[i] = f2b(w[(ci*64 + co)*16 + ky*4 + kx]);                // dw2(128,64,4,4)
}
// convt3 B-frags: wq6[p][kc][lane l][j] = w[tap(a,b,p)][ci=(kc&1)*32+lk*8+j][co=lm]
__global__ __launch_bounds__(256) void prep6_k(const float* __restrict__ w,
                                               unsigned short* __restrict__ wq) {
  const int i = blockIdx.x*256 + threadIdx.x;                 // 16384 exact
  const int j = i & 7, l = (i >> 3) & 63, kc = (i >> 9) & 7, p = i >> 12;
  const int lm = l & 15, lk = l >> 4;
  const int a = kc >> 2, b = (kc >> 1) & 1, ch = kc & 1;
  const int ci = ch*32 + lk*8 + j, co = lm;
  const int py = p >> 1, px = p & 1;
  const int ky = 2 - 2*a + (1 - py), kx = 2 - 2*b + (1 - px);
  wq[i] = (co < 3) ? f2b(w[(ci*3 + co)*16 + ky*4 + kx]) : (unsigned short)0;
}

// --------- MFMA implicit-GEMM conv: NHWC in -> NHWC out (64x64 spatial) -----
template<int CIN,int COUT,int HIN,int S,int KW,int NTAPS,int OSTRIDE,int P,
         bool PARITY,bool RELU,bool INF32,bool OUTF32>
__global__ __launch_bounds__(256) void mconv_k(const void* __restrict__ in_,
    const unsigned short* __restrict__ wq_, const float* __restrict__ bias,
    void* __restrict__ out_) {
  constexpr int NF  = COUT / 16;
  constexpr int NCH = CIN / 32;
  __shared__ short Al[128*40];      // 128 rows x 32 k, stride 40 (80B, 16B-mult)
  __shared__ short Bl[COUT*40];
  int py = 0, px = 0, PY = P, PX = P;
  const unsigned short* wq = wq_;
  if (PARITY) {
    py = blockIdx.y >> 1; px = blockIdx.y & 1;
    PY = 1 - py; PX = 1 - px;
    wq += blockIdx.y * (NTAPS*COUT*CIN);
  }
  const int m0 = blockIdx.x * 128;
  const int w  = threadIdx.x >> 6, l = threadIdx.x & 63;
  const int lm = l & 15, lk = l >> 4;
  f32x4 acc[2][NF];
  #pragma unroll
  for (int mi = 0; mi < 2; ++mi)
    #pragma unroll
    for (int ni = 0; ni < NF; ++ni) acc[mi][ni] = (f32x4)0.0f;

  for (int tap = 0; tap < NTAPS; ++tap) {
    const int ky = tap / KW, kx = tap % KW;
    for (int ch = 0; ch < NCH; ++ch) {
      const int c0 = ch * 32;
      __syncthreads();                       // prev iter frag reads done
      for (int s = threadIdx.x; s < 512; s += 256) {
        const int row = s >> 2, part = s & 3;
        const int m = m0 + row;
        const int n = m >> 12, oy = (m >> 6) & 63, ox = m & 63;
        const int iy = oy*S - PY + ky, ix = ox*S - PX + kx;
        short8 v = (short8)(short)0;
        if (iy >= 0 && iy < HIN && ix >= 0 && ix < HIN) {
          const int base = ((n*HIN + iy)*HIN + ix)*CIN + c0 + part*8;
          if (INF32) {
            const float* pf = (const float*)in_ + base;
            const f32x4 f0 = *(const f32x4*)pf;
            const f32x4 f1 = *(const f32x4*)(pf + 4);
            #pragma unroll
            for (int j = 0; j < 4; ++j) {
              v[j]     = (short)f2b(f0[j]);
              v[j + 4] = (short)f2b(f1[j]);
            }
          } else {
            v = *(const short8*)((const unsigned short*)in_ + base);
          }
        }
        *(short8*)&Al[row*40 + part*8] = v;
      }
      for (int s = threadIdx.x; s < COUT*4; s += 256) {
        const int co = s >> 2, part = s & 3;
        *(short8*)&Bl[co*40 + part*8] =
            *(const short8*)(wq + (tap*COUT + co)*CIN + c0 + part*8);
      }
      __syncthreads();
      short8 av[2];
      #pragma unroll
      for (int mi = 0; mi < 2; ++mi)
        av[mi] = *(const short8*)&Al[(w*32 + mi*16 + lm)*40 + lk*8];
      #pragma unroll
      for (int ni = 0; ni < NF; ++ni) {
        const short8 bv = *(const short8*)&Bl[(ni*16 + lm)*40 + lk*8];
        #pragma unroll
        for (int mi = 0; mi < 2; ++mi)
          acc[mi][ni] = __builtin_amdgcn_mfma_f32_16x16x32_bf16(
              __builtin_bit_cast(bf16x8, av[mi]),
              __builtin_bit_cast(bf16x8, bv),
              acc[mi][ni], 0, 0, 0);
      }
    }
  }
  #pragma unroll
  for (int ni = 0; ni < NF; ++ni) {
    const int co = ni*16 + lm;
    const float bv = bias[co];
    #pragma unroll
    for (int mi = 0; mi < 2; ++mi) {
      #pragma unroll
      for (int r = 0; r < 4; ++r) {
        const int ml = w*32 + mi*16 + lk*4 + r;
        const int m  = m0 + ml;
        float vv = acc[mi][ni][r] + bv;
        if (RELU) vv = fmaxf(vv, 0.f);
        int off;
        if (OSTRIDE == 1) {
          off = m*COUT + co;
        } else {
          const int n = m >> 12, oy = (m >> 6) & 63, ox = m & 63;
          off = ((n*128 + oy*2 + py)*128 + ox*2 + px)*COUT + co;
        }
        if (OUTF32) ((float*)out_)[off] = vv;
        else ((unsigned short*)out_)[off] = f2b(vv);
      }
    }
  }
}

// ---- conv1 via MFMA: x NCHW fp32 [32,3,256,256] -> h1 NHWC bf16
//      [32,128,128,64].  Block=(n,oy): stage 4 input rows (3ch, bf16) in LDS,
//      build swizzled im2col [128 ox][64 k] (k=ci*16+ky*4+kx, 48 real),
//      4 waves x 32 ox, N=64, K=64; epilogue staged in LDS -> coalesced writes.
__global__ __launch_bounds__(256) void conv1m_k(const float* __restrict__ x,
    const unsigned short* __restrict__ wv, const float* __restrict__ bias,
    unsigned short* __restrict__ out) {
  __shared__ __align__(16) short RAW[12*264];   // row g=ci*4+ky, idx=ix+4; 6336B
  __shared__ __align__(16) short IC[128*64];    // [ox][k] swizzled; 16384B
  const int wid = ((blockIdx.x & 7) << 9) + (blockIdx.x >> 3);
  const int q = wid & 127, n = wid >> 7;        // q = output row oy
  for (int i = threadIdx.x; i < 396; i += 256)
    *(short8*)&RAW[i*8] = (short8)(short)0;
  __syncthreads();
  for (int s = threadIdx.x; s < 768; s += 256) {   // 12 rows * 64 f32x4
    const int g = s >> 6, seg = s & 63;
    const int ci = g >> 2, ky = g & 3;
    const int iy = 2*q - 1 + ky;
    if (iy >= 0 && iy < 256) {
      const f32x4 v = *(const f32x4*)&x[((n*3 + ci)*256 + iy)*256 + seg*4];
      s16x4 sv;
      #pragma unroll
      for (int e = 0; e < 4; ++e) sv[e] = (short)f2b(v[e]);
      *(s16x4*)&RAW[g*264 + 4 + seg*4] = sv;
    }
  }
  __syncthreads();
  // im2col: IC[ox][k]; short8 task (ox, kb): k=kb*8.., groups g0=2kb, g1=2kb+1
  for (int s = threadIdx.x; s < 1024; s += 256) {
    const int kb = s & 7, ox = s >> 3;
    short8 v = (short8)(short)0;
    if (kb < 6) {
      // shorts idx 2ox+3..2ox+6 of rows g0,g1 (= ix 2ox-1..2ox+2)
      const unsigned* u0 = (const unsigned*)&RAW[(2*kb  )*264 + 2*ox + 2];
      const unsigned* u1 = (const unsigned*)&RAW[(2*kb+1)*264 + 2*ox + 2];
      const unsigned a0 = u0[0], a1 = u0[1], a2 = u0[2];
      const unsigned b0 = u1[0], b1 = u1[1], b2 = u1[2];
      uint32x4 uv;
      uv[0] = (a0 >> 16) | (a1 << 16);
      uv[1] = (a1 >> 16) | (a2 << 16);
      uv[2] = (b0 >> 16) | (b1 << 16);
      uv[3] = (b1 >> 16) | (b2 << 16);
      v = __builtin_bit_cast(short8, uv);
    }
    const int bo = ((ox << 7) + (kb << 4)) ^ ((ox & 7) << 4);
    *(short8*)((char*)IC + bo) = v;
  }
  __syncthreads();
  const int w = threadIdx.x >> 6, l = threadIdx.x & 63;
  const int lm = l & 15, lk = l >> 4;
  f32x4 acc[2][4];
  #pragma unroll
  for (int mi = 0; mi < 2; ++mi)
    #pragma unroll
    for (int ni = 0; ni < 4; ++ni) acc[mi][ni] = (f32x4)0.0f;
  #pragma unroll
  for (int ks = 0; ks < 2; ++ks) {
    short8 bv[4];
    #pragma unroll
    for (int ni = 0; ni < 4; ++ni)
      bv[ni] = *(const short8*)(wv + (((ks*4 + ni)*64 + l) << 3));
    #pragma unroll
    for (int mi = 0; mi < 2; ++mi) {
      const int ox = w*32 + mi*16 + lm;
      const int bo = ((ox << 7) + (ks << 6) + (lk << 4)) ^ ((ox & 7) << 4);
      const short8 av = *(const short8*)((const char*)IC + bo);
      #pragma unroll
      for (int ni = 0; ni < 4; ++ni)
        acc[mi][ni] = __builtin_amdgcn_mfma_f32_16x16x32_bf16(
            __builtin_bit_cast(bf16x8, av),
            __builtin_bit_cast(bf16x8, bv[ni]),
            acc[mi][ni], 0, 0, 0);
    }
  }
  __syncthreads();            // frag reads done; reuse IC for output staging
  #pragma unroll
  for (int mi = 0; mi < 2; ++mi)
    #pragma unroll
    for (int ni = 0; ni < 4; ++ni) {
      const int co = ni*16 + lm;
      const float bv = bias[co];
      #pragma unroll
      for (int r = 0; r < 4; ++r) {
        const int ox = w*32 + mi*16 + lk*4 + r;
        const int bo = ((ox << 7) + 2*co) ^ ((ox & 7) << 4);
        *(short*)((char*)IC + bo) = (short)f2b(fmaxf(acc[mi][ni][r] + bv, 0.f));
      }
    }
  __syncthreads();
  const long ob = ((long)(n*128 + q)) * 8192;   // 128 ox * 64 co
  for (int s = threadIdx.x; s < 1024; s += 256) {
    const int kb = s & 7, ox = s >> 3;
    const int bo = ((ox << 7) + (kb << 4)) ^ ((ox & 7) << 4);
    *(short8*)&out[ob + ox*64 + kb*8] = *(const short8*)((const char*)IC + bo);
  }
}

// ---- conv2 via single-pass MFMA: h1 NHWC bf16 [32,128,128,64] ->
//      h2 NHWC bf16 [32,64,64,128].
__global__ __launch_bounds__(256) void conv2m_k(const unsigned short* __restrict__ in,
    const unsigned short* __restrict__ wv, const float* __restrict__ bias,
    unsigned short* __restrict__ out) {
  __shared__ short IL[8*66*64];        // [(r*2+p)*66 + idx][ci], 67584 B
  const int wid = (blockIdx.x & 7)*256 + (blockIdx.x >> 3);
  const int q = wid & 63, n = wid >> 6;          // q = output row oy
  for (int i = threadIdx.x; i < 4160; i += 256) {  // 4 rows * 130 cols * 8 parts
    const int part = i & 7, t = i >> 3, col = t % 130, r = t / 130;
    const int iy = 2*q - 1 + r, ix = col - 1;
    short8 v = (short8)(short)0;
    if (iy >= 0 && iy < 128 && ix >= 0 && ix < 128)
      v = *(const short8*)(in + (((n*128 + iy)*128 + ix)*64 + part*8));
    const int p = 1 - (ix & 1 ? 0 : 1);            // odd ix (incl -1) -> p=1
    const int idx = (ix & 1) ? ((ix + 1) >> 1) : (ix >> 1);
    const int bo = ((((r*2 + p)*66 + idx) << 7) + (part << 4)) ^ ((idx & 7) << 4);
    *(short8*)((char*)IL + bo) = v;
  }
  const int w = threadIdx.x >> 6, l = threadIdx.x & 63;
  const int lm = l & 15, lk = l >> 4;
  __syncthreads();
  f32x4 acc[4][2];
  #pragma unroll
  for (int mi = 0; mi < 4; ++mi)
    #pragma unroll
    for (int ni = 0; ni < 2; ++ni) acc[mi][ni] = (f32x4)0.0f;
  for (int ks = 0; ks < 32; ++ks) {                // (tap, cc): K=1024 total
    const int tap = ks >> 1, cc = ks & 1;
    const int ky = tap >> 2, kx = tap & 3;
    const int p = 1 - (kx & 1), d = kx >> 1;       // plane, idx offset
    short8 bv[2];
    #pragma unroll
    for (int ni = 0; ni < 2; ++ni)
      bv[ni] = *(const short8*)(wv + (((ks*8 + w*2 + ni)*64 + l) << 3));
    #pragma unroll
    for (int mi = 0; mi < 4; ++mi) {
      const int idx = mi*16 + lm + d;
      const int bo = ((((ky*2 + p)*66 + idx) << 7) + (cc << 6) + (lk << 4))
                     ^ ((idx & 7) << 4);
      const short8 av = *(const short8*)((const char*)IL + bo);
      #pragma unroll
      for (int ni = 0; ni < 2; ++ni)
        acc[mi][ni] = __builtin_amdgcn_mfma_f32_16x16x32_bf16(
            __builtin_bit_cast(bf16x8, av),
            __builtin_bit_cast(bf16x8, bv[ni]),
            acc[mi][ni], 0, 0, 0);
    }
  }
  #pragma unroll
  for (int mi = 0; mi < 4; ++mi)
    #pragma unroll
    for (int r = 0; r < 4; ++r) {
      const int ox = mi*16 + lk*4 + r;
      const int ob = ((n*64 + q)*64 + ox)*128;
      #pragma unroll
      for (int ni = 0; ni < 2; ++ni) {
        const int co = (w*2 + ni)*16 + lm;
        out[ob + co] = f2b(fmaxf(acc[mi][ni][r] + bias[co], 0.f));
      }
    }
}

// ---- d2 convT via merged-parity MFMA: d1 NHWC bf16 [32,64,64,128] ->
//      d2 NHWC bf16 [32,128,128,64].
__global__ __launch_bounds__(256) void convt2m_k(const unsigned short* __restrict__ in,
    const unsigned short* __restrict__ wv, const float* __restrict__ bias,
    unsigned short* __restrict__ out) {
  __shared__ short IL[3*66*128];       // 50688 B, byteoff ^= ((col&7)<<4)
  const int wid = (blockIdx.x & 7)*256 + (blockIdx.x >> 3);
  const int q = wid & 63, n = wid >> 6;
  for (int i = threadIdx.x; i < 3168; i += 256) {   // 3 rows * 66 cols * 16 parts
    const int part = i & 15, t = i >> 4, col = t % 66, r = t / 66;
    const int iy = q - 1 + r, ix = col - 1;
    short8 v = (short8)(short)0;
    if (iy >= 0 && iy < 64 && ix >= 0 && ix < 64)
      v = *(const short8*)(in + (((n*64 + iy)*64 + ix)*128 + part*8));
    const int bo = (((r*66 + col) << 8) + (part << 4)) ^ ((col & 7) << 4);
    *(short8*)((char*)IL + bo) = v;
  }
  const int w = threadIdx.x >> 6, l = threadIdx.x & 63;
  const int py = w >> 1, px = w & 1;
  const int lm = l & 15, lk = l >> 4;
  __syncthreads();
  f32x4 acc[4][4];
  #pragma unroll
  for (int mi = 0; mi < 4; ++mi)
    #pragma unroll
    for (int ni = 0; ni < 4; ++ni) acc[mi][ni] = (f32x4)0.0f;
  for (int ks = 0; ks < 16; ++ks) {                  // (a,b,cc): K=512 total
    const int a = ks >> 3, b = (ks >> 2) & 1, cc = ks & 3;
    short8 bv[4];
    #pragma unroll
    for (int ni = 0; ni < 4; ++ni)
      bv[ni] = *(const short8*)(wv + ((((w*16 + ks)*4 + ni)*64 + l) << 3));
    const int r = py + a;
    #pragma unroll
    for (int mi = 0; mi < 4; ++mi) {
      const int col = mi*16 + lm + px + b;
      const int bo = (((r*66 + col) << 8) + (cc << 6) + (lk << 4)) ^ ((col & 7) << 4);
      const short8 av = *(const short8*)((const char*)IL + bo);
      #pragma unroll
      for (int ni = 0; ni < 4; ++ni)
        acc[mi][ni] = __builtin_amdgcn_mfma_f32_16x16x32_bf16(
            __builtin_bit_cast(bf16x8, av),
            __builtin_bit_cast(bf16x8, bv[ni]),
            acc[mi][ni], 0, 0, 0);
    }
  }
  const int oy = 2*q + py;
  #pragma unroll
  for (int mi = 0; mi < 4; ++mi)
    #pragma unroll
    for (int r = 0; r < 4; ++r) {
      const int ox = 2*(mi*16 + lk*4 + r) + px;
      const int ob = ((n*128 + oy)*128 + ox)*64;
      #pragma unroll
      for (int ni = 0; ni < 4; ++ni) {
        const int co = ni*16 + lm;
        out[ob + co] = f2b(fmaxf(acc[mi][ni][r] + bias[co], 0.f));
      }
    }
}

// ------- VQ via MFMA: z fp32 [131072,32] -> zq fp32 + loss partials ---------
__global__ __launch_bounds__(256) void vqm_k(const float* __restrict__ z,
    const float* __restrict__ embed, float* __restrict__ zq,
    float* __restrict__ partial) {
  __shared__ short Be[512*40];     // bf16 codes, pad stride 40 (40960 B)
  __shared__ float en[512];        // |e|^2 (bf16-rounded e), fp32
  __shared__ int   bidx[128];
  __shared__ float red[256];
  const int m0 = blockIdx.x * 128;
  for (int i = threadIdx.x; i < 4096; i += 256) {
    const int j = i >> 3, k0 = (i & 7) * 4;
    const f32x4 v = *(const f32x4*)&embed[j*32 + k0];
    s16x4 s;
    #pragma unroll
    for (int e = 0; e < 4; ++e) s[e] = (short)f2b(v[e]);
    *(s16x4*)&Be[j*40 + k0] = s;
  }
  __syncthreads();
  for (int j = threadIdx.x; j < 512; j += 256) {
    float s = 0.f;
    #pragma unroll
    for (int q = 0; q < 4; ++q) {
      const short8 v = *(const short8*)&Be[j*40 + q*8];
      #pragma unroll
      for (int e = 0; e < 8; ++e) {
        const float f = b2f((unsigned short)v[e]);
        s = fmaf(f, f, s);
      }
    }
    en[j] = s;
  }
  __syncthreads();
  const int w = threadIdx.x >> 6, l = threadIdx.x & 63;
  const int lm = l & 15, lk = l >> 4;
  const int rw = w * 32;
  short8 av[2];
  #pragma unroll
  for (int mi = 0; mi < 2; ++mi) {
    const float* zp = z + (long)(m0 + rw + mi*16 + lm)*32 + lk*8;
    const f32x4 f0 = *(const f32x4*)zp;
    const f32x4 f1 = *(const f32x4*)(zp + 4);
    short8 v;
    #pragma unroll
    for (int e = 0; e < 4; ++e) {
      v[e]     = (short)f2b(f0[e]);
      v[e + 4] = (short)f2b(f1[e]);
    }
    av[mi] = v;
  }
  float bd[2][4]; int bj[2][4];
  #pragma unroll
  for (int mi = 0; mi < 2; ++mi)
    #pragma unroll
    for (int r = 0; r < 4; ++r) { bd[mi][r] = 1e30f; bj[mi][r] = 0; }
  for (int nc = 0; nc < 8; ++nc) {               // N-chunks of 64 codes
    f32x4 acc[2][4];
    #pragma unroll
    for (int mi = 0; mi < 2; ++mi)
      #pragma unroll
      for (int ni = 0; ni < 4; ++ni) acc[mi][ni] = (f32x4)0.0f;
    #pragma unroll
    for (int ni = 0; ni < 4; ++ni) {
      const short8 bv = *(const short8*)&Be[(nc*64 + ni*16 + lm)*40 + lk*8];
      #pragma unroll
      for (int mi = 0; mi < 2; ++mi)
        acc[mi][ni] = __builtin_amdgcn_mfma_f32_16x16x32_bf16(
            __builtin_bit_cast(bf16x8, av[mi]),
            __builtin_bit_cast(bf16x8, bv),
            acc[mi][ni], 0, 0, 0);
    }
    #pragma unroll
    for (int ni = 0; ni < 4; ++ni) {
      const int j = nc*64 + ni*16 + lm;
      const float e_n = en[j];
      #pragma unroll
      for (int mi = 0; mi < 2; ++mi)
        #pragma unroll
        for (int r = 0; r < 4; ++r) {
          const float d = fmaf(-2.f, acc[mi][ni][r], e_n);
          if (d < bd[mi][r]) { bd[mi][r] = d; bj[mi][r] = j; }
        }
    }
  }
  #pragma unroll
  for (int mi = 0; mi < 2; ++mi)
    #pragma unroll
    for (int r = 0; r < 4; ++r) {
      float d = bd[mi][r]; int j = bj[mi][r];
      #pragma unroll
      for (int off = 1; off < 16; off <<= 1) {
        const float od = __shfl_xor(d, off);
        const int   oj = __shfl_xor(j, off);
        if (od < d || (od == d && oj < j)) { d = od; j = oj; }
      }
      if (lm == 0) bidx[rw + mi*16 + lk*4 + r] = j;
    }
  __syncthreads();
  const int pl = threadIdx.x >> 1, hf = (threadIdx.x & 1) * 16;
  const int code = bidx[pl];
  const long pb = (long)(m0 + pl)*32 + hf;
  float se = 0.f;
  #pragma unroll
  for (int q = 0; q < 4; ++q) {
    const f32x4 ev = *(const f32x4*)&embed[code*32 + hf + q*4];
    const f32x4 zv = *(const f32x4*)&z[pb + q*4];
    *(f32x4*)&zq[pb + q*4] = ev;
    const f32x4 df = ev - zv;
    #pragma unroll
    for (int e = 0; e < 4; ++e) se = fmaf(df[e], df[e], se);
  }
  red[threadIdx.x] = se; __syncthreads();
  for (int s = 128; s > 0; s >>= 1) {
    if (threadIdx.x < s) red[threadIdx.x] += red[threadIdx.x + s];
    __syncthreads();
  }
  if (threadIdx.x == 0) partial[blockIdx.x] = red[0];
}

__global__ __launch_bounds__(256) void loss_k(const float* __restrict__ part,
                                              float* __restrict__ out) {
  __shared__ float red[256];
  const int t = threadIdx.x;
  float s = 0.f;
  #pragma unroll
  for (int q = 0; q < 4; ++q) s += part[t + q*256];   // 1024 partials
  red[t] = s; __syncthreads();
  for (int st = 128; st > 0; st >>= 1) {
    if (t < st) red[t] += red[t + st];
    __syncthreads();
  }
  if (t == 0) out[0] = red[0] * (1.25f / (131072.f * 32.f));
}

// ---- convt3 via MFMA: d2 NHWC bf16 [32,128,128,64] -> x_recon NCHW fp32 ----
__global__ __launch_bounds__(256) void convt3m_k(const unsigned short* __restrict__ in,
    const unsigned short* __restrict__ wq6, const float* __restrict__ bias,
    float* __restrict__ out) {
  __shared__ short8 IL[3*8*66];      // [(r*8+c8)*66 + ixl], 25344 B
  const int h = blockIdx.x & 1, q = (blockIdx.x >> 1) & 127, n = blockIdx.x >> 8;
  for (int i = threadIdx.x; i < 1584; i += 256) {   // 3*66*8
    const int c8 = i & 7, t = i >> 3, ixl = t % 66, r = t / 66;
    const int iy = q - 1 + r, ix = h*64 - 1 + ixl;
    short8 v = (short8)(short)0;
    if (iy >= 0 && iy < 128 && ix >= 0 && ix < 128)
      v = *(const short8*)(in + (((long)(n*128 + iy)*128 + ix)*64 + c8*8));
    IL[(r*8 + c8)*66 + ixl] = v;
  }
  const int w = threadIdx.x >> 6, l = threadIdx.x & 63;
  const int py = w >> 1, px = w & 1;
  const int lm = l & 15, lk = l >> 4;
  short8 bfrag[8];
  #pragma unroll
  for (int kc = 0; kc < 8; ++kc)
    bfrag[kc] = *(const short8*)(wq6 + (((w*8 + kc)*64 + l) << 3));
  __syncthreads();
  f32x4 acc[4];
  #pragma unroll
  for (int mi = 0; mi < 4; ++mi) acc[mi] = (f32x4)0.0f;
  #pragma unroll
  for (int kc = 0; kc < 8; ++kc) {
    const int a = kc >> 2, b = (kc >> 1) & 1, ch = kc & 1;
    const int base = (((py + a)*8 + ch*4 + lk)*66) + px + b;   // + ixl(xq)
    #pragma unroll
    for (int mi = 0; mi < 4; ++mi) {
      const short8 av = *(const short8*)&IL[base + mi*16 + lm];
      acc[mi] = __builtin_amdgcn_mfma_f32_16x16x32_bf16(
          __builtin_bit_cast(bf16x8, av),
          __builtin_bit_cast(bf16x8, bfrag[kc]),
          acc[mi], 0, 0, 0);
    }
  }
  // epilogue: C row = xq (lk*4+r within tile), col = co (lanes lm<3 write)
  if (lm < 3) {
    const float bv = bias[lm];
    const int oy = 2*q + py;
    const long ob = ((long)(n*3 + lm))*65536 + oy*256;
    #pragma unroll
    for (int mi = 0; mi < 4; ++mi)
      #pragma unroll
      for (int r = 0; r < 4; ++r) {
        const int xq = mi*16 + lk*4 + r;
        out[ob + h*128 + 2*xq + px] = acc[mi][r] + bv;
      }
  }
}

extern "C" void kernel_launch(void* const* d_in, const int* in_sizes, int n_in,
                              void* d_out, int out_size, void* d_ws, size_t ws_size,
                              hipStream_t stream) {
  const float* x   = (const float*)d_in[0];
  const float* ew1 = (const float*)d_in[1];  const float* eb1 = (const float*)d_in[2];
  const float* ew2 = (const float*)d_in[3];  const float* eb2 = (const float*)d_in[4];
  const float* ew3 = (const float*)d_in[5];  const float* eb3 = (const float*)d_in[6];
  const float* emb = (const float*)d_in[7];
  const float* dw1 = (const float*)d_in[8];  const float* db1 = (const float*)d_in[9];
  const float* dw2 = (const float*)d_in[10]; const float* db2 = (const float*)d_in[11];
  const float* dw3 = (const float*)d_in[12]; const float* db3 = (const float*)d_in[13];
  float* out = (float*)d_out;

  // ws layout (bytes), total 134,217,728:
  //   h1  NHWC bf16 [32,128,128,64]  @ 0          (67108864)   -> reused as d2
  //   h2  NHWC bf16 [32, 64, 64,128] @ 67108864   (33554432)   -> reused as d1
  //   z   f32  [131072,32]           @ 100663296  (16777216)
  //   zq  f32  [131072,32]           @ 117440512  (16777216)
  //   loss partials (1024 f32) @ 67108864 — h2 region, DEAD during vqm_k
  //   wq2/wq3/wq1 overlaid in zq region (dead until vqm writes zq);
  //   wq4/wq5v/wq6 overlaid in z region (written after vqm, z dead then).
  uint8_t* w8 = (uint8_t*)d_ws;
  unsigned short* h1 = (unsigned short*)w8;
  unsigned short* h2 = (unsigned short*)(w8 + 67108864);
  float* z   = (float*)(w8 + 100663296);
  float* zq  = (float*)(w8 + 117440512);
  float* part = (float*)(w8 + 67108864);              // h2 region (dead @ vqm)
  unsigned short* wq2 = (unsigned short*)(w8 + 117440512);            // 262144 B
  unsigned short* wq3 = (unsigned short*)(w8 + 117440512 + 262144);   // 73728 B
  unsigned short* wq1 = (unsigned short*)(w8 + 117440512 + 335872);   // 8192 B
  unsigned short* wq4 = (unsigned short*)(w8 + 100663296);            // 73728 B
  unsigned short* wq5 = (unsigned short*)(w8 + 100663296 + 73728);    // 262144 B
  unsigned short* wq6 = (unsigned short*)(w8 + 100663296 + 335872);   // 32768 B
  unsigned short* d1 = h2;
  unsigned short* d2 = h1;

  // encoder weight prep (into zq region, consumed before vqm writes zq)
  prep1v_k<<<dim3(16),256,0,stream>>>(ew1, wq1);
  prep2v_k<<<dim3(512),256,0,stream>>>(ew2, wq2);
  prep3_k<<<dim3(144),256,0,stream>>>(ew3, wq3);
  // encoder
  conv1m_k<<<dim3(4096),256,0,stream>>>(x, wq1, eb1, h1);
  conv2m_k<<<dim3(2048),256,0,stream>>>(h1, wq2, eb2, h2);
  mconv_k<128,32,64,1,3,9,1,1,false,true,false,true>
      <<<dim3(1024),256,0,stream>>>(h2, wq3, eb3, z);
  // VQ (MFMA) + loss  (partials in h2 region; loss_k consumes before d1 write)
  vqm_k<<<dim3(1024),256,0,stream>>>(z, emb, zq, part);
  loss_k<<<dim3(1),256,0,stream>>>(part, out + 6291456);
  // decoder weight prep (into z region, dead after vqm)
  prep4_k<<<dim3(144),256,0,stream>>>(dw1, wq4);
  prep5v_k<<<dim3(512),256,0,stream>>>(dw2, wq5);
  prep6_k<<<dim3(64),256,0,stream>>>(dw3, wq6);
  // decoder
  mconv_k<32,128,64,1,3,9,1,1,false,true,true,false>
      <<<dim3(1024),256,0,stream>>>(zq, wq4, db1, d1);
  convt2m_k<<<dim3(2048),256,0,stream>>>(d1, wq5, db2, d2);
  convt3m_k<<<dim3(8192),256,0,stream>>>(d2, wq6, db3, out);
}

// Round 5
// 404.483 us; speedup vs baseline: 1.2808x; 1.0100x over previous
//
#include <hip/hip_runtime.h>

// VQ-VAE forward, MI355X round 15: R14 + conv2m/convt2m ks-loops fully
// unrolled with algebraically-precomputed swizzled LDS addresses (zero VALU
// per A-read) and compile-time B-frag offsets (prefetchable load stream).

typedef __attribute__((ext_vector_type(8))) short     short8;
typedef __attribute__((ext_vector_type(4))) short     s16x4;
typedef __attribute__((ext_vector_type(8))) __bf16    bf16x8;
typedef __attribute__((ext_vector_type(4))) float     f32x4;
typedef __attribute__((ext_vector_type(4))) unsigned  uint32x4;

#define BATCH 32

__device__ __forceinline__ float b2f(unsigned short b) {
  union { unsigned u; float f; } v; v.u = ((unsigned)b) << 16; return v.f;
}
__device__ __forceinline__ unsigned short f2b(float f) {  // round-to-nearest-even
  union { float f; unsigned u; } v; v.f = f;
  unsigned r = v.u + 0x7FFF + ((v.u >> 16) & 1);
  return (unsigned short)(r >> 16);
}

// ---------------- weight prep ------------------------------------------------
// conv1 B-frags: wq1[((ks*4+ni)*64+l)*8+j] = ew1[co=ni*16+lm][k], k=ks*32+lk*8+j
__global__ __launch_bounds__(256) void prep1v_k(const float* __restrict__ w,
                                                unsigned short* __restrict__ wq) {
  const int i = blockIdx.x*256 + threadIdx.x;                 // 4096 exact
  const int j = i & 7, l = (i >> 3) & 63, ni = (i >> 9) & 3, ks = i >> 11;
  const int k = ks*32 + (l >> 4)*8 + j;
  const int co = ni*16 + (l & 15);
  wq[i] = (k < 48) ? f2b(w[co*48 + k]) : (unsigned short)0;
}
// conv2 B-frags, frag-ordered for conv2m_k:
__global__ __launch_bounds__(256) void prep2v_k(const float* __restrict__ w,
                                                unsigned short* __restrict__ wq) {
  const int i = blockIdx.x*256 + threadIdx.x;                 // 131072 exact
  const int j = i & 7, l = (i >> 3) & 63, ni = (i >> 9) & 7, ks = i >> 12;
  const int lm = l & 15, lk = l >> 4;
  const int tap = ks >> 1, cc = ks & 1;
  const int co = ni*16 + lm, ci = cc*32 + lk*8 + j;
  wq[i] = f2b(w[(co*64 + ci)*16 + tap]);
}
__global__ __launch_bounds__(256) void prep3_k(const float* __restrict__ w,
                                               unsigned short* __restrict__ wq) {
  const int i = blockIdx.x*256 + threadIdx.x;                 // 36864 exact
  const int ci = i & 127, co = (i >> 7) & 31, t = i >> 12;
  wq[i] = f2b(w[(co*128 + ci)*9 + t]);                        // ew3 OIHW(32,128,3,3)
}
__global__ __launch_bounds__(256) void prep4_k(const float* __restrict__ w,
                                               unsigned short* __restrict__ wq) {
  const int i = blockIdx.x*256 + threadIdx.x;                 // 36864 exact
  const int ci = i & 31, co = (i >> 5) & 127, t = i >> 12;
  wq[i] = f2b(w[(ci*128 + co)*9 + (8 - t)]);                  // dw1(32,128,3,3), flipped
}
// d2 convT B-frags, frag-ordered for convt2m_k:
__global__ __launch_bounds__(256) void prep5v_k(const float* __restrict__ w,
                                                unsigned short* __restrict__ wq) {
  const int i = blockIdx.x*256 + threadIdx.x;                 // 131072 exact
  const int j = i & 7, l = (i >> 3) & 63, ni = (i >> 9) & 3;
  const int ks = (i >> 11) & 15, p = i >> 15;
  const int lm = l & 15, lk = l >> 4;
  const int py = p >> 1, px = p & 1;
  const int a = ks >> 3, b = (ks >> 2) & 1, cc = ks & 3;
  const int co = ni*16 + lm, ci = cc*32 + lk*8 + j;
  const int ky = 3 - 2*a - py, kx = 3 - 2*b - px;
  wq[i] = f2b(w[(ci*64 + co)*16 + ky*4 + kx]);                // dw2(128,64,4,4)
}
// convt3 B-frags: wq6[p][kc][lane l][j] = w[tap(a,b,p)][ci=(kc&1)*32+lk*8+j][co=lm]
__global__ __launch_bounds__(256) void prep6_k(const float* __restrict__ w,
                                               unsigned short* __restrict__ wq) {
  const int i = blockIdx.x*256 + threadIdx.x;                 // 16384 exact
  const int j = i & 7, l = (i >> 3) & 63, kc = (i >> 9) & 7, p = i >> 12;
  const int lm = l & 15, lk = l >> 4;
  const int a = kc >> 2, b = (kc >> 1) & 1, ch = kc & 1;
  const int ci = ch*32 + lk*8 + j, co = lm;
  const int py = p >> 1, px = p & 1;
  const int ky = 2 - 2*a + (1 - py), kx = 2 - 2*b + (1 - px);
  wq[i] = (co < 3) ? f2b(w[(ci*3 + co)*16 + ky*4 + kx]) : (unsigned short)0;
}

// --------- MFMA implicit-GEMM conv: NHWC in -> NHWC out (64x64 spatial) -----
template<int CIN,int COUT,int HIN,int S,int KW,int NTAPS,int OSTRIDE,int P,
         bool PARITY,bool RELU,bool INF32,bool OUTF32>
__global__ __launch_bounds__(256) void mconv_k(const void* __restrict__ in_,
    const unsigned short* __restrict__ wq_, const float* __restrict__ bias,
    void* __restrict__ out_) {
  constexpr int NF  = COUT / 16;
  constexpr int NCH = CIN / 32;
  __shared__ short Al[128*40];      // 128 rows x 32 k, stride 40 (80B, 16B-mult)
  __shared__ short Bl[COUT*40];
  int py = 0, px = 0, PY = P, PX = P;
  const unsigned short* wq = wq_;
  if (PARITY) {
    py = blockIdx.y >> 1; px = blockIdx.y & 1;
    PY = 1 - py; PX = 1 - px;
    wq += blockIdx.y * (NTAPS*COUT*CIN);
  }
  const int m0 = blockIdx.x * 128;
  const int w  = threadIdx.x >> 6, l = threadIdx.x & 63;
  const int lm = l & 15, lk = l >> 4;
  f32x4 acc[2][NF];
  #pragma unroll
  for (int mi = 0; mi < 2; ++mi)
    #pragma unroll
    for (int ni = 0; ni < NF; ++ni) acc[mi][ni] = (f32x4)0.0f;

  for (int tap = 0; tap < NTAPS; ++tap) {
    const int ky = tap / KW, kx = tap % KW;
    for (int ch = 0; ch < NCH; ++ch) {
      const int c0 = ch * 32;
      __syncthreads();                       // prev iter frag reads done
      for (int s = threadIdx.x; s < 512; s += 256) {
        const int row = s >> 2, part = s & 3;
        const int m = m0 + row;
        const int n = m >> 12, oy = (m >> 6) & 63, ox = m & 63;
        const int iy = oy*S - PY + ky, ix = ox*S - PX + kx;
        short8 v = (short8)(short)0;
        if (iy >= 0 && iy < HIN && ix >= 0 && ix < HIN) {
          const int base = ((n*HIN + iy)*HIN + ix)*CIN + c0 + part*8;
          if (INF32) {
            const float* pf = (const float*)in_ + base;
            const f32x4 f0 = *(const f32x4*)pf;
            const f32x4 f1 = *(const f32x4*)(pf + 4);
            #pragma unroll
            for (int j = 0; j < 4; ++j) {
              v[j]     = (short)f2b(f0[j]);
              v[j + 4] = (short)f2b(f1[j]);
            }
          } else {
            v = *(const short8*)((const unsigned short*)in_ + base);
          }
        }
        *(short8*)&Al[row*40 + part*8] = v;
      }
      for (int s = threadIdx.x; s < COUT*4; s += 256) {
        const int co = s >> 2, part = s & 3;
        *(short8*)&Bl[co*40 + part*8] =
            *(const short8*)(wq + (tap*COUT + co)*CIN + c0 + part*8);
      }
      __syncthreads();
      short8 av[2];
      #pragma unroll
      for (int mi = 0; mi < 2; ++mi)
        av[mi] = *(const short8*)&Al[(w*32 + mi*16 + lm)*40 + lk*8];
      #pragma unroll
      for (int ni = 0; ni < NF; ++ni) {
        const short8 bv = *(const short8*)&Bl[(ni*16 + lm)*40 + lk*8];
        #pragma unroll
        for (int mi = 0; mi < 2; ++mi)
          acc[mi][ni] = __builtin_amdgcn_mfma_f32_16x16x32_bf16(
              __builtin_bit_cast(bf16x8, av[mi]),
              __builtin_bit_cast(bf16x8, bv),
              acc[mi][ni], 0, 0, 0);
      }
    }
  }
  #pragma unroll
  for (int ni = 0; ni < NF; ++ni) {
    const int co = ni*16 + lm;
    const float bv = bias[co];
    #pragma unroll
    for (int mi = 0; mi < 2; ++mi) {
      #pragma unroll
      for (int r = 0; r < 4; ++r) {
        const int ml = w*32 + mi*16 + lk*4 + r;
        const int m  = m0 + ml;
        float vv = acc[mi][ni][r] + bv;
        if (RELU) vv = fmaxf(vv, 0.f);
        int off;
        if (OSTRIDE == 1) {
          off = m*COUT + co;
        } else {
          const int n = m >> 12, oy = (m >> 6) & 63, ox = m & 63;
          off = ((n*128 + oy*2 + py)*128 + ox*2 + px)*COUT + co;
        }
        if (OUTF32) ((float*)out_)[off] = vv;
        else ((unsigned short*)out_)[off] = f2b(vv);
      }
    }
  }
}

// ---- conv1 via MFMA: x NCHW fp32 [32,3,256,256] -> h1 NHWC bf16 ------------
__global__ __launch_bounds__(256) void conv1m_k(const float* __restrict__ x,
    const unsigned short* __restrict__ wv, const float* __restrict__ bias,
    unsigned short* __restrict__ out) {
  __shared__ __align__(16) short RAW[12*264];   // row g=ci*4+ky, idx=ix+4; 6336B
  __shared__ __align__(16) short IC[128*64];    // [ox][k] swizzled; 16384B
  const int wid = ((blockIdx.x & 7) << 9) + (blockIdx.x >> 3);
  const int q = wid & 127, n = wid >> 7;        // q = output row oy
  for (int i = threadIdx.x; i < 396; i += 256)
    *(short8*)&RAW[i*8] = (short8)(short)0;
  __syncthreads();
  for (int s = threadIdx.x; s < 768; s += 256) {   // 12 rows * 64 f32x4
    const int g = s >> 6, seg = s & 63;
    const int ci = g >> 2, ky = g & 3;
    const int iy = 2*q - 1 + ky;
    if (iy >= 0 && iy < 256) {
      const f32x4 v = *(const f32x4*)&x[((n*3 + ci)*256 + iy)*256 + seg*4];
      s16x4 sv;
      #pragma unroll
      for (int e = 0; e < 4; ++e) sv[e] = (short)f2b(v[e]);
      *(s16x4*)&RAW[g*264 + 4 + seg*4] = sv;
    }
  }
  __syncthreads();
  for (int s = threadIdx.x; s < 1024; s += 256) {
    const int kb = s & 7, ox = s >> 3;
    short8 v = (short8)(short)0;
    if (kb < 6) {
      const unsigned* u0 = (const unsigned*)&RAW[(2*kb  )*264 + 2*ox + 2];
      const unsigned* u1 = (const unsigned*)&RAW[(2*kb+1)*264 + 2*ox + 2];
      const unsigned a0 = u0[0], a1 = u0[1], a2 = u0[2];
      const unsigned b0 = u1[0], b1 = u1[1], b2 = u1[2];
      uint32x4 uv;
      uv[0] = (a0 >> 16) | (a1 << 16);
      uv[1] = (a1 >> 16) | (a2 << 16);
      uv[2] = (b0 >> 16) | (b1 << 16);
      uv[3] = (b1 >> 16) | (b2 << 16);
      v = __builtin_bit_cast(short8, uv);
    }
    const int bo = ((ox << 7) + (kb << 4)) ^ ((ox & 7) << 4);
    *(short8*)((char*)IC + bo) = v;
  }
  __syncthreads();
  const int w = threadIdx.x >> 6, l = threadIdx.x & 63;
  const int lm = l & 15, lk = l >> 4;
  f32x4 acc[2][4];
  #pragma unroll
  for (int mi = 0; mi < 2; ++mi)
    #pragma unroll
    for (int ni = 0; ni < 4; ++ni) acc[mi][ni] = (f32x4)0.0f;
  #pragma unroll
  for (int ks = 0; ks < 2; ++ks) {
    short8 bv[4];
    #pragma unroll
    for (int ni = 0; ni < 4; ++ni)
      bv[ni] = *(const short8*)(wv + (((ks*4 + ni)*64 + l) << 3));
    #pragma unroll
    for (int mi = 0; mi < 2; ++mi) {
      const int ox = w*32 + mi*16 + lm;
      const int bo = ((ox << 7) + (ks << 6) + (lk << 4)) ^ ((ox & 7) << 4);
      const short8 av = *(const short8*)((const char*)IC + bo);
      #pragma unroll
      for (int ni = 0; ni < 4; ++ni)
        acc[mi][ni] = __builtin_amdgcn_mfma_f32_16x16x32_bf16(
            __builtin_bit_cast(bf16x8, av),
            __builtin_bit_cast(bf16x8, bv[ni]),
            acc[mi][ni], 0, 0, 0);
    }
  }
  __syncthreads();            // frag reads done; reuse IC for output staging
  #pragma unroll
  for (int mi = 0; mi < 2; ++mi)
    #pragma unroll
    for (int ni = 0; ni < 4; ++ni) {
      const int co = ni*16 + lm;
      const float bv = bias[co];
      #pragma unroll
      for (int r = 0; r < 4; ++r) {
        const int ox = w*32 + mi*16 + lk*4 + r;
        const int bo = ((ox << 7) + 2*co) ^ ((ox & 7) << 4);
        *(short*)((char*)IC + bo) = (short)f2b(fmaxf(acc[mi][ni][r] + bv, 0.f));
      }
    }
  __syncthreads();
  const long ob = ((long)(n*128 + q)) * 8192;   // 128 ox * 64 co
  for (int s = threadIdx.x; s < 1024; s += 256) {
    const int kb = s & 7, ox = s >> 3;
    const int bo = ((ox << 7) + (kb << 4)) ^ ((ox & 7) << 4);
    *(short8*)&out[ob + ox*64 + kb*8] = *(const short8*)((const char*)IC + bo);
  }
}

// ---- conv2 via single-pass MFMA: h1 NHWC bf16 [32,128,128,64] ->
//      h2 NHWC bf16 [32,64,64,128].  ks-loop fully unrolled; swizzled LDS
//      address = precomputed per-thread base (Bdc) + compile-time immediate.
__global__ __launch_bounds__(256) void conv2m_k(const unsigned short* __restrict__ in,
    const unsigned short* __restrict__ wv, const float* __restrict__ bias,
    unsigned short* __restrict__ out) {
  __shared__ short IL[8*66*64];        // [(r*2+p)*66 + idx][ci], 67584 B
  const int wid = (blockIdx.x & 7)*256 + (blockIdx.x >> 3);
  const int q = wid & 63, n = wid >> 6;          // q = output row oy
  for (int i = threadIdx.x; i < 4160; i += 256) {  // 4 rows * 130 cols * 8 parts
    const int part = i & 7, t = i >> 3, col = t % 130, r = t / 130;
    const int iy = 2*q - 1 + r, ix = col - 1;
    short8 v = (short8)(short)0;
    if (iy >= 0 && iy < 128 && ix >= 0 && ix < 128)
      v = *(const short8*)(in + (((n*128 + iy)*128 + ix)*64 + part*8));
    const int p = 1 - (ix & 1 ? 0 : 1);            // odd ix (incl -1) -> p=1
    const int idx = (ix & 1) ? ((ix + 1) >> 1) : (ix >> 1);
    const int bo = ((((r*2 + p)*66 + idx) << 7) + (part << 4)) ^ ((idx & 7) << 4);
    *(short8*)((char*)IL + bo) = v;
  }
  const int w = threadIdx.x >> 6, l = threadIdx.x & 63;
  const int lm = l & 15, lk = l >> 4;
  // A-addr decomposition: bo(ks,mi) = [((ky*2+p)*66)<<7 + mi*2048]imm + Bdc[d][cc]
  // Bdc[d][cc] = ((lm+d)<<7) + ((lk<<4)^(x&0x30)) + ((x&0x40)^(cc<<6)),
  // x = ((lm+d)&7)<<4.  (bits 4-6 carry-free since cc*64+lk*16<128)
  int Bdc[2][2];
  #pragma unroll
  for (int d = 0; d < 2; ++d) {
    const int xd = ((lm + d) & 7) << 4;
    const int bs = ((lm + d) << 7) + ((lk << 4) ^ (xd & 0x30));
    Bdc[d][0] = bs + (xd & 0x40);
    Bdc[d][1] = bs + ((xd & 0x40) ^ 0x40);
  }
  const unsigned short* wb = wv + w*1024 + l*8;   // + ks*4096 + ni*512 (shorts)
  __syncthreads();
  f32x4 acc[4][2];
  #pragma unroll
  for (int mi = 0; mi < 4; ++mi)
    #pragma unroll
    for (int ni = 0; ni < 2; ++ni) acc[mi][ni] = (f32x4)0.0f;
  #pragma unroll
  for (int ks = 0; ks < 32; ++ks) {                // (tap, cc): K=1024 total
    const int tap = ks >> 1, cc = ks & 1;
    const int ky = tap >> 2, kx = tap & 3;
    const int p = 1 - (kx & 1), d = kx >> 1;       // plane, idx offset
    short8 bv[2];
    bv[0] = *(const short8*)(wb + ks*4096);
    bv[1] = *(const short8*)(wb + ks*4096 + 512);
    const char* Ab = (const char*)IL + Bdc[d][cc];
    const int imm0 = ((ky*2 + p)*66) << 7;         // compile-time
    #pragma unroll
    for (int mi = 0; mi < 4; ++mi) {
      const short8 av = *(const short8*)(Ab + imm0 + mi*2048);
      #pragma unroll
      for (int ni = 0; ni < 2; ++ni)
        acc[mi][ni] = __builtin_amdgcn_mfma_f32_16x16x32_bf16(
            __builtin_bit_cast(bf16x8, av),
            __builtin_bit_cast(bf16x8, bv[ni]),
            acc[mi][ni], 0, 0, 0);
    }
  }
  #pragma unroll
  for (int mi = 0; mi < 4; ++mi)
    #pragma unroll
    for (int r = 0; r < 4; ++r) {
      const int ox = mi*16 + lk*4 + r;
      const int ob = ((n*64 + q)*64 + ox)*128;
      #pragma unroll
      for (int ni = 0; ni < 2; ++ni) {
        const int co = (w*2 + ni)*16 + lm;
        out[ob + co] = f2b(fmaxf(acc[mi][ni][r] + bias[co], 0.f));
      }
    }
}

// ---- d2 convT via merged-parity MFMA: d1 NHWC bf16 [32,64,64,128] ->
//      d2 NHWC bf16 [32,128,128,64].  ks-loop unrolled + precomputed bases.
__global__ __launch_bounds__(256) void convt2m_k(const unsigned short* __restrict__ in,
    const unsigned short* __restrict__ wv, const float* __restrict__ bias,
    unsigned short* __restrict__ out) {
  __shared__ short IL[3*66*128];       // 50688 B, byteoff ^= ((col&7)<<4)
  const int wid = (blockIdx.x & 7)*256 + (blockIdx.x >> 3);
  const int q = wid & 63, n = wid >> 6;
  for (int i = threadIdx.x; i < 3168; i += 256) {   // 3 rows * 66 cols * 16 parts
    const int part = i & 15, t = i >> 4, col = t % 66, r = t / 66;
    const int iy = q - 1 + r, ix = col - 1;
    short8 v = (short8)(short)0;
    if (iy >= 0 && iy < 64 && ix >= 0 && ix < 64)
      v = *(const short8*)(in + (((n*64 + iy)*64 + ix)*128 + part*8));
    const int bo = (((r*66 + col) << 8) + (part << 4)) ^ ((col & 7) << 4);
    *(short8*)((char*)IL + bo) = v;
  }
  const int w = threadIdx.x >> 6, l = threadIdx.x & 63;
  const int py = w >> 1, px = w & 1;
  const int lm = l & 15, lk = l >> 4;
  // bo(ks,mi) = [a*16896 + ((cc>>1)<<7) + mi*4096]imm + pyb + Wb[b][cc&1]
  // Wb[b][c1] = (e<<8) + ((lk<<4)^(x&0x30)) + ((x&0x40)^(c1<<6)), e=lm+px+b,
  // x = (e&7)<<4.  (bits 4-7 carry-free since cc*64+lk*16<256)
  int Wb[2][2];
  #pragma unroll
  for (int b = 0; b < 2; ++b) {
    const int e = lm + px + b;
    const int xb = (e & 7) << 4;
    const int bs = (e << 8) + ((lk << 4) ^ (xb & 0x30));
    Wb[b][0] = bs + (xb & 0x40);
    Wb[b][1] = bs + ((xb & 0x40) ^ 0x40);
  }
  const int pyb = py * 16896;                       // wave-uniform
  const unsigned short* wb = wv + w*32768 + l*8;    // + ks*2048 + ni*512 (shorts)
  __syncthreads();
  f32x4 acc[4][4];
  #pragma unroll
  for (int mi = 0; mi < 4; ++mi)
    #pragma unroll
    for (int ni = 0; ni < 4; ++ni) acc[mi][ni] = (f32x4)0.0f;
  #pragma unroll
  for (int ks = 0; ks < 16; ++ks) {                  // (a,b,cc): K=512 total
    const int a = ks >> 3, b = (ks >> 2) & 1, cc = ks & 3;
    short8 bv[4];
    #pragma unroll
    for (int ni = 0; ni < 4; ++ni)
      bv[ni] = *(const short8*)(wb + ks*2048 + ni*512);
    const char* Ab = (const char*)IL + (pyb + Wb[b][cc & 1]);
    const int imm0 = a*16896 + ((cc >> 1) << 7);     // compile-time
    #pragma unroll
    for (int mi = 0; mi < 4; ++mi) {
      const short8 av = *(const short8*)(Ab + imm0 + mi*4096);
      #pragma unroll
      for (int ni = 0; ni < 4; ++ni)
        acc[mi][ni] = __builtin_amdgcn_mfma_f32_16x16x32_bf16(
            __builtin_bit_cast(bf16x8, av),
            __builtin_bit_cast(bf16x8, bv[ni]),
            acc[mi][ni], 0, 0, 0);
    }
  }
  const int oy = 2*q + py;
  #pragma unroll
  for (int mi = 0; mi < 4; ++mi)
    #pragma unroll
    for (int r = 0; r < 4; ++r) {
      const int ox = 2*(mi*16 + lk*4 + r) + px;
      const int ob = ((n*128 + oy)*128 + ox)*64;
      #pragma unroll
      for (int ni = 0; ni < 4; ++ni) {
        const int co = ni*16 + lm;
        out[ob + co] = f2b(fmaxf(acc[mi][ni][r] + bias[co], 0.f));
      }
    }
}

// ------- VQ via MFMA: z fp32 [131072,32] -> zq fp32 + loss partials ---------
__global__ __launch_bounds__(256) void vqm_k(const float* __restrict__ z,
    const float* __restrict__ embed, float* __restrict__ zq,
    float* __restrict__ partial) {
  __shared__ short Be[512*40];     // bf16 codes, pad stride 40 (40960 B)
  __shared__ float en[512];        // |e|^2 (bf16-rounded e), fp32
  __shared__ int   bidx[128];
  __shared__ float red[256];
  const int m0 = blockIdx.x * 128;
  for (int i = threadIdx.x; i < 4096; i += 256) {
    const int j = i >> 3, k0 = (i & 7) * 4;
    const f32x4 v = *(const f32x4*)&embed[j*32 + k0];
    s16x4 s;
    #pragma unroll
    for (int e = 0; e < 4; ++e) s[e] = (short)f2b(v[e]);
    *(s16x4*)&Be[j*40 + k0] = s;
  }
  __syncthreads();
  for (int j = threadIdx.x; j < 512; j += 256) {
    float s = 0.f;
    #pragma unroll
    for (int q = 0; q < 4; ++q) {
      const short8 v = *(const short8*)&Be[j*40 + q*8];
      #pragma unroll
      for (int e = 0; e < 8; ++e) {
        const float f = b2f((unsigned short)v[e]);
        s = fmaf(f, f, s);
      }
    }
    en[j] = s;
  }
  __syncthreads();
  const int w = threadIdx.x >> 6, l = threadIdx.x & 63;
  const int lm = l & 15, lk = l >> 4;
  const int rw = w * 32;
  short8 av[2];
  #pragma unroll
  for (int mi = 0; mi < 2; ++mi) {
    const float* zp = z + (long)(m0 + rw + mi*16 + lm)*32 + lk*8;
    const f32x4 f0 = *(const f32x4*)zp;
    const f32x4 f1 = *(const f32x4*)(zp + 4);
    short8 v;
    #pragma unroll
    for (int e = 0; e < 4; ++e) {
      v[e]     = (short)f2b(f0[e]);
      v[e + 4] = (short)f2b(f1[e]);
    }
    av[mi] = v;
  }
  float bd[2][4]; int bj[2][4];
  #pragma unroll
  for (int mi = 0; mi < 2; ++mi)
    #pragma unroll
    for (int r = 0; r < 4; ++r) { bd[mi][r] = 1e30f; bj[mi][r] = 0; }
  for (int nc = 0; nc < 8; ++nc) {               // N-chunks of 64 codes
    f32x4 acc[2][4];
    #pragma unroll
    for (int mi = 0; mi < 2; ++mi)
      #pragma unroll
      for (int ni = 0; ni < 4; ++ni) acc[mi][ni] = (f32x4)0.0f;
    #pragma unroll
    for (int ni = 0; ni < 4; ++ni) {
      const short8 bv = *(const short8*)&Be[(nc*64 + ni*16 + lm)*40 + lk*8];
      #pragma unroll
      for (int mi = 0; mi < 2; ++mi)
        acc[mi][ni] = __builtin_amdgcn_mfma_f32_16x16x32_bf16(
            __builtin_bit_cast(bf16x8, av[mi]),
            __builtin_bit_cast(bf16x8, bv),
            acc[mi][ni], 0, 0, 0);
    }
    #pragma unroll
    for (int ni = 0; ni < 4; ++ni) {
      const int j = nc*64 + ni*16 + lm;
      const float e_n = en[j];
      #pragma unroll
      for (int mi = 0; mi < 2; ++mi)
        #pragma unroll
        for (int r = 0; r < 4; ++r) {
          const float d = fmaf(-2.f, acc[mi][ni][r], e_n);
          if (d < bd[mi][r]) { bd[mi][r] = d; bj[mi][r] = j; }
        }
    }
  }
  #pragma unroll
  for (int mi = 0; mi < 2; ++mi)
    #pragma unroll
    for (int r = 0; r < 4; ++r) {
      float d = bd[mi][r]; int j = bj[mi][r];
      #pragma unroll
      for (int off = 1; off < 16; off <<= 1) {
        const float od = __shfl_xor(d, off);
        const int   oj = __shfl_xor(j, off);
        if (od < d || (od == d && oj < j)) { d = od; j = oj; }
      }
      if (lm == 0) bidx[rw + mi*16 + lk*4 + r] = j;
    }
  __syncthreads();
  const int pl = threadIdx.x >> 1, hf = (threadIdx.x & 1) * 16;
  const int code = bidx[pl];
  const long pb = (long)(m0 + pl)*32 + hf;
  float se = 0.f;
  #pragma unroll
  for (int q = 0; q < 4; ++q) {
    const f32x4 ev = *(const f32x4*)&embed[code*32 + hf + q*4];
    const f32x4 zv = *(const f32x4*)&z[pb + q*4];
    *(f32x4*)&zq[pb + q*4] = ev;
    const f32x4 df = ev - zv;
    #pragma unroll
    for (int e = 0; e < 4; ++e) se = fmaf(df[e], df[e], se);
  }
  red[threadIdx.x] = se; __syncthreads();
  for (int s = 128; s > 0; s >>= 1) {
    if (threadIdx.x < s) red[threadIdx.x] += red[threadIdx.x + s];
    __syncthreads();
  }
  if (threadIdx.x == 0) partial[blockIdx.x] = red[0];
}

__global__ __launch_bounds__(256) void loss_k(const float* __restrict__ part,
                                              float* __restrict__ out) {
  __shared__ float red[256];
  const int t = threadIdx.x;
  float s = 0.f;
  #pragma unroll
  for (int q = 0; q < 4; ++q) s += part[t + q*256];   // 1024 partials
  red[t] = s; __syncthreads();
  for (int st = 128; st > 0; st >>= 1) {
    if (t < st) red[t] += red[t + st];
    __syncthreads();
  }
  if (t == 0) out[0] = red[0] * (1.25f / (131072.f * 32.f));
}

// ---- convt3 via MFMA: d2 NHWC bf16 [32,128,128,64] -> x_recon NCHW fp32 ----
__global__ __launch_bounds__(256) void convt3m_k(const unsigned short* __restrict__ in,
    const unsigned short* __restrict__ wq6, const float* __restrict__ bias,
    float* __restrict__ out) {
  __shared__ short8 IL[3*8*66];      // [(r*8+c8)*66 + ixl], 25344 B
  const int h = blockIdx.x & 1, q = (blockIdx.x >> 1) & 127, n = blockIdx.x >> 8;
  for (int i = threadIdx.x; i < 1584; i += 256) {   // 3*66*8
    const int c8 = i & 7, t = i >> 3, ixl = t % 66, r = t / 66;
    const int iy = q - 1 + r, ix = h*64 - 1 + ixl;
    short8 v = (short8)(short)0;
    if (iy >= 0 && iy < 128 && ix >= 0 && ix < 128)
      v = *(const short8*)(in + (((long)(n*128 + iy)*128 + ix)*64 + c8*8));
    IL[(r*8 + c8)*66 + ixl] = v;
  }
  const int w = threadIdx.x >> 6, l = threadIdx.x & 63;
  const int py = w >> 1, px = w & 1;
  const int lm = l & 15, lk = l >> 4;
  short8 bfrag[8];
  #pragma unroll
  for (int kc = 0; kc < 8; ++kc)
    bfrag[kc] = *(const short8*)(wq6 + (((w*8 + kc)*64 + l) << 3));
  __syncthreads();
  f32x4 acc[4];
  #pragma unroll
  for (int mi = 0; mi < 4; ++mi) acc[mi] = (f32x4)0.0f;
  #pragma unroll
  for (int kc = 0; kc < 8; ++kc) {
    const int a = kc >> 2, b = (kc >> 1) & 1, ch = kc & 1;
    const int base = (((py + a)*8 + ch*4 + lk)*66) + px + b;   // + ixl(xq)
    #pragma unroll
    for (int mi = 0; mi < 4; ++mi) {
      const short8 av = *(const short8*)&IL[base + mi*16 + lm];
      acc[mi] = __builtin_amdgcn_mfma_f32_16x16x32_bf16(
          __builtin_bit_cast(bf16x8, av),
          __builtin_bit_cast(bf16x8, bfrag[kc]),
          acc[mi], 0, 0, 0);
    }
  }
  // epilogue: C row = xq (lk*4+r within tile), col = co (lanes lm<3 write)
  if (lm < 3) {
    const float bv = bias[lm];
    const int oy = 2*q + py;
    const long ob = ((long)(n*3 + lm))*65536 + oy*256;
    #pragma unroll
    for (int mi = 0; mi < 4; ++mi)
      #pragma unroll
      for (int r = 0; r < 4; ++r) {
        const int xq = mi*16 + lk*4 + r;
        out[ob + h*128 + 2*xq + px] = acc[mi][r] + bv;
      }
  }
}

extern "C" void kernel_launch(void* const* d_in, const int* in_sizes, int n_in,
                              void* d_out, int out_size, void* d_ws, size_t ws_size,
                              hipStream_t stream) {
  const float* x   = (const float*)d_in[0];
  const float* ew1 = (const float*)d_in[1];  const float* eb1 = (const float*)d_in[2];
  const float* ew2 = (const float*)d_in[3];  const float* eb2 = (const float*)d_in[4];
  const float* ew3 = (const float*)d_in[5];  const float* eb3 = (const float*)d_in[6];
  const float* emb = (const float*)d_in[7];
  const float* dw1 = (const float*)d_in[8];  const float* db1 = (const float*)d_in[9];
  const float* dw2 = (const float*)d_in[10]; const float* db2 = (const float*)d_in[11];
  const float* dw3 = (const float*)d_in[12]; const float* db3 = (const float*)d_in[13];
  float* out = (float*)d_out;

  uint8_t* w8 = (uint8_t*)d_ws;
  unsigned short* h1 = (unsigned short*)w8;
  unsigned short* h2 = (unsigned short*)(w8 + 67108864);
  float* z   = (float*)(w8 + 100663296);
  float* zq  = (float*)(w8 + 117440512);
  float* part = (float*)(w8 + 67108864);              // h2 region (dead @ vqm)
  unsigned short* wq2 = (unsigned short*)(w8 + 117440512);            // 262144 B
  unsigned short* wq3 = (unsigned short*)(w8 + 117440512 + 262144);   // 73728 B
  unsigned short* wq1 = (unsigned short*)(w8 + 117440512 + 335872);   // 8192 B
  unsigned short* wq4 = (unsigned short*)(w8 + 100663296);            // 73728 B
  unsigned short* wq5 = (unsigned short*)(w8 + 100663296 + 73728);    // 262144 B
  unsigned short* wq6 = (unsigned short*)(w8 + 100663296 + 335872);   // 32768 B
  unsigned short* d1 = h2;
  unsigned short* d2 = h1;

  // encoder weight prep (into zq region, consumed before vqm writes zq)
  prep1v_k<<<dim3(16),256,0,stream>>>(ew1, wq1);
  prep2v_k<<<dim3(512),256,0,stream>>>(ew2, wq2);
  prep3_k<<<dim3(144),256,0,stream>>>(ew3, wq3);
  // encoder
  conv1m_k<<<dim3(4096),256,0,stream>>>(x, wq1, eb1, h1);
  conv2m_k<<<dim3(2048),256,0,stream>>>(h1, wq2, eb2, h2);
  mconv_k<128,32,64,1,3,9,1,1,false,true,false,true>
      <<<dim3(1024),256,0,stream>>>(h2, wq3, eb3, z);
  // VQ (MFMA) + loss  (partials in h2 region; loss_k consumes before d1 write)
  vqm_k<<<dim3(1024),256,0,stream>>>(z, emb, zq, part);
  loss_k<<<dim3(1),256,0,stream>>>(part, out + 6291456);
  // decoder weight prep (into z region, dead after vqm)
  prep4_k<<<dim3(144),256,0,stream>>>(dw1, wq4);
  prep5v_k<<<dim3(512),256,0,stream>>>(dw2, wq5);
  prep6_k<<<dim3(64),256,0,stream>>>(dw3, wq6);
  // decoder
  mconv_k<32,128,64,1,3,9,1,1,false,true,true,false>
      <<<dim3(1024),256,0,stream>>>(zq, wq4, db1, d1);
  convt2m_k<<<dim3(2048),256,0,stream>>>(d1, wq5, db2, d2);
  convt3m_k<<<dim3(8192),256,0,stream>>>(d2, wq6, db3, out);
}

// Round 6
// 391.140 us; speedup vs baseline: 1.3245x; 1.0341x over previous
//
#include <hip/hip_runtime.h>

// VQ-VAE forward, MI355X round 16: R15 + conv2m/convt2m ci-split into two
// staged phases -> LDS halved (33.8KB / 25.3KB), occupancy 2->4 / 3->6
// blocks/CU. conv2m's 64B-entry layout is naturally conflict-free (no XOR).

typedef __attribute__((ext_vector_type(8))) short     short8;
typedef __attribute__((ext_vector_type(4))) short     s16x4;
typedef __attribute__((ext_vector_type(8))) __bf16    bf16x8;
typedef __attribute__((ext_vector_type(4))) float     f32x4;
typedef __attribute__((ext_vector_type(4))) unsigned  uint32x4;

#define BATCH 32

__device__ __forceinline__ float b2f(unsigned short b) {
  union { unsigned u; float f; } v; v.u = ((unsigned)b) << 16; return v.f;
}
__device__ __forceinline__ unsigned short f2b(float f) {  // round-to-nearest-even
  union { float f; unsigned u; } v; v.f = f;
  unsigned r = v.u + 0x7FFF + ((v.u >> 16) & 1);
  return (unsigned short)(r >> 16);
}

// ---------------- weight prep ------------------------------------------------
// conv1 B-frags: wq1[((ks*4+ni)*64+l)*8+j] = ew1[co=ni*16+lm][k], k=ks*32+lk*8+j
__global__ __launch_bounds__(256) void prep1v_k(const float* __restrict__ w,
                                                unsigned short* __restrict__ wq) {
  const int i = blockIdx.x*256 + threadIdx.x;                 // 4096 exact
  const int j = i & 7, l = (i >> 3) & 63, ni = (i >> 9) & 3, ks = i >> 11;
  const int k = ks*32 + (l >> 4)*8 + j;
  const int co = ni*16 + (l & 15);
  wq[i] = (k < 48) ? f2b(w[co*48 + k]) : (unsigned short)0;
}
// conv2 B-frags, frag-ordered for conv2m_k:
__global__ __launch_bounds__(256) void prep2v_k(const float* __restrict__ w,
                                                unsigned short* __restrict__ wq) {
  const int i = blockIdx.x*256 + threadIdx.x;                 // 131072 exact
  const int j = i & 7, l = (i >> 3) & 63, ni = (i >> 9) & 7, ks = i >> 12;
  const int lm = l & 15, lk = l >> 4;
  const int tap = ks >> 1, cc = ks & 1;
  const int co = ni*16 + lm, ci = cc*32 + lk*8 + j;
  wq[i] = f2b(w[(co*64 + ci)*16 + tap]);
}
__global__ __launch_bounds__(256) void prep3_k(const float* __restrict__ w,
                                               unsigned short* __restrict__ wq) {
  const int i = blockIdx.x*256 + threadIdx.x;                 // 36864 exact
  const int ci = i & 127, co = (i >> 7) & 31, t = i >> 12;
  wq[i] = f2b(w[(co*128 + ci)*9 + t]);                        // ew3 OIHW(32,128,3,3)
}
__global__ __launch_bounds__(256) void prep4_k(const float* __restrict__ w,
                                               unsigned short* __restrict__ wq) {
  const int i = blockIdx.x*256 + threadIdx.x;                 // 36864 exact
  const int ci = i & 31, co = (i >> 5) & 127, t = i >> 12;
  wq[i] = f2b(w[(ci*128 + co)*9 + (8 - t)]);                  // dw1(32,128,3,3), flipped
}
// d2 convT B-frags, frag-ordered for convt2m_k:
__global__ __launch_bounds__(256) void prep5v_k(const float* __restrict__ w,
                                                unsigned short* __restrict__ wq) {
  const int i = blockIdx.x*256 + threadIdx.x;                 // 131072 exact
  const int j = i & 7, l = (i >> 3) & 63, ni = (i >> 9) & 3;
  const int ks = (i >> 11) & 15, p = i >> 15;
  const int lm = l & 15, lk = l >> 4;
  const int py = p >> 1, px = p & 1;
  const int a = ks >> 3, b = (ks >> 2) & 1, cc = ks & 3;
  const int co = ni*16 + lm, ci = cc*32 + lk*8 + j;
  const int ky = 3 - 2*a - py, kx = 3 - 2*b - px;
  wq[i] = f2b(w[(ci*64 + co)*16 + ky*4 + kx]);                // dw2(128,64,4,4)
}
// convt3 B-frags: wq6[p][kc][lane l][j] = w[tap(a,b,p)][ci=(kc&1)*32+lk*8+j][co=lm]
__global__ __launch_bounds__(256) void prep6_k(const float* __restrict__ w,
                                               unsigned short* __restrict__ wq) {
  const int i = blockIdx.x*256 + threadIdx.x;                 // 16384 exact
  const int j = i & 7, l = (i >> 3) & 63, kc = (i >> 9) & 7, p = i >> 12;
  const int lm = l & 15, lk = l >> 4;
  const int a = kc >> 2, b = (kc >> 1) & 1, ch = kc & 1;
  const int ci = ch*32 + lk*8 + j, co = lm;
  const int py = p >> 1, px = p & 1;
  const int ky = 2 - 2*a + (1 - py), kx = 2 - 2*b + (1 - px);
  wq[i] = (co < 3) ? f2b(w[(ci*3 + co)*16 + ky*4 + kx]) : (unsigned short)0;
}

// --------- MFMA implicit-GEMM conv: NHWC in -> NHWC out (64x64 spatial) -----
template<int CIN,int COUT,int HIN,int S,int KW,int NTAPS,int OSTRIDE,int P,
         bool PARITY,bool RELU,bool INF32,bool OUTF32>
__global__ __launch_bounds__(256) void mconv_k(const void* __restrict__ in_,
    const unsigned short* __restrict__ wq_, const float* __restrict__ bias,
    void* __restrict__ out_) {
  constexpr int NF  = COUT / 16;
  constexpr int NCH = CIN / 32;
  __shared__ short Al[128*40];      // 128 rows x 32 k, stride 40 (80B, 16B-mult)
  __shared__ short Bl[COUT*40];
  int py = 0, px = 0, PY = P, PX = P;
  const unsigned short* wq = wq_;
  if (PARITY) {
    py = blockIdx.y >> 1; px = blockIdx.y & 1;
    PY = 1 - py; PX = 1 - px;
    wq += blockIdx.y * (NTAPS*COUT*CIN);
  }
  const int m0 = blockIdx.x * 128;
  const int w  = threadIdx.x >> 6, l = threadIdx.x & 63;
  const int lm = l & 15, lk = l >> 4;
  f32x4 acc[2][NF];
  #pragma unroll
  for (int mi = 0; mi < 2; ++mi)
    #pragma unroll
    for (int ni = 0; ni < NF; ++ni) acc[mi][ni] = (f32x4)0.0f;

  for (int tap = 0; tap < NTAPS; ++tap) {
    const int ky = tap / KW, kx = tap % KW;
    for (int ch = 0; ch < NCH; ++ch) {
      const int c0 = ch * 32;
      __syncthreads();                       // prev iter frag reads done
      for (int s = threadIdx.x; s < 512; s += 256) {
        const int row = s >> 2, part = s & 3;
        const int m = m0 + row;
        const int n = m >> 12, oy = (m >> 6) & 63, ox = m & 63;
        const int iy = oy*S - PY + ky, ix = ox*S - PX + kx;
        short8 v = (short8)(short)0;
        if (iy >= 0 && iy < HIN && ix >= 0 && ix < HIN) {
          const int base = ((n*HIN + iy)*HIN + ix)*CIN + c0 + part*8;
          if (INF32) {
            const float* pf = (const float*)in_ + base;
            const f32x4 f0 = *(const f32x4*)pf;
            const f32x4 f1 = *(const f32x4*)(pf + 4);
            #pragma unroll
            for (int j = 0; j < 4; ++j) {
              v[j]     = (short)f2b(f0[j]);
              v[j + 4] = (short)f2b(f1[j]);
            }
          } else {
            v = *(const short8*)((const unsigned short*)in_ + base);
          }
        }
        *(short8*)&Al[row*40 + part*8] = v;
      }
      for (int s = threadIdx.x; s < COUT*4; s += 256) {
        const int co = s >> 2, part = s & 3;
        *(short8*)&Bl[co*40 + part*8] =
            *(const short8*)(wq + (tap*COUT + co)*CIN + c0 + part*8);
      }
      __syncthreads();
      short8 av[2];
      #pragma unroll
      for (int mi = 0; mi < 2; ++mi)
        av[mi] = *(const short8*)&Al[(w*32 + mi*16 + lm)*40 + lk*8];
      #pragma unroll
      for (int ni = 0; ni < NF; ++ni) {
        const short8 bv = *(const short8*)&Bl[(ni*16 + lm)*40 + lk*8];
        #pragma unroll
        for (int mi = 0; mi < 2; ++mi)
          acc[mi][ni] = __builtin_amdgcn_mfma_f32_16x16x32_bf16(
              __builtin_bit_cast(bf16x8, av[mi]),
              __builtin_bit_cast(bf16x8, bv),
              acc[mi][ni], 0, 0, 0);
      }
    }
  }
  #pragma unroll
  for (int ni = 0; ni < NF; ++ni) {
    const int co = ni*16 + lm;
    const float bv = bias[co];
    #pragma unroll
    for (int mi = 0; mi < 2; ++mi) {
      #pragma unroll
      for (int r = 0; r < 4; ++r) {
        const int ml = w*32 + mi*16 + lk*4 + r;
        const int m  = m0 + ml;
        float vv = acc[mi][ni][r] + bv;
        if (RELU) vv = fmaxf(vv, 0.f);
        int off;
        if (OSTRIDE == 1) {
          off = m*COUT + co;
        } else {
          const int n = m >> 12, oy = (m >> 6) & 63, ox = m & 63;
          off = ((n*128 + oy*2 + py)*128 + ox*2 + px)*COUT + co;
        }
        if (OUTF32) ((float*)out_)[off] = vv;
        else ((unsigned short*)out_)[off] = f2b(vv);
      }
    }
  }
}

// ---- conv1 via MFMA: x NCHW fp32 [32,3,256,256] -> h1 NHWC bf16 ------------
__global__ __launch_bounds__(256) void conv1m_k(const float* __restrict__ x,
    const unsigned short* __restrict__ wv, const float* __restrict__ bias,
    unsigned short* __restrict__ out) {
  __shared__ __align__(16) short RAW[12*264];   // row g=ci*4+ky, idx=ix+4; 6336B
  __shared__ __align__(16) short IC[128*64];    // [ox][k] swizzled; 16384B
  const int wid = ((blockIdx.x & 7) << 9) + (blockIdx.x >> 3);
  const int q = wid & 127, n = wid >> 7;        // q = output row oy
  for (int i = threadIdx.x; i < 396; i += 256)
    *(short8*)&RAW[i*8] = (short8)(short)0;
  __syncthreads();
  for (int s = threadIdx.x; s < 768; s += 256) {   // 12 rows * 64 f32x4
    const int g = s >> 6, seg = s & 63;
    const int ci = g >> 2, ky = g & 3;
    const int iy = 2*q - 1 + ky;
    if (iy >= 0 && iy < 256) {
      const f32x4 v = *(const f32x4*)&x[((n*3 + ci)*256 + iy)*256 + seg*4];
      s16x4 sv;
      #pragma unroll
      for (int e = 0; e < 4; ++e) sv[e] = (short)f2b(v[e]);
      *(s16x4*)&RAW[g*264 + 4 + seg*4] = sv;
    }
  }
  __syncthreads();
  for (int s = threadIdx.x; s < 1024; s += 256) {
    const int kb = s & 7, ox = s >> 3;
    short8 v = (short8)(short)0;
    if (kb < 6) {
      const unsigned* u0 = (const unsigned*)&RAW[(2*kb  )*264 + 2*ox + 2];
      const unsigned* u1 = (const unsigned*)&RAW[(2*kb+1)*264 + 2*ox + 2];
      const unsigned a0 = u0[0], a1 = u0[1], a2 = u0[2];
      const unsigned b0 = u1[0], b1 = u1[1], b2 = u1[2];
      uint32x4 uv;
      uv[0] = (a0 >> 16) | (a1 << 16);
      uv[1] = (a1 >> 16) | (a2 << 16);
      uv[2] = (b0 >> 16) | (b1 << 16);
      uv[3] = (b1 >> 16) | (b2 << 16);
      v = __builtin_bit_cast(short8, uv);
    }
    const int bo = ((ox << 7) + (kb << 4)) ^ ((ox & 7) << 4);
    *(short8*)((char*)IC + bo) = v;
  }
  __syncthreads();
  const int w = threadIdx.x >> 6, l = threadIdx.x & 63;
  const int lm = l & 15, lk = l >> 4;
  f32x4 acc[2][4];
  #pragma unroll
  for (int mi = 0; mi < 2; ++mi)
    #pragma unroll
    for (int ni = 0; ni < 4; ++ni) acc[mi][ni] = (f32x4)0.0f;
  #pragma unroll
  for (int ks = 0; ks < 2; ++ks) {
    short8 bv[4];
    #pragma unroll
    for (int ni = 0; ni < 4; ++ni)
      bv[ni] = *(const short8*)(wv + (((ks*4 + ni)*64 + l) << 3));
    #pragma unroll
    for (int mi = 0; mi < 2; ++mi) {
      const int ox = w*32 + mi*16 + lm;
      const int bo = ((ox << 7) + (ks << 6) + (lk << 4)) ^ ((ox & 7) << 4);
      const short8 av = *(const short8*)((const char*)IC + bo);
      #pragma unroll
      for (int ni = 0; ni < 4; ++ni)
        acc[mi][ni] = __builtin_amdgcn_mfma_f32_16x16x32_bf16(
            __builtin_bit_cast(bf16x8, av),
            __builtin_bit_cast(bf16x8, bv[ni]),
            acc[mi][ni], 0, 0, 0);
    }
  }
  __syncthreads();            // frag reads done; reuse IC for output staging
  #pragma unroll
  for (int mi = 0; mi < 2; ++mi)
    #pragma unroll
    for (int ni = 0; ni < 4; ++ni) {
      const int co = ni*16 + lm;
      const float bv = bias[co];
      #pragma unroll
      for (int r = 0; r < 4; ++r) {
        const int ox = w*32 + mi*16 + lk*4 + r;
        const int bo = ((ox << 7) + 2*co) ^ ((ox & 7) << 4);
        *(short*)((char*)IC + bo) = (short)f2b(fmaxf(acc[mi][ni][r] + bv, 0.f));
      }
    }
  __syncthreads();
  const long ob = ((long)(n*128 + q)) * 8192;   // 128 ox * 64 co
  for (int s = threadIdx.x; s < 1024; s += 256) {
    const int kb = s & 7, ox = s >> 3;
    const int bo = ((ox << 7) + (kb << 4)) ^ ((ox & 7) << 4);
    *(short8*)&out[ob + ox*64 + kb*8] = *(const short8*)((const char*)IC + bo);
  }
}

// ---- conv2 via two-phase MFMA: h1 NHWC bf16 [32,128,128,64] ->
//      h2 NHWC bf16 [32,64,64,128].  Phase c stages ci-half c (64B entries,
//      naturally conflict-free), computes 16 taps; acc persists in regs.
//      LDS 33792B -> 4 blocks/CU.
__global__ __launch_bounds__(256) void conv2m_k(const unsigned short* __restrict__ in,
    const unsigned short* __restrict__ wv, const float* __restrict__ bias,
    unsigned short* __restrict__ out) {
  __shared__ short IL[8*66*32];        // [(r*2+p)*66+idx][ci_local 32], 33792 B
  const int wid = (blockIdx.x & 7)*256 + (blockIdx.x >> 3);
  const int q = wid & 63, n = wid >> 6;          // q = output row oy
  const int w = threadIdx.x >> 6, l = threadIdx.x & 63;
  const int lm = l & 15, lk = l >> 4;
  const int Bd0 = lm*64 + lk*16;                 // A-read byte base, d=0
  const unsigned short* wb = wv + w*1024 + l*8;  // + ks*4096 (+512 for ni=1)
  f32x4 acc[4][2];
  #pragma unroll
  for (int mi = 0; mi < 4; ++mi)
    #pragma unroll
    for (int ni = 0; ni < 2; ++ni) acc[mi][ni] = (f32x4)0.0f;
  #pragma unroll
  for (int c = 0; c < 2; ++c) {                  // ci-half phase
    if (c) __syncthreads();                      // compute done before overwrite
    for (int i = threadIdx.x; i < 2112; i += 256) {   // 8 rp * 66 idx * 4 part
      const int part = i & 3, e = i >> 2;
      const int idx = e % 66, rp = e / 66;
      const int r = rp >> 1, p = rp & 1;
      const int iy = 2*q - 1 + r, ix = 2*idx - p;
      short8 v = (short8)(short)0;
      if (iy >= 0 && iy < 128 && ix >= 0 && ix < 128)
        v = *(const short8*)(in + (((n*128 + iy)*128 + ix)*64 + c*32 + part*8));
      *(short8*)&IL[e*32 + part*8] = v;
    }
    __syncthreads();
    #pragma unroll
    for (int t = 0; t < 16; ++t) {               // tap; ks = t*2+c
      const int ky = t >> 2, kx = t & 3;
      const int p = 1 - (kx & 1), d = kx >> 1;   // plane, idx offset
      const short8 bv0 = *(const short8*)(wb + (t*2 + c)*4096);
      const short8 bv1 = *(const short8*)(wb + (t*2 + c)*4096 + 512);
      const char* Ab = (const char*)IL + (Bd0 + d*64);
      const int imm0 = ((ky*2 + p)*66) << 6;     // compile-time (entries*64B)
      #pragma unroll
      for (int mi = 0; mi < 4; ++mi) {
        const short8 av = *(const short8*)(Ab + imm0 + mi*1024);
        acc[mi][0] = __builtin_amdgcn_mfma_f32_16x16x32_bf16(
            __builtin_bit_cast(bf16x8, av), __builtin_bit_cast(bf16x8, bv0),
            acc[mi][0], 0, 0, 0);
        acc[mi][1] = __builtin_amdgcn_mfma_f32_16x16x32_bf16(
            __builtin_bit_cast(bf16x8, av), __builtin_bit_cast(bf16x8, bv1),
            acc[mi][1], 0, 0, 0);
      }
    }
  }
  #pragma unroll
  for (int mi = 0; mi < 4; ++mi)
    #pragma unroll
    for (int r = 0; r < 4; ++r) {
      const int ox = mi*16 + lk*4 + r;
      const int ob = ((n*64 + q)*64 + ox)*128;
      #pragma unroll
      for (int ni = 0; ni < 2; ++ni) {
        const int co = (w*2 + ni)*16 + lm;
        out[ob + co] = f2b(fmaxf(acc[mi][ni][r] + bias[co], 0.f));
      }
    }
}

// ---- d2 convT via two-phase merged-parity MFMA: d1 NHWC bf16 [32,64,64,128]
//      -> d2 NHWC bf16 [32,128,128,64].  Phase c stages ci-half (128B entries,
//      XOR-swizzled), computes 8 (a,b,c1) steps. LDS 25344B -> 6 blocks/CU.
__global__ __launch_bounds__(256) void convt2m_k(const unsigned short* __restrict__ in,
    const unsigned short* __restrict__ wv, const float* __restrict__ bias,
    unsigned short* __restrict__ out) {
  __shared__ short IL[3*66*64];        // [r*66+col][ci_local 32+32], 25344 B
  const int wid = (blockIdx.x & 7)*256 + (blockIdx.x >> 3);
  const int q = wid & 63, n = wid >> 6;
  const int w = threadIdx.x >> 6, l = threadIdx.x & 63;
  const int py = w >> 1, px = w & 1;
  const int lm = l & 15, lk = l >> 4;
  // A-read: bo = pyb + a*8448 + mi*2048 + Wb[b][c1]
  // Wb[b][c1] = (e<<7) + (((c1<<6)|(lk<<4)) ^ ((e&7)<<4)), e = lm+px+b
  int Wb[2][2];
  #pragma unroll
  for (int b = 0; b < 2; ++b) {
    const int e = lm + px + b;
    Wb[b][0] = (e << 7) + ((lk << 4) ^ ((e & 7) << 4));
    Wb[b][1] = Wb[b][0] ^ 0x40;
  }
  const int pyb = py * 8448;                       // 66 entries * 128 B
  const unsigned short* wb = wv + w*32768 + l*8;   // + ks*2048 + ni*512
  f32x4 acc[4][4];
  #pragma unroll
  for (int mi = 0; mi < 4; ++mi)
    #pragma unroll
    for (int ni = 0; ni < 4; ++ni) acc[mi][ni] = (f32x4)0.0f;
  #pragma unroll
  for (int c = 0; c < 2; ++c) {                    // ci-half phase
    if (c) __syncthreads();
    for (int i = threadIdx.x; i < 1584; i += 256) {   // 198 entries * 8 parts
      const int part = i & 7, e = i >> 3;
      const int col = e % 66, r = e / 66;
      const int iy = q - 1 + r, ix = col - 1;
      short8 v = (short8)(short)0;
      if (iy >= 0 && iy < 64 && ix >= 0 && ix < 64)
        v = *(const short8*)(in + (((n*64 + iy)*64 + ix)*128 + c*64 + part*8));
      const int bo = (e << 7) + ((part << 4) ^ ((col & 7) << 4));
      *(short8*)((char*)IL + bo) = v;
    }
    __syncthreads();
    #pragma unroll
    for (int u = 0; u < 8; ++u) {                  // (a,b,c1); cc = 2c+c1
      const int a = u >> 2, b = (u >> 1) & 1, c1 = u & 1;
      const int ks = (a << 3) | (b << 2) | (2*c + c1);
      short8 bv[4];
      #pragma unroll
      for (int ni = 0; ni < 4; ++ni)
        bv[ni] = *(const short8*)(wb + ks*2048 + ni*512);
      const char* Ab = (const char*)IL + (pyb + Wb[b][c1]);
      const int imm0 = a*8448;                     // compile-time
      #pragma unroll
      for (int mi = 0; mi < 4; ++mi) {
        const short8 av = *(const short8*)(Ab + imm0 + mi*2048);
        #pragma unroll
        for (int ni = 0; ni < 4; ++ni)
          acc[mi][ni] = __builtin_amdgcn_mfma_f32_16x16x32_bf16(
              __builtin_bit_cast(bf16x8, av),
              __builtin_bit_cast(bf16x8, bv[ni]),
              acc[mi][ni], 0, 0, 0);
      }
    }
  }
  const int oy = 2*q + py;
  #pragma unroll
  for (int mi = 0; mi < 4; ++mi)
    #pragma unroll
    for (int r = 0; r < 4; ++r) {
      const int ox = 2*(mi*16 + lk*4 + r) + px;
      const int ob = ((n*128 + oy)*128 + ox)*64;
      #pragma unroll
      for (int ni = 0; ni < 4; ++ni) {
        const int co = ni*16 + lm;
        out[ob + co] = f2b(fmaxf(acc[mi][ni][r] + bias[co], 0.f));
      }
    }
}

// ------- VQ via MFMA: z fp32 [131072,32] -> zq fp32 + loss partials ---------
__global__ __launch_bounds__(256) void vqm_k(const float* __restrict__ z,
    const float* __restrict__ embed, float* __restrict__ zq,
    float* __restrict__ partial) {
  __shared__ short Be[512*40];     // bf16 codes, pad stride 40 (40960 B)
  __shared__ float en[512];        // |e|^2 (bf16-rounded e), fp32
  __shared__ int   bidx[128];
  __shared__ float red[256];
  const int m0 = blockIdx.x * 128;
  for (int i = threadIdx.x; i < 4096; i += 256) {
    const int j = i >> 3, k0 = (i & 7) * 4;
    const f32x4 v = *(const f32x4*)&embed[j*32 + k0];
    s16x4 s;
    #pragma unroll
    for (int e = 0; e < 4; ++e) s[e] = (short)f2b(v[e]);
    *(s16x4*)&Be[j*40 + k0] = s;
  }
  __syncthreads();
  for (int j = threadIdx.x; j < 512; j += 256) {
    float s = 0.f;
    #pragma unroll
    for (int q = 0; q < 4; ++q) {
      const short8 v = *(const short8*)&Be[j*40 + q*8];
      #pragma unroll
      for (int e = 0; e < 8; ++e) {
        const float f = b2f((unsigned short)v[e]);
        s = fmaf(f, f, s);
      }
    }
    en[j] = s;
  }
  __syncthreads();
  const int w = threadIdx.x >> 6, l = threadIdx.x & 63;
  const int lm = l & 15, lk = l >> 4;
  const int rw = w * 32;
  short8 av[2];
  #pragma unroll
  for (int mi = 0; mi < 2; ++mi) {
    const float* zp = z + (long)(m0 + rw + mi*16 + lm)*32 + lk*8;
    const f32x4 f0 = *(const f32x4*)zp;
    const f32x4 f1 = *(const f32x4*)(zp + 4);
    short8 v;
    #pragma unroll
    for (int e = 0; e < 4; ++e) {
      v[e]     = (short)f2b(f0[e]);
      v[e + 4] = (short)f2b(f1[e]);
    }
    av[mi] = v;
  }
  float bd[2][4]; int bj[2][4];
  #pragma unroll
  for (int mi = 0; mi < 2; ++mi)
    #pragma unroll
    for (int r = 0; r < 4; ++r) { bd[mi][r] = 1e30f; bj[mi][r] = 0; }
  for (int nc = 0; nc < 8; ++nc) {               // N-chunks of 64 codes
    f32x4 acc[2][4];
    #pragma unroll
    for (int mi = 0; mi < 2; ++mi)
      #pragma unroll
      for (int ni = 0; ni < 4; ++ni) acc[mi][ni] = (f32x4)0.0f;
    #pragma unroll
    for (int ni = 0; ni < 4; ++ni) {
      const short8 bv = *(const short8*)&Be[(nc*64 + ni*16 + lm)*40 + lk*8];
      #pragma unroll
      for (int mi = 0; mi < 2; ++mi)
        acc[mi][ni] = __builtin_amdgcn_mfma_f32_16x16x32_bf16(
            __builtin_bit_cast(bf16x8, av[mi]),
            __builtin_bit_cast(bf16x8, bv),
            acc[mi][ni], 0, 0, 0);
    }
    #pragma unroll
    for (int ni = 0; ni < 4; ++ni) {
      const int j = nc*64 + ni*16 + lm;
      const float e_n = en[j];
      #pragma unroll
      for (int mi = 0; mi < 2; ++mi)
        #pragma unroll
        for (int r = 0; r < 4; ++r) {
          const float d = fmaf(-2.f, acc[mi][ni][r], e_n);
          if (d < bd[mi][r]) { bd[mi][r] = d; bj[mi][r] = j; }
        }
    }
  }
  #pragma unroll
  for (int mi = 0; mi < 2; ++mi)
    #pragma unroll
    for (int r = 0; r < 4; ++r) {
      float d = bd[mi][r]; int j = bj[mi][r];
      #pragma unroll
      for (int off = 1; off < 16; off <<= 1) {
        const float od = __shfl_xor(d, off);
        const int   oj = __shfl_xor(j, off);
        if (od < d || (od == d && oj < j)) { d = od; j = oj; }
      }
      if (lm == 0) bidx[rw + mi*16 + lk*4 + r] = j;
    }
  __syncthreads();
  const int pl = threadIdx.x >> 1, hf = (threadIdx.x & 1) * 16;
  const int code = bidx[pl];
  const long pb = (long)(m0 + pl)*32 + hf;
  float se = 0.f;
  #pragma unroll
  for (int q = 0; q < 4; ++q) {
    const f32x4 ev = *(const f32x4*)&embed[code*32 + hf + q*4];
    const f32x4 zv = *(const f32x4*)&z[pb + q*4];
    *(f32x4*)&zq[pb + q*4] = ev;
    const f32x4 df = ev - zv;
    #pragma unroll
    for (int e = 0; e < 4; ++e) se = fmaf(df[e], df[e], se);
  }
  red[threadIdx.x] = se; __syncthreads();
  for (int s = 128; s > 0; s >>= 1) {
    if (threadIdx.x < s) red[threadIdx.x] += red[threadIdx.x + s];
    __syncthreads();
  }
  if (threadIdx.x == 0) partial[blockIdx.x] = red[0];
}

__global__ __launch_bounds__(256) void loss_k(const float* __restrict__ part,
                                              float* __restrict__ out) {
  __shared__ float red[256];
  const int t = threadIdx.x;
  float s = 0.f;
  #pragma unroll
  for (int q = 0; q < 4; ++q) s += part[t + q*256];   // 1024 partials
  red[t] = s; __syncthreads();
  for (int st = 128; st > 0; st >>= 1) {
    if (t < st) red[t] += red[t + st];
    __syncthreads();
  }
  if (t == 0) out[0] = red[0] * (1.25f / (131072.f * 32.f));
}

// ---- convt3 via MFMA: d2 NHWC bf16 [32,128,128,64] -> x_recon NCHW fp32 ----
__global__ __launch_bounds__(256) void convt3m_k(const unsigned short* __restrict__ in,
    const unsigned short* __restrict__ wq6, const float* __restrict__ bias,
    float* __restrict__ out) {
  __shared__ short8 IL[3*8*66];      // [(r*8+c8)*66 + ixl], 25344 B
  const int h = blockIdx.x & 1, q = (blockIdx.x >> 1) & 127, n = blockIdx.x >> 8;
  for (int i = threadIdx.x; i < 1584; i += 256) {   // 3*66*8
    const int c8 = i & 7, t = i >> 3, ixl = t % 66, r = t / 66;
    const int iy = q - 1 + r, ix = h*64 - 1 + ixl;
    short8 v = (short8)(short)0;
    if (iy >= 0 && iy < 128 && ix >= 0 && ix < 128)
      v = *(const short8*)(in + (((long)(n*128 + iy)*128 + ix)*64 + c8*8));
    IL[(r*8 + c8)*66 + ixl] = v;
  }
  const int w = threadIdx.x >> 6, l = threadIdx.x & 63;
  const int py = w >> 1, px = w & 1;
  const int lm = l & 15, lk = l >> 4;
  short8 bfrag[8];
  #pragma unroll
  for (int kc = 0; kc < 8; ++kc)
    bfrag[kc] = *(const short8*)(wq6 + (((w*8 + kc)*64 + l) << 3));
  __syncthreads();
  f32x4 acc[4];
  #pragma unroll
  for (int mi = 0; mi < 4; ++mi) acc[mi] = (f32x4)0.0f;
  #pragma unroll
  for (int kc = 0; kc < 8; ++kc) {
    const int a = kc >> 2, b = (kc >> 1) & 1, ch = kc & 1;
    const int base = (((py + a)*8 + ch*4 + lk)*66) + px + b;   // + ixl(xq)
    #pragma unroll
    for (int mi = 0; mi < 4; ++mi) {
      const short8 av = *(const short8*)&IL[base + mi*16 + lm];
      acc[mi] = __builtin_amdgcn_mfma_f32_16x16x32_bf16(
          __builtin_bit_cast(bf16x8, av),
          __builtin_bit_cast(bf16x8, bfrag[kc]),
          acc[mi], 0, 0, 0);
    }
  }
  // epilogue: C row = xq (lk*4+r within tile), col = co (lanes lm<3 write)
  if (lm < 3) {
    const float bv = bias[lm];
    const int oy = 2*q + py;
    const long ob = ((long)(n*3 + lm))*65536 + oy*256;
    #pragma unroll
    for (int mi = 0; mi < 4; ++mi)
      #pragma unroll
      for (int r = 0; r < 4; ++r) {
        const int xq = mi*16 + lk*4 + r;
        out[ob + h*128 + 2*xq + px] = acc[mi][r] + bv;
      }
  }
}

extern "C" void kernel_launch(void* const* d_in, const int* in_sizes, int n_in,
                              void* d_out, int out_size, void* d_ws, size_t ws_size,
                              hipStream_t stream) {
  const float* x   = (const float*)d_in[0];
  const float* ew1 = (const float*)d_in[1];  const float* eb1 = (const float*)d_in[2];
  const float* ew2 = (const float*)d_in[3];  const float* eb2 = (const float*)d_in[4];
  const float* ew3 = (const float*)d_in[5];  const float* eb3 = (const float*)d_in[6];
  const float* emb = (const float*)d_in[7];
  const float* dw1 = (const float*)d_in[8];  const float* db1 = (const float*)d_in[9];
  const float* dw2 = (const float*)d_in[10]; const float* db2 = (const float*)d_in[11];
  const float* dw3 = (const float*)d_in[12]; const float* db3 = (const float*)d_in[13];
  float* out = (float*)d_out;

  uint8_t* w8 = (uint8_t*)d_ws;
  unsigned short* h1 = (unsigned short*)w8;
  unsigned short* h2 = (unsigned short*)(w8 + 67108864);
  float* z   = (float*)(w8 + 100663296);
  float* zq  = (float*)(w8 + 117440512);
  float* part = (float*)(w8 + 67108864);              // h2 region (dead @ vqm)
  unsigned short* wq2 = (unsigned short*)(w8 + 117440512);            // 262144 B
  unsigned short* wq3 = (unsigned short*)(w8 + 117440512 + 262144);   // 73728 B
  unsigned short* wq1 = (unsigned short*)(w8 + 117440512 + 335872);   // 8192 B
  unsigned short* wq4 = (unsigned short*)(w8 + 100663296);            // 73728 B
  unsigned short* wq5 = (unsigned short*)(w8 + 100663296 + 73728);    // 262144 B
  unsigned short* wq6 = (unsigned short*)(w8 + 100663296 + 335872);   // 32768 B
  unsigned short* d1 = h2;
  unsigned short* d2 = h1;

  // encoder weight prep (into zq region, consumed before vqm writes zq)
  prep1v_k<<<dim3(16),256,0,stream>>>(ew1, wq1);
  prep2v_k<<<dim3(512),256,0,stream>>>(ew2, wq2);
  prep3_k<<<dim3(144),256,0,stream>>>(ew3, wq3);
  // encoder
  conv1m_k<<<dim3(4096),256,0,stream>>>(x, wq1, eb1, h1);
  conv2m_k<<<dim3(2048),256,0,stream>>>(h1, wq2, eb2, h2);
  mconv_k<128,32,64,1,3,9,1,1,false,true,false,true>
      <<<dim3(1024),256,0,stream>>>(h2, wq3, eb3, z);
  // VQ (MFMA) + loss  (partials in h2 region; loss_k consumes before d1 write)
  vqm_k<<<dim3(1024),256,0,stream>>>(z, emb, zq, part);
  loss_k<<<dim3(1),256,0,stream>>>(part, out + 6291456);
  // decoder weight prep (into z region, dead after vqm)
  prep4_k<<<dim3(144),256,0,stream>>>(dw1, wq4);
  prep5v_k<<<dim3(512),256,0,stream>>>(dw2, wq5);
  prep6_k<<<dim3(64),256,0,stream>>>(dw3, wq6);
  // decoder
  mconv_k<32,128,64,1,3,9,1,1,false,true,true,false>
      <<<dim3(1024),256,0,stream>>>(zq, wq4, db1, d1);
  convt2m_k<<<dim3(2048),256,0,stream>>>(d1, wq5, db2, d2);
  convt3m_k<<<dim3(8192),256,0,stream>>>(d2, wq6, db3, out);
}

// Round 7
// 382.200 us; speedup vs baseline: 1.3555x; 1.0234x over previous
//
#include <hip/hip_runtime.h>

// VQ-VAE forward, MI355X round 17: R16 + T14 async-stage split in conv2m /
// convt2m: phase-1 global loads issued into registers BEFORE phase-0 compute
// (latency hidden under 128 MFMAs), LDS-written after the barrier.

typedef __attribute__((ext_vector_type(8))) short     short8;
typedef __attribute__((ext_vector_type(4))) short     s16x4;
typedef __attribute__((ext_vector_type(8))) __bf16    bf16x8;
typedef __attribute__((ext_vector_type(4))) float     f32x4;
typedef __attribute__((ext_vector_type(4))) unsigned  uint32x4;

#define BATCH 32

__device__ __forceinline__ float b2f(unsigned short b) {
  union { unsigned u; float f; } v; v.u = ((unsigned)b) << 16; return v.f;
}
__device__ __forceinline__ unsigned short f2b(float f) {  // round-to-nearest-even
  union { float f; unsigned u; } v; v.f = f;
  unsigned r = v.u + 0x7FFF + ((v.u >> 16) & 1);
  return (unsigned short)(r >> 16);
}

// ---------------- weight prep ------------------------------------------------
__global__ __launch_bounds__(256) void prep1v_k(const float* __restrict__ w,
                                                unsigned short* __restrict__ wq) {
  const int i = blockIdx.x*256 + threadIdx.x;                 // 4096 exact
  const int j = i & 7, l = (i >> 3) & 63, ni = (i >> 9) & 3, ks = i >> 11;
  const int k = ks*32 + (l >> 4)*8 + j;
  const int co = ni*16 + (l & 15);
  wq[i] = (k < 48) ? f2b(w[co*48 + k]) : (unsigned short)0;
}
__global__ __launch_bounds__(256) void prep2v_k(const float* __restrict__ w,
                                                unsigned short* __restrict__ wq) {
  const int i = blockIdx.x*256 + threadIdx.x;                 // 131072 exact
  const int j = i & 7, l = (i >> 3) & 63, ni = (i >> 9) & 7, ks = i >> 12;
  const int lm = l & 15, lk = l >> 4;
  const int tap = ks >> 1, cc = ks & 1;
  const int co = ni*16 + lm, ci = cc*32 + lk*8 + j;
  wq[i] = f2b(w[(co*64 + ci)*16 + tap]);
}
__global__ __launch_bounds__(256) void prep3_k(const float* __restrict__ w,
                                               unsigned short* __restrict__ wq) {
  const int i = blockIdx.x*256 + threadIdx.x;                 // 36864 exact
  const int ci = i & 127, co = (i >> 7) & 31, t = i >> 12;
  wq[i] = f2b(w[(co*128 + ci)*9 + t]);                        // ew3 OIHW(32,128,3,3)
}
__global__ __launch_bounds__(256) void prep4_k(const float* __restrict__ w,
                                               unsigned short* __restrict__ wq) {
  const int i = blockIdx.x*256 + threadIdx.x;                 // 36864 exact
  const int ci = i & 31, co = (i >> 5) & 127, t = i >> 12;
  wq[i] = f2b(w[(ci*128 + co)*9 + (8 - t)]);                  // dw1(32,128,3,3), flipped
}
__global__ __launch_bounds__(256) void prep5v_k(const float* __restrict__ w,
                                                unsigned short* __restrict__ wq) {
  const int i = blockIdx.x*256 + threadIdx.x;                 // 131072 exact
  const int j = i & 7, l = (i >> 3) & 63, ni = (i >> 9) & 3;
  const int ks = (i >> 11) & 15, p = i >> 15;
  const int lm = l & 15, lk = l >> 4;
  const int py = p >> 1, px = p & 1;
  const int a = ks >> 3, b = (ks >> 2) & 1, cc = ks & 3;
  const int co = ni*16 + lm, ci = cc*32 + lk*8 + j;
  const int ky = 3 - 2*a - py, kx = 3 - 2*b - px;
  wq[i] = f2b(w[(ci*64 + co)*16 + ky*4 + kx]);                // dw2(128,64,4,4)
}
__global__ __launch_bounds__(256) void prep6_k(const float* __restrict__ w,
                                               unsigned short* __restrict__ wq) {
  const int i = blockIdx.x*256 + threadIdx.x;                 // 16384 exact
  const int j = i & 7, l = (i >> 3) & 63, kc = (i >> 9) & 7, p = i >> 12;
  const int lm = l & 15, lk = l >> 4;
  const int a = kc >> 2, b = (kc >> 1) & 1, ch = kc & 1;
  const int ci = ch*32 + lk*8 + j, co = lm;
  const int py = p >> 1, px = p & 1;
  const int ky = 2 - 2*a + (1 - py), kx = 2 - 2*b + (1 - px);
  wq[i] = (co < 3) ? f2b(w[(ci*3 + co)*16 + ky*4 + kx]) : (unsigned short)0;
}

// --------- MFMA implicit-GEMM conv: NHWC in -> NHWC out (64x64 spatial) -----
template<int CIN,int COUT,int HIN,int S,int KW,int NTAPS,int OSTRIDE,int P,
         bool PARITY,bool RELU,bool INF32,bool OUTF32>
__global__ __launch_bounds__(256) void mconv_k(const void* __restrict__ in_,
    const unsigned short* __restrict__ wq_, const float* __restrict__ bias,
    void* __restrict__ out_) {
  constexpr int NF  = COUT / 16;
  constexpr int NCH = CIN / 32;
  __shared__ short Al[128*40];      // 128 rows x 32 k, stride 40 (80B, 16B-mult)
  __shared__ short Bl[COUT*40];
  int py = 0, px = 0, PY = P, PX = P;
  const unsigned short* wq = wq_;
  if (PARITY) {
    py = blockIdx.y >> 1; px = blockIdx.y & 1;
    PY = 1 - py; PX = 1 - px;
    wq += blockIdx.y * (NTAPS*COUT*CIN);
  }
  const int m0 = blockIdx.x * 128;
  const int w  = threadIdx.x >> 6, l = threadIdx.x & 63;
  const int lm = l & 15, lk = l >> 4;
  f32x4 acc[2][NF];
  #pragma unroll
  for (int mi = 0; mi < 2; ++mi)
    #pragma unroll
    for (int ni = 0; ni < NF; ++ni) acc[mi][ni] = (f32x4)0.0f;

  for (int tap = 0; tap < NTAPS; ++tap) {
    const int ky = tap / KW, kx = tap % KW;
    for (int ch = 0; ch < NCH; ++ch) {
      const int c0 = ch * 32;
      __syncthreads();                       // prev iter frag reads done
      for (int s = threadIdx.x; s < 512; s += 256) {
        const int row = s >> 2, part = s & 3;
        const int m = m0 + row;
        const int n = m >> 12, oy = (m >> 6) & 63, ox = m & 63;
        const int iy = oy*S - PY + ky, ix = ox*S - PX + kx;
        short8 v = (short8)(short)0;
        if (iy >= 0 && iy < HIN && ix >= 0 && ix < HIN) {
          const int base = ((n*HIN + iy)*HIN + ix)*CIN + c0 + part*8;
          if (INF32) {
            const float* pf = (const float*)in_ + base;
            const f32x4 f0 = *(const f32x4*)pf;
            const f32x4 f1 = *(const f32x4*)(pf + 4);
            #pragma unroll
            for (int j = 0; j < 4; ++j) {
              v[j]     = (short)f2b(f0[j]);
              v[j + 4] = (short)f2b(f1[j]);
            }
          } else {
            v = *(const short8*)((const unsigned short*)in_ + base);
          }
        }
        *(short8*)&Al[row*40 + part*8] = v;
      }
      for (int s = threadIdx.x; s < COUT*4; s += 256) {
        const int co = s >> 2, part = s & 3;
        *(short8*)&Bl[co*40 + part*8] =
            *(const short8*)(wq + (tap*COUT + co)*CIN + c0 + part*8);
      }
      __syncthreads();
      short8 av[2];
      #pragma unroll
      for (int mi = 0; mi < 2; ++mi)
        av[mi] = *(const short8*)&Al[(w*32 + mi*16 + lm)*40 + lk*8];
      #pragma unroll
      for (int ni = 0; ni < NF; ++ni) {
        const short8 bv = *(const short8*)&Bl[(ni*16 + lm)*40 + lk*8];
        #pragma unroll
        for (int mi = 0; mi < 2; ++mi)
          acc[mi][ni] = __builtin_amdgcn_mfma_f32_16x16x32_bf16(
              __builtin_bit_cast(bf16x8, av[mi]),
              __builtin_bit_cast(bf16x8, bv),
              acc[mi][ni], 0, 0, 0);
      }
    }
  }
  #pragma unroll
  for (int ni = 0; ni < NF; ++ni) {
    const int co = ni*16 + lm;
    const float bv = bias[co];
    #pragma unroll
    for (int mi = 0; mi < 2; ++mi) {
      #pragma unroll
      for (int r = 0; r < 4; ++r) {
        const int ml = w*32 + mi*16 + lk*4 + r;
        const int m  = m0 + ml;
        float vv = acc[mi][ni][r] + bv;
        if (RELU) vv = fmaxf(vv, 0.f);
        int off;
        if (OSTRIDE == 1) {
          off = m*COUT + co;
        } else {
          const int n = m >> 12, oy = (m >> 6) & 63, ox = m & 63;
          off = ((n*128 + oy*2 + py)*128 + ox*2 + px)*COUT + co;
        }
        if (OUTF32) ((float*)out_)[off] = vv;
        else ((unsigned short*)out_)[off] = f2b(vv);
      }
    }
  }
}

// ---- conv1 via MFMA: x NCHW fp32 [32,3,256,256] -> h1 NHWC bf16 ------------
__global__ __launch_bounds__(256) void conv1m_k(const float* __restrict__ x,
    const unsigned short* __restrict__ wv, const float* __restrict__ bias,
    unsigned short* __restrict__ out) {
  __shared__ __align__(16) short RAW[12*264];   // row g=ci*4+ky, idx=ix+4; 6336B
  __shared__ __align__(16) short IC[128*64];    // [ox][k] swizzled; 16384B
  const int wid = ((blockIdx.x & 7) << 9) + (blockIdx.x >> 3);
  const int q = wid & 127, n = wid >> 7;        // q = output row oy
  for (int i = threadIdx.x; i < 396; i += 256)
    *(short8*)&RAW[i*8] = (short8)(short)0;
  __syncthreads();
  for (int s = threadIdx.x; s < 768; s += 256) {   // 12 rows * 64 f32x4
    const int g = s >> 6, seg = s & 63;
    const int ci = g >> 2, ky = g & 3;
    const int iy = 2*q - 1 + ky;
    if (iy >= 0 && iy < 256) {
      const f32x4 v = *(const f32x4*)&x[((n*3 + ci)*256 + iy)*256 + seg*4];
      s16x4 sv;
      #pragma unroll
      for (int e = 0; e < 4; ++e) sv[e] = (short)f2b(v[e]);
      *(s16x4*)&RAW[g*264 + 4 + seg*4] = sv;
    }
  }
  __syncthreads();
  for (int s = threadIdx.x; s < 1024; s += 256) {
    const int kb = s & 7, ox = s >> 3;
    short8 v = (short8)(short)0;
    if (kb < 6) {
      const unsigned* u0 = (const unsigned*)&RAW[(2*kb  )*264 + 2*ox + 2];
      const unsigned* u1 = (const unsigned*)&RAW[(2*kb+1)*264 + 2*ox + 2];
      const unsigned a0 = u0[0], a1 = u0[1], a2 = u0[2];
      const unsigned b0 = u1[0], b1 = u1[1], b2 = u1[2];
      uint32x4 uv;
      uv[0] = (a0 >> 16) | (a1 << 16);
      uv[1] = (a1 >> 16) | (a2 << 16);
      uv[2] = (b0 >> 16) | (b1 << 16);
      uv[3] = (b1 >> 16) | (b2 << 16);
      v = __builtin_bit_cast(short8, uv);
    }
    const int bo = ((ox << 7) + (kb << 4)) ^ ((ox & 7) << 4);
    *(short8*)((char*)IC + bo) = v;
  }
  __syncthreads();
  const int w = threadIdx.x >> 6, l = threadIdx.x & 63;
  const int lm = l & 15, lk = l >> 4;
  f32x4 acc[2][4];
  #pragma unroll
  for (int mi = 0; mi < 2; ++mi)
    #pragma unroll
    for (int ni = 0; ni < 4; ++ni) acc[mi][ni] = (f32x4)0.0f;
  #pragma unroll
  for (int ks = 0; ks < 2; ++ks) {
    short8 bv[4];
    #pragma unroll
    for (int ni = 0; ni < 4; ++ni)
      bv[ni] = *(const short8*)(wv + (((ks*4 + ni)*64 + l) << 3));
    #pragma unroll
    for (int mi = 0; mi < 2; ++mi) {
      const int ox = w*32 + mi*16 + lm;
      const int bo = ((ox << 7) + (ks << 6) + (lk << 4)) ^ ((ox & 7) << 4);
      const short8 av = *(const short8*)((const char*)IC + bo);
      #pragma unroll
      for (int ni = 0; ni < 4; ++ni)
        acc[mi][ni] = __builtin_amdgcn_mfma_f32_16x16x32_bf16(
            __builtin_bit_cast(bf16x8, av),
            __builtin_bit_cast(bf16x8, bv[ni]),
            acc[mi][ni], 0, 0, 0);
    }
  }
  __syncthreads();            // frag reads done; reuse IC for output staging
  #pragma unroll
  for (int mi = 0; mi < 2; ++mi)
    #pragma unroll
    for (int ni = 0; ni < 4; ++ni) {
      const int co = ni*16 + lm;
      const float bv = bias[co];
      #pragma unroll
      for (int r = 0; r < 4; ++r) {
        const int ox = w*32 + mi*16 + lk*4 + r;
        const int bo = ((ox << 7) + 2*co) ^ ((ox & 7) << 4);
        *(short*)((char*)IC + bo) = (short)f2b(fmaxf(acc[mi][ni][r] + bv, 0.f));
      }
    }
  __syncthreads();
  const long ob = ((long)(n*128 + q)) * 8192;   // 128 ox * 64 co
  for (int s = threadIdx.x; s < 1024; s += 256) {
    const int kb = s & 7, ox = s >> 3;
    const int bo = ((ox << 7) + (kb << 4)) ^ ((ox & 7) << 4);
    *(short8*)&out[ob + ox*64 + kb*8] = *(const short8*)((const char*)IC + bo);
  }
}

// ---- conv2 via two-phase MFMA + async stage: h1 -> h2 ----------------------
#define C2_LOAD(c) \
  _Pragma("unroll") \
  for (int s = 0; s < 9; ++s) { \
    st[s] = (short8)(short)0; \
    if (goff[s] >= 0) st[s] = *(const short8*)(in + goff[s] + (c)*32); \
  }
#define C2_WRITE \
  _Pragma("unroll") \
  for (int s = 0; s < 9; ++s) \
    if (lb[s] >= 0) *(short8*)((char*)IL + lb[s]) = st[s];
#define C2_COMPUTE(c) \
  _Pragma("unroll") \
  for (int t = 0; t < 16; ++t) { \
    const int ky = t >> 2, kx = t & 3; \
    const int p = 1 - (kx & 1), d = kx >> 1; \
    const short8 bv0 = *(const short8*)(wb + (t*2 + (c))*4096); \
    const short8 bv1 = *(const short8*)(wb + (t*2 + (c))*4096 + 512); \
    const char* Ab = (const char*)IL + (Bd0 + d*64); \
    const int imm0 = ((ky*2 + p)*66) << 6; \
    _Pragma("unroll") \
    for (int mi = 0; mi < 4; ++mi) { \
      const short8 av = *(const short8*)(Ab + imm0 + mi*1024); \
      acc[mi][0] = __builtin_amdgcn_mfma_f32_16x16x32_bf16( \
          __builtin_bit_cast(bf16x8, av), __builtin_bit_cast(bf16x8, bv0), \
          acc[mi][0], 0, 0, 0); \
      acc[mi][1] = __builtin_amdgcn_mfma_f32_16x16x32_bf16( \
          __builtin_bit_cast(bf16x8, av), __builtin_bit_cast(bf16x8, bv1), \
          acc[mi][1], 0, 0, 0); \
    } \
  }
__global__ __launch_bounds__(256) void conv2m_k(const unsigned short* __restrict__ in,
    const unsigned short* __restrict__ wv, const float* __restrict__ bias,
    unsigned short* __restrict__ out) {
  __shared__ short IL[8*66*32];        // [(r*2+p)*66+idx][ci_local 32], 33792 B
  const int wid = (blockIdx.x & 7)*256 + (blockIdx.x >> 3);
  const int q = wid & 63, n = wid >> 6;          // q = output row oy
  const int w = threadIdx.x >> 6, l = threadIdx.x & 63;
  const int lm = l & 15, lk = l >> 4;
  const int Bd0 = lm*64 + lk*16;                 // A-read byte base, d=0
  const unsigned short* wb = wv + w*1024 + l*8;  // + ks*4096 (+512 for ni=1)
  // staging slot addresses (9 slots; 2112 tasks = 8 rp * 66 idx * 4 part)
  int goff[9], lb[9];
  #pragma unroll
  for (int s = 0; s < 9; ++s) {
    const int i = threadIdx.x + s*256;
    const int part = i & 3, e = i >> 2;
    const int idx = e % 66, rp = e / 66;
    const int r = rp >> 1, p = rp & 1;
    const int iy = 2*q - 1 + r, ix = 2*idx - p;
    const bool ok = (i < 2112) && iy >= 0 && iy < 128 && ix >= 0 && ix < 128;
    goff[s] = ok ? (((n*128 + iy)*128 + ix)*64 + part*8) : -1;
    lb[s]   = (i < 2112) ? (e*64 + part*16) : -1;
  }
  f32x4 acc[4][2];
  #pragma unroll
  for (int mi = 0; mi < 4; ++mi)
    #pragma unroll
    for (int ni = 0; ni < 2; ++ni) acc[mi][ni] = (f32x4)0.0f;
  short8 st[9];
  C2_LOAD(0); C2_WRITE;
  __syncthreads();
  C2_LOAD(1);                          // issue phase-1 loads (in flight)
  C2_COMPUTE(0);
  __syncthreads();                     // phase-0 LDS reads done
  C2_WRITE;                            // waits vmcnt for st, writes LDS
  __syncthreads();
  C2_COMPUTE(1);
  #pragma unroll
  for (int mi = 0; mi < 4; ++mi)
    #pragma unroll
    for (int r = 0; r < 4; ++r) {
      const int ox = mi*16 + lk*4 + r;
      const int ob = ((n*64 + q)*64 + ox)*128;
      #pragma unroll
      for (int ni = 0; ni < 2; ++ni) {
        const int co = (w*2 + ni)*16 + lm;
        out[ob + co] = f2b(fmaxf(acc[mi][ni][r] + bias[co], 0.f));
      }
    }
}

// ---- d2 convT via two-phase merged-parity MFMA + async stage: d1 -> d2 -----
#define CT2_LOAD(c) \
  _Pragma("unroll") \
  for (int s = 0; s < 7; ++s) { \
    st[s] = (short8)(short)0; \
    if (goff[s] >= 0) st[s] = *(const short8*)(in + goff[s] + (c)*64); \
  }
#define CT2_WRITE \
  _Pragma("unroll") \
  for (int s = 0; s < 7; ++s) \
    if (lb[s] >= 0) *(short8*)((char*)IL + lb[s]) = st[s];
#define CT2_COMPUTE(c) \
  _Pragma("unroll") \
  for (int u = 0; u < 8; ++u) { \
    const int a = u >> 2, b = (u >> 1) & 1, c1 = u & 1; \
    const int ks = (a << 3) | (b << 2) | (2*(c) + c1); \
    short8 bv[4]; \
    _Pragma("unroll") \
    for (int ni = 0; ni < 4; ++ni) \
      bv[ni] = *(const short8*)(wb + ks*2048 + ni*512); \
    const char* Ab = (const char*)IL + (pyb + Wb[b][c1]); \
    const int imm0 = a*8448; \
    _Pragma("unroll") \
    for (int mi = 0; mi < 4; ++mi) { \
      const short8 av = *(const short8*)(Ab + imm0 + mi*2048); \
      _Pragma("unroll") \
      for (int ni = 0; ni < 4; ++ni) \
        acc[mi][ni] = __builtin_amdgcn_mfma_f32_16x16x32_bf16( \
            __builtin_bit_cast(bf16x8, av), \
            __builtin_bit_cast(bf16x8, bv[ni]), \
            acc[mi][ni], 0, 0, 0); \
    } \
  }
__global__ __launch_bounds__(256) void convt2m_k(const unsigned short* __restrict__ in,
    const unsigned short* __restrict__ wv, const float* __restrict__ bias,
    unsigned short* __restrict__ out) {
  __shared__ short IL[3*66*64];        // [r*66+col][ci_local 32+32], 25344 B
  const int wid = (blockIdx.x & 7)*256 + (blockIdx.x >> 3);
  const int q = wid & 63, n = wid >> 6;
  const int w = threadIdx.x >> 6, l = threadIdx.x & 63;
  const int py = w >> 1, px = w & 1;
  const int lm = l & 15, lk = l >> 4;
  int Wb[2][2];
  #pragma unroll
  for (int b = 0; b < 2; ++b) {
    const int e = lm + px + b;
    Wb[b][0] = (e << 7) + ((lk << 4) ^ ((e & 7) << 4));
    Wb[b][1] = Wb[b][0] ^ 0x40;
  }
  const int pyb = py * 8448;                       // 66 entries * 128 B
  const unsigned short* wb = wv + w*32768 + l*8;   // + ks*2048 + ni*512
  // staging slot addresses (7 slots; 1584 tasks = 198 entries * 8 part)
  int goff[7], lb[7];
  #pragma unroll
  for (int s = 0; s < 7; ++s) {
    const int i = threadIdx.x + s*256;
    const int part = i & 7, e = i >> 3;
    const int col = e % 66, r = e / 66;
    const int iy = q - 1 + r, ix = col - 1;
    const bool ok = (i < 1584) && iy >= 0 && iy < 64 && ix >= 0 && ix < 64;
    goff[s] = ok ? (((n*64 + iy)*64 + ix)*128 + part*8) : -1;
    lb[s]   = (i < 1584) ? ((e << 7) + ((part << 4) ^ ((col & 7) << 4))) : -1;
  }
  f32x4 acc[4][4];
  #pragma unroll
  for (int mi = 0; mi < 4; ++mi)
    #pragma unroll
    for (int ni = 0; ni < 4; ++ni) acc[mi][ni] = (f32x4)0.0f;
  short8 st[7];
  CT2_LOAD(0); CT2_WRITE;
  __syncthreads();
  CT2_LOAD(1);                         // issue phase-1 loads (in flight)
  CT2_COMPUTE(0);
  __syncthreads();                     // phase-0 LDS reads done
  CT2_WRITE;                           // waits vmcnt, writes LDS
  __syncthreads();
  CT2_COMPUTE(1);
  const int oy = 2*q + py;
  #pragma unroll
  for (int mi = 0; mi < 4; ++mi)
    #pragma unroll
    for (int r = 0; r < 4; ++r) {
      const int ox = 2*(mi*16 + lk*4 + r) + px;
      const int ob = ((n*128 + oy)*128 + ox)*64;
      #pragma unroll
      for (int ni = 0; ni < 4; ++ni) {
        const int co = ni*16 + lm;
        out[ob + co] = f2b(fmaxf(acc[mi][ni][r] + bias[co], 0.f));
      }
    }
}

// ------- VQ via MFMA: z fp32 [131072,32] -> zq fp32 + loss partials ---------
__global__ __launch_bounds__(256) void vqm_k(const float* __restrict__ z,
    const float* __restrict__ embed, float* __restrict__ zq,
    float* __restrict__ partial) {
  __shared__ short Be[512*40];     // bf16 codes, pad stride 40 (40960 B)
  __shared__ float en[512];        // |e|^2 (bf16-rounded e), fp32
  __shared__ int   bidx[128];
  __shared__ float red[256];
  const int m0 = blockIdx.x * 128;
  for (int i = threadIdx.x; i < 4096; i += 256) {
    const int j = i >> 3, k0 = (i & 7) * 4;
    const f32x4 v = *(const f32x4*)&embed[j*32 + k0];
    s16x4 s;
    #pragma unroll
    for (int e = 0; e < 4; ++e) s[e] = (short)f2b(v[e]);
    *(s16x4*)&Be[j*40 + k0] = s;
  }
  __syncthreads();
  for (int j = threadIdx.x; j < 512; j += 256) {
    float s = 0.f;
    #pragma unroll
    for (int q = 0; q < 4; ++q) {
      const short8 v = *(const short8*)&Be[j*40 + q*8];
      #pragma unroll
      for (int e = 0; e < 8; ++e) {
        const float f = b2f((unsigned short)v[e]);
        s = fmaf(f, f, s);
      }
    }
    en[j] = s;
  }
  __syncthreads();
  const int w = threadIdx.x >> 6, l = threadIdx.x & 63;
  const int lm = l & 15, lk = l >> 4;
  const int rw = w * 32;
  short8 av[2];
  #pragma unroll
  for (int mi = 0; mi < 2; ++mi) {
    const float* zp = z + (long)(m0 + rw + mi*16 + lm)*32 + lk*8;
    const f32x4 f0 = *(const f32x4*)zp;
    const f32x4 f1 = *(const f32x4*)(zp + 4);
    short8 v;
    #pragma unroll
    for (int e = 0; e < 4; ++e) {
      v[e]     = (short)f2b(f0[e]);
      v[e + 4] = (short)f2b(f1[e]);
    }
    av[mi] = v;
  }
  float bd[2][4]; int bj[2][4];
  #pragma unroll
  for (int mi = 0; mi < 2; ++mi)
    #pragma unroll
    for (int r = 0; r < 4; ++r) { bd[mi][r] = 1e30f; bj[mi][r] = 0; }
  for (int nc = 0; nc < 8; ++nc) {               // N-chunks of 64 codes
    f32x4 acc[2][4];
    #pragma unroll
    for (int mi = 0; mi < 2; ++mi)
      #pragma unroll
      for (int ni = 0; ni < 4; ++ni) acc[mi][ni] = (f32x4)0.0f;
    #pragma unroll
    for (int ni = 0; ni < 4; ++ni) {
      const short8 bv = *(const short8*)&Be[(nc*64 + ni*16 + lm)*40 + lk*8];
      #pragma unroll
      for (int mi = 0; mi < 2; ++mi)
        acc[mi][ni] = __builtin_amdgcn_mfma_f32_16x16x32_bf16(
            __builtin_bit_cast(bf16x8, av[mi]),
            __builtin_bit_cast(bf16x8, bv),
            acc[mi][ni], 0, 0, 0);
    }
    #pragma unroll
    for (int ni = 0; ni < 4; ++ni) {
      const int j = nc*64 + ni*16 + lm;
      const float e_n = en[j];
      #pragma unroll
      for (int mi = 0; mi < 2; ++mi)
        #pragma unroll
        for (int r = 0; r < 4; ++r) {
          const float d = fmaf(-2.f, acc[mi][ni][r], e_n);
          if (d < bd[mi][r]) { bd[mi][r] = d; bj[mi][r] = j; }
        }
    }
  }
  #pragma unroll
  for (int mi = 0; mi < 2; ++mi)
    #pragma unroll
    for (int r = 0; r < 4; ++r) {
      float d = bd[mi][r]; int j = bj[mi][r];
      #pragma unroll
      for (int off = 1; off < 16; off <<= 1) {
        const float od = __shfl_xor(d, off);
        const int   oj = __shfl_xor(j, off);
        if (od < d || (od == d && oj < j)) { d = od; j = oj; }
      }
      if (lm == 0) bidx[rw + mi*16 + lk*4 + r] = j;
    }
  __syncthreads();
  const int pl = threadIdx.x >> 1, hf = (threadIdx.x & 1) * 16;
  const int code = bidx[pl];
  const long pb = (long)(m0 + pl)*32 + hf;
  float se = 0.f;
  #pragma unroll
  for (int q = 0; q < 4; ++q) {
    const f32x4 ev = *(const f32x4*)&embed[code*32 + hf + q*4];
    const f32x4 zv = *(const f32x4*)&z[pb + q*4];
    *(f32x4*)&zq[pb + q*4] = ev;
    const f32x4 df = ev - zv;
    #pragma unroll
    for (int e = 0; e < 4; ++e) se = fmaf(df[e], df[e], se);
  }
  red[threadIdx.x] = se; __syncthreads();
  for (int s = 128; s > 0; s >>= 1) {
    if (threadIdx.x < s) red[threadIdx.x] += red[threadIdx.x + s];
    __syncthreads();
  }
  if (threadIdx.x == 0) partial[blockIdx.x] = red[0];
}

__global__ __launch_bounds__(256) void loss_k(const float* __restrict__ part,
                                              float* __restrict__ out) {
  __shared__ float red[256];
  const int t = threadIdx.x;
  float s = 0.f;
  #pragma unroll
  for (int q = 0; q < 4; ++q) s += part[t + q*256];   // 1024 partials
  red[t] = s; __syncthreads();
  for (int st = 128; st > 0; st >>= 1) {
    if (t < st) red[t] += red[t + st];
    __syncthreads();
  }
  if (t == 0) out[0] = red[0] * (1.25f / (131072.f * 32.f));
}

// ---- convt3 via MFMA: d2 NHWC bf16 [32,128,128,64] -> x_recon NCHW fp32 ----
__global__ __launch_bounds__(256) void convt3m_k(const unsigned short* __restrict__ in,
    const unsigned short* __restrict__ wq6, const float* __restrict__ bias,
    float* __restrict__ out) {
  __shared__ short8 IL[3*8*66];      // [(r*8+c8)*66 + ixl], 25344 B
  const int h = blockIdx.x & 1, q = (blockIdx.x >> 1) & 127, n = blockIdx.x >> 8;
  for (int i = threadIdx.x; i < 1584; i += 256) {   // 3*66*8
    const int c8 = i & 7, t = i >> 3, ixl = t % 66, r = t / 66;
    const int iy = q - 1 + r, ix = h*64 - 1 + ixl;
    short8 v = (short8)(short)0;
    if (iy >= 0 && iy < 128 && ix >= 0 && ix < 128)
      v = *(const short8*)(in + (((long)(n*128 + iy)*128 + ix)*64 + c8*8));
    IL[(r*8 + c8)*66 + ixl] = v;
  }
  const int w = threadIdx.x >> 6, l = threadIdx.x & 63;
  const int py = w >> 1, px = w & 1;
  const int lm = l & 15, lk = l >> 4;
  short8 bfrag[8];
  #pragma unroll
  for (int kc = 0; kc < 8; ++kc)
    bfrag[kc] = *(const short8*)(wq6 + (((w*8 + kc)*64 + l) << 3));
  __syncthreads();
  f32x4 acc[4];
  #pragma unroll
  for (int mi = 0; mi < 4; ++mi) acc[mi] = (f32x4)0.0f;
  #pragma unroll
  for (int kc = 0; kc < 8; ++kc) {
    const int a = kc >> 2, b = (kc >> 1) & 1, ch = kc & 1;
    const int base = (((py + a)*8 + ch*4 + lk)*66) + px + b;   // + ixl(xq)
    #pragma unroll
    for (int mi = 0; mi < 4; ++mi) {
      const short8 av = *(const short8*)&IL[base + mi*16 + lm];
      acc[mi] = __builtin_amdgcn_mfma_f32_16x16x32_bf16(
          __builtin_bit_cast(bf16x8, av),
          __builtin_bit_cast(bf16x8, bfrag[kc]),
          acc[mi], 0, 0, 0);
    }
  }
  // epilogue: C row = xq (lk*4+r within tile), col = co (lanes lm<3 write)
  if (lm < 3) {
    const float bv = bias[lm];
    const int oy = 2*q + py;
    const long ob = ((long)(n*3 + lm))*65536 + oy*256;
    #pragma unroll
    for (int mi = 0; mi < 4; ++mi)
      #pragma unroll
      for (int r = 0; r < 4; ++r) {
        const int xq = mi*16 + lk*4 + r;
        out[ob + h*128 + 2*xq + px] = acc[mi][r] + bv;
      }
  }
}

extern "C" void kernel_launch(void* const* d_in, const int* in_sizes, int n_in,
                              void* d_out, int out_size, void* d_ws, size_t ws_size,
                              hipStream_t stream) {
  const float* x   = (const float*)d_in[0];
  const float* ew1 = (const float*)d_in[1];  const float* eb1 = (const float*)d_in[2];
  const float* ew2 = (const float*)d_in[3];  const float* eb2 = (const float*)d_in[4];
  const float* ew3 = (const float*)d_in[5];  const float* eb3 = (const float*)d_in[6];
  const float* emb = (const float*)d_in[7];
  const float* dw1 = (const float*)d_in[8];  const float* db1 = (const float*)d_in[9];
  const float* dw2 = (const float*)d_in[10]; const float* db2 = (const float*)d_in[11];
  const float* dw3 = (const float*)d_in[12]; const float* db3 = (const float*)d_in[13];
  float* out = (float*)d_out;

  uint8_t* w8 = (uint8_t*)d_ws;
  unsigned short* h1 = (unsigned short*)w8;
  unsigned short* h2 = (unsigned short*)(w8 + 67108864);
  float* z   = (float*)(w8 + 100663296);
  float* zq  = (float*)(w8 + 117440512);
  float* part = (float*)(w8 + 67108864);              // h2 region (dead @ vqm)
  unsigned short* wq2 = (unsigned short*)(w8 + 117440512);            // 262144 B
  unsigned short* wq3 = (unsigned short*)(w8 + 117440512 + 262144);   // 73728 B
  unsigned short* wq1 = (unsigned short*)(w8 + 117440512 + 335872);   // 8192 B
  unsigned short* wq4 = (unsigned short*)(w8 + 100663296);            // 73728 B
  unsigned short* wq5 = (unsigned short*)(w8 + 100663296 + 73728);    // 262144 B
  unsigned short* wq6 = (unsigned short*)(w8 + 100663296 + 335872);   // 32768 B
  unsigned short* d1 = h2;
  unsigned short* d2 = h1;

  // encoder weight prep (into zq region, consumed before vqm writes zq)
  prep1v_k<<<dim3(16),256,0,stream>>>(ew1, wq1);
  prep2v_k<<<dim3(512),256,0,stream>>>(ew2, wq2);
  prep3_k<<<dim3(144),256,0,stream>>>(ew3, wq3);
  // encoder
  conv1m_k<<<dim3(4096),256,0,stream>>>(x, wq1, eb1, h1);
  conv2m_k<<<dim3(2048),256,0,stream>>>(h1, wq2, eb2, h2);
  mconv_k<128,32,64,1,3,9,1,1,false,true,false,true>
      <<<dim3(1024),256,0,stream>>>(h2, wq3, eb3, z);
  // VQ (MFMA) + loss  (partials in h2 region; loss_k consumes before d1 write)
  vqm_k<<<dim3(1024),256,0,stream>>>(z, emb, zq, part);
  loss_k<<<dim3(1),256,0,stream>>>(part, out + 6291456);
  // decoder weight prep (into z region, dead after vqm)
  prep4_k<<<dim3(144),256,0,stream>>>(dw1, wq4);
  prep5v_k<<<dim3(512),256,0,stream>>>(dw2, wq5);
  prep6_k<<<dim3(64),256,0,stream>>>(dw3, wq6);
  // decoder
  mconv_k<32,128,64,1,3,9,1,1,false,true,true,false>
      <<<dim3(1024),256,0,stream>>>(zq, wq4, db1, d1);
  convt2m_k<<<dim3(2048),256,0,stream>>>(d1, wq5, db2, d2);
  convt3m_k<<<dim3(8192),256,0,stream>>>(d2, wq6, db3, out);
}

// Round 8
// 358.688 us; speedup vs baseline: 1.4443x; 1.0656x over previous
//
#include <hip/hip_runtime.h>

// VQ-VAE forward, MI355X round 18: R17 + conv3/d1 rewritten from the old
// 2-barrier-per-K-step mconv_k into single-pass MFMA kernels (conv3m_k:
// 2-phase ci-split + async stage; d1m_k: single phase). mconv_k retired.

typedef __attribute__((ext_vector_type(8))) short     short8;
typedef __attribute__((ext_vector_type(4))) short     s16x4;
typedef __attribute__((ext_vector_type(8))) __bf16    bf16x8;
typedef __attribute__((ext_vector_type(4))) float     f32x4;
typedef __attribute__((ext_vector_type(4))) unsigned  uint32x4;

__device__ __forceinline__ float b2f(unsigned short b) {
  union { unsigned u; float f; } v; v.u = ((unsigned)b) << 16; return v.f;
}
__device__ __forceinline__ unsigned short f2b(float f) {  // round-to-nearest-even
  union { float f; unsigned u; } v; v.f = f;
  unsigned r = v.u + 0x7FFF + ((v.u >> 16) & 1);
  return (unsigned short)(r >> 16);
}

// ---------------- weight prep ------------------------------------------------
__global__ __launch_bounds__(256) void prep1v_k(const float* __restrict__ w,
                                                unsigned short* __restrict__ wq) {
  const int i = blockIdx.x*256 + threadIdx.x;                 // 4096 exact
  const int j = i & 7, l = (i >> 3) & 63, ni = (i >> 9) & 3, ks = i >> 11;
  const int k = ks*32 + (l >> 4)*8 + j;
  const int co = ni*16 + (l & 15);
  wq[i] = (k < 48) ? f2b(w[co*48 + k]) : (unsigned short)0;
}
__global__ __launch_bounds__(256) void prep2v_k(const float* __restrict__ w,
                                                unsigned short* __restrict__ wq) {
  const int i = blockIdx.x*256 + threadIdx.x;                 // 131072 exact
  const int j = i & 7, l = (i >> 3) & 63, ni = (i >> 9) & 7, ks = i >> 12;
  const int lm = l & 15, lk = l >> 4;
  const int tap = ks >> 1, cc = ks & 1;
  const int co = ni*16 + lm, ci = cc*32 + lk*8 + j;
  wq[i] = f2b(w[(co*64 + ci)*16 + tap]);
}
// conv3 B-frags: wq3v[((ks*2+ni)*64+l)*8+j] = ew3[co=ni*16+lm][ci=cf*32+lk*8+j][tap]
// ks = tap*4 + cf, cf = ci-chunk 0..3.  ew3 OIHW (32,128,3,3).
__global__ __launch_bounds__(256) void prep3v_k(const float* __restrict__ w,
                                                unsigned short* __restrict__ wq) {
  const int i = blockIdx.x*256 + threadIdx.x;                 // 36864 exact
  const int j = i & 7, l = (i >> 3) & 63, ni = (i >> 9) & 1, ks = i >> 10;
  const int lm = l & 15, lk = l >> 4;
  const int tap = ks >> 2, cf = ks & 3;
  const int co = ni*16 + lm, ci = cf*32 + lk*8 + j;
  wq[i] = f2b(w[(co*128 + ci)*9 + tap]);
}
// d1 B-frags: wq4v[((tap*8+ni)*64+l)*8+j] = flip(dw1)[tap][co=ni*16+lm][ci=lk*8+j]
__global__ __launch_bounds__(256) void prep4v_k(const float* __restrict__ w,
                                                unsigned short* __restrict__ wq) {
  const int i = blockIdx.x*256 + threadIdx.x;                 // 36864 exact
  const int j = i & 7, l = (i >> 3) & 63, ni = (i >> 9) & 7, tap = i >> 12;
  const int lm = l & 15, lk = l >> 4;
  const int co = ni*16 + lm, ci = lk*8 + j;
  wq[i] = f2b(w[(ci*128 + co)*9 + (8 - tap)]);                // dw1(32,128,3,3)
}
__global__ __launch_bounds__(256) void prep5v_k(const float* __restrict__ w,
                                                unsigned short* __restrict__ wq) {
  const int i = blockIdx.x*256 + threadIdx.x;                 // 131072 exact
  const int j = i & 7, l = (i >> 3) & 63, ni = (i >> 9) & 3;
  const int ks = (i >> 11) & 15, p = i >> 15;
  const int lm = l & 15, lk = l >> 4;
  const int py = p >> 1, px = p & 1;
  const int a = ks >> 3, b = (ks >> 2) & 1, cc = ks & 3;
  const int co = ni*16 + lm, ci = cc*32 + lk*8 + j;
  const int ky = 3 - 2*a - py, kx = 3 - 2*b - px;
  wq[i] = f2b(w[(ci*64 + co)*16 + ky*4 + kx]);                // dw2(128,64,4,4)
}
__global__ __launch_bounds__(256) void prep6_k(const float* __restrict__ w,
                                               unsigned short* __restrict__ wq) {
  const int i = blockIdx.x*256 + threadIdx.x;                 // 16384 exact
  const int j = i & 7, l = (i >> 3) & 63, kc = (i >> 9) & 7, p = i >> 12;
  const int lm = l & 15, lk = l >> 4;
  const int a = kc >> 2, b = (kc >> 1) & 1, ch = kc & 1;
  const int ci = ch*32 + lk*8 + j, co = lm;
  const int py = p >> 1, px = p & 1;
  const int ky = 2 - 2*a + (1 - py), kx = 2 - 2*b + (1 - px);
  wq[i] = (co < 3) ? f2b(w[(ci*3 + co)*16 + ky*4 + kx]) : (unsigned short)0;
}

// ---- conv1 via MFMA: x NCHW fp32 [32,3,256,256] -> h1 NHWC bf16 ------------
__global__ __launch_bounds__(256) void conv1m_k(const float* __restrict__ x,
    const unsigned short* __restrict__ wv, const float* __restrict__ bias,
    unsigned short* __restrict__ out) {
  __shared__ __align__(16) short RAW[12*264];   // row g=ci*4+ky, idx=ix+4; 6336B
  __shared__ __align__(16) short IC[128*64];    // [ox][k] swizzled; 16384B
  const int wid = ((blockIdx.x & 7) << 9) + (blockIdx.x >> 3);
  const int q = wid & 127, n = wid >> 7;        // q = output row oy
  for (int i = threadIdx.x; i < 396; i += 256)
    *(short8*)&RAW[i*8] = (short8)(short)0;
  __syncthreads();
  for (int s = threadIdx.x; s < 768; s += 256) {   // 12 rows * 64 f32x4
    const int g = s >> 6, seg = s & 63;
    const int ci = g >> 2, ky = g & 3;
    const int iy = 2*q - 1 + ky;
    if (iy >= 0 && iy < 256) {
      const f32x4 v = *(const f32x4*)&x[((n*3 + ci)*256 + iy)*256 + seg*4];
      s16x4 sv;
      #pragma unroll
      for (int e = 0; e < 4; ++e) sv[e] = (short)f2b(v[e]);
      *(s16x4*)&RAW[g*264 + 4 + seg*4] = sv;
    }
  }
  __syncthreads();
  for (int s = threadIdx.x; s < 1024; s += 256) {
    const int kb = s & 7, ox = s >> 3;
    short8 v = (short8)(short)0;
    if (kb < 6) {
      const unsigned* u0 = (const unsigned*)&RAW[(2*kb  )*264 + 2*ox + 2];
      const unsigned* u1 = (const unsigned*)&RAW[(2*kb+1)*264 + 2*ox + 2];
      const unsigned a0 = u0[0], a1 = u0[1], a2 = u0[2];
      const unsigned b0 = u1[0], b1 = u1[1], b2 = u1[2];
      uint32x4 uv;
      uv[0] = (a0 >> 16) | (a1 << 16);
      uv[1] = (a1 >> 16) | (a2 << 16);
      uv[2] = (b0 >> 16) | (b1 << 16);
      uv[3] = (b1 >> 16) | (b2 << 16);
      v = __builtin_bit_cast(short8, uv);
    }
    const int bo = ((ox << 7) + (kb << 4)) ^ ((ox & 7) << 4);
    *(short8*)((char*)IC + bo) = v;
  }
  __syncthreads();
  const int w = threadIdx.x >> 6, l = threadIdx.x & 63;
  const int lm = l & 15, lk = l >> 4;
  f32x4 acc[2][4];
  #pragma unroll
  for (int mi = 0; mi < 2; ++mi)
    #pragma unroll
    for (int ni = 0; ni < 4; ++ni) acc[mi][ni] = (f32x4)0.0f;
  #pragma unroll
  for (int ks = 0; ks < 2; ++ks) {
    short8 bv[4];
    #pragma unroll
    for (int ni = 0; ni < 4; ++ni)
      bv[ni] = *(const short8*)(wv + (((ks*4 + ni)*64 + l) << 3));
    #pragma unroll
    for (int mi = 0; mi < 2; ++mi) {
      const int ox = w*32 + mi*16 + lm;
      const int bo = ((ox << 7) + (ks << 6) + (lk << 4)) ^ ((ox & 7) << 4);
      const short8 av = *(const short8*)((const char*)IC + bo);
      #pragma unroll
      for (int ni = 0; ni < 4; ++ni)
        acc[mi][ni] = __builtin_amdgcn_mfma_f32_16x16x32_bf16(
            __builtin_bit_cast(bf16x8, av),
            __builtin_bit_cast(bf16x8, bv[ni]),
            acc[mi][ni], 0, 0, 0);
    }
  }
  __syncthreads();            // frag reads done; reuse IC for output staging
  #pragma unroll
  for (int mi = 0; mi < 2; ++mi)
    #pragma unroll
    for (int ni = 0; ni < 4; ++ni) {
      const int co = ni*16 + lm;
      const float bv = bias[co];
      #pragma unroll
      for (int r = 0; r < 4; ++r) {
        const int ox = w*32 + mi*16 + lk*4 + r;
        const int bo = ((ox << 7) + 2*co) ^ ((ox & 7) << 4);
        *(short*)((char*)IC + bo) = (short)f2b(fmaxf(acc[mi][ni][r] + bv, 0.f));
      }
    }
  __syncthreads();
  const long ob = ((long)(n*128 + q)) * 8192;   // 128 ox * 64 co
  for (int s = threadIdx.x; s < 1024; s += 256) {
    const int kb = s & 7, ox = s >> 3;
    const int bo = ((ox << 7) + (kb << 4)) ^ ((ox & 7) << 4);
    *(short8*)&out[ob + ox*64 + kb*8] = *(const short8*)((const char*)IC + bo);
  }
}

// ---- conv2 via two-phase MFMA + async stage: h1 -> h2 ----------------------
#define C2_LOAD(c) \
  _Pragma("unroll") \
  for (int s = 0; s < 9; ++s) { \
    st[s] = (short8)(short)0; \
    if (goff[s] >= 0) st[s] = *(const short8*)(in + goff[s] + (c)*32); \
  }
#define C2_WRITE \
  _Pragma("unroll") \
  for (int s = 0; s < 9; ++s) \
    if (lb[s] >= 0) *(short8*)((char*)IL + lb[s]) = st[s];
#define C2_COMPUTE(c) \
  _Pragma("unroll") \
  for (int t = 0; t < 16; ++t) { \
    const int ky = t >> 2, kx = t & 3; \
    const int p = 1 - (kx & 1), d = kx >> 1; \
    const short8 bv0 = *(const short8*)(wb + (t*2 + (c))*4096); \
    const short8 bv1 = *(const short8*)(wb + (t*2 + (c))*4096 + 512); \
    const char* Ab = (const char*)IL + (Bd0 + d*64); \
    const int imm0 = ((ky*2 + p)*66) << 6; \
    _Pragma("unroll") \
    for (int mi = 0; mi < 4; ++mi) { \
      const short8 av = *(const short8*)(Ab + imm0 + mi*1024); \
      acc[mi][0] = __builtin_amdgcn_mfma_f32_16x16x32_bf16( \
          __builtin_bit_cast(bf16x8, av), __builtin_bit_cast(bf16x8, bv0), \
          acc[mi][0], 0, 0, 0); \
      acc[mi][1] = __builtin_amdgcn_mfma_f32_16x16x32_bf16( \
          __builtin_bit_cast(bf16x8, av), __builtin_bit_cast(bf16x8, bv1), \
          acc[mi][1], 0, 0, 0); \
    } \
  }
__global__ __launch_bounds__(256) void conv2m_k(const unsigned short* __restrict__ in,
    const unsigned short* __restrict__ wv, const float* __restrict__ bias,
    unsigned short* __restrict__ out) {
  __shared__ short IL[8*66*32];        // [(r*2+p)*66+idx][ci_local 32], 33792 B
  const int wid = (blockIdx.x & 7)*256 + (blockIdx.x >> 3);
  const int q = wid & 63, n = wid >> 6;          // q = output row oy
  const int w = threadIdx.x >> 6, l = threadIdx.x & 63;
  const int lm = l & 15, lk = l >> 4;
  const int Bd0 = lm*64 + lk*16;                 // A-read byte base, d=0
  const unsigned short* wb = wv + w*1024 + l*8;  // + ks*4096 (+512 for ni=1)
  int goff[9], lb[9];
  #pragma unroll
  for (int s = 0; s < 9; ++s) {
    const int i = threadIdx.x + s*256;
    const int part = i & 3, e = i >> 2;
    const int idx = e % 66, rp = e / 66;
    const int r = rp >> 1, p = rp & 1;
    const int iy = 2*q - 1 + r, ix = 2*idx - p;
    const bool ok = (i < 2112) && iy >= 0 && iy < 128 && ix >= 0 && ix < 128;
    goff[s] = ok ? (((n*128 + iy)*128 + ix)*64 + part*8) : -1;
    lb[s]   = (i < 2112) ? (e*64 + part*16) : -1;
  }
  f32x4 acc[4][2];
  #pragma unroll
  for (int mi = 0; mi < 4; ++mi)
    #pragma unroll
    for (int ni = 0; ni < 2; ++ni) acc[mi][ni] = (f32x4)0.0f;
  short8 st[9];
  C2_LOAD(0); C2_WRITE;
  __syncthreads();
  C2_LOAD(1);                          // issue phase-1 loads (in flight)
  C2_COMPUTE(0);
  __syncthreads();                     // phase-0 LDS reads done
  C2_WRITE;                            // waits vmcnt for st, writes LDS
  __syncthreads();
  C2_COMPUTE(1);
  #pragma unroll
  for (int mi = 0; mi < 4; ++mi)
    #pragma unroll
    for (int r = 0; r < 4; ++r) {
      const int ox = mi*16 + lk*4 + r;
      const int ob = ((n*64 + q)*64 + ox)*128;
      #pragma unroll
      for (int ni = 0; ni < 2; ++ni) {
        const int co = (w*2 + ni)*16 + lm;
        out[ob + co] = f2b(fmaxf(acc[mi][ni][r] + bias[co], 0.f));
      }
    }
}

// ---- conv3 via two-phase MFMA + async stage: h2 NHWC bf16 [32,64,64,128]
//      -> z f32 [131072,32].  Block=(n,oy-pair): rows 2q-1..2q+2 x 66 cols,
//      ci-half per phase (128B entries, XOR swz). 4 waves x M=32, N=32.
#define C3_LOAD(c) \
  _Pragma("unroll") \
  for (int s = 0; s < 9; ++s) { \
    st[s] = (short8)(short)0; \
    if (goff[s] >= 0) st[s] = *(const short8*)(in + goff[s] + (c)*64); \
  }
#define C3_WRITE \
  _Pragma("unroll") \
  for (int s = 0; s < 9; ++s) \
    if (lb[s] >= 0) *(short8*)((char*)IL + lb[s]) = st[s];
#define C3_COMPUTE(c) \
  _Pragma("unroll") \
  for (int u = 0; u < 18; ++u) { \
    const int tap = u >> 1, cc = u & 1; \
    const int ky = tap / 3, kx = tap % 3; \
    const int ks = tap*4 + (c)*2 + cc; \
    const short8 bv0 = *(const short8*)(wb + ks*1024); \
    const short8 bv1 = *(const short8*)(wb + ks*1024 + 512); \
    const char* Ab = (const char*)IL + (Wc[kx][cc]); \
    const int imm0 = ky*8448; \
    _Pragma("unroll") \
    for (int mi = 0; mi < 2; ++mi) { \
      const short8 av = *(const short8*)(Ab + imm0 + mi*2048); \
      acc[mi][0] = __builtin_amdgcn_mfma_f32_16x16x32_bf16( \
          __builtin_bit_cast(bf16x8, av), __builtin_bit_cast(bf16x8, bv0), \
          acc[mi][0], 0, 0, 0); \
      acc[mi][1] = __builtin_amdgcn_mfma_f32_16x16x32_bf16( \
          __builtin_bit_cast(bf16x8, av), __builtin_bit_cast(bf16x8, bv1), \
          acc[mi][1], 0, 0, 0); \
    } \
  }
__global__ __launch_bounds__(256) void conv3m_k(const unsigned short* __restrict__ in,
    const unsigned short* __restrict__ wv, const float* __restrict__ bias,
    float* __restrict__ out) {
  __shared__ short IL[4*66*64];        // [r*66+col][ci_local 64], 33792 B
  const int wid = (blockIdx.x & 7)*128 + (blockIdx.x >> 3);
  const int q = wid & 31, n = wid >> 5;          // oy0 = 2q
  const int w = threadIdx.x >> 6, l = threadIdx.x & 63;
  const int lm = l & 15, lk = l >> 4;
  const int row = w >> 1, oxb = (w & 1) * 32;
  int goff[9], lb[9];
  #pragma unroll
  for (int s = 0; s < 9; ++s) {
    const int i = threadIdx.x + s*256;
    const int part = i & 7, e = i >> 3;
    const int col = e % 66, r = e / 66;
    const int iy = 2*q - 1 + r, ix = col - 1;
    const bool ok = (i < 2112) && iy >= 0 && iy < 64 && ix >= 0 && ix < 64;
    goff[s] = ok ? (((n*64 + iy)*64 + ix)*128 + part*8) : -1;
    lb[s]   = (i < 2112) ? ((e << 7) + ((part << 4) ^ ((col & 7) << 4))) : -1;
  }
  // A-bases: Ab = IL + Wc[kx][cc]; imm = ky*8448 + mi*2048
  int Wc[3][2];
  #pragma unroll
  for (int kx = 0; kx < 3; ++kx) {
    const int e = oxb + lm + kx;
    Wc[kx][0] = row*8448 + (e << 7) + ((lk << 4) ^ ((e & 7) << 4));
    Wc[kx][1] = Wc[kx][0] ^ 0x40;
  }
  const unsigned short* wb = wv + l*8;           // + ks*1024 + ni*512
  f32x4 acc[2][2];
  #pragma unroll
  for (int mi = 0; mi < 2; ++mi)
    #pragma unroll
    for (int ni = 0; ni < 2; ++ni) acc[mi][ni] = (f32x4)0.0f;
  short8 st[9];
  C3_LOAD(0); C3_WRITE;
  __syncthreads();
  C3_LOAD(1);
  C3_COMPUTE(0);
  __syncthreads();
  C3_WRITE;
  __syncthreads();
  C3_COMPUTE(1);
  const int oy = 2*q + row;
  #pragma unroll
  for (int mi = 0; mi < 2; ++mi)
    #pragma unroll
    for (int r = 0; r < 4; ++r) {
      const int ox = oxb + mi*16 + lk*4 + r;
      const long mb = ((long)((n*64 + oy)*64 + ox)) * 32;
      #pragma unroll
      for (int ni = 0; ni < 2; ++ni) {
        const int co = ni*16 + lm;
        out[mb + co] = fmaxf(acc[mi][ni][r] + bias[co], 0.f);
      }
    }
}

// ---- d1 convT via MFMA: zq f32 [131072,32] -> d1 NHWC bf16 [32,64,64,128]
//      Block=(n,oy-pair): rows 2q-1..2q+2 x 66 cols x 32ci (f32->bf16),
//      80B-stride entries (bank-safe). 4 waves x M=32, N=128, 9 taps.
__global__ __launch_bounds__(256) void d1m_k(const float* __restrict__ in,
    const unsigned short* __restrict__ wv, const float* __restrict__ bias,
    unsigned short* __restrict__ out) {
  __shared__ short IL[264*40];         // [r*66+col][40-short stride], 21120 B
  const int wid = (blockIdx.x & 7)*128 + (blockIdx.x >> 3);
  const int q = wid & 31, n = wid >> 5;
  const int w = threadIdx.x >> 6, l = threadIdx.x & 63;
  const int lm = l & 15, lk = l >> 4;
  const int row = w >> 1, oxb = (w & 1) * 32;
  for (int i = threadIdx.x; i < 1056; i += 256) {  // 264 entries * 4 parts
    const int part = i & 3, e = i >> 2;
    const int col = e % 66, r = e / 66;
    const int iy = 2*q - 1 + r, ix = col - 1;
    short8 v = (short8)(short)0;
    if (iy >= 0 && iy < 64 && ix >= 0 && ix < 64) {
      const float* p = in + (((long)((n*64 + iy)*64 + ix)) * 32 + part*8);
      const f32x4 f0 = *(const f32x4*)p;
      const f32x4 f1 = *(const f32x4*)(p + 4);
      #pragma unroll
      for (int e2 = 0; e2 < 4; ++e2) {
        v[e2]     = (short)f2b(f0[e2]);
        v[e2 + 4] = (short)f2b(f1[e2]);
      }
    }
    *(short8*)&IL[e*40 + part*8] = v;
  }
  const unsigned short* wb = wv + l*8;             // + (tap*8+ni)*512
  int Wd[3];
  #pragma unroll
  for (int kx = 0; kx < 3; ++kx)
    Wd[kx] = row*5280 + (oxb + lm + kx)*80 + lk*16;   // bytes
  __syncthreads();
  f32x4 acc[2][8];
  #pragma unroll
  for (int mi = 0; mi < 2; ++mi)
    #pragma unroll
    for (int ni = 0; ni < 8; ++ni) acc[mi][ni] = (f32x4)0.0f;
  #pragma unroll
  for (int tap = 0; tap < 9; ++tap) {
    const int ky = tap / 3, kx = tap % 3;
    short8 bv[8];
    #pragma unroll
    for (int ni = 0; ni < 8; ++ni)
      bv[ni] = *(const short8*)(wb + (tap*8 + ni)*512);
    const char* Ab = (const char*)IL + Wd[kx];
    const int imm0 = ky*5280;
    #pragma unroll
    for (int mi = 0; mi < 2; ++mi) {
      const short8 av = *(const short8*)(Ab + imm0 + mi*1280);
      #pragma unroll
      for (int ni = 0; ni < 8; ++ni)
        acc[mi][ni] = __builtin_amdgcn_mfma_f32_16x16x32_bf16(
            __builtin_bit_cast(bf16x8, av),
            __builtin_bit_cast(bf16x8, bv[ni]),
            acc[mi][ni], 0, 0, 0);
    }
  }
  const int oy = 2*q + row;
  #pragma unroll
  for (int mi = 0; mi < 2; ++mi)
    #pragma unroll
    for (int r = 0; r < 4; ++r) {
      const int ox = oxb + mi*16 + lk*4 + r;
      const int ob = ((n*64 + oy)*64 + ox)*128;
      #pragma unroll
      for (int ni = 0; ni < 8; ++ni) {
        const int co = ni*16 + lm;
        out[ob + co] = f2b(fmaxf(acc[mi][ni][r] + bias[co], 0.f));
      }
    }
}

// ---- d2 convT via two-phase merged-parity MFMA + async stage: d1 -> d2 -----
#define CT2_LOAD(c) \
  _Pragma("unroll") \
  for (int s = 0; s < 7; ++s) { \
    st[s] = (short8)(short)0; \
    if (goff[s] >= 0) st[s] = *(const short8*)(in + goff[s] + (c)*64); \
  }
#define CT2_WRITE \
  _Pragma("unroll") \
  for (int s = 0; s < 7; ++s) \
    if (lb[s] >= 0) *(short8*)((char*)IL + lb[s]) = st[s];
#define CT2_COMPUTE(c) \
  _Pragma("unroll") \
  for (int u = 0; u < 8; ++u) { \
    const int a = u >> 2, b = (u >> 1) & 1, c1 = u & 1; \
    const int ks = (a << 3) | (b << 2) | (2*(c) + c1); \
    short8 bv[4]; \
    _Pragma("unroll") \
    for (int ni = 0; ni < 4; ++ni) \
      bv[ni] = *(const short8*)(wb + ks*2048 + ni*512); \
    const char* Ab = (const char*)IL + (pyb + Wb[b][c1]); \
    const int imm0 = a*8448; \
    _Pragma("unroll") \
    for (int mi = 0; mi < 4; ++mi) { \
      const short8 av = *(const short8*)(Ab + imm0 + mi*2048); \
      _Pragma("unroll") \
      for (int ni = 0; ni < 4; ++ni) \
        acc[mi][ni] = __builtin_amdgcn_mfma_f32_16x16x32_bf16( \
            __builtin_bit_cast(bf16x8, av), \
            __builtin_bit_cast(bf16x8, bv[ni]), \
            acc[mi][ni], 0, 0, 0); \
    } \
  }
__global__ __launch_bounds__(256) void convt2m_k(const unsigned short* __restrict__ in,
    const unsigned short* __restrict__ wv, const float* __restrict__ bias,
    unsigned short* __restrict__ out) {
  __shared__ short IL[3*66*64];        // [r*66+col][ci_local 32+32], 25344 B
  const int wid = (blockIdx.x & 7)*256 + (blockIdx.x >> 3);
  const int q = wid & 63, n = wid >> 6;
  const int w = threadIdx.x >> 6, l = threadIdx.x & 63;
  const int py = w >> 1, px = w & 1;
  const int lm = l & 15, lk = l >> 4;
  int Wb[2][2];
  #pragma unroll
  for (int b = 0; b < 2; ++b) {
    const int e = lm + px + b;
    Wb[b][0] = (e << 7) + ((lk << 4) ^ ((e & 7) << 4));
    Wb[b][1] = Wb[b][0] ^ 0x40;
  }
  const int pyb = py * 8448;                       // 66 entries * 128 B
  const unsigned short* wb = wv + w*32768 + l*8;   // + ks*2048 + ni*512
  int goff[7], lb[7];
  #pragma unroll
  for (int s = 0; s < 7; ++s) {
    const int i = threadIdx.x + s*256;
    const int part = i & 7, e = i >> 3;
    const int col = e % 66, r = e / 66;
    const int iy = q - 1 + r, ix = col - 1;
    const bool ok = (i < 1584) && iy >= 0 && iy < 64 && ix >= 0 && ix < 64;
    goff[s] = ok ? (((n*64 + iy)*64 + ix)*128 + part*8) : -1;
    lb[s]   = (i < 1584) ? ((e << 7) + ((part << 4) ^ ((col & 7) << 4))) : -1;
  }
  f32x4 acc[4][4];
  #pragma unroll
  for (int mi = 0; mi < 4; ++mi)
    #pragma unroll
    for (int ni = 0; ni < 4; ++ni) acc[mi][ni] = (f32x4)0.0f;
  short8 st[7];
  CT2_LOAD(0); CT2_WRITE;
  __syncthreads();
  CT2_LOAD(1);
  CT2_COMPUTE(0);
  __syncthreads();
  CT2_WRITE;
  __syncthreads();
  CT2_COMPUTE(1);
  const int oy = 2*q + py;
  #pragma unroll
  for (int mi = 0; mi < 4; ++mi)
    #pragma unroll
    for (int r = 0; r < 4; ++r) {
      const int ox = 2*(mi*16 + lk*4 + r) + px;
      const int ob = ((n*128 + oy)*128 + ox)*64;
      #pragma unroll
      for (int ni = 0; ni < 4; ++ni) {
        const int co = ni*16 + lm;
        out[ob + co] = f2b(fmaxf(acc[mi][ni][r] + bias[co], 0.f));
      }
    }
}

// ------- VQ via MFMA: z fp32 [131072,32] -> zq fp32 + loss partials ---------
__global__ __launch_bounds__(256) void vqm_k(const float* __restrict__ z,
    const float* __restrict__ embed, float* __restrict__ zq,
    float* __restrict__ partial) {
  __shared__ short Be[512*40];     // bf16 codes, pad stride 40 (40960 B)
  __shared__ float en[512];        // |e|^2 (bf16-rounded e), fp32
  __shared__ int   bidx[128];
  __shared__ float red[256];
  const int m0 = blockIdx.x * 128;
  for (int i = threadIdx.x; i < 4096; i += 256) {
    const int j = i >> 3, k0 = (i & 7) * 4;
    const f32x4 v = *(const f32x4*)&embed[j*32 + k0];
    s16x4 s;
    #pragma unroll
    for (int e = 0; e < 4; ++e) s[e] = (short)f2b(v[e]);
    *(s16x4*)&Be[j*40 + k0] = s;
  }
  __syncthreads();
  for (int j = threadIdx.x; j < 512; j += 256) {
    float s = 0.f;
    #pragma unroll
    for (int q = 0; q < 4; ++q) {
      const short8 v = *(const short8*)&Be[j*40 + q*8];
      #pragma unroll
      for (int e = 0; e < 8; ++e) {
        const float f = b2f((unsigned short)v[e]);
        s = fmaf(f, f, s);
      }
    }
    en[j] = s;
  }
  __syncthreads();
  const int w = threadIdx.x >> 6, l = threadIdx.x & 63;
  const int lm = l & 15, lk = l >> 4;
  const int rw = w * 32;
  short8 av[2];
  #pragma unroll
  for (int mi = 0; mi < 2; ++mi) {
    const float* zp = z + (long)(m0 + rw + mi*16 + lm)*32 + lk*8;
    const f32x4 f0 = *(const f32x4*)zp;
    const f32x4 f1 = *(const f32x4*)(zp + 4);
    short8 v;
    #pragma unroll
    for (int e = 0; e < 4; ++e) {
      v[e]     = (short)f2b(f0[e]);
      v[e + 4] = (short)f2b(f1[e]);
    }
    av[mi] = v;
  }
  float bd[2][4]; int bj[2][4];
  #pragma unroll
  for (int mi = 0; mi < 2; ++mi)
    #pragma unroll
    for (int r = 0; r < 4; ++r) { bd[mi][r] = 1e30f; bj[mi][r] = 0; }
  for (int nc = 0; nc < 8; ++nc) {               // N-chunks of 64 codes
    f32x4 acc[2][4];
    #pragma unroll
    for (int mi = 0; mi < 2; ++mi)
      #pragma unroll
      for (int ni = 0; ni < 4; ++ni) acc[mi][ni] = (f32x4)0.0f;
    #pragma unroll
    for (int ni = 0; ni < 4; ++ni) {
      const short8 bv = *(const short8*)&Be[(nc*64 + ni*16 + lm)*40 + lk*8];
      #pragma unroll
      for (int mi = 0; mi < 2; ++mi)
        acc[mi][ni] = __builtin_amdgcn_mfma_f32_16x16x32_bf16(
            __builtin_bit_cast(bf16x8, av[mi]),
            __builtin_bit_cast(bf16x8, bv),
            acc[mi][ni], 0, 0, 0);
    }
    #pragma unroll
    for (int ni = 0; ni < 4; ++ni) {
      const int j = nc*64 + ni*16 + lm;
      const float e_n = en[j];
      #pragma unroll
      for (int mi = 0; mi < 2; ++mi)
        #pragma unroll
        for (int r = 0; r < 4; ++r) {
          const float d = fmaf(-2.f, acc[mi][ni][r], e_n);
          if (d < bd[mi][r]) { bd[mi][r] = d; bj[mi][r] = j; }
        }
    }
  }
  #pragma unroll
  for (int mi = 0; mi < 2; ++mi)
    #pragma unroll
    for (int r = 0; r < 4; ++r) {
      float d = bd[mi][r]; int j = bj[mi][r];
      #pragma unroll
      for (int off = 1; off < 16; off <<= 1) {
        const float od = __shfl_xor(d, off);
        const int   oj = __shfl_xor(j, off);
        if (od < d || (od == d && oj < j)) { d = od; j = oj; }
      }
      if (lm == 0) bidx[rw + mi*16 + lk*4 + r] = j;
    }
  __syncthreads();
  const int pl = threadIdx.x >> 1, hf = (threadIdx.x & 1) * 16;
  const int code = bidx[pl];
  const long pb = (long)(m0 + pl)*32 + hf;
  float se = 0.f;
  #pragma unroll
  for (int q = 0; q < 4; ++q) {
    const f32x4 ev = *(const f32x4*)&embed[code*32 + hf + q*4];
    const f32x4 zv = *(const f32x4*)&z[pb + q*4];
    *(f32x4*)&zq[pb + q*4] = ev;
    const f32x4 df = ev - zv;
    #pragma unroll
    for (int e = 0; e < 4; ++e) se = fmaf(df[e], df[e], se);
  }
  red[threadIdx.x] = se; __syncthreads();
  for (int s = 128; s > 0; s >>= 1) {
    if (threadIdx.x < s) red[threadIdx.x] += red[threadIdx.x + s];
    __syncthreads();
  }
  if (threadIdx.x == 0) partial[blockIdx.x] = red[0];
}

__global__ __launch_bounds__(256) void loss_k(const float* __restrict__ part,
                                              float* __restrict__ out) {
  __shared__ float red[256];
  const int t = threadIdx.x;
  float s = 0.f;
  #pragma unroll
  for (int q = 0; q < 4; ++q) s += part[t + q*256];   // 1024 partials
  red[t] = s; __syncthreads();
  for (int st = 128; st > 0; st >>= 1) {
    if (t < st) red[t] += red[t + st];
    __syncthreads();
  }
  if (t == 0) out[0] = red[0] * (1.25f / (131072.f * 32.f));
}

// ---- convt3 via MFMA: d2 NHWC bf16 [32,128,128,64] -> x_recon NCHW fp32 ----
__global__ __launch_bounds__(256) void convt3m_k(const unsigned short* __restrict__ in,
    const unsigned short* __restrict__ wq6, const float* __restrict__ bias,
    float* __restrict__ out) {
  __shared__ short8 IL[3*8*66];      // [(r*8+c8)*66 + ixl], 25344 B
  const int h = blockIdx.x & 1, q = (blockIdx.x >> 1) & 127, n = blockIdx.x >> 8;
  for (int i = threadIdx.x; i < 1584; i += 256) {   // 3*66*8
    const int c8 = i & 7, t = i >> 3, ixl = t % 66, r = t / 66;
    const int iy = q - 1 + r, ix = h*64 - 1 + ixl;
    short8 v = (short8)(short)0;
    if (iy >= 0 && iy < 128 && ix >= 0 && ix < 128)
      v = *(const short8*)(in + (((long)(n*128 + iy)*128 + ix)*64 + c8*8));
    IL[(r*8 + c8)*66 + ixl] = v;
  }
  const int w = threadIdx.x >> 6, l = threadIdx.x & 63;
  const int py = w >> 1, px = w & 1;
  const int lm = l & 15, lk = l >> 4;
  short8 bfrag[8];
  #pragma unroll
  for (int kc = 0; kc < 8; ++kc)
    bfrag[kc] = *(const short8*)(wq6 + (((w*8 + kc)*64 + l) << 3));
  __syncthreads();
  f32x4 acc[4];
  #pragma unroll
  for (int mi = 0; mi < 4; ++mi) acc[mi] = (f32x4)0.0f;
  #pragma unroll
  for (int kc = 0; kc < 8; ++kc) {
    const int a = kc >> 2, b = (kc >> 1) & 1, ch = kc & 1;
    const int base = (((py + a)*8 + ch*4 + lk)*66) + px + b;   // + ixl(xq)
    #pragma unroll
    for (int mi = 0; mi < 4; ++mi) {
      const short8 av = *(const short8*)&IL[base + mi*16 + lm];
      acc[mi] = __builtin_amdgcn_mfma_f32_16x16x32_bf16(
          __builtin_bit_cast(bf16x8, av),
          __builtin_bit_cast(bf16x8, bfrag[kc]),
          acc[mi], 0, 0, 0);
    }
  }
  if (lm < 3) {
    const float bv = bias[lm];
    const int oy = 2*q + py;
    const long ob = ((long)(n*3 + lm))*65536 + oy*256;
    #pragma unroll
    for (int mi = 0; mi < 4; ++mi)
      #pragma unroll
      for (int r = 0; r < 4; ++r) {
        const int xq = mi*16 + lk*4 + r;
        out[ob + h*128 + 2*xq + px] = acc[mi][r] + bv;
      }
  }
}

extern "C" void kernel_launch(void* const* d_in, const int* in_sizes, int n_in,
                              void* d_out, int out_size, void* d_ws, size_t ws_size,
                              hipStream_t stream) {
  const float* x   = (const float*)d_in[0];
  const float* ew1 = (const float*)d_in[1];  const float* eb1 = (const float*)d_in[2];
  const float* ew2 = (const float*)d_in[3];  const float* eb2 = (const float*)d_in[4];
  const float* ew3 = (const float*)d_in[5];  const float* eb3 = (const float*)d_in[6];
  const float* emb = (const float*)d_in[7];
  const float* dw1 = (const float*)d_in[8];  const float* db1 = (const float*)d_in[9];
  const float* dw2 = (const float*)d_in[10]; const float* db2 = (const float*)d_in[11];
  const float* dw3 = (const float*)d_in[12]; const float* db3 = (const float*)d_in[13];
  float* out = (float*)d_out;

  uint8_t* w8 = (uint8_t*)d_ws;
  unsigned short* h1 = (unsigned short*)w8;
  unsigned short* h2 = (unsigned short*)(w8 + 67108864);
  float* z   = (float*)(w8 + 100663296);
  float* zq  = (float*)(w8 + 117440512);
  float* part = (float*)(w8 + 67108864);              // h2 region (dead @ vqm)
  unsigned short* wq2 = (unsigned short*)(w8 + 117440512);            // 262144 B
  unsigned short* wq3 = (unsigned short*)(w8 + 117440512 + 262144);   // 73728 B
  unsigned short* wq1 = (unsigned short*)(w8 + 117440512 + 335872);   // 8192 B
  unsigned short* wq4 = (unsigned short*)(w8 + 100663296);            // 73728 B
  unsigned short* wq5 = (unsigned short*)(w8 + 100663296 + 73728);    // 262144 B
  unsigned short* wq6 = (unsigned short*)(w8 + 100663296 + 335872);   // 32768 B
  unsigned short* d1 = h2;
  unsigned short* d2 = h1;

  // encoder weight prep (into zq region, consumed before vqm writes zq)
  prep1v_k<<<dim3(16),256,0,stream>>>(ew1, wq1);
  prep2v_k<<<dim3(512),256,0,stream>>>(ew2, wq2);
  prep3v_k<<<dim3(144),256,0,stream>>>(ew3, wq3);
  // encoder
  conv1m_k<<<dim3(4096),256,0,stream>>>(x, wq1, eb1, h1);
  conv2m_k<<<dim3(2048),256,0,stream>>>(h1, wq2, eb2, h2);
  conv3m_k<<<dim3(1024),256,0,stream>>>(h2, wq3, eb3, z);
  // VQ (MFMA) + loss  (partials in h2 region; loss_k consumes before d1 write)
  vqm_k<<<dim3(1024),256,0,stream>>>(z, emb, zq, part);
  loss_k<<<dim3(1),256,0,stream>>>(part, out + 6291456);
  // decoder weight prep (into z region, dead after vqm)
  prep4v_k<<<dim3(144),256,0,stream>>>(dw1, wq4);
  prep5v_k<<<dim3(512),256,0,stream>>>(dw2, wq5);
  prep6_k<<<dim3(64),256,0,stream>>>(dw3, wq6);
  // decoder
  d1m_k<<<dim3(1024),256,0,stream>>>(zq, wq4, db1, d1);
  convt2m_k<<<dim3(2048),256,0,stream>>>(d1, wq5, db2, d2);
  convt3m_k<<<dim3(8192),256,0,stream>>>(d2, wq6, db3, out);
}

// Round 9
// 355.803 us; speedup vs baseline: 1.4560x; 1.0081x over previous
//
#include <hip/hip_runtime.h>

// VQ-VAE forward, MI355X round 19: R18 + VQ fused into conv3 (conv3v_k):
// z never materialized; embed distances via MFMA against prepped frag-ordered
// bf16 embed (prepe_k); argmin/gather/loss epilogue identical math to vqm_k.

typedef __attribute__((ext_vector_type(8))) short     short8;
typedef __attribute__((ext_vector_type(4))) short     s16x4;
typedef __attribute__((ext_vector_type(8))) __bf16    bf16x8;
typedef __attribute__((ext_vector_type(4))) float     f32x4;
typedef __attribute__((ext_vector_type(4))) unsigned  uint32x4;

__device__ __forceinline__ float b2f(unsigned short b) {
  union { unsigned u; float f; } v; v.u = ((unsigned)b) << 16; return v.f;
}
__device__ __forceinline__ unsigned short f2b(float f) {  // round-to-nearest-even
  union { float f; unsigned u; } v; v.f = f;
  unsigned r = v.u + 0x7FFF + ((v.u >> 16) & 1);
  return (unsigned short)(r >> 16);
}

// ---------------- weight prep ------------------------------------------------
__global__ __launch_bounds__(256) void prep1v_k(const float* __restrict__ w,
                                                unsigned short* __restrict__ wq) {
  const int i = blockIdx.x*256 + threadIdx.x;                 // 4096 exact
  const int j = i & 7, l = (i >> 3) & 63, ni = (i >> 9) & 3, ks = i >> 11;
  const int k = ks*32 + (l >> 4)*8 + j;
  const int co = ni*16 + (l & 15);
  wq[i] = (k < 48) ? f2b(w[co*48 + k]) : (unsigned short)0;
}
__global__ __launch_bounds__(256) void prep2v_k(const float* __restrict__ w,
                                                unsigned short* __restrict__ wq) {
  const int i = blockIdx.x*256 + threadIdx.x;                 // 131072 exact
  const int j = i & 7, l = (i >> 3) & 63, ni = (i >> 9) & 7, ks = i >> 12;
  const int lm = l & 15, lk = l >> 4;
  const int tap = ks >> 1, cc = ks & 1;
  const int co = ni*16 + lm, ci = cc*32 + lk*8 + j;
  wq[i] = f2b(w[(co*64 + ci)*16 + tap]);
}
// conv3 B-frags: wq3v[((ks*2+ni)*64+l)*8+j] = ew3[co=ni*16+lm][ci=cf*32+lk*8+j][tap]
__global__ __launch_bounds__(256) void prep3v_k(const float* __restrict__ w,
                                                unsigned short* __restrict__ wq) {
  const int i = blockIdx.x*256 + threadIdx.x;                 // 36864 exact
  const int j = i & 7, l = (i >> 3) & 63, ni = (i >> 9) & 1, ks = i >> 10;
  const int lm = l & 15, lk = l >> 4;
  const int tap = ks >> 2, cf = ks & 3;
  const int co = ni*16 + lm, ci = cf*32 + lk*8 + j;
  wq[i] = f2b(w[(co*128 + ci)*9 + tap]);
}
// d1 B-frags: wq4v[((tap*8+ni)*64+l)*8+j] = flip(dw1)[tap][co=ni*16+lm][ci=lk*8+j]
__global__ __launch_bounds__(256) void prep4v_k(const float* __restrict__ w,
                                                unsigned short* __restrict__ wq) {
  const int i = blockIdx.x*256 + threadIdx.x;                 // 36864 exact
  const int j = i & 7, l = (i >> 3) & 63, ni = (i >> 9) & 7, tap = i >> 12;
  const int lm = l & 15, lk = l >> 4;
  const int co = ni*16 + lm, ci = lk*8 + j;
  wq[i] = f2b(w[(ci*128 + co)*9 + (8 - tap)]);                // dw1(32,128,3,3)
}
__global__ __launch_bounds__(256) void prep5v_k(const float* __restrict__ w,
                                                unsigned short* __restrict__ wq) {
  const int i = blockIdx.x*256 + threadIdx.x;                 // 131072 exact
  const int j = i & 7, l = (i >> 3) & 63, ni = (i >> 9) & 3;
  const int ks = (i >> 11) & 15, p = i >> 15;
  const int lm = l & 15, lk = l >> 4;
  const int py = p >> 1, px = p & 1;
  const int a = ks >> 3, b = (ks >> 2) & 1, cc = ks & 3;
  const int co = ni*16 + lm, ci = cc*32 + lk*8 + j;
  const int ky = 3 - 2*a - py, kx = 3 - 2*b - px;
  wq[i] = f2b(w[(ci*64 + co)*16 + ky*4 + kx]);                // dw2(128,64,4,4)
}
__global__ __launch_bounds__(256) void prep6_k(const float* __restrict__ w,
                                               unsigned short* __restrict__ wq) {
  const int i = blockIdx.x*256 + threadIdx.x;                 // 16384 exact
  const int j = i & 7, l = (i >> 3) & 63, kc = (i >> 9) & 7, p = i >> 12;
  const int lm = l & 15, lk = l >> 4;
  const int a = kc >> 2, b = (kc >> 1) & 1, ch = kc & 1;
  const int ci = ch*32 + lk*8 + j, co = lm;
  const int py = p >> 1, px = p & 1;
  const int ky = 2 - 2*a + (1 - py), kx = 2 - 2*b + (1 - px);
  wq[i] = (co < 3) ? f2b(w[(ci*3 + co)*16 + ky*4 + kx]) : (unsigned short)0;
}
// embed B-frags + |e|^2: wqe[((nc*4+ni)*64+l)*8+j] = f2b(emb[nc*64+ni*16+lm][lk*8+j])
__global__ __launch_bounds__(256) void prepe_k(const float* __restrict__ emb,
    unsigned short* __restrict__ wqe, float* __restrict__ en) {
  const int i = blockIdx.x*256 + threadIdx.x;                 // 16384 exact
  const int j = i & 7, l = (i >> 3) & 63, ni = (i >> 9) & 3, nc = i >> 11;
  const int lm = l & 15, lk = l >> 4;
  wqe[i] = f2b(emb[(nc*64 + ni*16 + lm)*32 + lk*8 + j]);
  if (i < 512) {
    float s = 0.f;
    #pragma unroll
    for (int k = 0; k < 32; ++k) {
      const float f = b2f(f2b(emb[i*32 + k]));
      s = fmaf(f, f, s);
    }
    en[i] = s;
  }
}

// ---- conv1 via MFMA: x NCHW fp32 [32,3,256,256] -> h1 NHWC bf16 ------------
__global__ __launch_bounds__(256) void conv1m_k(const float* __restrict__ x,
    const unsigned short* __restrict__ wv, const float* __restrict__ bias,
    unsigned short* __restrict__ out) {
  __shared__ __align__(16) short RAW[12*264];   // row g=ci*4+ky, idx=ix+4; 6336B
  __shared__ __align__(16) short IC[128*64];    // [ox][k] swizzled; 16384B
  const int wid = ((blockIdx.x & 7) << 9) + (blockIdx.x >> 3);
  const int q = wid & 127, n = wid >> 7;        // q = output row oy
  for (int i = threadIdx.x; i < 396; i += 256)
    *(short8*)&RAW[i*8] = (short8)(short)0;
  __syncthreads();
  for (int s = threadIdx.x; s < 768; s += 256) {   // 12 rows * 64 f32x4
    const int g = s >> 6, seg = s & 63;
    const int ci = g >> 2, ky = g & 3;
    const int iy = 2*q - 1 + ky;
    if (iy >= 0 && iy < 256) {
      const f32x4 v = *(const f32x4*)&x[((n*3 + ci)*256 + iy)*256 + seg*4];
      s16x4 sv;
      #pragma unroll
      for (int e = 0; e < 4; ++e) sv[e] = (short)f2b(v[e]);
      *(s16x4*)&RAW[g*264 + 4 + seg*4] = sv;
    }
  }
  __syncthreads();
  for (int s = threadIdx.x; s < 1024; s += 256) {
    const int kb = s & 7, ox = s >> 3;
    short8 v = (short8)(short)0;
    if (kb < 6) {
      const unsigned* u0 = (const unsigned*)&RAW[(2*kb  )*264 + 2*ox + 2];
      const unsigned* u1 = (const unsigned*)&RAW[(2*kb+1)*264 + 2*ox + 2];
      const unsigned a0 = u0[0], a1 = u0[1], a2 = u0[2];
      const unsigned b0 = u1[0], b1 = u1[1], b2 = u1[2];
      uint32x4 uv;
      uv[0] = (a0 >> 16) | (a1 << 16);
      uv[1] = (a1 >> 16) | (a2 << 16);
      uv[2] = (b0 >> 16) | (b1 << 16);
      uv[3] = (b1 >> 16) | (b2 << 16);
      v = __builtin_bit_cast(short8, uv);
    }
    const int bo = ((ox << 7) + (kb << 4)) ^ ((ox & 7) << 4);
    *(short8*)((char*)IC + bo) = v;
  }
  __syncthreads();
  const int w = threadIdx.x >> 6, l = threadIdx.x & 63;
  const int lm = l & 15, lk = l >> 4;
  f32x4 acc[2][4];
  #pragma unroll
  for (int mi = 0; mi < 2; ++mi)
    #pragma unroll
    for (int ni = 0; ni < 4; ++ni) acc[mi][ni] = (f32x4)0.0f;
  #pragma unroll
  for (int ks = 0; ks < 2; ++ks) {
    short8 bv[4];
    #pragma unroll
    for (int ni = 0; ni < 4; ++ni)
      bv[ni] = *(const short8*)(wv + (((ks*4 + ni)*64 + l) << 3));
    #pragma unroll
    for (int mi = 0; mi < 2; ++mi) {
      const int ox = w*32 + mi*16 + lm;
      const int bo = ((ox << 7) + (ks << 6) + (lk << 4)) ^ ((ox & 7) << 4);
      const short8 av = *(const short8*)((const char*)IC + bo);
      #pragma unroll
      for (int ni = 0; ni < 4; ++ni)
        acc[mi][ni] = __builtin_amdgcn_mfma_f32_16x16x32_bf16(
            __builtin_bit_cast(bf16x8, av),
            __builtin_bit_cast(bf16x8, bv[ni]),
            acc[mi][ni], 0, 0, 0);
    }
  }
  __syncthreads();            // frag reads done; reuse IC for output staging
  #pragma unroll
  for (int mi = 0; mi < 2; ++mi)
    #pragma unroll
    for (int ni = 0; ni < 4; ++ni) {
      const int co = ni*16 + lm;
      const float bv = bias[co];
      #pragma unroll
      for (int r = 0; r < 4; ++r) {
        const int ox = w*32 + mi*16 + lk*4 + r;
        const int bo = ((ox << 7) + 2*co) ^ ((ox & 7) << 4);
        *(short*)((char*)IC + bo) = (short)f2b(fmaxf(acc[mi][ni][r] + bv, 0.f));
      }
    }
  __syncthreads();
  const long ob = ((long)(n*128 + q)) * 8192;   // 128 ox * 64 co
  for (int s = threadIdx.x; s < 1024; s += 256) {
    const int kb = s & 7, ox = s >> 3;
    const int bo = ((ox << 7) + (kb << 4)) ^ ((ox & 7) << 4);
    *(short8*)&out[ob + ox*64 + kb*8] = *(const short8*)((const char*)IC + bo);
  }
}

// ---- conv2 via two-phase MFMA + async stage: h1 -> h2 ----------------------
#define C2_LOAD(c) \
  _Pragma("unroll") \
  for (int s = 0; s < 9; ++s) { \
    st[s] = (short8)(short)0; \
    if (goff[s] >= 0) st[s] = *(const short8*)(in + goff[s] + (c)*32); \
  }
#define C2_WRITE \
  _Pragma("unroll") \
  for (int s = 0; s < 9; ++s) \
    if (lb[s] >= 0) *(short8*)((char*)IL + lb[s]) = st[s];
#define C2_COMPUTE(c) \
  _Pragma("unroll") \
  for (int t = 0; t < 16; ++t) { \
    const int ky = t >> 2, kx = t & 3; \
    const int p = 1 - (kx & 1), d = kx >> 1; \
    const short8 bv0 = *(const short8*)(wb + (t*2 + (c))*4096); \
    const short8 bv1 = *(const short8*)(wb + (t*2 + (c))*4096 + 512); \
    const char* Ab = (const char*)IL + (Bd0 + d*64); \
    const int imm0 = ((ky*2 + p)*66) << 6; \
    _Pragma("unroll") \
    for (int mi = 0; mi < 4; ++mi) { \
      const short8 av = *(const short8*)(Ab + imm0 + mi*1024); \
      acc[mi][0] = __builtin_amdgcn_mfma_f32_16x16x32_bf16( \
          __builtin_bit_cast(bf16x8, av), __builtin_bit_cast(bf16x8, bv0), \
          acc[mi][0], 0, 0, 0); \
      acc[mi][1] = __builtin_amdgcn_mfma_f32_16x16x32_bf16( \
          __builtin_bit_cast(bf16x8, av), __builtin_bit_cast(bf16x8, bv1), \
          acc[mi][1], 0, 0, 0); \
    } \
  }
__global__ __launch_bounds__(256) void conv2m_k(const unsigned short* __restrict__ in,
    const unsigned short* __restrict__ wv, const float* __restrict__ bias,
    unsigned short* __restrict__ out) {
  __shared__ short IL[8*66*32];        // [(r*2+p)*66+idx][ci_local 32], 33792 B
  const int wid = (blockIdx.x & 7)*256 + (blockIdx.x >> 3);
  const int q = wid & 63, n = wid >> 6;          // q = output row oy
  const int w = threadIdx.x >> 6, l = threadIdx.x & 63;
  const int lm = l & 15, lk = l >> 4;
  const int Bd0 = lm*64 + lk*16;                 // A-read byte base, d=0
  const unsigned short* wb = wv + w*1024 + l*8;  // + ks*4096 (+512 for ni=1)
  int goff[9], lb[9];
  #pragma unroll
  for (int s = 0; s < 9; ++s) {
    const int i = threadIdx.x + s*256;
    const int part = i & 3, e = i >> 2;
    const int idx = e % 66, rp = e / 66;
    const int r = rp >> 1, p = rp & 1;
    const int iy = 2*q - 1 + r, ix = 2*idx - p;
    const bool ok = (i < 2112) && iy >= 0 && iy < 128 && ix >= 0 && ix < 128;
    goff[s] = ok ? (((n*128 + iy)*128 + ix)*64 + part*8) : -1;
    lb[s]   = (i < 2112) ? (e*64 + part*16) : -1;
  }
  f32x4 acc[4][2];
  #pragma unroll
  for (int mi = 0; mi < 4; ++mi)
    #pragma unroll
    for (int ni = 0; ni < 2; ++ni) acc[mi][ni] = (f32x4)0.0f;
  short8 st[9];
  C2_LOAD(0); C2_WRITE;
  __syncthreads();
  C2_LOAD(1);                          // issue phase-1 loads (in flight)
  C2_COMPUTE(0);
  __syncthreads();                     // phase-0 LDS reads done
  C2_WRITE;                            // waits vmcnt for st, writes LDS
  __syncthreads();
  C2_COMPUTE(1);
  #pragma unroll
  for (int mi = 0; mi < 4; ++mi)
    #pragma unroll
    for (int r = 0; r < 4; ++r) {
      const int ox = mi*16 + lk*4 + r;
      const int ob = ((n*64 + q)*64 + ox)*128;
      #pragma unroll
      for (int ni = 0; ni < 2; ++ni) {
        const int co = (w*2 + ni)*16 + lm;
        out[ob + co] = f2b(fmaxf(acc[mi][ni][r] + bias[co], 0.f));
      }
    }
}

// ---- conv3 + fused VQ: h2 NHWC bf16 [32,64,64,128] -> zq f32 [131072,32]
//      + loss partials.  Conv part = R18 conv3m (2-phase ci-split + async
//      stage); epilogue: z-tile -> LDS (bf16 frag tile + f32 copy), MFMA
//      distances vs prepped embed frags, vqm-identical argmin/gather/loss.
#define C3_LOAD(c) \
  _Pragma("unroll") \
  for (int s = 0; s < 9; ++s) { \
    st[s] = (short8)(short)0; \
    if (goff[s] >= 0) st[s] = *(const short8*)(in + goff[s] + (c)*64); \
  }
#define C3_WRITE \
  _Pragma("unroll") \
  for (int s = 0; s < 9; ++s) \
    if (lb[s] >= 0) *(short8*)((char*)IL + lb[s]) = st[s];
#define C3_COMPUTE(c) \
  _Pragma("unroll") \
  for (int u = 0; u < 18; ++u) { \
    const int tap = u >> 1, cc = u & 1; \
    const int ky = tap / 3, kx = tap % 3; \
    const int ks = tap*4 + (c)*2 + cc; \
    const short8 bv0 = *(const short8*)(wb + ks*1024); \
    const short8 bv1 = *(const short8*)(wb + ks*1024 + 512); \
    const char* Ab = (const char*)IL + (Wc[kx][cc]); \
    const int imm0 = ky*8448; \
    _Pragma("unroll") \
    for (int mi = 0; mi < 2; ++mi) { \
      const short8 av = *(const short8*)(Ab + imm0 + mi*2048); \
      acc[mi][0] = __builtin_amdgcn_mfma_f32_16x16x32_bf16( \
          __builtin_bit_cast(bf16x8, av), __builtin_bit_cast(bf16x8, bv0), \
          acc[mi][0], 0, 0, 0); \
      acc[mi][1] = __builtin_amdgcn_mfma_f32_16x16x32_bf16( \
          __builtin_bit_cast(bf16x8, av), __builtin_bit_cast(bf16x8, bv1), \
          acc[mi][1], 0, 0, 0); \
    } \
  }
__global__ __launch_bounds__(256) void conv3v_k(const unsigned short* __restrict__ in,
    const unsigned short* __restrict__ wv, const float* __restrict__ bias,
    const unsigned short* __restrict__ wqe, const float* __restrict__ eng,
    const float* __restrict__ emb, float* __restrict__ zq,
    float* __restrict__ part) {
  __shared__ short IL[4*66*64];        // 33792 B; unions below after compute
  const int wid = (blockIdx.x & 7)*128 + (blockIdx.x >> 3);
  const int q = wid & 31, n = wid >> 5;          // oy0 = 2q
  const int w = threadIdx.x >> 6, l = threadIdx.x & 63;
  const int lm = l & 15, lk = l >> 4;
  const int row = w >> 1, oxb = (w & 1) * 32;
  int goff[9], lb[9];
  #pragma unroll
  for (int s = 0; s < 9; ++s) {
    const int i = threadIdx.x + s*256;
    const int part_ = i & 7, e = i >> 3;
    const int col = e % 66, r = e / 66;
    const int iy = 2*q - 1 + r, ix = col - 1;
    const bool ok = (i < 2112) && iy >= 0 && iy < 64 && ix >= 0 && ix < 64;
    goff[s] = ok ? (((n*64 + iy)*64 + ix)*128 + part_*8) : -1;
    lb[s]   = (i < 2112) ? ((e << 7) + ((part_ << 4) ^ ((col & 7) << 4))) : -1;
  }
  int Wc[3][2];
  #pragma unroll
  for (int kx = 0; kx < 3; ++kx) {
    const int e = oxb + lm + kx;
    Wc[kx][0] = row*8448 + (e << 7) + ((lk << 4) ^ ((e & 7) << 4));
    Wc[kx][1] = Wc[kx][0] ^ 0x40;
  }
  const unsigned short* wb = wv + l*8;           // + ks*1024 + ni*512
  f32x4 acc[2][2];
  #pragma unroll
  for (int mi = 0; mi < 2; ++mi)
    #pragma unroll
    for (int ni = 0; ni < 2; ++ni) acc[mi][ni] = (f32x4)0.0f;
  short8 st[9];
  C3_LOAD(0); C3_WRITE;
  __syncthreads();
  C3_LOAD(1);
  C3_COMPUTE(0);
  __syncthreads();
  C3_WRITE;
  __syncthreads();
  C3_COMPUTE(1);
  // ---- fused VQ ----
  __syncthreads();                               // all IL reads done
  short* ZB  = (short*)IL;                       // [128][40] bf16, 10240 B
  float* ZF  = (float*)((char*)IL + 10240);      // [128][36] f32, 18432 B
  int*  bidx = (int*)((char*)IL + 28672);        // 128 ints
  float* red = (float*)((char*)IL + 29184);      // 256 floats
  #pragma unroll
  for (int mi = 0; mi < 2; ++mi)
    #pragma unroll
    for (int ni = 0; ni < 2; ++ni) {
      const int co = ni*16 + lm;
      const float bv = bias[co];
      #pragma unroll
      for (int r = 0; r < 4; ++r) {
        const int pos = row*64 + oxb + mi*16 + lk*4 + r;
        const float v = fmaxf(acc[mi][ni][r] + bv, 0.f);
        ZB[pos*40 + co] = (short)f2b(v);
        ZF[pos*36 + co] = v;
      }
    }
  __syncthreads();
  short8 av[2];
  #pragma unroll
  for (int mi = 0; mi < 2; ++mi)
    av[mi] = *(const short8*)&ZB[(row*64 + oxb + mi*16 + lm)*40 + lk*8];
  float bd[2][4]; int bj[2][4];
  #pragma unroll
  for (int mi = 0; mi < 2; ++mi)
    #pragma unroll
    for (int r = 0; r < 4; ++r) { bd[mi][r] = 1e30f; bj[mi][r] = 0; }
  for (int nc = 0; nc < 8; ++nc) {               // chunks of 64 codes
    f32x4 a2[2][4];
    #pragma unroll
    for (int mi = 0; mi < 2; ++mi)
      #pragma unroll
      for (int ni = 0; ni < 4; ++ni) a2[mi][ni] = (f32x4)0.0f;
    #pragma unroll
    for (int ni = 0; ni < 4; ++ni) {
      const short8 bv = *(const short8*)(wqe + (((nc*4 + ni)*64 + l) << 3));
      #pragma unroll
      for (int mi = 0; mi < 2; ++mi)
        a2[mi][ni] = __builtin_amdgcn_mfma_f32_16x16x32_bf16(
            __builtin_bit_cast(bf16x8, av[mi]),
            __builtin_bit_cast(bf16x8, bv),
            a2[mi][ni], 0, 0, 0);
    }
    #pragma unroll
    for (int ni = 0; ni < 4; ++ni) {
      const int j = nc*64 + ni*16 + lm;
      const float e_n = eng[j];
      #pragma unroll
      for (int mi = 0; mi < 2; ++mi)
        #pragma unroll
        for (int r = 0; r < 4; ++r) {
          const float d = fmaf(-2.f, a2[mi][ni][r], e_n);
          if (d < bd[mi][r]) { bd[mi][r] = d; bj[mi][r] = j; }
        }
    }
  }
  #pragma unroll
  for (int mi = 0; mi < 2; ++mi)
    #pragma unroll
    for (int r = 0; r < 4; ++r) {
      float d = bd[mi][r]; int j = bj[mi][r];
      #pragma unroll
      for (int off = 1; off < 16; off <<= 1) {
        const float od = __shfl_xor(d, off);
        const int   oj = __shfl_xor(j, off);
        if (od < d || (od == d && oj < j)) { d = od; j = oj; }
      }
      if (lm == 0) bidx[row*64 + oxb + mi*16 + lk*4 + r] = j;
    }
  __syncthreads();
  const int pl = threadIdx.x >> 1, hf = (threadIdx.x & 1) * 16;
  const int code = bidx[pl];
  const int oy2 = 2*q + (pl >> 6), ox2 = pl & 63;
  const long zqo = ((long)((n*64 + oy2)*64 + ox2)) * 32 + hf;
  float se = 0.f;
  #pragma unroll
  for (int qq = 0; qq < 4; ++qq) {
    const f32x4 ev = *(const f32x4*)&emb[code*32 + hf + qq*4];
    const f32x4 zv = *(const f32x4*)&ZF[pl*36 + hf + qq*4];
    *(f32x4*)&zq[zqo + qq*4] = ev;
    const f32x4 df = ev - zv;
    #pragma unroll
    for (int e = 0; e < 4; ++e) se = fmaf(df[e], df[e], se);
  }
  red[threadIdx.x] = se; __syncthreads();
  for (int s2 = 128; s2 > 0; s2 >>= 1) {
    if (threadIdx.x < s2) red[threadIdx.x] += red[threadIdx.x + s2];
    __syncthreads();
  }
  if (threadIdx.x == 0) part[blockIdx.x] = red[0];
}

// ---- d1 convT via MFMA: zq f32 [131072,32] -> d1 NHWC bf16 [32,64,64,128]
__global__ __launch_bounds__(256) void d1m_k(const float* __restrict__ in,
    const unsigned short* __restrict__ wv, const float* __restrict__ bias,
    unsigned short* __restrict__ out) {
  __shared__ short IL[264*40];         // [r*66+col][40-short stride], 21120 B
  const int wid = (blockIdx.x & 7)*128 + (blockIdx.x >> 3);
  const int q = wid & 31, n = wid >> 5;
  const int w = threadIdx.x >> 6, l = threadIdx.x & 63;
  const int lm = l & 15, lk = l >> 4;
  const int row = w >> 1, oxb = (w & 1) * 32;
  for (int i = threadIdx.x; i < 1056; i += 256) {  // 264 entries * 4 parts
    const int part = i & 3, e = i >> 2;
    const int col = e % 66, r = e / 66;
    const int iy = 2*q - 1 + r, ix = col - 1;
    short8 v = (short8)(short)0;
    if (iy >= 0 && iy < 64 && ix >= 0 && ix < 64) {
      const float* p = in + (((long)((n*64 + iy)*64 + ix)) * 32 + part*8);
      const f32x4 f0 = *(const f32x4*)p;
      const f32x4 f1 = *(const f32x4*)(p + 4);
      #pragma unroll
      for (int e2 = 0; e2 < 4; ++e2) {
        v[e2]     = (short)f2b(f0[e2]);
        v[e2 + 4] = (short)f2b(f1[e2]);
      }
    }
    *(short8*)&IL[e*40 + part*8] = v;
  }
  const unsigned short* wb = wv + l*8;             // + (tap*8+ni)*512
  int Wd[3];
  #pragma unroll
  for (int kx = 0; kx < 3; ++kx)
    Wd[kx] = row*5280 + (oxb + lm + kx)*80 + lk*16;   // bytes
  __syncthreads();
  f32x4 acc[2][8];
  #pragma unroll
  for (int mi = 0; mi < 2; ++mi)
    #pragma unroll
    for (int ni = 0; ni < 8; ++ni) acc[mi][ni] = (f32x4)0.0f;
  #pragma unroll
  for (int tap = 0; tap < 9; ++tap) {
    const int ky = tap / 3, kx = tap % 3;
    short8 bv[8];
    #pragma unroll
    for (int ni = 0; ni < 8; ++ni)
      bv[ni] = *(const short8*)(wb + (tap*8 + ni)*512);
    const char* Ab = (const char*)IL + Wd[kx];
    const int imm0 = ky*5280;
    #pragma unroll
    for (int mi = 0; mi < 2; ++mi) {
      const short8 av = *(const short8*)(Ab + imm0 + mi*1280);
      #pragma unroll
      for (int ni = 0; ni < 8; ++ni)
        acc[mi][ni] = __builtin_amdgcn_mfma_f32_16x16x32_bf16(
            __builtin_bit_cast(bf16x8, av),
            __builtin_bit_cast(bf16x8, bv[ni]),
            acc[mi][ni], 0, 0, 0);
    }
  }
  const int oy = 2*q + row;
  #pragma unroll
  for (int mi = 0; mi < 2; ++mi)
    #pragma unroll
    for (int r = 0; r < 4; ++r) {
      const int ox = oxb + mi*16 + lk*4 + r;
      const int ob = ((n*64 + oy)*64 + ox)*128;
      #pragma unroll
      for (int ni = 0; ni < 8; ++ni) {
        const int co = ni*16 + lm;
        out[ob + co] = f2b(fmaxf(acc[mi][ni][r] + bias[co], 0.f));
      }
    }
}

// ---- d2 convT via two-phase merged-parity MFMA + async stage: d1 -> d2 -----
#define CT2_LOAD(c) \
  _Pragma("unroll") \
  for (int s = 0; s < 7; ++s) { \
    st[s] = (short8)(short)0; \
    if (goff[s] >= 0) st[s] = *(const short8*)(in + goff[s] + (c)*64); \
  }
#define CT2_WRITE \
  _Pragma("unroll") \
  for (int s = 0; s < 7; ++s) \
    if (lb[s] >= 0) *(short8*)((char*)IL + lb[s]) = st[s];
#define CT2_COMPUTE(c) \
  _Pragma("unroll") \
  for (int u = 0; u < 8; ++u) { \
    const int a = u >> 2, b = (u >> 1) & 1, c1 = u & 1; \
    const int ks = (a << 3) | (b << 2) | (2*(c) + c1); \
    short8 bv[4]; \
    _Pragma("unroll") \
    for (int ni = 0; ni < 4; ++ni) \
      bv[ni] = *(const short8*)(wb + ks*2048 + ni*512); \
    const char* Ab = (const char*)IL + (pyb + Wb[b][c1]); \
    const int imm0 = a*8448; \
    _Pragma("unroll") \
    for (int mi = 0; mi < 4; ++mi) { \
      const short8 av = *(const short8*)(Ab + imm0 + mi*2048); \
      _Pragma("unroll") \
      for (int ni = 0; ni < 4; ++ni) \
        acc[mi][ni] = __builtin_amdgcn_mfma_f32_16x16x32_bf16( \
            __builtin_bit_cast(bf16x8, av), \
            __builtin_bit_cast(bf16x8, bv[ni]), \
            acc[mi][ni], 0, 0, 0); \
    } \
  }
__global__ __launch_bounds__(256) void convt2m_k(const unsigned short* __restrict__ in,
    const unsigned short* __restrict__ wv, const float* __restrict__ bias,
    unsigned short* __restrict__ out) {
  __shared__ short IL[3*66*64];        // [r*66+col][ci_local 32+32], 25344 B
  const int wid = (blockIdx.x & 7)*256 + (blockIdx.x >> 3);
  const int q = wid & 63, n = wid >> 6;
  const int w = threadIdx.x >> 6, l = threadIdx.x & 63;
  const int py = w >> 1, px = w & 1;
  const int lm = l & 15, lk = l >> 4;
  int Wb[2][2];
  #pragma unroll
  for (int b = 0; b < 2; ++b) {
    const int e = lm + px + b;
    Wb[b][0] = (e << 7) + ((lk << 4) ^ ((e & 7) << 4));
    Wb[b][1] = Wb[b][0] ^ 0x40;
  }
  const int pyb = py * 8448;                       // 66 entries * 128 B
  const unsigned short* wb = wv + w*32768 + l*8;   // + ks*2048 + ni*512
  int goff[7], lb[7];
  #pragma unroll
  for (int s = 0; s < 7; ++s) {
    const int i = threadIdx.x + s*256;
    const int part = i & 7, e = i >> 3;
    const int col = e % 66, r = e / 66;
    const int iy = q - 1 + r, ix = col - 1;
    const bool ok = (i < 1584) && iy >= 0 && iy < 64 && ix >= 0 && ix < 64;
    goff[s] = ok ? (((n*64 + iy)*64 + ix)*128 + part*8) : -1;
    lb[s]   = (i < 1584) ? ((e << 7) + ((part << 4) ^ ((col & 7) << 4))) : -1;
  }
  f32x4 acc[4][4];
  #pragma unroll
  for (int mi = 0; mi < 4; ++mi)
    #pragma unroll
    for (int ni = 0; ni < 4; ++ni) acc[mi][ni] = (f32x4)0.0f;
  short8 st[7];
  CT2_LOAD(0); CT2_WRITE;
  __syncthreads();
  CT2_LOAD(1);
  CT2_COMPUTE(0);
  __syncthreads();
  CT2_WRITE;
  __syncthreads();
  CT2_COMPUTE(1);
  const int oy = 2*q + py;
  #pragma unroll
  for (int mi = 0; mi < 4; ++mi)
    #pragma unroll
    for (int r = 0; r < 4; ++r) {
      const int ox = 2*(mi*16 + lk*4 + r) + px;
      const int ob = ((n*128 + oy)*128 + ox)*64;
      #pragma unroll
      for (int ni = 0; ni < 4; ++ni) {
        const int co = ni*16 + lm;
        out[ob + co] = f2b(fmaxf(acc[mi][ni][r] + bias[co], 0.f));
      }
    }
}

__global__ __launch_bounds__(256) void loss_k(const float* __restrict__ part,
                                              float* __restrict__ out) {
  __shared__ float red[256];
  const int t = threadIdx.x;
  float s = 0.f;
  #pragma unroll
  for (int q = 0; q < 4; ++q) s += part[t + q*256];   // 1024 partials
  red[t] = s; __syncthreads();
  for (int st = 128; st > 0; st >>= 1) {
    if (t < st) red[t] += red[t + st];
    __syncthreads();
  }
  if (t == 0) out[0] = red[0] * (1.25f / (131072.f * 32.f));
}

// ---- convt3 via MFMA: d2 NHWC bf16 [32,128,128,64] -> x_recon NCHW fp32 ----
__global__ __launch_bounds__(256) void convt3m_k(const unsigned short* __restrict__ in,
    const unsigned short* __restrict__ wq6, const float* __restrict__ bias,
    float* __restrict__ out) {
  __shared__ short8 IL[3*8*66];      // [(r*8+c8)*66 + ixl], 25344 B
  const int h = blockIdx.x & 1, q = (blockIdx.x >> 1) & 127, n = blockIdx.x >> 8;
  for (int i = threadIdx.x; i < 1584; i += 256) {   // 3*66*8
    const int c8 = i & 7, t = i >> 3, ixl = t % 66, r = t / 66;
    const int iy = q - 1 + r, ix = h*64 - 1 + ixl;
    short8 v = (short8)(short)0;
    if (iy >= 0 && iy < 128 && ix >= 0 && ix < 128)
      v = *(const short8*)(in + (((long)(n*128 + iy)*128 + ix)*64 + c8*8));
    IL[(r*8 + c8)*66 + ixl] = v;
  }
  const int w = threadIdx.x >> 6, l = threadIdx.x & 63;
  const int py = w >> 1, px = w & 1;
  const int lm = l & 15, lk = l >> 4;
  short8 bfrag[8];
  #pragma unroll
  for (int kc = 0; kc < 8; ++kc)
    bfrag[kc] = *(const short8*)(wq6 + (((w*8 + kc)*64 + l) << 3));
  __syncthreads();
  f32x4 acc[4];
  #pragma unroll
  for (int mi = 0; mi < 4; ++mi) acc[mi] = (f32x4)0.0f;
  #pragma unroll
  for (int kc = 0; kc < 8; ++kc) {
    const int a = kc >> 2, b = (kc >> 1) & 1, ch = kc & 1;
    const int base = (((py + a)*8 + ch*4 + lk)*66) + px + b;   // + ixl(xq)
    #pragma unroll
    for (int mi = 0; mi < 4; ++mi) {
      const short8 av = *(const short8*)&IL[base + mi*16 + lm];
      acc[mi] = __builtin_amdgcn_mfma_f32_16x16x32_bf16(
          __builtin_bit_cast(bf16x8, av),
          __builtin_bit_cast(bf16x8, bfrag[kc]),
          acc[mi], 0, 0, 0);
    }
  }
  if (lm < 3) {
    const float bv = bias[lm];
    const int oy = 2*q + py;
    const long ob = ((long)(n*3 + lm))*65536 + oy*256;
    #pragma unroll
    for (int mi = 0; mi < 4; ++mi)
      #pragma unroll
      for (int r = 0; r < 4; ++r) {
        const int xq = mi*16 + lk*4 + r;
        out[ob + h*128 + 2*xq + px] = acc[mi][r] + bv;
      }
  }
}

extern "C" void kernel_launch(void* const* d_in, const int* in_sizes, int n_in,
                              void* d_out, int out_size, void* d_ws, size_t ws_size,
                              hipStream_t stream) {
  const float* x   = (const float*)d_in[0];
  const float* ew1 = (const float*)d_in[1];  const float* eb1 = (const float*)d_in[2];
  const float* ew2 = (const float*)d_in[3];  const float* eb2 = (const float*)d_in[4];
  const float* ew3 = (const float*)d_in[5];  const float* eb3 = (const float*)d_in[6];
  const float* emb = (const float*)d_in[7];
  const float* dw1 = (const float*)d_in[8];  const float* db1 = (const float*)d_in[9];
  const float* dw2 = (const float*)d_in[10]; const float* db2 = (const float*)d_in[11];
  const float* dw3 = (const float*)d_in[12]; const float* db3 = (const float*)d_in[13];
  float* out = (float*)d_out;

  // ws layout: h1/d2 bf16 @0 (64MB); h2/d1 bf16 @64MB (32MB);
  //   z-region @96MB (16MB): wqe/eng/part/wq3/wq4/wq5/wq6 (z never materialized);
  //   zq f32 @112MB (16MB): also wq2/wq1 overlay (consumed before conv3v
  //   writes zq — stream order guarantees).
  uint8_t* w8 = (uint8_t*)d_ws;
  unsigned short* h1 = (unsigned short*)w8;
  unsigned short* h2 = (unsigned short*)(w8 + 67108864);
  uint8_t* zr = w8 + 100663296;
  float* zq  = (float*)(w8 + 117440512);
  unsigned short* wqe = (unsigned short*)zr;                  // 32768 B
  float* eng = (float*)(zr + 32768);                          // 2048 B
  float* part = (float*)(zr + 36864);                         // 4096 B
  unsigned short* wq3 = (unsigned short*)(zr + 40960);        // 73728 B
  unsigned short* wq4 = (unsigned short*)(zr + 131072);       // 73728 B
  unsigned short* wq5 = (unsigned short*)(zr + 262144);       // 262144 B
  unsigned short* wq6 = (unsigned short*)(zr + 524288);       // 32768 B
  unsigned short* wq2 = (unsigned short*)(w8 + 117440512);            // 262144 B
  unsigned short* wq1 = (unsigned short*)(w8 + 117440512 + 335872);   // 8192 B
  unsigned short* d1 = h2;
  unsigned short* d2 = h1;

  // all weight/embed prep upfront
  prepe_k<<<dim3(64),256,0,stream>>>(emb, wqe, eng);
  prep1v_k<<<dim3(16),256,0,stream>>>(ew1, wq1);
  prep2v_k<<<dim3(512),256,0,stream>>>(ew2, wq2);
  prep3v_k<<<dim3(144),256,0,stream>>>(ew3, wq3);
  prep4v_k<<<dim3(144),256,0,stream>>>(dw1, wq4);
  prep5v_k<<<dim3(512),256,0,stream>>>(dw2, wq5);
  prep6_k<<<dim3(64),256,0,stream>>>(dw3, wq6);
  // encoder + fused VQ
  conv1m_k<<<dim3(4096),256,0,stream>>>(x, wq1, eb1, h1);
  conv2m_k<<<dim3(2048),256,0,stream>>>(h1, wq2, eb2, h2);
  conv3v_k<<<dim3(1024),256,0,stream>>>(h2, wq3, eb3, wqe, eng, emb, zq, part);
  loss_k<<<dim3(1),256,0,stream>>>(part, out + 6291456);
  // decoder
  d1m_k<<<dim3(1024),256,0,stream>>>(zq, wq4, db1, d1);
  convt2m_k<<<dim3(2048),256,0,stream>>>(d1, wq5, db2, d2);
  convt3m_k<<<dim3(8192),256,0,stream>>>(d2, wq6, db3, out);
}

// Round 10
// 340.541 us; speedup vs baseline: 1.5213x; 1.0448x over previous
//
#include <hip/hip_runtime.h>

// VQ-VAE forward, MI355X round 20: R19 + LDS-coalesced epilogues for
// conv2m/convt2m/d1m/convt3m (scattered 2B stores -> contiguous 64B/thread)
// + all 7 weight-prep launches fused into one prepall_k.

typedef __attribute__((ext_vector_type(8))) short     short8;
typedef __attribute__((ext_vector_type(4))) short     s16x4;
typedef __attribute__((ext_vector_type(8))) __bf16    bf16x8;
typedef __attribute__((ext_vector_type(4))) float     f32x4;
typedef __attribute__((ext_vector_type(4))) unsigned  uint32x4;

__device__ __forceinline__ float b2f(unsigned short b) {
  union { unsigned u; float f; } v; v.u = ((unsigned)b) << 16; return v.f;
}
__device__ __forceinline__ unsigned short f2b(float f) {  // round-to-nearest-even
  union { float f; unsigned u; } v; v.f = f;
  unsigned r = v.u + 0x7FFF + ((v.u >> 16) & 1);
  return (unsigned short)(r >> 16);
}

// ---------------- fused weight/embed prep (all layers, 1 launch) ------------
__global__ __launch_bounds__(256) void prepall_k(
    const float* __restrict__ ew1, const float* __restrict__ ew2,
    const float* __restrict__ ew3, const float* __restrict__ dw1,
    const float* __restrict__ dw2, const float* __restrict__ dw3,
    const float* __restrict__ emb,
    unsigned short* __restrict__ wq1, unsigned short* __restrict__ wq2,
    unsigned short* __restrict__ wq3, unsigned short* __restrict__ wq4,
    unsigned short* __restrict__ wq5, unsigned short* __restrict__ wq6,
    unsigned short* __restrict__ wqe, float* __restrict__ eng) {
  const int b = blockIdx.x;
  if (b < 64) {                                   // prepe: 16384
    const int i = b*256 + threadIdx.x;
    const int j = i & 7, l = (i >> 3) & 63, ni = (i >> 9) & 3, nc = i >> 11;
    const int lm = l & 15, lk = l >> 4;
    wqe[i] = f2b(emb[(nc*64 + ni*16 + lm)*32 + lk*8 + j]);
    if (i < 512) {
      float s = 0.f;
      #pragma unroll
      for (int k = 0; k < 32; ++k) {
        const float f = b2f(f2b(emb[i*32 + k]));
        s = fmaf(f, f, s);
      }
      eng[i] = s;
    }
  } else if (b < 80) {                            // prep1v: 4096
    const int i = (b - 64)*256 + threadIdx.x;
    const int j = i & 7, l = (i >> 3) & 63, ni = (i >> 9) & 3, ks = i >> 11;
    const int k = ks*32 + (l >> 4)*8 + j;
    const int co = ni*16 + (l & 15);
    wq1[i] = (k < 48) ? f2b(ew1[co*48 + k]) : (unsigned short)0;
  } else if (b < 592) {                           // prep2v: 131072
    const int i = (b - 80)*256 + threadIdx.x;
    const int j = i & 7, l = (i >> 3) & 63, ni = (i >> 9) & 7, ks = i >> 12;
    const int lm = l & 15, lk = l >> 4;
    const int tap = ks >> 1, cc = ks & 1;
    const int co = ni*16 + lm, ci = cc*32 + lk*8 + j;
    wq2[i] = f2b(ew2[(co*64 + ci)*16 + tap]);
  } else if (b < 736) {                           // prep3v: 36864
    const int i = (b - 592)*256 + threadIdx.x;
    const int j = i & 7, l = (i >> 3) & 63, ni = (i >> 9) & 1, ks = i >> 10;
    const int lm = l & 15, lk = l >> 4;
    const int tap = ks >> 2, cf = ks & 3;
    const int co = ni*16 + lm, ci = cf*32 + lk*8 + j;
    wq3[i] = f2b(ew3[(co*128 + ci)*9 + tap]);
  } else if (b < 880) {                           // prep4v: 36864
    const int i = (b - 736)*256 + threadIdx.x;
    const int j = i & 7, l = (i >> 3) & 63, ni = (i >> 9) & 7, tap = i >> 12;
    const int lm = l & 15, lk = l >> 4;
    const int co = ni*16 + lm, ci = lk*8 + j;
    wq4[i] = f2b(dw1[(ci*128 + co)*9 + (8 - tap)]);
  } else if (b < 1392) {                          // prep5v: 131072
    const int i = (b - 880)*256 + threadIdx.x;
    const int j = i & 7, l = (i >> 3) & 63, ni = (i >> 9) & 3;
    const int ks = (i >> 11) & 15, p = i >> 15;
    const int lm = l & 15, lk = l >> 4;
    const int py = p >> 1, px = p & 1;
    const int a = ks >> 3, bb = (ks >> 2) & 1, cc = ks & 3;
    const int co = ni*16 + lm, ci = cc*32 + lk*8 + j;
    const int ky = 3 - 2*a - py, kx = 3 - 2*bb - px;
    wq5[i] = f2b(dw2[(ci*64 + co)*16 + ky*4 + kx]);
  } else {                                        // prep6: 16384
    const int i = (b - 1392)*256 + threadIdx.x;
    const int j = i & 7, l = (i >> 3) & 63, kc = (i >> 9) & 7, p = i >> 12;
    const int lm = l & 15, lk = l >> 4;
    const int a = kc >> 2, bb = (kc >> 1) & 1, ch = kc & 1;
    const int ci = ch*32 + lk*8 + j, co = lm;
    const int py = p >> 1, px = p & 1;
    const int ky = 2 - 2*a + (1 - py), kx = 2 - 2*bb + (1 - px);
    wq6[i] = (co < 3) ? f2b(dw3[(ci*3 + co)*16 + ky*4 + kx]) : (unsigned short)0;
  }
}

// ---- conv1 via MFMA: x NCHW fp32 [32,3,256,256] -> h1 NHWC bf16 ------------
__global__ __launch_bounds__(256) void conv1m_k(const float* __restrict__ x,
    const unsigned short* __restrict__ wv, const float* __restrict__ bias,
    unsigned short* __restrict__ out) {
  __shared__ __align__(16) short RAW[12*264];   // row g=ci*4+ky, idx=ix+4; 6336B
  __shared__ __align__(16) short IC[128*64];    // [ox][k] swizzled; 16384B
  const int wid = ((blockIdx.x & 7) << 9) + (blockIdx.x >> 3);
  const int q = wid & 127, n = wid >> 7;        // q = output row oy
  for (int i = threadIdx.x; i < 396; i += 256)
    *(short8*)&RAW[i*8] = (short8)(short)0;
  __syncthreads();
  for (int s = threadIdx.x; s < 768; s += 256) {   // 12 rows * 64 f32x4
    const int g = s >> 6, seg = s & 63;
    const int ci = g >> 2, ky = g & 3;
    const int iy = 2*q - 1 + ky;
    if (iy >= 0 && iy < 256) {
      const f32x4 v = *(const f32x4*)&x[((n*3 + ci)*256 + iy)*256 + seg*4];
      s16x4 sv;
      #pragma unroll
      for (int e = 0; e < 4; ++e) sv[e] = (short)f2b(v[e]);
      *(s16x4*)&RAW[g*264 + 4 + seg*4] = sv;
    }
  }
  __syncthreads();
  for (int s = threadIdx.x; s < 1024; s += 256) {
    const int kb = s & 7, ox = s >> 3;
    short8 v = (short8)(short)0;
    if (kb < 6) {
      const unsigned* u0 = (const unsigned*)&RAW[(2*kb  )*264 + 2*ox + 2];
      const unsigned* u1 = (const unsigned*)&RAW[(2*kb+1)*264 + 2*ox + 2];
      const unsigned a0 = u0[0], a1 = u0[1], a2 = u0[2];
      const unsigned b0 = u1[0], b1 = u1[1], b2 = u1[2];
      uint32x4 uv;
      uv[0] = (a0 >> 16) | (a1 << 16);
      uv[1] = (a1 >> 16) | (a2 << 16);
      uv[2] = (b0 >> 16) | (b1 << 16);
      uv[3] = (b1 >> 16) | (b2 << 16);
      v = __builtin_bit_cast(short8, uv);
    }
    const int bo = ((ox << 7) + (kb << 4)) ^ ((ox & 7) << 4);
    *(short8*)((char*)IC + bo) = v;
  }
  __syncthreads();
  const int w = threadIdx.x >> 6, l = threadIdx.x & 63;
  const int lm = l & 15, lk = l >> 4;
  f32x4 acc[2][4];
  #pragma unroll
  for (int mi = 0; mi < 2; ++mi)
    #pragma unroll
    for (int ni = 0; ni < 4; ++ni) acc[mi][ni] = (f32x4)0.0f;
  #pragma unroll
  for (int ks = 0; ks < 2; ++ks) {
    short8 bv[4];
    #pragma unroll
    for (int ni = 0; ni < 4; ++ni)
      bv[ni] = *(const short8*)(wv + (((ks*4 + ni)*64 + l) << 3));
    #pragma unroll
    for (int mi = 0; mi < 2; ++mi) {
      const int ox = w*32 + mi*16 + lm;
      const int bo = ((ox << 7) + (ks << 6) + (lk << 4)) ^ ((ox & 7) << 4);
      const short8 av = *(const short8*)((const char*)IC + bo);
      #pragma unroll
      for (int ni = 0; ni < 4; ++ni)
        acc[mi][ni] = __builtin_amdgcn_mfma_f32_16x16x32_bf16(
            __builtin_bit_cast(bf16x8, av),
            __builtin_bit_cast(bf16x8, bv[ni]),
            acc[mi][ni], 0, 0, 0);
    }
  }
  __syncthreads();            // frag reads done; reuse IC for output staging
  #pragma unroll
  for (int mi = 0; mi < 2; ++mi)
    #pragma unroll
    for (int ni = 0; ni < 4; ++ni) {
      const int co = ni*16 + lm;
      const float bv = bias[co];
      #pragma unroll
      for (int r = 0; r < 4; ++r) {
        const int ox = w*32 + mi*16 + lk*4 + r;
        const int bo = ((ox << 7) + 2*co) ^ ((ox & 7) << 4);
        *(short*)((char*)IC + bo) = (short)f2b(fmaxf(acc[mi][ni][r] + bv, 0.f));
      }
    }
  __syncthreads();
  const long ob = ((long)(n*128 + q)) * 8192;   // 128 ox * 64 co
  for (int s = threadIdx.x; s < 1024; s += 256) {
    const int kb = s & 7, ox = s >> 3;
    const int bo = ((ox << 7) + (kb << 4)) ^ ((ox & 7) << 4);
    *(short8*)&out[ob + ox*64 + kb*8] = *(const short8*)((const char*)IC + bo);
  }
}

// ---- conv2 via two-phase MFMA + async stage: h1 -> h2 ----------------------
#define C2_LOAD(c) \
  _Pragma("unroll") \
  for (int s = 0; s < 9; ++s) { \
    st[s] = (short8)(short)0; \
    if (goff[s] >= 0) st[s] = *(const short8*)(in + goff[s] + (c)*32); \
  }
#define C2_WRITE \
  _Pragma("unroll") \
  for (int s = 0; s < 9; ++s) \
    if (lb[s] >= 0) *(short8*)((char*)IL + lb[s]) = st[s];
#define C2_COMPUTE(c) \
  _Pragma("unroll") \
  for (int t = 0; t < 16; ++t) { \
    const int ky = t >> 2, kx = t & 3; \
    const int p = 1 - (kx & 1), d = kx >> 1; \
    const short8 bv0 = *(const short8*)(wb + (t*2 + (c))*4096); \
    const short8 bv1 = *(const short8*)(wb + (t*2 + (c))*4096 + 512); \
    const char* Ab = (const char*)IL + (Bd0 + d*64); \
    const int imm0 = ((ky*2 + p)*66) << 6; \
    _Pragma("unroll") \
    for (int mi = 0; mi < 4; ++mi) { \
      const short8 av = *(const short8*)(Ab + imm0 + mi*1024); \
      acc[mi][0] = __builtin_amdgcn_mfma_f32_16x16x32_bf16( \
          __builtin_bit_cast(bf16x8, av), __builtin_bit_cast(bf16x8, bv0), \
          acc[mi][0], 0, 0, 0); \
      acc[mi][1] = __builtin_amdgcn_mfma_f32_16x16x32_bf16( \
          __builtin_bit_cast(bf16x8, av), __builtin_bit_cast(bf16x8, bv1), \
          acc[mi][1], 0, 0, 0); \
    } \
  }
__global__ __launch_bounds__(256) void conv2m_k(const unsigned short* __restrict__ in,
    const unsigned short* __restrict__ wv, const float* __restrict__ bias,
    unsigned short* __restrict__ out) {
  __shared__ short IL[8*66*32];        // [(r*2+p)*66+idx][ci_local 32], 33792 B
  const int wid = (blockIdx.x & 7)*256 + (blockIdx.x >> 3);
  const int q = wid & 63, n = wid >> 6;          // q = output row oy
  const int w = threadIdx.x >> 6, l = threadIdx.x & 63;
  const int lm = l & 15, lk = l >> 4;
  const int Bd0 = lm*64 + lk*16;                 // A-read byte base, d=0
  const unsigned short* wb = wv + w*1024 + l*8;  // + ks*4096 (+512 for ni=1)
  int goff[9], lb[9];
  #pragma unroll
  for (int s = 0; s < 9; ++s) {
    const int i = threadIdx.x + s*256;
    const int part = i & 3, e = i >> 2;
    const int idx = e % 66, rp = e / 66;
    const int r = rp >> 1, p = rp & 1;
    const int iy = 2*q - 1 + r, ix = 2*idx - p;
    const bool ok = (i < 2112) && iy >= 0 && iy < 128 && ix >= 0 && ix < 128;
    goff[s] = ok ? (((n*128 + iy)*128 + ix)*64 + part*8) : -1;
    lb[s]   = (i < 2112) ? (e*64 + part*16) : -1;
  }
  f32x4 acc[4][2];
  #pragma unroll
  for (int mi = 0; mi < 4; ++mi)
    #pragma unroll
    for (int ni = 0; ni < 2; ++ni) acc[mi][ni] = (f32x4)0.0f;
  short8 st[9];
  C2_LOAD(0); C2_WRITE;
  __syncthreads();
  C2_LOAD(1);                          // issue phase-1 loads (in flight)
  C2_COMPUTE(0);
  __syncthreads();                     // phase-0 LDS reads done
  C2_WRITE;                            // waits vmcnt for st, writes LDS
  __syncthreads();
  C2_COMPUTE(1);
  // coalesced epilogue: PB[64 ox][144 shorts] over IL (18432 B)
  __syncthreads();                     // compute(1) IL reads done
  short* PB = (short*)IL;
  #pragma unroll
  for (int mi = 0; mi < 4; ++mi)
    #pragma unroll
    for (int r = 0; r < 4; ++r) {
      const int ox = mi*16 + lk*4 + r;
      #pragma unroll
      for (int ni = 0; ni < 2; ++ni) {
        const int co = (w*2 + ni)*16 + lm;
        PB[ox*144 + co] = (short)f2b(fmaxf(acc[mi][ni][r] + bias[co], 0.f));
      }
    }
  __syncthreads();
  {
    const int pos = threadIdx.x >> 2, coq = (threadIdx.x & 3) << 5;
    const long ob = ((long)((n*64 + q)*64 + pos))*128 + coq;
    #pragma unroll
    for (int u2 = 0; u2 < 4; ++u2)
      *(short8*)&out[ob + u2*8] = *(const short8*)&PB[pos*144 + coq + u2*8];
  }
}

// ---- conv3 + fused VQ: h2 NHWC bf16 [32,64,64,128] -> zq f32 + loss --------
#define C3_LOAD(c) \
  _Pragma("unroll") \
  for (int s = 0; s < 9; ++s) { \
    st[s] = (short8)(short)0; \
    if (goff[s] >= 0) st[s] = *(const short8*)(in + goff[s] + (c)*64); \
  }
#define C3_WRITE \
  _Pragma("unroll") \
  for (int s = 0; s < 9; ++s) \
    if (lb[s] >= 0) *(short8*)((char*)IL + lb[s]) = st[s];
#define C3_COMPUTE(c) \
  _Pragma("unroll") \
  for (int u = 0; u < 18; ++u) { \
    const int tap = u >> 1, cc = u & 1; \
    const int ky = tap / 3, kx = tap % 3; \
    const int ks = tap*4 + (c)*2 + cc; \
    const short8 bv0 = *(const short8*)(wb + ks*1024); \
    const short8 bv1 = *(const short8*)(wb + ks*1024 + 512); \
    const char* Ab = (const char*)IL + (Wc[kx][cc]); \
    const int imm0 = ky*8448; \
    _Pragma("unroll") \
    for (int mi = 0; mi < 2; ++mi) { \
      const short8 av = *(const short8*)(Ab + imm0 + mi*2048); \
      acc[mi][0] = __builtin_amdgcn_mfma_f32_16x16x32_bf16( \
          __builtin_bit_cast(bf16x8, av), __builtin_bit_cast(bf16x8, bv0), \
          acc[mi][0], 0, 0, 0); \
      acc[mi][1] = __builtin_amdgcn_mfma_f32_16x16x32_bf16( \
          __builtin_bit_cast(bf16x8, av), __builtin_bit_cast(bf16x8, bv1), \
          acc[mi][1], 0, 0, 0); \
    } \
  }
__global__ __launch_bounds__(256) void conv3v_k(const unsigned short* __restrict__ in,
    const unsigned short* __restrict__ wv, const float* __restrict__ bias,
    const unsigned short* __restrict__ wqe, const float* __restrict__ eng,
    const float* __restrict__ emb, float* __restrict__ zq,
    float* __restrict__ part) {
  __shared__ short IL[4*66*64];        // 33792 B; unions below after compute
  const int wid = (blockIdx.x & 7)*128 + (blockIdx.x >> 3);
  const int q = wid & 31, n = wid >> 5;          // oy0 = 2q
  const int w = threadIdx.x >> 6, l = threadIdx.x & 63;
  const int lm = l & 15, lk = l >> 4;
  const int row = w >> 1, oxb = (w & 1) * 32;
  int goff[9], lb[9];
  #pragma unroll
  for (int s = 0; s < 9; ++s) {
    const int i = threadIdx.x + s*256;
    const int part_ = i & 7, e = i >> 3;
    const int col = e % 66, r = e / 66;
    const int iy = 2*q - 1 + r, ix = col - 1;
    const bool ok = (i < 2112) && iy >= 0 && iy < 64 && ix >= 0 && ix < 64;
    goff[s] = ok ? (((n*64 + iy)*64 + ix)*128 + part_*8) : -1;
    lb[s]   = (i < 2112) ? ((e << 7) + ((part_ << 4) ^ ((col & 7) << 4))) : -1;
  }
  int Wc[3][2];
  #pragma unroll
  for (int kx = 0; kx < 3; ++kx) {
    const int e = oxb + lm + kx;
    Wc[kx][0] = row*8448 + (e << 7) + ((lk << 4) ^ ((e & 7) << 4));
    Wc[kx][1] = Wc[kx][0] ^ 0x40;
  }
  const unsigned short* wb = wv + l*8;           // + ks*1024 + ni*512
  f32x4 acc[2][2];
  #pragma unroll
  for (int mi = 0; mi < 2; ++mi)
    #pragma unroll
    for (int ni = 0; ni < 2; ++ni) acc[mi][ni] = (f32x4)0.0f;
  short8 st[9];
  C3_LOAD(0); C3_WRITE;
  __syncthreads();
  C3_LOAD(1);
  C3_COMPUTE(0);
  __syncthreads();
  C3_WRITE;
  __syncthreads();
  C3_COMPUTE(1);
  // ---- fused VQ ----
  __syncthreads();                               // all IL reads done
  short* ZB  = (short*)IL;                       // [128][40] bf16, 10240 B
  float* ZF  = (float*)((char*)IL + 10240);      // [128][36] f32, 18432 B
  int*  bidx = (int*)((char*)IL + 28672);        // 128 ints
  float* red = (float*)((char*)IL + 29184);      // 256 floats
  #pragma unroll
  for (int mi = 0; mi < 2; ++mi)
    #pragma unroll
    for (int ni = 0; ni < 2; ++ni) {
      const int co = ni*16 + lm;
      const float bv = bias[co];
      #pragma unroll
      for (int r = 0; r < 4; ++r) {
        const int pos = row*64 + oxb + mi*16 + lk*4 + r;
        const float v = fmaxf(acc[mi][ni][r] + bv, 0.f);
        ZB[pos*40 + co] = (short)f2b(v);
        ZF[pos*36 + co] = v;
      }
    }
  __syncthreads();
  short8 av[2];
  #pragma unroll
  for (int mi = 0; mi < 2; ++mi)
    av[mi] = *(const short8*)&ZB[(row*64 + oxb + mi*16 + lm)*40 + lk*8];
  float bd[2][4]; int bj[2][4];
  #pragma unroll
  for (int mi = 0; mi < 2; ++mi)
    #pragma unroll
    for (int r = 0; r < 4; ++r) { bd[mi][r] = 1e30f; bj[mi][r] = 0; }
  for (int nc = 0; nc < 8; ++nc) {               // chunks of 64 codes
    f32x4 a2[2][4];
    #pragma unroll
    for (int mi = 0; mi < 2; ++mi)
      #pragma unroll
      for (int ni = 0; ni < 4; ++ni) a2[mi][ni] = (f32x4)0.0f;
    #pragma unroll
    for (int ni = 0; ni < 4; ++ni) {
      const short8 bv = *(const short8*)(wqe + (((nc*4 + ni)*64 + l) << 3));
      #pragma unroll
      for (int mi = 0; mi < 2; ++mi)
        a2[mi][ni] = __builtin_amdgcn_mfma_f32_16x16x32_bf16(
            __builtin_bit_cast(bf16x8, av[mi]),
            __builtin_bit_cast(bf16x8, bv),
            a2[mi][ni], 0, 0, 0);
    }
    #pragma unroll
    for (int ni = 0; ni < 4; ++ni) {
      const int j = nc*64 + ni*16 + lm;
      const float e_n = eng[j];
      #pragma unroll
      for (int mi = 0; mi < 2; ++mi)
        #pragma unroll
        for (int r = 0; r < 4; ++r) {
          const float d = fmaf(-2.f, a2[mi][ni][r], e_n);
          if (d < bd[mi][r]) { bd[mi][r] = d; bj[mi][r] = j; }
        }
    }
  }
  #pragma unroll
  for (int mi = 0; mi < 2; ++mi)
    #pragma unroll
    for (int r = 0; r < 4; ++r) {
      float d = bd[mi][r]; int j = bj[mi][r];
      #pragma unroll
      for (int off = 1; off < 16; off <<= 1) {
        const float od = __shfl_xor(d, off);
        const int   oj = __shfl_xor(j, off);
        if (od < d || (od == d && oj < j)) { d = od; j = oj; }
      }
      if (lm == 0) bidx[row*64 + oxb + mi*16 + lk*4 + r] = j;
    }
  __syncthreads();
  const int pl = threadIdx.x >> 1, hf = (threadIdx.x & 1) * 16;
  const int code = bidx[pl];
  const int oy2 = 2*q + (pl >> 6), ox2 = pl & 63;
  const long zqo = ((long)((n*64 + oy2)*64 + ox2)) * 32 + hf;
  float se = 0.f;
  #pragma unroll
  for (int qq = 0; qq < 4; ++qq) {
    const f32x4 ev = *(const f32x4*)&emb[code*32 + hf + qq*4];
    const f32x4 zv = *(const f32x4*)&ZF[pl*36 + hf + qq*4];
    *(f32x4*)&zq[zqo + qq*4] = ev;
    const f32x4 df = ev - zv;
    #pragma unroll
    for (int e = 0; e < 4; ++e) se = fmaf(df[e], df[e], se);
  }
  red[threadIdx.x] = se; __syncthreads();
  for (int s2 = 128; s2 > 0; s2 >>= 1) {
    if (threadIdx.x < s2) red[threadIdx.x] += red[threadIdx.x + s2];
    __syncthreads();
  }
  if (threadIdx.x == 0) part[blockIdx.x] = red[0];
}

// ---- d1 convT via MFMA: zq f32 [131072,32] -> d1 NHWC bf16 [32,64,64,128]
__global__ __launch_bounds__(256) void d1m_k(const float* __restrict__ in,
    const unsigned short* __restrict__ wv, const float* __restrict__ bias,
    unsigned short* __restrict__ out) {
  __shared__ short IL[264*40];         // [r*66+col][40-short stride], 21120 B
  const int wid = (blockIdx.x & 7)*128 + (blockIdx.x >> 3);
  const int q = wid & 31, n = wid >> 5;
  const int w = threadIdx.x >> 6, l = threadIdx.x & 63;
  const int lm = l & 15, lk = l >> 4;
  const int row = w >> 1, oxb = (w & 1) * 32;
  for (int i = threadIdx.x; i < 1056; i += 256) {  // 264 entries * 4 parts
    const int part = i & 3, e = i >> 2;
    const int col = e % 66, r = e / 66;
    const int iy = 2*q - 1 + r, ix = col - 1;
    short8 v = (short8)(short)0;
    if (iy >= 0 && iy < 64 && ix >= 0 && ix < 64) {
      const float* p = in + (((long)((n*64 + iy)*64 + ix)) * 32 + part*8);
      const f32x4 f0 = *(const f32x4*)p;
      const f32x4 f1 = *(const f32x4*)(p + 4);
      #pragma unroll
      for (int e2 = 0; e2 < 4; ++e2) {
        v[e2]     = (short)f2b(f0[e2]);
        v[e2 + 4] = (short)f2b(f1[e2]);
      }
    }
    *(short8*)&IL[e*40 + part*8] = v;
  }
  const unsigned short* wb = wv + l*8;             // + (tap*8+ni)*512
  int Wd[3];
  #pragma unroll
  for (int kx = 0; kx < 3; ++kx)
    Wd[kx] = row*5280 + (oxb + lm + kx)*80 + lk*16;   // bytes
  __syncthreads();
  f32x4 acc[2][8];
  #pragma unroll
  for (int mi = 0; mi < 2; ++mi)
    #pragma unroll
    for (int ni = 0; ni < 8; ++ni) acc[mi][ni] = (f32x4)0.0f;
  #pragma unroll
  for (int tap = 0; tap < 9; ++tap) {
    const int ky = tap / 3, kx = tap % 3;
    short8 bv[8];
    #pragma unroll
    for (int ni = 0; ni < 8; ++ni)
      bv[ni] = *(const short8*)(wb + (tap*8 + ni)*512);
    const char* Ab = (const char*)IL + Wd[kx];
    const int imm0 = ky*5280;
    #pragma unroll
    for (int mi = 0; mi < 2; ++mi) {
      const short8 av = *(const short8*)(Ab + imm0 + mi*1280);
      #pragma unroll
      for (int ni = 0; ni < 8; ++ni)
        acc[mi][ni] = __builtin_amdgcn_mfma_f32_16x16x32_bf16(
            __builtin_bit_cast(bf16x8, av),
            __builtin_bit_cast(bf16x8, bv[ni]),
            acc[mi][ni], 0, 0, 0);
    }
  }
  // coalesced epilogue: 2 row passes, PB[64 ox][144 shorts] over IL (18432 B)
  short* PB = (short*)IL;
  #pragma unroll
  for (int rp = 0; rp < 2; ++rp) {
    __syncthreads();                   // IL reads / prior pass reads done
    if (row == rp) {
      #pragma unroll
      for (int mi = 0; mi < 2; ++mi)
        #pragma unroll
        for (int r = 0; r < 4; ++r) {
          const int ox = oxb + mi*16 + lk*4 + r;
          #pragma unroll
          for (int ni = 0; ni < 8; ++ni) {
            const int co = ni*16 + lm;
            PB[ox*144 + co] = (short)f2b(fmaxf(acc[mi][ni][r] + bias[co], 0.f));
          }
        }
    }
    __syncthreads();
    const int pos = threadIdx.x >> 2, coq = (threadIdx.x & 3) << 5;
    const long ob = ((long)((n*64 + 2*q + rp)*64 + pos))*128 + coq;
    #pragma unroll
    for (int u2 = 0; u2 < 4; ++u2)
      *(short8*)&out[ob + u2*8] = *(const short8*)&PB[pos*144 + coq + u2*8];
  }
}

// ---- d2 convT via two-phase merged-parity MFMA + async stage: d1 -> d2 -----
#define CT2_LOAD(c) \
  _Pragma("unroll") \
  for (int s = 0; s < 7; ++s) { \
    st[s] = (short8)(short)0; \
    if (goff[s] >= 0) st[s] = *(const short8*)(in + goff[s] + (c)*64); \
  }
#define CT2_WRITE \
  _Pragma("unroll") \
  for (int s = 0; s < 7; ++s) \
    if (lb[s] >= 0) *(short8*)((char*)IL + lb[s]) = st[s];
#define CT2_COMPUTE(c) \
  _Pragma("unroll") \
  for (int u = 0; u < 8; ++u) { \
    const int a = u >> 2, b = (u >> 1) & 1, c1 = u & 1; \
    const int ks = (a << 3) | (b << 2) | (2*(c) + c1); \
    short8 bv[4]; \
    _Pragma("unroll") \
    for (int ni = 0; ni < 4; ++ni) \
      bv[ni] = *(const short8*)(wb + ks*2048 + ni*512); \
    const char* Ab = (const char*)IL + (pyb + Wb[b][c1]); \
    const int imm0 = a*8448; \
    _Pragma("unroll") \
    for (int mi = 0; mi < 4; ++mi) { \
      const short8 av = *(const short8*)(Ab + imm0 + mi*2048); \
      _Pragma("unroll") \
      for (int ni = 0; ni < 4; ++ni) \
        acc[mi][ni] = __builtin_amdgcn_mfma_f32_16x16x32_bf16( \
            __builtin_bit_cast(bf16x8, av), \
            __builtin_bit_cast(bf16x8, bv[ni]), \
            acc[mi][ni], 0, 0, 0); \
    } \
  }
__global__ __launch_bounds__(256) void convt2m_k(const unsigned short* __restrict__ in,
    const unsigned short* __restrict__ wv, const float* __restrict__ bias,
    unsigned short* __restrict__ out) {
  __shared__ short IL[3*66*64];        // [r*66+col][ci_local 32+32], 25344 B
  const int wid = (blockIdx.x & 7)*256 + (blockIdx.x >> 3);
  const int q = wid & 63, n = wid >> 6;
  const int w = threadIdx.x >> 6, l = threadIdx.x & 63;
  const int py = w >> 1, px = w & 1;
  const int lm = l & 15, lk = l >> 4;
  int Wb[2][2];
  #pragma unroll
  for (int b = 0; b < 2; ++b) {
    const int e = lm + px + b;
    Wb[b][0] = (e << 7) + ((lk << 4) ^ ((e & 7) << 4));
    Wb[b][1] = Wb[b][0] ^ 0x40;
  }
  const int pyb = py * 8448;                       // 66 entries * 128 B
  const unsigned short* wb = wv + w*32768 + l*8;   // + ks*2048 + ni*512
  int goff[7], lb[7];
  #pragma unroll
  for (int s = 0; s < 7; ++s) {
    const int i = threadIdx.x + s*256;
    const int part = i & 7, e = i >> 3;
    const int col = e % 66, r = e / 66;
    const int iy = q - 1 + r, ix = col - 1;
    const bool ok = (i < 1584) && iy >= 0 && iy < 64 && ix >= 0 && ix < 64;
    goff[s] = ok ? (((n*64 + iy)*64 + ix)*128 + part*8) : -1;
    lb[s]   = (i < 1584) ? ((e << 7) + ((part << 4) ^ ((col & 7) << 4))) : -1;
  }
  f32x4 acc[4][4];
  #pragma unroll
  for (int mi = 0; mi < 4; ++mi)
    #pragma unroll
    for (int ni = 0; ni < 4; ++ni) acc[mi][ni] = (f32x4)0.0f;
  short8 st[7];
  CT2_LOAD(0); CT2_WRITE;
  __syncthreads();
  CT2_LOAD(1);
  CT2_COMPUTE(0);
  __syncthreads();
  CT2_WRITE;
  __syncthreads();
  CT2_COMPUTE(1);
  // coalesced epilogue: 2 co-half passes, PB[256 pos][40 shorts] (20480 B)
  short* PB = (short*)IL;
  #pragma unroll
  for (int half = 0; half < 2; ++half) {
    __syncthreads();                   // IL reads / prior pass reads done
    #pragma unroll
    for (int mi = 0; mi < 4; ++mi)
      #pragma unroll
      for (int r = 0; r < 4; ++r) {
        const int ox = 2*(mi*16 + lk*4 + r) + px;
        const int pos = py*128 + ox;
        #pragma unroll
        for (int nn = 0; nn < 2; ++nn) {
          const int co = (half*2 + nn)*16 + lm;
          PB[pos*40 + (co & 31)] =
              (short)f2b(fmaxf(acc[mi][half*2 + nn][r] + bias[co], 0.f));
        }
      }
    __syncthreads();
    const int pos = threadIdx.x;
    const long ob = ((long)((n*128 + 2*q + (pos >> 7))*128 + (pos & 127)))*64
                    + half*32;
    #pragma unroll
    for (int u2 = 0; u2 < 4; ++u2)
      *(short8*)&out[ob + u2*8] = *(const short8*)&PB[pos*40 + u2*8];
  }
}

__global__ __launch_bounds__(256) void loss_k(const float* __restrict__ part,
                                              float* __restrict__ out) {
  __shared__ float red[256];
  const int t = threadIdx.x;
  float s = 0.f;
  #pragma unroll
  for (int q = 0; q < 4; ++q) s += part[t + q*256];   // 1024 partials
  red[t] = s; __syncthreads();
  for (int st = 128; st > 0; st >>= 1) {
    if (t < st) red[t] += red[t + st];
    __syncthreads();
  }
  if (t == 0) out[0] = red[0] * (1.25f / (131072.f * 32.f));
}

// ---- convt3 via MFMA: d2 NHWC bf16 [32,128,128,64] -> x_recon NCHW fp32 ----
__global__ __launch_bounds__(256) void convt3m_k(const unsigned short* __restrict__ in,
    const unsigned short* __restrict__ wq6, const float* __restrict__ bias,
    float* __restrict__ out) {
  __shared__ short8 IL[3*8*66];      // [(r*8+c8)*66 + ixl], 25344 B
  const int h = blockIdx.x & 1, q = (blockIdx.x >> 1) & 127, n = blockIdx.x >> 8;
  for (int i = threadIdx.x; i < 1584; i += 256) {   // 3*66*8
    const int c8 = i & 7, t = i >> 3, ixl = t % 66, r = t / 66;
    const int iy = q - 1 + r, ix = h*64 - 1 + ixl;
    short8 v = (short8)(short)0;
    if (iy >= 0 && iy < 128 && ix >= 0 && ix < 128)
      v = *(const short8*)(in + (((long)(n*128 + iy)*128 + ix)*64 + c8*8));
    IL[(r*8 + c8)*66 + ixl] = v;
  }
  const int w = threadIdx.x >> 6, l = threadIdx.x & 63;
  const int py = w >> 1, px = w & 1;
  const int lm = l & 15, lk = l >> 4;
  short8 bfrag[8];
  #pragma unroll
  for (int kc = 0; kc < 8; ++kc)
    bfrag[kc] = *(const short8*)(wq6 + (((w*8 + kc)*64 + l) << 3));
  __syncthreads();
  f32x4 acc[4];
  #pragma unroll
  for (int mi = 0; mi < 4; ++mi) acc[mi] = (f32x4)0.0f;
  #pragma unroll
  for (int kc = 0; kc < 8; ++kc) {
    const int a = kc >> 2, b = (kc >> 1) & 1, ch = kc & 1;
    const int base = (((py + a)*8 + ch*4 + lk)*66) + px + b;   // + ixl(xq)
    #pragma unroll
    for (int mi = 0; mi < 4; ++mi) {
      const short8 av = *(const short8*)&IL[base + mi*16 + lm];
      acc[mi] = __builtin_amdgcn_mfma_f32_16x16x32_bf16(
          __builtin_bit_cast(bf16x8, av),
          __builtin_bit_cast(bf16x8, bfrag[kc]),
          acc[mi], 0, 0, 0);
    }
  }
  // coalesced epilogue via LDS (768 floats over IL)
  __syncthreads();                     // IL reads done
  float* PB3 = (float*)IL;
  if (lm < 3) {
    const float bv = bias[lm];
    #pragma unroll
    for (int mi = 0; mi < 4; ++mi)
      #pragma unroll
      for (int r = 0; r < 4; ++r) {
        const int xq = mi*16 + lk*4 + r;
        PB3[(lm*2 + py)*128 + 2*xq + px] = acc[mi][r] + bv;
      }
  }
  __syncthreads();
  for (int t = threadIdx.x; t < 768; t += 256) {
    const int co = t >> 8, rem = t & 255, pyl = rem >> 7, xx = rem & 127;
    out[((long)(n*3 + co))*65536 + (2*q + pyl)*256 + h*128 + xx] = PB3[t];
  }
}

extern "C" void kernel_launch(void* const* d_in, const int* in_sizes, int n_in,
                              void* d_out, int out_size, void* d_ws, size_t ws_size,
                              hipStream_t stream) {
  const float* x   = (const float*)d_in[0];
  const float* ew1 = (const float*)d_in[1];  const float* eb1 = (const float*)d_in[2];
  const float* ew2 = (const float*)d_in[3];  const float* eb2 = (const float*)d_in[4];
  const float* ew3 = (const float*)d_in[5];  const float* eb3 = (const float*)d_in[6];
  const float* emb = (const float*)d_in[7];
  const float* dw1 = (const float*)d_in[8];  const float* db1 = (const float*)d_in[9];
  const float* dw2 = (const float*)d_in[10]; const float* db2 = (const float*)d_in[11];
  const float* dw3 = (const float*)d_in[12]; const float* db3 = (const float*)d_in[13];
  float* out = (float*)d_out;

  uint8_t* w8 = (uint8_t*)d_ws;
  unsigned short* h1 = (unsigned short*)w8;
  unsigned short* h2 = (unsigned short*)(w8 + 67108864);
  uint8_t* zr = w8 + 100663296;
  float* zq  = (float*)(w8 + 117440512);
  unsigned short* wqe = (unsigned short*)zr;                  // 32768 B
  float* eng = (float*)(zr + 32768);                          // 2048 B
  float* part = (float*)(zr + 36864);                         // 4096 B
  unsigned short* wq3 = (unsigned short*)(zr + 40960);        // 73728 B
  unsigned short* wq4 = (unsigned short*)(zr + 131072);       // 73728 B
  unsigned short* wq5 = (unsigned short*)(zr + 262144);       // 262144 B
  unsigned short* wq6 = (unsigned short*)(zr + 524288);       // 32768 B
  unsigned short* wq2 = (unsigned short*)(w8 + 117440512);            // 262144 B
  unsigned short* wq1 = (unsigned short*)(w8 + 117440512 + 335872);   // 8192 B
  unsigned short* d1 = h2;
  unsigned short* d2 = h1;

  // all weight/embed prep in one launch
  prepall_k<<<dim3(1456),256,0,stream>>>(ew1, ew2, ew3, dw1, dw2, dw3, emb,
                                         wq1, wq2, wq3, wq4, wq5, wq6, wqe, eng);
  // encoder + fused VQ
  conv1m_k<<<dim3(4096),256,0,stream>>>(x, wq1, eb1, h1);
  conv2m_k<<<dim3(2048),256,0,stream>>>(h1, wq2, eb2, h2);
  conv3v_k<<<dim3(1024),256,0,stream>>>(h2, wq3, eb3, wqe, eng, emb, zq, part);
  loss_k<<<dim3(1),256,0,stream>>>(part, out + 6291456);
  // decoder
  d1m_k<<<dim3(1024),256,0,stream>>>(zq, wq4, db1, d1);
  convt2m_k<<<dim3(2048),256,0,stream>>>(d1, wq5, db2, d2);
  convt3m_k<<<dim3(8192),256,0,stream>>>(d2, wq6, db3, out);
}

// Round 11
// 339.701 us; speedup vs baseline: 1.5250x; 1.0025x over previous
//
#include <hip/hip_runtime.h>

// VQ-VAE forward, MI355X round 21: R20 + convt2m rebuilt as q-pair / 8-wave
// (512-thread) blocks: wave=(qi,parity), 4-row halo staged once serves two
// output row-pairs; per-wave regs unchanged; 4 blocks/CU (thread-cap max).

typedef __attribute__((ext_vector_type(8))) short     short8;
typedef __attribute__((ext_vector_type(4))) short     s16x4;
typedef __attribute__((ext_vector_type(8))) __bf16    bf16x8;
typedef __attribute__((ext_vector_type(4))) float     f32x4;
typedef __attribute__((ext_vector_type(4))) unsigned  uint32x4;

__device__ __forceinline__ float b2f(unsigned short b) {
  union { unsigned u; float f; } v; v.u = ((unsigned)b) << 16; return v.f;
}
__device__ __forceinline__ unsigned short f2b(float f) {  // round-to-nearest-even
  union { float f; unsigned u; } v; v.f = f;
  unsigned r = v.u + 0x7FFF + ((v.u >> 16) & 1);
  return (unsigned short)(r >> 16);
}

// ---------------- fused weight/embed prep (all layers, 1 launch) ------------
__global__ __launch_bounds__(256) void prepall_k(
    const float* __restrict__ ew1, const float* __restrict__ ew2,
    const float* __restrict__ ew3, const float* __restrict__ dw1,
    const float* __restrict__ dw2, const float* __restrict__ dw3,
    const float* __restrict__ emb,
    unsigned short* __restrict__ wq1, unsigned short* __restrict__ wq2,
    unsigned short* __restrict__ wq3, unsigned short* __restrict__ wq4,
    unsigned short* __restrict__ wq5, unsigned short* __restrict__ wq6,
    unsigned short* __restrict__ wqe, float* __restrict__ eng) {
  const int b = blockIdx.x;
  if (b < 64) {                                   // prepe: 16384
    const int i = b*256 + threadIdx.x;
    const int j = i & 7, l = (i >> 3) & 63, ni = (i >> 9) & 3, nc = i >> 11;
    const int lm = l & 15, lk = l >> 4;
    wqe[i] = f2b(emb[(nc*64 + ni*16 + lm)*32 + lk*8 + j]);
    if (i < 512) {
      float s = 0.f;
      #pragma unroll
      for (int k = 0; k < 32; ++k) {
        const float f = b2f(f2b(emb[i*32 + k]));
        s = fmaf(f, f, s);
      }
      eng[i] = s;
    }
  } else if (b < 80) {                            // prep1v: 4096
    const int i = (b - 64)*256 + threadIdx.x;
    const int j = i & 7, l = (i >> 3) & 63, ni = (i >> 9) & 3, ks = i >> 11;
    const int k = ks*32 + (l >> 4)*8 + j;
    const int co = ni*16 + (l & 15);
    wq1[i] = (k < 48) ? f2b(ew1[co*48 + k]) : (unsigned short)0;
  } else if (b < 592) {                           // prep2v: 131072
    const int i = (b - 80)*256 + threadIdx.x;
    const int j = i & 7, l = (i >> 3) & 63, ni = (i >> 9) & 7, ks = i >> 12;
    const int lm = l & 15, lk = l >> 4;
    const int tap = ks >> 1, cc = ks & 1;
    const int co = ni*16 + lm, ci = cc*32 + lk*8 + j;
    wq2[i] = f2b(ew2[(co*64 + ci)*16 + tap]);
  } else if (b < 736) {                           // prep3v: 36864
    const int i = (b - 592)*256 + threadIdx.x;
    const int j = i & 7, l = (i >> 3) & 63, ni = (i >> 9) & 1, ks = i >> 10;
    const int lm = l & 15, lk = l >> 4;
    const int tap = ks >> 2, cf = ks & 3;
    const int co = ni*16 + lm, ci = cf*32 + lk*8 + j;
    wq3[i] = f2b(ew3[(co*128 + ci)*9 + tap]);
  } else if (b < 880) {                           // prep4v: 36864
    const int i = (b - 736)*256 + threadIdx.x;
    const int j = i & 7, l = (i >> 3) & 63, ni = (i >> 9) & 7, tap = i >> 12;
    const int lm = l & 15, lk = l >> 4;
    const int co = ni*16 + lm, ci = lk*8 + j;
    wq4[i] = f2b(dw1[(ci*128 + co)*9 + (8 - tap)]);
  } else if (b < 1392) {                          // prep5v: 131072
    const int i = (b - 880)*256 + threadIdx.x;
    const int j = i & 7, l = (i >> 3) & 63, ni = (i >> 9) & 3;
    const int ks = (i >> 11) & 15, p = i >> 15;
    const int lm = l & 15, lk = l >> 4;
    const int py = p >> 1, px = p & 1;
    const int a = ks >> 3, bb = (ks >> 2) & 1, cc = ks & 3;
    const int co = ni*16 + lm, ci = cc*32 + lk*8 + j;
    const int ky = 3 - 2*a - py, kx = 3 - 2*bb - px;
    wq5[i] = f2b(dw2[(ci*64 + co)*16 + ky*4 + kx]);
  } else {                                        // prep6: 16384
    const int i = (b - 1392)*256 + threadIdx.x;
    const int j = i & 7, l = (i >> 3) & 63, kc = (i >> 9) & 7, p = i >> 12;
    const int lm = l & 15, lk = l >> 4;
    const int a = kc >> 2, bb = (kc >> 1) & 1, ch = kc & 1;
    const int ci = ch*32 + lk*8 + j, co = lm;
    const int py = p >> 1, px = p & 1;
    const int ky = 2 - 2*a + (1 - py), kx = 2 - 2*bb + (1 - px);
    wq6[i] = (co < 3) ? f2b(dw3[(ci*3 + co)*16 + ky*4 + kx]) : (unsigned short)0;
  }
}

// ---- conv1 via MFMA: x NCHW fp32 [32,3,256,256] -> h1 NHWC bf16 ------------
__global__ __launch_bounds__(256) void conv1m_k(const float* __restrict__ x,
    const unsigned short* __restrict__ wv, const float* __restrict__ bias,
    unsigned short* __restrict__ out) {
  __shared__ __align__(16) short RAW[12*264];   // row g=ci*4+ky, idx=ix+4; 6336B
  __shared__ __align__(16) short IC[128*64];    // [ox][k] swizzled; 16384B
  const int wid = ((blockIdx.x & 7) << 9) + (blockIdx.x >> 3);
  const int q = wid & 127, n = wid >> 7;        // q = output row oy
  for (int i = threadIdx.x; i < 396; i += 256)
    *(short8*)&RAW[i*8] = (short8)(short)0;
  __syncthreads();
  for (int s = threadIdx.x; s < 768; s += 256) {   // 12 rows * 64 f32x4
    const int g = s >> 6, seg = s & 63;
    const int ci = g >> 2, ky = g & 3;
    const int iy = 2*q - 1 + ky;
    if (iy >= 0 && iy < 256) {
      const f32x4 v = *(const f32x4*)&x[((n*3 + ci)*256 + iy)*256 + seg*4];
      s16x4 sv;
      #pragma unroll
      for (int e = 0; e < 4; ++e) sv[e] = (short)f2b(v[e]);
      *(s16x4*)&RAW[g*264 + 4 + seg*4] = sv;
    }
  }
  __syncthreads();
  for (int s = threadIdx.x; s < 1024; s += 256) {
    const int kb = s & 7, ox = s >> 3;
    short8 v = (short8)(short)0;
    if (kb < 6) {
      const unsigned* u0 = (const unsigned*)&RAW[(2*kb  )*264 + 2*ox + 2];
      const unsigned* u1 = (const unsigned*)&RAW[(2*kb+1)*264 + 2*ox + 2];
      const unsigned a0 = u0[0], a1 = u0[1], a2 = u0[2];
      const unsigned b0 = u1[0], b1 = u1[1], b2 = u1[2];
      uint32x4 uv;
      uv[0] = (a0 >> 16) | (a1 << 16);
      uv[1] = (a1 >> 16) | (a2 << 16);
      uv[2] = (b0 >> 16) | (b1 << 16);
      uv[3] = (b1 >> 16) | (b2 << 16);
      v = __builtin_bit_cast(short8, uv);
    }
    const int bo = ((ox << 7) + (kb << 4)) ^ ((ox & 7) << 4);
    *(short8*)((char*)IC + bo) = v;
  }
  __syncthreads();
  const int w = threadIdx.x >> 6, l = threadIdx.x & 63;
  const int lm = l & 15, lk = l >> 4;
  f32x4 acc[2][4];
  #pragma unroll
  for (int mi = 0; mi < 2; ++mi)
    #pragma unroll
    for (int ni = 0; ni < 4; ++ni) acc[mi][ni] = (f32x4)0.0f;
  #pragma unroll
  for (int ks = 0; ks < 2; ++ks) {
    short8 bv[4];
    #pragma unroll
    for (int ni = 0; ni < 4; ++ni)
      bv[ni] = *(const short8*)(wv + (((ks*4 + ni)*64 + l) << 3));
    #pragma unroll
    for (int mi = 0; mi < 2; ++mi) {
      const int ox = w*32 + mi*16 + lm;
      const int bo = ((ox << 7) + (ks << 6) + (lk << 4)) ^ ((ox & 7) << 4);
      const short8 av = *(const short8*)((const char*)IC + bo);
      #pragma unroll
      for (int ni = 0; ni < 4; ++ni)
        acc[mi][ni] = __builtin_amdgcn_mfma_f32_16x16x32_bf16(
            __builtin_bit_cast(bf16x8, av),
            __builtin_bit_cast(bf16x8, bv[ni]),
            acc[mi][ni], 0, 0, 0);
    }
  }
  __syncthreads();            // frag reads done; reuse IC for output staging
  #pragma unroll
  for (int mi = 0; mi < 2; ++mi)
    #pragma unroll
    for (int ni = 0; ni < 4; ++ni) {
      const int co = ni*16 + lm;
      const float bv = bias[co];
      #pragma unroll
      for (int r = 0; r < 4; ++r) {
        const int ox = w*32 + mi*16 + lk*4 + r;
        const int bo = ((ox << 7) + 2*co) ^ ((ox & 7) << 4);
        *(short*)((char*)IC + bo) = (short)f2b(fmaxf(acc[mi][ni][r] + bv, 0.f));
      }
    }
  __syncthreads();
  const long ob = ((long)(n*128 + q)) * 8192;   // 128 ox * 64 co
  for (int s = threadIdx.x; s < 1024; s += 256) {
    const int kb = s & 7, ox = s >> 3;
    const int bo = ((ox << 7) + (kb << 4)) ^ ((ox & 7) << 4);
    *(short8*)&out[ob + ox*64 + kb*8] = *(const short8*)((const char*)IC + bo);
  }
}

// ---- conv2 via two-phase MFMA + async stage: h1 -> h2 ----------------------
#define C2_LOAD(c) \
  _Pragma("unroll") \
  for (int s = 0; s < 9; ++s) { \
    st[s] = (short8)(short)0; \
    if (goff[s] >= 0) st[s] = *(const short8*)(in + goff[s] + (c)*32); \
  }
#define C2_WRITE \
  _Pragma("unroll") \
  for (int s = 0; s < 9; ++s) \
    if (lb[s] >= 0) *(short8*)((char*)IL + lb[s]) = st[s];
#define C2_COMPUTE(c) \
  _Pragma("unroll") \
  for (int t = 0; t < 16; ++t) { \
    const int ky = t >> 2, kx = t & 3; \
    const int p = 1 - (kx & 1), d = kx >> 1; \
    const short8 bv0 = *(const short8*)(wb + (t*2 + (c))*4096); \
    const short8 bv1 = *(const short8*)(wb + (t*2 + (c))*4096 + 512); \
    const char* Ab = (const char*)IL + (Bd0 + d*64); \
    const int imm0 = ((ky*2 + p)*66) << 6; \
    _Pragma("unroll") \
    for (int mi = 0; mi < 4; ++mi) { \
      const short8 av = *(const short8*)(Ab + imm0 + mi*1024); \
      acc[mi][0] = __builtin_amdgcn_mfma_f32_16x16x32_bf16( \
          __builtin_bit_cast(bf16x8, av), __builtin_bit_cast(bf16x8, bv0), \
          acc[mi][0], 0, 0, 0); \
      acc[mi][1] = __builtin_amdgcn_mfma_f32_16x16x32_bf16( \
          __builtin_bit_cast(bf16x8, av), __builtin_bit_cast(bf16x8, bv1), \
          acc[mi][1], 0, 0, 0); \
    } \
  }
__global__ __launch_bounds__(256) void conv2m_k(const unsigned short* __restrict__ in,
    const unsigned short* __restrict__ wv, const float* __restrict__ bias,
    unsigned short* __restrict__ out) {
  __shared__ short IL[8*66*32];        // [(r*2+p)*66+idx][ci_local 32], 33792 B
  const int wid = (blockIdx.x & 7)*256 + (blockIdx.x >> 3);
  const int q = wid & 63, n = wid >> 6;          // q = output row oy
  const int w = threadIdx.x >> 6, l = threadIdx.x & 63;
  const int lm = l & 15, lk = l >> 4;
  const int Bd0 = lm*64 + lk*16;                 // A-read byte base, d=0
  const unsigned short* wb = wv + w*1024 + l*8;  // + ks*4096 (+512 for ni=1)
  int goff[9], lb[9];
  #pragma unroll
  for (int s = 0; s < 9; ++s) {
    const int i = threadIdx.x + s*256;
    const int part = i & 3, e = i >> 2;
    const int idx = e % 66, rp = e / 66;
    const int r = rp >> 1, p = rp & 1;
    const int iy = 2*q - 1 + r, ix = 2*idx - p;
    const bool ok = (i < 2112) && iy >= 0 && iy < 128 && ix >= 0 && ix < 128;
    goff[s] = ok ? (((n*128 + iy)*128 + ix)*64 + part*8) : -1;
    lb[s]   = (i < 2112) ? (e*64 + part*16) : -1;
  }
  f32x4 acc[4][2];
  #pragma unroll
  for (int mi = 0; mi < 4; ++mi)
    #pragma unroll
    for (int ni = 0; ni < 2; ++ni) acc[mi][ni] = (f32x4)0.0f;
  short8 st[9];
  C2_LOAD(0); C2_WRITE;
  __syncthreads();
  C2_LOAD(1);                          // issue phase-1 loads (in flight)
  C2_COMPUTE(0);
  __syncthreads();                     // phase-0 LDS reads done
  C2_WRITE;                            // waits vmcnt for st, writes LDS
  __syncthreads();
  C2_COMPUTE(1);
  // coalesced epilogue: PB[64 ox][144 shorts] over IL (18432 B)
  __syncthreads();                     // compute(1) IL reads done
  short* PB = (short*)IL;
  #pragma unroll
  for (int mi = 0; mi < 4; ++mi)
    #pragma unroll
    for (int r = 0; r < 4; ++r) {
      const int ox = mi*16 + lk*4 + r;
      #pragma unroll
      for (int ni = 0; ni < 2; ++ni) {
        const int co = (w*2 + ni)*16 + lm;
        PB[ox*144 + co] = (short)f2b(fmaxf(acc[mi][ni][r] + bias[co], 0.f));
      }
    }
  __syncthreads();
  {
    const int pos = threadIdx.x >> 2, coq = (threadIdx.x & 3) << 5;
    const long ob = ((long)((n*64 + q)*64 + pos))*128 + coq;
    #pragma unroll
    for (int u2 = 0; u2 < 4; ++u2)
      *(short8*)&out[ob + u2*8] = *(const short8*)&PB[pos*144 + coq + u2*8];
  }
}

// ---- conv3 + fused VQ: h2 NHWC bf16 [32,64,64,128] -> zq f32 + loss --------
#define C3_LOAD(c) \
  _Pragma("unroll") \
  for (int s = 0; s < 9; ++s) { \
    st[s] = (short8)(short)0; \
    if (goff[s] >= 0) st[s] = *(const short8*)(in + goff[s] + (c)*64); \
  }
#define C3_WRITE \
  _Pragma("unroll") \
  for (int s = 0; s < 9; ++s) \
    if (lb[s] >= 0) *(short8*)((char*)IL + lb[s]) = st[s];
#define C3_COMPUTE(c) \
  _Pragma("unroll") \
  for (int u = 0; u < 18; ++u) { \
    const int tap = u >> 1, cc = u & 1; \
    const int ky = tap / 3, kx = tap % 3; \
    const int ks = tap*4 + (c)*2 + cc; \
    const short8 bv0 = *(const short8*)(wb + ks*1024); \
    const short8 bv1 = *(const short8*)(wb + ks*1024 + 512); \
    const char* Ab = (const char*)IL + (Wc[kx][cc]); \
    const int imm0 = ky*8448; \
    _Pragma("unroll") \
    for (int mi = 0; mi < 2; ++mi) { \
      const short8 av = *(const short8*)(Ab + imm0 + mi*2048); \
      acc[mi][0] = __builtin_amdgcn_mfma_f32_16x16x32_bf16( \
          __builtin_bit_cast(bf16x8, av), __builtin_bit_cast(bf16x8, bv0), \
          acc[mi][0], 0, 0, 0); \
      acc[mi][1] = __builtin_amdgcn_mfma_f32_16x16x32_bf16( \
          __builtin_bit_cast(bf16x8, av), __builtin_bit_cast(bf16x8, bv1), \
          acc[mi][1], 0, 0, 0); \
    } \
  }
__global__ __launch_bounds__(256) void conv3v_k(const unsigned short* __restrict__ in,
    const unsigned short* __restrict__ wv, const float* __restrict__ bias,
    const unsigned short* __restrict__ wqe, const float* __restrict__ eng,
    const float* __restrict__ emb, float* __restrict__ zq,
    float* __restrict__ part) {
  __shared__ short IL[4*66*64];        // 33792 B; unions below after compute
  const int wid = (blockIdx.x & 7)*128 + (blockIdx.x >> 3);
  const int q = wid & 31, n = wid >> 5;          // oy0 = 2q
  const int w = threadIdx.x >> 6, l = threadIdx.x & 63;
  const int lm = l & 15, lk = l >> 4;
  const int row = w >> 1, oxb = (w & 1) * 32;
  int goff[9], lb[9];
  #pragma unroll
  for (int s = 0; s < 9; ++s) {
    const int i = threadIdx.x + s*256;
    const int part_ = i & 7, e = i >> 3;
    const int col = e % 66, r = e / 66;
    const int iy = 2*q - 1 + r, ix = col - 1;
    const bool ok = (i < 2112) && iy >= 0 && iy < 64 && ix >= 0 && ix < 64;
    goff[s] = ok ? (((n*64 + iy)*64 + ix)*128 + part_*8) : -1;
    lb[s]   = (i < 2112) ? ((e << 7) + ((part_ << 4) ^ ((col & 7) << 4))) : -1;
  }
  int Wc[3][2];
  #pragma unroll
  for (int kx = 0; kx < 3; ++kx) {
    const int e = oxb + lm + kx;
    Wc[kx][0] = row*8448 + (e << 7) + ((lk << 4) ^ ((e & 7) << 4));
    Wc[kx][1] = Wc[kx][0] ^ 0x40;
  }
  const unsigned short* wb = wv + l*8;           // + ks*1024 + ni*512
  f32x4 acc[2][2];
  #pragma unroll
  for (int mi = 0; mi < 2; ++mi)
    #pragma unroll
    for (int ni = 0; ni < 2; ++ni) acc[mi][ni] = (f32x4)0.0f;
  short8 st[9];
  C3_LOAD(0); C3_WRITE;
  __syncthreads();
  C3_LOAD(1);
  C3_COMPUTE(0);
  __syncthreads();
  C3_WRITE;
  __syncthreads();
  C3_COMPUTE(1);
  // ---- fused VQ ----
  __syncthreads();                               // all IL reads done
  short* ZB  = (short*)IL;                       // [128][40] bf16, 10240 B
  float* ZF  = (float*)((char*)IL + 10240);      // [128][36] f32, 18432 B
  int*  bidx = (int*)((char*)IL + 28672);        // 128 ints
  float* red = (float*)((char*)IL + 29184);      // 256 floats
  #pragma unroll
  for (int mi = 0; mi < 2; ++mi)
    #pragma unroll
    for (int ni = 0; ni < 2; ++ni) {
      const int co = ni*16 + lm;
      const float bv = bias[co];
      #pragma unroll
      for (int r = 0; r < 4; ++r) {
        const int pos = row*64 + oxb + mi*16 + lk*4 + r;
        const float v = fmaxf(acc[mi][ni][r] + bv, 0.f);
        ZB[pos*40 + co] = (short)f2b(v);
        ZF[pos*36 + co] = v;
      }
    }
  __syncthreads();
  short8 av[2];
  #pragma unroll
  for (int mi = 0; mi < 2; ++mi)
    av[mi] = *(const short8*)&ZB[(row*64 + oxb + mi*16 + lm)*40 + lk*8];
  float bd[2][4]; int bj[2][4];
  #pragma unroll
  for (int mi = 0; mi < 2; ++mi)
    #pragma unroll
    for (int r = 0; r < 4; ++r) { bd[mi][r] = 1e30f; bj[mi][r] = 0; }
  for (int nc = 0; nc < 8; ++nc) {               // chunks of 64 codes
    f32x4 a2[2][4];
    #pragma unroll
    for (int mi = 0; mi < 2; ++mi)
      #pragma unroll
      for (int ni = 0; ni < 4; ++ni) a2[mi][ni] = (f32x4)0.0f;
    #pragma unroll
    for (int ni = 0; ni < 4; ++ni) {
      const short8 bv = *(const short8*)(wqe + (((nc*4 + ni)*64 + l) << 3));
      #pragma unroll
      for (int mi = 0; mi < 2; ++mi)
        a2[mi][ni] = __builtin_amdgcn_mfma_f32_16x16x32_bf16(
            __builtin_bit_cast(bf16x8, av[mi]),
            __builtin_bit_cast(bf16x8, bv),
            a2[mi][ni], 0, 0, 0);
    }
    #pragma unroll
    for (int ni = 0; ni < 4; ++ni) {
      const int j = nc*64 + ni*16 + lm;
      const float e_n = eng[j];
      #pragma unroll
      for (int mi = 0; mi < 2; ++mi)
        #pragma unroll
        for (int r = 0; r < 4; ++r) {
          const float d = fmaf(-2.f, a2[mi][ni][r], e_n);
          if (d < bd[mi][r]) { bd[mi][r] = d; bj[mi][r] = j; }
        }
    }
  }
  #pragma unroll
  for (int mi = 0; mi < 2; ++mi)
    #pragma unroll
    for (int r = 0; r < 4; ++r) {
      float d = bd[mi][r]; int j = bj[mi][r];
      #pragma unroll
      for (int off = 1; off < 16; off <<= 1) {
        const float od = __shfl_xor(d, off);
        const int   oj = __shfl_xor(j, off);
        if (od < d || (od == d && oj < j)) { d = od; j = oj; }
      }
      if (lm == 0) bidx[row*64 + oxb + mi*16 + lk*4 + r] = j;
    }
  __syncthreads();
  const int pl = threadIdx.x >> 1, hf = (threadIdx.x & 1) * 16;
  const int code = bidx[pl];
  const int oy2 = 2*q + (pl >> 6), ox2 = pl & 63;
  const long zqo = ((long)((n*64 + oy2)*64 + ox2)) * 32 + hf;
  float se = 0.f;
  #pragma unroll
  for (int qq = 0; qq < 4; ++qq) {
    const f32x4 ev = *(const f32x4*)&emb[code*32 + hf + qq*4];
    const f32x4 zv = *(const f32x4*)&ZF[pl*36 + hf + qq*4];
    *(f32x4*)&zq[zqo + qq*4] = ev;
    const f32x4 df = ev - zv;
    #pragma unroll
    for (int e = 0; e < 4; ++e) se = fmaf(df[e], df[e], se);
  }
  red[threadIdx.x] = se; __syncthreads();
  for (int s2 = 128; s2 > 0; s2 >>= 1) {
    if (threadIdx.x < s2) red[threadIdx.x] += red[threadIdx.x + s2];
    __syncthreads();
  }
  if (threadIdx.x == 0) part[blockIdx.x] = red[0];
}

// ---- d1 convT via MFMA: zq f32 [131072,32] -> d1 NHWC bf16 [32,64,64,128]
__global__ __launch_bounds__(256) void d1m_k(const float* __restrict__ in,
    const unsigned short* __restrict__ wv, const float* __restrict__ bias,
    unsigned short* __restrict__ out) {
  __shared__ short IL[264*40];         // [r*66+col][40-short stride], 21120 B
  const int wid = (blockIdx.x & 7)*128 + (blockIdx.x >> 3);
  const int q = wid & 31, n = wid >> 5;
  const int w = threadIdx.x >> 6, l = threadIdx.x & 63;
  const int lm = l & 15, lk = l >> 4;
  const int row = w >> 1, oxb = (w & 1) * 32;
  for (int i = threadIdx.x; i < 1056; i += 256) {  // 264 entries * 4 parts
    const int part = i & 3, e = i >> 2;
    const int col = e % 66, r = e / 66;
    const int iy = 2*q - 1 + r, ix = col - 1;
    short8 v = (short8)(short)0;
    if (iy >= 0 && iy < 64 && ix >= 0 && ix < 64) {
      const float* p = in + (((long)((n*64 + iy)*64 + ix)) * 32 + part*8);
      const f32x4 f0 = *(const f32x4*)p;
      const f32x4 f1 = *(const f32x4*)(p + 4);
      #pragma unroll
      for (int e2 = 0; e2 < 4; ++e2) {
        v[e2]     = (short)f2b(f0[e2]);
        v[e2 + 4] = (short)f2b(f1[e2]);
      }
    }
    *(short8*)&IL[e*40 + part*8] = v;
  }
  const unsigned short* wb = wv + l*8;             // + (tap*8+ni)*512
  int Wd[3];
  #pragma unroll
  for (int kx = 0; kx < 3; ++kx)
    Wd[kx] = row*5280 + (oxb + lm + kx)*80 + lk*16;   // bytes
  __syncthreads();
  f32x4 acc[2][8];
  #pragma unroll
  for (int mi = 0; mi < 2; ++mi)
    #pragma unroll
    for (int ni = 0; ni < 8; ++ni) acc[mi][ni] = (f32x4)0.0f;
  #pragma unroll
  for (int tap = 0; tap < 9; ++tap) {
    const int ky = tap / 3, kx = tap % 3;
    short8 bv[8];
    #pragma unroll
    for (int ni = 0; ni < 8; ++ni)
      bv[ni] = *(const short8*)(wb + (tap*8 + ni)*512);
    const char* Ab = (const char*)IL + Wd[kx];
    const int imm0 = ky*5280;
    #pragma unroll
    for (int mi = 0; mi < 2; ++mi) {
      const short8 av = *(const short8*)(Ab + imm0 + mi*1280);
      #pragma unroll
      for (int ni = 0; ni < 8; ++ni)
        acc[mi][ni] = __builtin_amdgcn_mfma_f32_16x16x32_bf16(
            __builtin_bit_cast(bf16x8, av),
            __builtin_bit_cast(bf16x8, bv[ni]),
            acc[mi][ni], 0, 0, 0);
    }
  }
  // coalesced epilogue: 2 row passes, PB[64 ox][144 shorts] over IL (18432 B)
  short* PB = (short*)IL;
  #pragma unroll
  for (int rp = 0; rp < 2; ++rp) {
    __syncthreads();                   // IL reads / prior pass reads done
    if (row == rp) {
      #pragma unroll
      for (int mi = 0; mi < 2; ++mi)
        #pragma unroll
        for (int r = 0; r < 4; ++r) {
          const int ox = oxb + mi*16 + lk*4 + r;
          #pragma unroll
          for (int ni = 0; ni < 8; ++ni) {
            const int co = ni*16 + lm;
            PB[ox*144 + co] = (short)f2b(fmaxf(acc[mi][ni][r] + bias[co], 0.f));
          }
        }
    }
    __syncthreads();
    const int pos = threadIdx.x >> 2, coq = (threadIdx.x & 3) << 5;
    const long ob = ((long)((n*64 + 2*q + rp)*64 + pos))*128 + coq;
    #pragma unroll
    for (int u2 = 0; u2 < 4; ++u2)
      *(short8*)&out[ob + u2*8] = *(const short8*)&PB[pos*144 + coq + u2*8];
  }
}

// ---- d2 convT: q-pair / 8-wave merged-parity MFMA + async stage ------------
//      d1 NHWC bf16 [32,64,64,128] -> d2 NHWC bf16 [32,128,128,64].
//      Block=(n, q-pair): stages input rows q0-1..q0+2 once (264x128B, XOR
//      swz); wave=(qi,parity) computes output row-pair 2(q0+qi)+py.
#define CT2_LOAD(c) \
  _Pragma("unroll") \
  for (int s = 0; s < 5; ++s) { \
    st[s] = (short8)(short)0; \
    if (goff[s] >= 0) st[s] = *(const short8*)(in + goff[s] + (c)*64); \
  }
#define CT2_WRITE \
  _Pragma("unroll") \
  for (int s = 0; s < 5; ++s) \
    if (lb[s] >= 0) *(short8*)((char*)IL + lb[s]) = st[s];
#define CT2_COMPUTE(c) \
  _Pragma("unroll") \
  for (int u = 0; u < 8; ++u) { \
    const int a = u >> 2, b = (u >> 1) & 1, c1 = u & 1; \
    const int ks = (a << 3) | (b << 2) | (2*(c) + c1); \
    short8 bv[4]; \
    _Pragma("unroll") \
    for (int ni = 0; ni < 4; ++ni) \
      bv[ni] = *(const short8*)(wb + ks*2048 + ni*512); \
    const char* Ab = (const char*)IL + (pyb + Wb[b][c1]); \
    const int imm0 = a*8448; \
    _Pragma("unroll") \
    for (int mi = 0; mi < 4; ++mi) { \
      const short8 av = *(const short8*)(Ab + imm0 + mi*2048); \
      _Pragma("unroll") \
      for (int ni = 0; ni < 4; ++ni) \
        acc[mi][ni] = __builtin_amdgcn_mfma_f32_16x16x32_bf16( \
            __builtin_bit_cast(bf16x8, av), \
            __builtin_bit_cast(bf16x8, bv[ni]), \
            acc[mi][ni], 0, 0, 0); \
    } \
  }
__global__ __launch_bounds__(512) void convt2m_k(const unsigned short* __restrict__ in,
    const unsigned short* __restrict__ wv, const float* __restrict__ bias,
    unsigned short* __restrict__ out) {
  __shared__ short IL[4*66*64];        // 264 entries x 128 B, 33792 B
  const int wid = (blockIdx.x & 7)*128 + (blockIdx.x >> 3);
  const int qp = wid & 31, n = wid >> 5;
  const int q0 = 2*qp;
  const int tid = threadIdx.x;
  const int w = tid >> 6, l = tid & 63;
  const int qi = w >> 2;
  const int py = (w >> 1) & 1, px = w & 1;
  const int lm = l & 15, lk = l >> 4;
  int Wb[2][2];
  #pragma unroll
  for (int b = 0; b < 2; ++b) {
    const int e = lm + px + b;
    Wb[b][0] = (e << 7) + ((lk << 4) ^ ((e & 7) << 4));
    Wb[b][1] = Wb[b][0] ^ 0x40;
  }
  const int pyb = (py + qi) * 8448;                // staged-row base
  const unsigned short* wb = wv + (w & 3)*32768 + l*8;   // parity weights
  int goff[5], lb[5];
  #pragma unroll
  for (int s = 0; s < 5; ++s) {
    const int i = tid + s*512;
    const int part = i & 7, e = i >> 3;
    const int col = e % 66, r = e / 66;
    const int iy = q0 - 1 + r, ix = col - 1;
    const bool ok = (i < 2112) && iy >= 0 && iy < 64 && ix >= 0 && ix < 64;
    goff[s] = ok ? (((n*64 + iy)*64 + ix)*128 + part*8) : -1;
    lb[s]   = (i < 2112) ? ((e << 7) + ((part << 4) ^ ((col & 7) << 4))) : -1;
  }
  f32x4 acc[4][4];
  #pragma unroll
  for (int mi = 0; mi < 4; ++mi)
    #pragma unroll
    for (int ni = 0; ni < 4; ++ni) acc[mi][ni] = (f32x4)0.0f;
  short8 st[5];
  CT2_LOAD(0); CT2_WRITE;
  __syncthreads();
  CT2_LOAD(1);                         // issue phase-1 loads (in flight)
  CT2_COMPUTE(0);
  __syncthreads();                     // phase-0 LDS reads done
  CT2_WRITE;                           // waits vmcnt, writes LDS
  __syncthreads();
  CT2_COMPUTE(1);
  // coalesced epilogue: 4 passes (qq x co-half), PB[256 pos][40 shorts]
  short* PB = (short*)IL;
  #pragma unroll
  for (int qq = 0; qq < 2; ++qq)
    #pragma unroll
    for (int half = 0; half < 2; ++half) {
      __syncthreads();                 // IL / prior-pass reads done
      if (qi == qq) {
        #pragma unroll
        for (int mi = 0; mi < 4; ++mi)
          #pragma unroll
          for (int r = 0; r < 4; ++r) {
            const int ox = 2*(mi*16 + lk*4 + r) + px;
            const int pos = py*128 + ox;
            #pragma unroll
            for (int nn = 0; nn < 2; ++nn) {
              const int co = (half*2 + nn)*16 + lm;
              PB[pos*40 + (co & 31)] =
                  (short)f2b(fmaxf(acc[mi][half*2 + nn][r] + bias[co], 0.f));
            }
          }
      }
      __syncthreads();
      const int pos = tid >> 1, hh = (tid & 1) << 4;
      const long ob = ((long)((n*128 + 2*(q0 + qq) + (pos >> 7))*128
                              + (pos & 127)))*64 + half*32 + hh;
      *(short8*)&out[ob]     = *(const short8*)&PB[pos*40 + hh];
      *(short8*)&out[ob + 8] = *(const short8*)&PB[pos*40 + hh + 8];
    }
}

__global__ __launch_bounds__(256) void loss_k(const float* __restrict__ part,
                                              float* __restrict__ out) {
  __shared__ float red[256];
  const int t = threadIdx.x;
  float s = 0.f;
  #pragma unroll
  for (int q = 0; q < 4; ++q) s += part[t + q*256];   // 1024 partials
  red[t] = s; __syncthreads();
  for (int st = 128; st > 0; st >>= 1) {
    if (t < st) red[t] += red[t + st];
    __syncthreads();
  }
  if (t == 0) out[0] = red[0] * (1.25f / (131072.f * 32.f));
}

// ---- convt3 via MFMA: d2 NHWC bf16 [32,128,128,64] -> x_recon NCHW fp32 ----
__global__ __launch_bounds__(256) void convt3m_k(const unsigned short* __restrict__ in,
    const unsigned short* __restrict__ wq6, const float* __restrict__ bias,
    float* __restrict__ out) {
  __shared__ short8 IL[3*8*66];      // [(r*8+c8)*66 + ixl], 25344 B
  const int h = blockIdx.x & 1, q = (blockIdx.x >> 1) & 127, n = blockIdx.x >> 8;
  for (int i = threadIdx.x; i < 1584; i += 256) {   // 3*66*8
    const int c8 = i & 7, t = i >> 3, ixl = t % 66, r = t / 66;
    const int iy = q - 1 + r, ix = h*64 - 1 + ixl;
    short8 v = (short8)(short)0;
    if (iy >= 0 && iy < 128 && ix >= 0 && ix < 128)
      v = *(const short8*)(in + (((long)(n*128 + iy)*128 + ix)*64 + c8*8));
    IL[(r*8 + c8)*66 + ixl] = v;
  }
  const int w = threadIdx.x >> 6, l = threadIdx.x & 63;
  const int py = w >> 1, px = w & 1;
  const int lm = l & 15, lk = l >> 4;
  short8 bfrag[8];
  #pragma unroll
  for (int kc = 0; kc < 8; ++kc)
    bfrag[kc] = *(const short8*)(wq6 + (((w*8 + kc)*64 + l) << 3));
  __syncthreads();
  f32x4 acc[4];
  #pragma unroll
  for (int mi = 0; mi < 4; ++mi) acc[mi] = (f32x4)0.0f;
  #pragma unroll
  for (int kc = 0; kc < 8; ++kc) {
    const int a = kc >> 2, b = (kc >> 1) & 1, ch = kc & 1;
    const int base = (((py + a)*8 + ch*4 + lk)*66) + px + b;   // + ixl(xq)
    #pragma unroll
    for (int mi = 0; mi < 4; ++mi) {
      const short8 av = *(const short8*)&IL[base + mi*16 + lm];
      acc[mi] = __builtin_amdgcn_mfma_f32_16x16x32_bf16(
          __builtin_bit_cast(bf16x8, av),
          __builtin_bit_cast(bf16x8, bfrag[kc]),
          acc[mi], 0, 0, 0);
    }
  }
  // coalesced epilogue via LDS (768 floats over IL)
  __syncthreads();                     // IL reads done
  float* PB3 = (float*)IL;
  if (lm < 3) {
    const float bv = bias[lm];
    #pragma unroll
    for (int mi = 0; mi < 4; ++mi)
      #pragma unroll
      for (int r = 0; r < 4; ++r) {
        const int xq = mi*16 + lk*4 + r;
        PB3[(lm*2 + py)*128 + 2*xq + px] = acc[mi][r] + bv;
      }
  }
  __syncthreads();
  for (int t = threadIdx.x; t < 768; t += 256) {
    const int co = t >> 8, rem = t & 255, pyl = rem >> 7, xx = rem & 127;
    out[((long)(n*3 + co))*65536 + (2*q + pyl)*256 + h*128 + xx] = PB3[t];
  }
}

extern "C" void kernel_launch(void* const* d_in, const int* in_sizes, int n_in,
                              void* d_out, int out_size, void* d_ws, size_t ws_size,
                              hipStream_t stream) {
  const float* x   = (const float*)d_in[0];
  const float* ew1 = (const float*)d_in[1];  const float* eb1 = (const float*)d_in[2];
  const float* ew2 = (const float*)d_in[3];  const float* eb2 = (const float*)d_in[4];
  const float* ew3 = (const float*)d_in[5];  const float* eb3 = (const float*)d_in[6];
  const float* emb = (const float*)d_in[7];
  const float* dw1 = (const float*)d_in[8];  const float* db1 = (const float*)d_in[9];
  const float* dw2 = (const float*)d_in[10]; const float* db2 = (const float*)d_in[11];
  const float* dw3 = (const float*)d_in[12]; const float* db3 = (const float*)d_in[13];
  float* out = (float*)d_out;

  uint8_t* w8 = (uint8_t*)d_ws;
  unsigned short* h1 = (unsigned short*)w8;
  unsigned short* h2 = (unsigned short*)(w8 + 67108864);
  uint8_t* zr = w8 + 100663296;
  float* zq  = (float*)(w8 + 117440512);
  unsigned short* wqe = (unsigned short*)zr;                  // 32768 B
  float* eng = (float*)(zr + 32768);                          // 2048 B
  float* part = (float*)(zr + 36864);                         // 4096 B
  unsigned short* wq3 = (unsigned short*)(zr + 40960);        // 73728 B
  unsigned short* wq4 = (unsigned short*)(zr + 131072);       // 73728 B
  unsigned short* wq5 = (unsigned short*)(zr + 262144);       // 262144 B
  unsigned short* wq6 = (unsigned short*)(zr + 524288);       // 32768 B
  unsigned short* wq2 = (unsigned short*)(w8 + 117440512);            // 262144 B
  unsigned short* wq1 = (unsigned short*)(w8 + 117440512 + 335872);   // 8192 B
  unsigned short* d1 = h2;
  unsigned short* d2 = h1;

  // all weight/embed prep in one launch
  prepall_k<<<dim3(1456),256,0,stream>>>(ew1, ew2, ew3, dw1, dw2, dw3, emb,
                                         wq1, wq2, wq3, wq4, wq5, wq6, wqe, eng);
  // encoder + fused VQ
  conv1m_k<<<dim3(4096),256,0,stream>>>(x, wq1, eb1, h1);
  conv2m_k<<<dim3(2048),256,0,stream>>>(h1, wq2, eb2, h2);
  conv3v_k<<<dim3(1024),256,0,stream>>>(h2, wq3, eb3, wqe, eng, emb, zq, part);
  loss_k<<<dim3(1),256,0,stream>>>(part, out + 6291456);
  // decoder
  d1m_k<<<dim3(1024),256,0,stream>>>(zq, wq4, db1, d1);
  convt2m_k<<<dim3(1024),512,0,stream>>>(d1, wq5, db2, d2);
  convt3m_k<<<dim3(8192),256,0,stream>>>(d2, wq6, db3, out);
}

// Round 12
// 339.285 us; speedup vs baseline: 1.5269x; 1.0012x over previous
//
#include <hip/hip_runtime.h>

// VQ-VAE forward, MI355X round 22: R21 + convt2m register diet: staging
// addresses recomputed inline (frees goff/lb arrays), __launch_bounds__(512,4)
// -> total regs <=128/wave -> 4 waves/SIMD (was 3). Same math, same schedule.

typedef __attribute__((ext_vector_type(8))) short     short8;
typedef __attribute__((ext_vector_type(4))) short     s16x4;
typedef __attribute__((ext_vector_type(8))) __bf16    bf16x8;
typedef __attribute__((ext_vector_type(4))) float     f32x4;
typedef __attribute__((ext_vector_type(4))) unsigned  uint32x4;

__device__ __forceinline__ float b2f(unsigned short b) {
  union { unsigned u; float f; } v; v.u = ((unsigned)b) << 16; return v.f;
}
__device__ __forceinline__ unsigned short f2b(float f) {  // round-to-nearest-even
  union { float f; unsigned u; } v; v.f = f;
  unsigned r = v.u + 0x7FFF + ((v.u >> 16) & 1);
  return (unsigned short)(r >> 16);
}

// ---------------- fused weight/embed prep (all layers, 1 launch) ------------
__global__ __launch_bounds__(256) void prepall_k(
    const float* __restrict__ ew1, const float* __restrict__ ew2,
    const float* __restrict__ ew3, const float* __restrict__ dw1,
    const float* __restrict__ dw2, const float* __restrict__ dw3,
    const float* __restrict__ emb,
    unsigned short* __restrict__ wq1, unsigned short* __restrict__ wq2,
    unsigned short* __restrict__ wq3, unsigned short* __restrict__ wq4,
    unsigned short* __restrict__ wq5, unsigned short* __restrict__ wq6,
    unsigned short* __restrict__ wqe, float* __restrict__ eng) {
  const int b = blockIdx.x;
  if (b < 64) {                                   // prepe: 16384
    const int i = b*256 + threadIdx.x;
    const int j = i & 7, l = (i >> 3) & 63, ni = (i >> 9) & 3, nc = i >> 11;
    const int lm = l & 15, lk = l >> 4;
    wqe[i] = f2b(emb[(nc*64 + ni*16 + lm)*32 + lk*8 + j]);
    if (i < 512) {
      float s = 0.f;
      #pragma unroll
      for (int k = 0; k < 32; ++k) {
        const float f = b2f(f2b(emb[i*32 + k]));
        s = fmaf(f, f, s);
      }
      eng[i] = s;
    }
  } else if (b < 80) {                            // prep1v: 4096
    const int i = (b - 64)*256 + threadIdx.x;
    const int j = i & 7, l = (i >> 3) & 63, ni = (i >> 9) & 3, ks = i >> 11;
    const int k = ks*32 + (l >> 4)*8 + j;
    const int co = ni*16 + (l & 15);
    wq1[i] = (k < 48) ? f2b(ew1[co*48 + k]) : (unsigned short)0;
  } else if (b < 592) {                           // prep2v: 131072
    const int i = (b - 80)*256 + threadIdx.x;
    const int j = i & 7, l = (i >> 3) & 63, ni = (i >> 9) & 7, ks = i >> 12;
    const int lm = l & 15, lk = l >> 4;
    const int tap = ks >> 1, cc = ks & 1;
    const int co = ni*16 + lm, ci = cc*32 + lk*8 + j;
    wq2[i] = f2b(ew2[(co*64 + ci)*16 + tap]);
  } else if (b < 736) {                           // prep3v: 36864
    const int i = (b - 592)*256 + threadIdx.x;
    const int j = i & 7, l = (i >> 3) & 63, ni = (i >> 9) & 1, ks = i >> 10;
    const int lm = l & 15, lk = l >> 4;
    const int tap = ks >> 2, cf = ks & 3;
    const int co = ni*16 + lm, ci = cf*32 + lk*8 + j;
    wq3[i] = f2b(ew3[(co*128 + ci)*9 + tap]);
  } else if (b < 880) {                           // prep4v: 36864
    const int i = (b - 736)*256 + threadIdx.x;
    const int j = i & 7, l = (i >> 3) & 63, ni = (i >> 9) & 7, tap = i >> 12;
    const int lm = l & 15, lk = l >> 4;
    const int co = ni*16 + lm, ci = lk*8 + j;
    wq4[i] = f2b(dw1[(ci*128 + co)*9 + (8 - tap)]);
  } else if (b < 1392) {                          // prep5v: 131072
    const int i = (b - 880)*256 + threadIdx.x;
    const int j = i & 7, l = (i >> 3) & 63, ni = (i >> 9) & 3;
    const int ks = (i >> 11) & 15, p = i >> 15;
    const int lm = l & 15, lk = l >> 4;
    const int py = p >> 1, px = p & 1;
    const int a = ks >> 3, bb = (ks >> 2) & 1, cc = ks & 3;
    const int co = ni*16 + lm, ci = cc*32 + lk*8 + j;
    const int ky = 3 - 2*a - py, kx = 3 - 2*bb - px;
    wq5[i] = f2b(dw2[(ci*64 + co)*16 + ky*4 + kx]);
  } else {                                        // prep6: 16384
    const int i = (b - 1392)*256 + threadIdx.x;
    const int j = i & 7, l = (i >> 3) & 63, kc = (i >> 9) & 7, p = i >> 12;
    const int lm = l & 15, lk = l >> 4;
    const int a = kc >> 2, bb = (kc >> 1) & 1, ch = kc & 1;
    const int ci = ch*32 + lk*8 + j, co = lm;
    const int py = p >> 1, px = p & 1;
    const int ky = 2 - 2*a + (1 - py), kx = 2 - 2*bb + (1 - px);
    wq6[i] = (co < 3) ? f2b(dw3[(ci*3 + co)*16 + ky*4 + kx]) : (unsigned short)0;
  }
}

// ---- conv1 via MFMA: x NCHW fp32 [32,3,256,256] -> h1 NHWC bf16 ------------
__global__ __launch_bounds__(256) void conv1m_k(const float* __restrict__ x,
    const unsigned short* __restrict__ wv, const float* __restrict__ bias,
    unsigned short* __restrict__ out) {
  __shared__ __align__(16) short RAW[12*264];   // row g=ci*4+ky, idx=ix+4; 6336B
  __shared__ __align__(16) short IC[128*64];    // [ox][k] swizzled; 16384B
  const int wid = ((blockIdx.x & 7) << 9) + (blockIdx.x >> 3);
  const int q = wid & 127, n = wid >> 7;        // q = output row oy
  for (int i = threadIdx.x; i < 396; i += 256)
    *(short8*)&RAW[i*8] = (short8)(short)0;
  __syncthreads();
  for (int s = threadIdx.x; s < 768; s += 256) {   // 12 rows * 64 f32x4
    const int g = s >> 6, seg = s & 63;
    const int ci = g >> 2, ky = g & 3;
    const int iy = 2*q - 1 + ky;
    if (iy >= 0 && iy < 256) {
      const f32x4 v = *(const f32x4*)&x[((n*3 + ci)*256 + iy)*256 + seg*4];
      s16x4 sv;
      #pragma unroll
      for (int e = 0; e < 4; ++e) sv[e] = (short)f2b(v[e]);
      *(s16x4*)&RAW[g*264 + 4 + seg*4] = sv;
    }
  }
  __syncthreads();
  for (int s = threadIdx.x; s < 1024; s += 256) {
    const int kb = s & 7, ox = s >> 3;
    short8 v = (short8)(short)0;
    if (kb < 6) {
      const unsigned* u0 = (const unsigned*)&RAW[(2*kb  )*264 + 2*ox + 2];
      const unsigned* u1 = (const unsigned*)&RAW[(2*kb+1)*264 + 2*ox + 2];
      const unsigned a0 = u0[0], a1 = u0[1], a2 = u0[2];
      const unsigned b0 = u1[0], b1 = u1[1], b2 = u1[2];
      uint32x4 uv;
      uv[0] = (a0 >> 16) | (a1 << 16);
      uv[1] = (a1 >> 16) | (a2 << 16);
      uv[2] = (b0 >> 16) | (b1 << 16);
      uv[3] = (b1 >> 16) | (b2 << 16);
      v = __builtin_bit_cast(short8, uv);
    }
    const int bo = ((ox << 7) + (kb << 4)) ^ ((ox & 7) << 4);
    *(short8*)((char*)IC + bo) = v;
  }
  __syncthreads();
  const int w = threadIdx.x >> 6, l = threadIdx.x & 63;
  const int lm = l & 15, lk = l >> 4;
  f32x4 acc[2][4];
  #pragma unroll
  for (int mi = 0; mi < 2; ++mi)
    #pragma unroll
    for (int ni = 0; ni < 4; ++ni) acc[mi][ni] = (f32x4)0.0f;
  #pragma unroll
  for (int ks = 0; ks < 2; ++ks) {
    short8 bv[4];
    #pragma unroll
    for (int ni = 0; ni < 4; ++ni)
      bv[ni] = *(const short8*)(wv + (((ks*4 + ni)*64 + l) << 3));
    #pragma unroll
    for (int mi = 0; mi < 2; ++mi) {
      const int ox = w*32 + mi*16 + lm;
      const int bo = ((ox << 7) + (ks << 6) + (lk << 4)) ^ ((ox & 7) << 4);
      const short8 av = *(const short8*)((const char*)IC + bo);
      #pragma unroll
      for (int ni = 0; ni < 4; ++ni)
        acc[mi][ni] = __builtin_amdgcn_mfma_f32_16x16x32_bf16(
            __builtin_bit_cast(bf16x8, av),
            __builtin_bit_cast(bf16x8, bv[ni]),
            acc[mi][ni], 0, 0, 0);
    }
  }
  __syncthreads();            // frag reads done; reuse IC for output staging
  #pragma unroll
  for (int mi = 0; mi < 2; ++mi)
    #pragma unroll
    for (int ni = 0; ni < 4; ++ni) {
      const int co = ni*16 + lm;
      const float bv = bias[co];
      #pragma unroll
      for (int r = 0; r < 4; ++r) {
        const int ox = w*32 + mi*16 + lk*4 + r;
        const int bo = ((ox << 7) + 2*co) ^ ((ox & 7) << 4);
        *(short*)((char*)IC + bo) = (short)f2b(fmaxf(acc[mi][ni][r] + bv, 0.f));
      }
    }
  __syncthreads();
  const long ob = ((long)(n*128 + q)) * 8192;   // 128 ox * 64 co
  for (int s = threadIdx.x; s < 1024; s += 256) {
    const int kb = s & 7, ox = s >> 3;
    const int bo = ((ox << 7) + (kb << 4)) ^ ((ox & 7) << 4);
    *(short8*)&out[ob + ox*64 + kb*8] = *(const short8*)((const char*)IC + bo);
  }
}

// ---- conv2 via two-phase MFMA + async stage: h1 -> h2 ----------------------
#define C2_LOAD(c) \
  _Pragma("unroll") \
  for (int s = 0; s < 9; ++s) { \
    st[s] = (short8)(short)0; \
    if (goff[s] >= 0) st[s] = *(const short8*)(in + goff[s] + (c)*32); \
  }
#define C2_WRITE \
  _Pragma("unroll") \
  for (int s = 0; s < 9; ++s) \
    if (lb[s] >= 0) *(short8*)((char*)IL + lb[s]) = st[s];
#define C2_COMPUTE(c) \
  _Pragma("unroll") \
  for (int t = 0; t < 16; ++t) { \
    const int ky = t >> 2, kx = t & 3; \
    const int p = 1 - (kx & 1), d = kx >> 1; \
    const short8 bv0 = *(const short8*)(wb + (t*2 + (c))*4096); \
    const short8 bv1 = *(const short8*)(wb + (t*2 + (c))*4096 + 512); \
    const char* Ab = (const char*)IL + (Bd0 + d*64); \
    const int imm0 = ((ky*2 + p)*66) << 6; \
    _Pragma("unroll") \
    for (int mi = 0; mi < 4; ++mi) { \
      const short8 av = *(const short8*)(Ab + imm0 + mi*1024); \
      acc[mi][0] = __builtin_amdgcn_mfma_f32_16x16x32_bf16( \
          __builtin_bit_cast(bf16x8, av), __builtin_bit_cast(bf16x8, bv0), \
          acc[mi][0], 0, 0, 0); \
      acc[mi][1] = __builtin_amdgcn_mfma_f32_16x16x32_bf16( \
          __builtin_bit_cast(bf16x8, av), __builtin_bit_cast(bf16x8, bv1), \
          acc[mi][1], 0, 0, 0); \
    } \
  }
__global__ __launch_bounds__(256) void conv2m_k(const unsigned short* __restrict__ in,
    const unsigned short* __restrict__ wv, const float* __restrict__ bias,
    unsigned short* __restrict__ out) {
  __shared__ short IL[8*66*32];        // [(r*2+p)*66+idx][ci_local 32], 33792 B
  const int wid = (blockIdx.x & 7)*256 + (blockIdx.x >> 3);
  const int q = wid & 63, n = wid >> 6;          // q = output row oy
  const int w = threadIdx.x >> 6, l = threadIdx.x & 63;
  const int lm = l & 15, lk = l >> 4;
  const int Bd0 = lm*64 + lk*16;                 // A-read byte base, d=0
  const unsigned short* wb = wv + w*1024 + l*8;  // + ks*4096 (+512 for ni=1)
  int goff[9], lb[9];
  #pragma unroll
  for (int s = 0; s < 9; ++s) {
    const int i = threadIdx.x + s*256;
    const int part = i & 3, e = i >> 2;
    const int idx = e % 66, rp = e / 66;
    const int r = rp >> 1, p = rp & 1;
    const int iy = 2*q - 1 + r, ix = 2*idx - p;
    const bool ok = (i < 2112) && iy >= 0 && iy < 128 && ix >= 0 && ix < 128;
    goff[s] = ok ? (((n*128 + iy)*128 + ix)*64 + part*8) : -1;
    lb[s]   = (i < 2112) ? (e*64 + part*16) : -1;
  }
  f32x4 acc[4][2];
  #pragma unroll
  for (int mi = 0; mi < 4; ++mi)
    #pragma unroll
    for (int ni = 0; ni < 2; ++ni) acc[mi][ni] = (f32x4)0.0f;
  short8 st[9];
  C2_LOAD(0); C2_WRITE;
  __syncthreads();
  C2_LOAD(1);                          // issue phase-1 loads (in flight)
  C2_COMPUTE(0);
  __syncthreads();                     // phase-0 LDS reads done
  C2_WRITE;                            // waits vmcnt for st, writes LDS
  __syncthreads();
  C2_COMPUTE(1);
  // coalesced epilogue: PB[64 ox][144 shorts] over IL (18432 B)
  __syncthreads();                     // compute(1) IL reads done
  short* PB = (short*)IL;
  #pragma unroll
  for (int mi = 0; mi < 4; ++mi)
    #pragma unroll
    for (int r = 0; r < 4; ++r) {
      const int ox = mi*16 + lk*4 + r;
      #pragma unroll
      for (int ni = 0; ni < 2; ++ni) {
        const int co = (w*2 + ni)*16 + lm;
        PB[ox*144 + co] = (short)f2b(fmaxf(acc[mi][ni][r] + bias[co], 0.f));
      }
    }
  __syncthreads();
  {
    const int pos = threadIdx.x >> 2, coq = (threadIdx.x & 3) << 5;
    const long ob = ((long)((n*64 + q)*64 + pos))*128 + coq;
    #pragma unroll
    for (int u2 = 0; u2 < 4; ++u2)
      *(short8*)&out[ob + u2*8] = *(const short8*)&PB[pos*144 + coq + u2*8];
  }
}

// ---- conv3 + fused VQ: h2 NHWC bf16 [32,64,64,128] -> zq f32 + loss --------
#define C3_LOAD(c) \
  _Pragma("unroll") \
  for (int s = 0; s < 9; ++s) { \
    st[s] = (short8)(short)0; \
    if (goff[s] >= 0) st[s] = *(const short8*)(in + goff[s] + (c)*64); \
  }
#define C3_WRITE \
  _Pragma("unroll") \
  for (int s = 0; s < 9; ++s) \
    if (lb[s] >= 0) *(short8*)((char*)IL + lb[s]) = st[s];
#define C3_COMPUTE(c) \
  _Pragma("unroll") \
  for (int u = 0; u < 18; ++u) { \
    const int tap = u >> 1, cc = u & 1; \
    const int ky = tap / 3, kx = tap % 3; \
    const int ks = tap*4 + (c)*2 + cc; \
    const short8 bv0 = *(const short8*)(wb + ks*1024); \
    const short8 bv1 = *(const short8*)(wb + ks*1024 + 512); \
    const char* Ab = (const char*)IL + (Wc[kx][cc]); \
    const int imm0 = ky*8448; \
    _Pragma("unroll") \
    for (int mi = 0; mi < 2; ++mi) { \
      const short8 av = *(const short8*)(Ab + imm0 + mi*2048); \
      acc[mi][0] = __builtin_amdgcn_mfma_f32_16x16x32_bf16( \
          __builtin_bit_cast(bf16x8, av), __builtin_bit_cast(bf16x8, bv0), \
          acc[mi][0], 0, 0, 0); \
      acc[mi][1] = __builtin_amdgcn_mfma_f32_16x16x32_bf16( \
          __builtin_bit_cast(bf16x8, av), __builtin_bit_cast(bf16x8, bv1), \
          acc[mi][1], 0, 0, 0); \
    } \
  }
__global__ __launch_bounds__(256) void conv3v_k(const unsigned short* __restrict__ in,
    const unsigned short* __restrict__ wv, const float* __restrict__ bias,
    const unsigned short* __restrict__ wqe, const float* __restrict__ eng,
    const float* __restrict__ emb, float* __restrict__ zq,
    float* __restrict__ part) {
  __shared__ short IL[4*66*64];        // 33792 B; unions below after compute
  const int wid = (blockIdx.x & 7)*128 + (blockIdx.x >> 3);
  const int q = wid & 31, n = wid >> 5;          // oy0 = 2q
  const int w = threadIdx.x >> 6, l = threadIdx.x & 63;
  const int lm = l & 15, lk = l >> 4;
  const int row = w >> 1, oxb = (w & 1) * 32;
  int goff[9], lb[9];
  #pragma unroll
  for (int s = 0; s < 9; ++s) {
    const int i = threadIdx.x + s*256;
    const int part_ = i & 7, e = i >> 3;
    const int col = e % 66, r = e / 66;
    const int iy = 2*q - 1 + r, ix = col - 1;
    const bool ok = (i < 2112) && iy >= 0 && iy < 64 && ix >= 0 && ix < 64;
    goff[s] = ok ? (((n*64 + iy)*64 + ix)*128 + part_*8) : -1;
    lb[s]   = (i < 2112) ? ((e << 7) + ((part_ << 4) ^ ((col & 7) << 4))) : -1;
  }
  int Wc[3][2];
  #pragma unroll
  for (int kx = 0; kx < 3; ++kx) {
    const int e = oxb + lm + kx;
    Wc[kx][0] = row*8448 + (e << 7) + ((lk << 4) ^ ((e & 7) << 4));
    Wc[kx][1] = Wc[kx][0] ^ 0x40;
  }
  const unsigned short* wb = wv + l*8;           // + ks*1024 + ni*512
  f32x4 acc[2][2];
  #pragma unroll
  for (int mi = 0; mi < 2; ++mi)
    #pragma unroll
    for (int ni = 0; ni < 2; ++ni) acc[mi][ni] = (f32x4)0.0f;
  short8 st[9];
  C3_LOAD(0); C3_WRITE;
  __syncthreads();
  C3_LOAD(1);
  C3_COMPUTE(0);
  __syncthreads();
  C3_WRITE;
  __syncthreads();
  C3_COMPUTE(1);
  // ---- fused VQ ----
  __syncthreads();                               // all IL reads done
  short* ZB  = (short*)IL;                       // [128][40] bf16, 10240 B
  float* ZF  = (float*)((char*)IL + 10240);      // [128][36] f32, 18432 B
  int*  bidx = (int*)((char*)IL + 28672);        // 128 ints
  float* red = (float*)((char*)IL + 29184);      // 256 floats
  #pragma unroll
  for (int mi = 0; mi < 2; ++mi)
    #pragma unroll
    for (int ni = 0; ni < 2; ++ni) {
      const int co = ni*16 + lm;
      const float bv = bias[co];
      #pragma unroll
      for (int r = 0; r < 4; ++r) {
        const int pos = row*64 + oxb + mi*16 + lk*4 + r;
        const float v = fmaxf(acc[mi][ni][r] + bv, 0.f);
        ZB[pos*40 + co] = (short)f2b(v);
        ZF[pos*36 + co] = v;
      }
    }
  __syncthreads();
  short8 av[2];
  #pragma unroll
  for (int mi = 0; mi < 2; ++mi)
    av[mi] = *(const short8*)&ZB[(row*64 + oxb + mi*16 + lm)*40 + lk*8];
  float bd[2][4]; int bj[2][4];
  #pragma unroll
  for (int mi = 0; mi < 2; ++mi)
    #pragma unroll
    for (int r = 0; r < 4; ++r) { bd[mi][r] = 1e30f; bj[mi][r] = 0; }
  for (int nc = 0; nc < 8; ++nc) {               // chunks of 64 codes
    f32x4 a2[2][4];
    #pragma unroll
    for (int mi = 0; mi < 2; ++mi)
      #pragma unroll
      for (int ni = 0; ni < 4; ++ni) a2[mi][ni] = (f32x4)0.0f;
    #pragma unroll
    for (int ni = 0; ni < 4; ++ni) {
      const short8 bv = *(const short8*)(wqe + (((nc*4 + ni)*64 + l) << 3));
      #pragma unroll
      for (int mi = 0; mi < 2; ++mi)
        a2[mi][ni] = __builtin_amdgcn_mfma_f32_16x16x32_bf16(
            __builtin_bit_cast(bf16x8, av[mi]),
            __builtin_bit_cast(bf16x8, bv),
            a2[mi][ni], 0, 0, 0);
    }
    #pragma unroll
    for (int ni = 0; ni < 4; ++ni) {
      const int j = nc*64 + ni*16 + lm;
      const float e_n = eng[j];
      #pragma unroll
      for (int mi = 0; mi < 2; ++mi)
        #pragma unroll
        for (int r = 0; r < 4; ++r) {
          const float d = fmaf(-2.f, a2[mi][ni][r], e_n);
          if (d < bd[mi][r]) { bd[mi][r] = d; bj[mi][r] = j; }
        }
    }
  }
  #pragma unroll
  for (int mi = 0; mi < 2; ++mi)
    #pragma unroll
    for (int r = 0; r < 4; ++r) {
      float d = bd[mi][r]; int j = bj[mi][r];
      #pragma unroll
      for (int off = 1; off < 16; off <<= 1) {
        const float od = __shfl_xor(d, off);
        const int   oj = __shfl_xor(j, off);
        if (od < d || (od == d && oj < j)) { d = od; j = oj; }
      }
      if (lm == 0) bidx[row*64 + oxb + mi*16 + lk*4 + r] = j;
    }
  __syncthreads();
  const int pl = threadIdx.x >> 1, hf = (threadIdx.x & 1) * 16;
  const int code = bidx[pl];
  const int oy2 = 2*q + (pl >> 6), ox2 = pl & 63;
  const long zqo = ((long)((n*64 + oy2)*64 + ox2)) * 32 + hf;
  float se = 0.f;
  #pragma unroll
  for (int qq = 0; qq < 4; ++qq) {
    const f32x4 ev = *(const f32x4*)&emb[code*32 + hf + qq*4];
    const f32x4 zv = *(const f32x4*)&ZF[pl*36 + hf + qq*4];
    *(f32x4*)&zq[zqo + qq*4] = ev;
    const f32x4 df = ev - zv;
    #pragma unroll
    for (int e = 0; e < 4; ++e) se = fmaf(df[e], df[e], se);
  }
  red[threadIdx.x] = se; __syncthreads();
  for (int s2 = 128; s2 > 0; s2 >>= 1) {
    if (threadIdx.x < s2) red[threadIdx.x] += red[threadIdx.x + s2];
    __syncthreads();
  }
  if (threadIdx.x == 0) part[blockIdx.x] = red[0];
}

// ---- d1 convT via MFMA: zq f32 [131072,32] -> d1 NHWC bf16 [32,64,64,128]
__global__ __launch_bounds__(256) void d1m_k(const float* __restrict__ in,
    const unsigned short* __restrict__ wv, const float* __restrict__ bias,
    unsigned short* __restrict__ out) {
  __shared__ short IL[264*40];         // [r*66+col][40-short stride], 21120 B
  const int wid = (blockIdx.x & 7)*128 + (blockIdx.x >> 3);
  const int q = wid & 31, n = wid >> 5;
  const int w = threadIdx.x >> 6, l = threadIdx.x & 63;
  const int lm = l & 15, lk = l >> 4;
  const int row = w >> 1, oxb = (w & 1) * 32;
  for (int i = threadIdx.x; i < 1056; i += 256) {  // 264 entries * 4 parts
    const int part = i & 3, e = i >> 2;
    const int col = e % 66, r = e / 66;
    const int iy = 2*q - 1 + r, ix = col - 1;
    short8 v = (short8)(short)0;
    if (iy >= 0 && iy < 64 && ix >= 0 && ix < 64) {
      const float* p = in + (((long)((n*64 + iy)*64 + ix)) * 32 + part*8);
      const f32x4 f0 = *(const f32x4*)p;
      const f32x4 f1 = *(const f32x4*)(p + 4);
      #pragma unroll
      for (int e2 = 0; e2 < 4; ++e2) {
        v[e2]     = (short)f2b(f0[e2]);
        v[e2 + 4] = (short)f2b(f1[e2]);
      }
    }
    *(short8*)&IL[e*40 + part*8] = v;
  }
  const unsigned short* wb = wv + l*8;             // + (tap*8+ni)*512
  int Wd[3];
  #pragma unroll
  for (int kx = 0; kx < 3; ++kx)
    Wd[kx] = row*5280 + (oxb + lm + kx)*80 + lk*16;   // bytes
  __syncthreads();
  f32x4 acc[2][8];
  #pragma unroll
  for (int mi = 0; mi < 2; ++mi)
    #pragma unroll
    for (int ni = 0; ni < 8; ++ni) acc[mi][ni] = (f32x4)0.0f;
  #pragma unroll
  for (int tap = 0; tap < 9; ++tap) {
    const int ky = tap / 3, kx = tap % 3;
    short8 bv[8];
    #pragma unroll
    for (int ni = 0; ni < 8; ++ni)
      bv[ni] = *(const short8*)(wb + (tap*8 + ni)*512);
    const char* Ab = (const char*)IL + Wd[kx];
    const int imm0 = ky*5280;
    #pragma unroll
    for (int mi = 0; mi < 2; ++mi) {
      const short8 av = *(const short8*)(Ab + imm0 + mi*1280);
      #pragma unroll
      for (int ni = 0; ni < 8; ++ni)
        acc[mi][ni] = __builtin_amdgcn_mfma_f32_16x16x32_bf16(
            __builtin_bit_cast(bf16x8, av),
            __builtin_bit_cast(bf16x8, bv[ni]),
            acc[mi][ni], 0, 0, 0);
    }
  }
  // coalesced epilogue: 2 row passes, PB[64 ox][144 shorts] over IL (18432 B)
  short* PB = (short*)IL;
  #pragma unroll
  for (int rp = 0; rp < 2; ++rp) {
    __syncthreads();                   // IL reads / prior pass reads done
    if (row == rp) {
      #pragma unroll
      for (int mi = 0; mi < 2; ++mi)
        #pragma unroll
        for (int r = 0; r < 4; ++r) {
          const int ox = oxb + mi*16 + lk*4 + r;
          #pragma unroll
          for (int ni = 0; ni < 8; ++ni) {
            const int co = ni*16 + lm;
            PB[ox*144 + co] = (short)f2b(fmaxf(acc[mi][ni][r] + bias[co], 0.f));
          }
        }
    }
    __syncthreads();
    const int pos = threadIdx.x >> 2, coq = (threadIdx.x & 3) << 5;
    const long ob = ((long)((n*64 + 2*q + rp)*64 + pos))*128 + coq;
    #pragma unroll
    for (int u2 = 0; u2 < 4; ++u2)
      *(short8*)&out[ob + u2*8] = *(const short8*)&PB[pos*144 + coq + u2*8];
  }
}

// ---- d2 convT: q-pair / 8-wave merged-parity MFMA + async stage ------------
//      Register diet: staging addresses recomputed inline (no goff/lb arrays);
//      __launch_bounds__(512,4) caps regs at 128/wave -> 4 waves/SIMD.
__device__ __forceinline__ int ct2_goff(int i, int q0, int n) {
  const int part = i & 7, e = i >> 3;
  const int col = e % 66, r = e / 66;
  const int iy = q0 - 1 + r, ix = col - 1;
  return (i < 2112 && iy >= 0 && iy < 64 && ix >= 0 && ix < 64)
         ? (((n*64 + iy)*64 + ix)*128 + part*8) : -1;
}
__device__ __forceinline__ int ct2_lb(int i) {
  const int part = i & 7, e = i >> 3;
  const int col = e % 66;
  return (i < 2112) ? ((e << 7) + ((part << 4) ^ ((col & 7) << 4))) : -1;
}
#define CT2_LOAD(c) \
  _Pragma("unroll") \
  for (int s = 0; s < 5; ++s) { \
    const int g = ct2_goff(tid + s*512, q0, n); \
    st[s] = (short8)(short)0; \
    if (g >= 0) st[s] = *(const short8*)(in + g + (c)*64); \
  }
#define CT2_WRITE \
  _Pragma("unroll") \
  for (int s = 0; s < 5; ++s) { \
    const int b_ = ct2_lb(tid + s*512); \
    if (b_ >= 0) *(short8*)((char*)IL + b_) = st[s]; \
  }
#define CT2_COMPUTE(c) \
  _Pragma("unroll") \
  for (int u = 0; u < 8; ++u) { \
    const int a = u >> 2, b = (u >> 1) & 1, c1 = u & 1; \
    const int ks = (a << 3) | (b << 2) | (2*(c) + c1); \
    short8 bv[4]; \
    _Pragma("unroll") \
    for (int ni = 0; ni < 4; ++ni) \
      bv[ni] = *(const short8*)(wb + ks*2048 + ni*512); \
    const char* Ab = (const char*)IL + (pyb + Wb[b][c1]); \
    const int imm0 = a*8448; \
    _Pragma("unroll") \
    for (int mi = 0; mi < 4; ++mi) { \
      const short8 av = *(const short8*)(Ab + imm0 + mi*2048); \
      _Pragma("unroll") \
      for (int ni = 0; ni < 4; ++ni) \
        acc[mi][ni] = __builtin_amdgcn_mfma_f32_16x16x32_bf16( \
            __builtin_bit_cast(bf16x8, av), \
            __builtin_bit_cast(bf16x8, bv[ni]), \
            acc[mi][ni], 0, 0, 0); \
    } \
  }
__global__ __launch_bounds__(512, 4) void convt2m_k(
    const unsigned short* __restrict__ in,
    const unsigned short* __restrict__ wv, const float* __restrict__ bias,
    unsigned short* __restrict__ out) {
  __shared__ short IL[4*66*64];        // 264 entries x 128 B, 33792 B
  const int wid = (blockIdx.x & 7)*128 + (blockIdx.x >> 3);
  const int qp = wid & 31, n = wid >> 5;
  const int q0 = 2*qp;
  const int tid = threadIdx.x;
  const int w = tid >> 6, l = tid & 63;
  const int qi = w >> 2;
  const int py = (w >> 1) & 1, px = w & 1;
  const int lm = l & 15, lk = l >> 4;
  int Wb[2][2];
  #pragma unroll
  for (int b = 0; b < 2; ++b) {
    const int e = lm + px + b;
    Wb[b][0] = (e << 7) + ((lk << 4) ^ ((e & 7) << 4));
    Wb[b][1] = Wb[b][0] ^ 0x40;
  }
  const int pyb = (py + qi) * 8448;                // staged-row base
  const unsigned short* wb = wv + (w & 3)*32768 + l*8;   // parity weights
  f32x4 acc[4][4];
  #pragma unroll
  for (int mi = 0; mi < 4; ++mi)
    #pragma unroll
    for (int ni = 0; ni < 4; ++ni) acc[mi][ni] = (f32x4)0.0f;
  short8 st[5];
  CT2_LOAD(0); CT2_WRITE;
  __syncthreads();
  CT2_LOAD(1);                         // issue phase-1 loads (in flight)
  CT2_COMPUTE(0);
  __syncthreads();                     // phase-0 LDS reads done
  CT2_WRITE;                           // waits vmcnt, writes LDS
  __syncthreads();
  CT2_COMPUTE(1);
  // coalesced epilogue: 4 passes (qq x co-half), PB[256 pos][40 shorts]
  short* PB = (short*)IL;
  #pragma unroll
  for (int qq = 0; qq < 2; ++qq)
    #pragma unroll
    for (int half = 0; half < 2; ++half) {
      __syncthreads();                 // IL / prior-pass reads done
      if (qi == qq) {
        #pragma unroll
        for (int mi = 0; mi < 4; ++mi)
          #pragma unroll
          for (int r = 0; r < 4; ++r) {
            const int ox = 2*(mi*16 + lk*4 + r) + px;
            const int pos = py*128 + ox;
            #pragma unroll
            for (int nn = 0; nn < 2; ++nn) {
              const int co = (half*2 + nn)*16 + lm;
              PB[pos*40 + (co & 31)] =
                  (short)f2b(fmaxf(acc[mi][half*2 + nn][r] + bias[co], 0.f));
            }
          }
      }
      __syncthreads();
      const int pos = tid >> 1, hh = (tid & 1) << 4;
      const long ob = ((long)((n*128 + 2*(q0 + qq) + (pos >> 7))*128
                              + (pos & 127)))*64 + half*32 + hh;
      *(short8*)&out[ob]     = *(const short8*)&PB[pos*40 + hh];
      *(short8*)&out[ob + 8] = *(const short8*)&PB[pos*40 + hh + 8];
    }
}

__global__ __launch_bounds__(256) void loss_k(const float* __restrict__ part,
                                              float* __restrict__ out) {
  __shared__ float red[256];
  const int t = threadIdx.x;
  float s = 0.f;
  #pragma unroll
  for (int q = 0; q < 4; ++q) s += part[t + q*256];   // 1024 partials
  red[t] = s; __syncthreads();
  for (int st = 128; st > 0; st >>= 1) {
    if (t < st) red[t] += red[t + st];
    __syncthreads();
  }
  if (t == 0) out[0] = red[0] * (1.25f / (131072.f * 32.f));
}

// ---- convt3 via MFMA: d2 NHWC bf16 [32,128,128,64] -> x_recon NCHW fp32 ----
__global__ __launch_bounds__(256) void convt3m_k(const unsigned short* __restrict__ in,
    const unsigned short* __restrict__ wq6, const float* __restrict__ bias,
    float* __restrict__ out) {
  __shared__ short8 IL[3*8*66];      // [(r*8+c8)*66 + ixl], 25344 B
  const int h = blockIdx.x & 1, q = (blockIdx.x >> 1) & 127, n = blockIdx.x >> 8;
  for (int i = threadIdx.x; i < 1584; i += 256) {   // 3*66*8
    const int c8 = i & 7, t = i >> 3, ixl = t % 66, r = t / 66;
    const int iy = q - 1 + r, ix = h*64 - 1 + ixl;
    short8 v = (short8)(short)0;
    if (iy >= 0 && iy < 128 && ix >= 0 && ix < 128)
      v = *(const short8*)(in + (((long)(n*128 + iy)*128 + ix)*64 + c8*8));
    IL[(r*8 + c8)*66 + ixl] = v;
  }
  const int w = threadIdx.x >> 6, l = threadIdx.x & 63;
  const int py = w >> 1, px = w & 1;
  const int lm = l & 15, lk = l >> 4;
  short8 bfrag[8];
  #pragma unroll
  for (int kc = 0; kc < 8; ++kc)
    bfrag[kc] = *(const short8*)(wq6 + (((w*8 + kc)*64 + l) << 3));
  __syncthreads();
  f32x4 acc[4];
  #pragma unroll
  for (int mi = 0; mi < 4; ++mi) acc[mi] = (f32x4)0.0f;
  #pragma unroll
  for (int kc = 0; kc < 8; ++kc) {
    const int a = kc >> 2, b = (kc >> 1) & 1, ch = kc & 1;
    const int base = (((py + a)*8 + ch*4 + lk)*66) + px + b;   // + ixl(xq)
    #pragma unroll
    for (int mi = 0; mi < 4; ++mi) {
      const short8 av = *(const short8*)&IL[base + mi*16 + lm];
      acc[mi] = __builtin_amdgcn_mfma_f32_16x16x32_bf16(
          __builtin_bit_cast(bf16x8, av),
          __builtin_bit_cast(bf16x8, bfrag[kc]),
          acc[mi], 0, 0, 0);
    }
  }
  // coalesced epilogue via LDS (768 floats over IL)
  __syncthreads();                     // IL reads done
  float* PB3 = (float*)IL;
  if (lm < 3) {
    const float bv = bias[lm];
    #pragma unroll
    for (int mi = 0; mi < 4; ++mi)
      #pragma unroll
      for (int r = 0; r < 4; ++r) {
        const int xq = mi*16 + lk*4 + r;
        PB3[(lm*2 + py)*128 + 2*xq + px] = acc[mi][r] + bv;
      }
  }
  __syncthreads();
  for (int t = threadIdx.x; t < 768; t += 256) {
    const int co = t >> 8, rem = t & 255, pyl = rem >> 7, xx = rem & 127;
    out[((long)(n*3 + co))*65536 + (2*q + pyl)*256 + h*128 + xx] = PB3[t];
  }
}

extern "C" void kernel_launch(void* const* d_in, const int* in_sizes, int n_in,
                              void* d_out, int out_size, void* d_ws, size_t ws_size,
                              hipStream_t stream) {
  const float* x   = (const float*)d_in[0];
  const float* ew1 = (const float*)d_in[1];  const float* eb1 = (const float*)d_in[2];
  const float* ew2 = (const float*)d_in[3];  const float* eb2 = (const float*)d_in[4];
  const float* ew3 = (const float*)d_in[5];  const float* eb3 = (const float*)d_in[6];
  const float* emb = (const float*)d_in[7];
  const float* dw1 = (const float*)d_in[8];  const float* db1 = (const float*)d_in[9];
  const float* dw2 = (const float*)d_in[10]; const float* db2 = (const float*)d_in[11];
  const float* dw3 = (const float*)d_in[12]; const float* db3 = (const float*)d_in[13];
  float* out = (float*)d_out;

  uint8_t* w8 = (uint8_t*)d_ws;
  unsigned short* h1 = (unsigned short*)w8;
  unsigned short* h2 = (unsigned short*)(w8 + 67108864);
  uint8_t* zr = w8 + 100663296;
  float* zq  = (float*)(w8 + 117440512);
  unsigned short* wqe = (unsigned short*)zr;                  // 32768 B
  float* eng = (float*)(zr + 32768);                          // 2048 B
  float* part = (float*)(zr + 36864);                         // 4096 B
  unsigned short* wq3 = (unsigned short*)(zr + 40960);        // 73728 B
  unsigned short* wq4 = (unsigned short*)(zr + 131072);       // 73728 B
  unsigned short* wq5 = (unsigned short*)(zr + 262144);       // 262144 B
  unsigned short* wq6 = (unsigned short*)(zr + 524288);       // 32768 B
  unsigned short* wq2 = (unsigned short*)(w8 + 117440512);            // 262144 B
  unsigned short* wq1 = (unsigned short*)(w8 + 117440512 + 335872);   // 8192 B
  unsigned short* d1 = h2;
  unsigned short* d2 = h1;

  // all weight/embed prep in one launch
  prepall_k<<<dim3(1456),256,0,stream>>>(ew1, ew2, ew3, dw1, dw2, dw3, emb,
                                         wq1, wq2, wq3, wq4, wq5, wq6, wqe, eng);
  // encoder + fused VQ
  conv1m_k<<<dim3(4096),256,0,stream>>>(x, wq1, eb1, h1);
  conv2m_k<<<dim3(2048),256,0,stream>>>(h1, wq2, eb2, h2);
  conv3v_k<<<dim3(1024),256,0,stream>>>(h2, wq3, eb3, wqe, eng, emb, zq, part);
  loss_k<<<dim3(1),256,0,stream>>>(part, out + 6291456);
  // decoder
  d1m_k<<<dim3(1024),256,0,stream>>>(zq, wq4, db1, d1);
  convt2m_k<<<dim3(1024),512,0,stream>>>(d1, wq5, db2, d2);
  convt3m_k<<<dim3(8192),256,0,stream>>>(d2, wq6, db3, out);
}